// Round 2
// baseline (814.786 us; speedup 1.0000x reference)
//
#include <hip/hip_runtime.h>
#include <hip/hip_bf16.h>

using bf16 = __hip_bfloat16;
typedef short short8 __attribute__((ext_vector_type(8)));
typedef float float4v __attribute__((ext_vector_type(4)));

__device__ __forceinline__ float b2f(unsigned short u){
  unsigned int x = ((unsigned int)u) << 16; float f;
  __builtin_memcpy(&f, &x, 4); return f;
}
__device__ __forceinline__ float b2f(bf16 v){ return __bfloat162float(v); }
__device__ __forceinline__ unsigned short f2bu(float x){
  bf16 h = __float2bfloat16(x); unsigned short u;
  __builtin_memcpy(&u, &h, 2); return u;
}

// -------- batched permuted transpose fp32->bf16: per z, in[R][Cc] -> out[(q%D)*G+q/D][R] -
template<class TO>
__launch_bounds__(256)
__global__ void permT_k(const float* __restrict__ inp, TO* __restrict__ outp,
                        int Cc, int R, int D, int G, long inS, long outS){
  __shared__ float t[64][65];
  int z = blockIdx.z;
  const float* in = inp + (size_t)z*inS;
  TO* out = outp + (size_t)z*outS;
  int c0 = blockIdx.x*64, r0 = blockIdx.y*64;
  int tid = threadIdx.x;
  int rr = tid>>2, c4 = (tid&3)*16;
  const float* p = in + (size_t)(r0+rr)*Cc + c0 + c4;
  #pragma unroll
  for (int j=0;j<16;j+=4){
    float4 q = *reinterpret_cast<const float4*>(p+j);
    t[rr][c4+j]=q.x; t[rr][c4+j+1]=q.y; t[rr][c4+j+2]=q.z; t[rr][c4+j+3]=q.w;
  }
  __syncthreads();
  int ql = tid>>2;
  int q = c0 + ql;
  int orow = (q % D)*G + q / D;
  TO* op = out + (size_t)orow*R + r0 + c4;
  #pragma unroll
  for (int j=0;j<16;j++){
    if constexpr (sizeof(TO)==2) op[j] = __float2bfloat16(t[c4+j][ql]);
    else op[j] = t[c4+j][ql];
  }
}

// -------- 3-block split transpose: rows of length 3R.
// PAT=0 (A-side): blocks (hi, lo, hi).  PAT=1 (B-side): blocks (hi, hi, lo).
// Paired dot over 3R gives ah*bh + al*bh + ah*bl  == fp32-accurate product.
template<int PAT>
__launch_bounds__(256)
__global__ void permTsplit3_k(const float* __restrict__ inp, unsigned short* __restrict__ outp,
                              int Cc, int R, int D, int G, long inS, long outS){
  __shared__ float t[64][65];
  int z = blockIdx.z;
  const float* in = inp + (size_t)z*inS;
  unsigned short* out = outp + (size_t)z*outS;
  int c0 = blockIdx.x*64, r0 = blockIdx.y*64;
  int tid = threadIdx.x;
  int rr = tid>>2, c4 = (tid&3)*16;
  const float* p = in + (size_t)(r0+rr)*Cc + c0 + c4;
  #pragma unroll
  for (int j=0;j<16;j+=4){
    float4 q = *reinterpret_cast<const float4*>(p+j);
    t[rr][c4+j]=q.x; t[rr][c4+j+1]=q.y; t[rr][c4+j+2]=q.z; t[rr][c4+j+3]=q.w;
  }
  __syncthreads();
  int ql = tid>>2;
  int q = c0 + ql;
  int orow = (q % D)*G + q / D;
  unsigned short* op = out + (size_t)orow*(3*R);
  #pragma unroll
  for (int j=0;j<16;j++){
    float v = t[c4+j][ql];
    unsigned short h = f2bu(v);
    unsigned short l = f2bu(v - b2f(h));
    int idx = r0 + c4 + j;
    if constexpr (PAT==0){
      op[idx] = h; op[R+idx] = l; op[2*R+idx] = h;
    } else {
      op[idx] = h; op[R+idx] = h; op[2*R+idx] = l;
    }
  }
}

// -------- row split (no transpose): in[1024][512] fp32 -> out[1024][1536] bf16 (h,l,h) --
__launch_bounds__(256)
__global__ void splitA_k(const float* __restrict__ in, unsigned short* __restrict__ out){
  int idx = blockIdx.x*256 + threadIdx.x;   // 1024*512
  int m = idx >> 9, j = idx & 511;
  float v = in[idx];
  unsigned short h = f2bu(v);
  unsigned short l = f2bu(v - b2f(h));
  unsigned short* op = out + (size_t)m*1536 + j;
  op[0] = h; op[512] = l; op[1024] = h;
}

// ================= unified LDS-staged MFMA GEMM with register prefetch ===================
// C[m][f] = sum_k A[m][k]*B[f][k], bf16, BK=32, f-tile 128 (4 waves x 2 n-frags).
// LDS layout: 16B chunk c of row r stored at slot r*4 + (c ^ ((r>>1)&3))  -> staging stays
// 64B-coalesced per row; fragment ds_read_b128 hits <=2-way banks (free).
// MODE 0: nonlocal (relu(acc+bias)+residual -> fp32), 1: conv3d im2col K-split z,
// MODE 2: up1 (relu+bias, convT scatter 8x8->16x16, 3-block h/l/h out), 3: up2 (bias, scatter, fp32)
// MODE 4: weff = split-A . split-B -> bf16 [m][1024] (no bias)
// MODE 1/2: XCD-aware bijective swizzle (m204) with z-major / x / y-minor work order.
//   (MODE 0/3/4: natural mapping keeps XCD = bx mod 8 invariant across y (gx % 8 == 0)
//    or kernel is tiny, so A chunk stays L2-resident; left unswizzled.)
// MTM=2 for grid-limited kernels (conv / nonlocal): doubles resident waves/CU.
template<int MTM, int MODE>
__launch_bounds__(256)
__global__ void mmL_k(const unsigned short* __restrict__ A,
                      const unsigned short* __restrict__ B,
                      const float* __restrict__ bias,
                      const unsigned short* __restrict__ res,
                      float* __restrict__ outf,
                      unsigned short* __restrict__ outs,
                      int K){
  constexpr int AR = MTM*16;
  constexpr int ASLOT = AR*4;          // 16B slots in A tile
  __shared__ __align__(16) short As[AR*32];
  __shared__ __align__(16) short Bs[128*32];
  const int tid = threadIdx.x;
  const int wv = tid>>6, lane = tid&63, l15 = lane&15, quad = lane>>4;

  int bx = blockIdx.x, by = blockIdx.y, bz = blockIdx.z;
  if constexpr (MODE==1 || MODE==2){
    const int gx = gridDim.x, gy = gridDim.y, gz = gridDim.z;
    const int n = gx*gy*gz;
    const int lin = bx + gx*(by + gy*bz);
    const int q = n >> 3, r = n & 7;
    const int xcd = lin & 7, j = lin >> 3;
    const int work = (xcd < r ? xcd*(q+1) : r*(q+1) + (xcd-r)*q) + j;
    by = work % gy;                 // y minor
    const int t = work / gy;
    bx = t % gx;                    // x middle
    bz = t / gx;                    // z major (chunk == one kt/kh slice)
  }
  const int m0 = bx*AR;
  const int fblk = by*128;
  const int z = bz;

  // ---- staging addresses ----
  size_t aAddr = 0;
  {
    int arow = tid>>2, acs = tid&3;
    int ac = acs ^ ((arow>>1)&3);
    if (tid < ASLOT){
      int m = m0 + arow;
      if constexpr (MODE==1){
        int mm = m < 1568 ? m : 1567;
        int b = mm/392, r = mm%392;
        int t = r/196, r2 = r%196;
        int hh = r2/14, ww = r2%14;
        int kt = z/3, kh = z%3;
        int sp = ((b*4 + t + kt)*16 + hh + kh)*16 + ww;
        aAddr = (size_t)sp*1024 + ac*8;
      } else {
        aAddr = (size_t)m*K + ac*8;
      }
    }
  }
  size_t bAddr[2];
  #pragma unroll
  for (int it=0; it<2; ++it){
    int s = tid + it*256;
    int row = s>>2, cs = s&3;
    int c = cs ^ ((row>>1)&3);
    int f = fblk + row;
    if constexpr (MODE==0)      bAddr[it] = (size_t)f*1024 + c*8;
    else if constexpr (MODE==1) bAddr[it] = (size_t)f*27648 + (size_t)z*3072 + c*8;
    else                        bAddr[it] = ((size_t)z*512 + f)*(size_t)K + c*8;
  }
  // ---- fragment LDS slots (swizzled) ----
  int aslot[MTM];
  #pragma unroll
  for (int mt=0;mt<MTM;++mt){
    int row = mt*16 + l15;
    aslot[mt] = row*4 + (quad ^ ((row>>1)&3));
  }
  int bslot[2];
  #pragma unroll
  for (int nt=0;nt<2;++nt){
    int row = wv*32 + nt*16 + l15;
    bslot[nt] = row*4 + (quad ^ ((row>>1)&3));
  }

  float4v acc[MTM][2];
  #pragma unroll
  for (int i=0;i<MTM;i++){ acc[i][0]=(float4v){0,0,0,0}; acc[i][1]=(float4v){0,0,0,0}; }

  uint4 pa = {}, pb0, pb1;
  if (tid < ASLOT) pa = *reinterpret_cast<const uint4*>(A + aAddr);
  pb0 = *reinterpret_cast<const uint4*>(B + bAddr[0]);
  pb1 = *reinterpret_cast<const uint4*>(B + bAddr[1]);

  for (int k0=0; k0<K; k0+=32){
    __syncthreads();
    if (tid < ASLOT) *reinterpret_cast<uint4*>(As + tid*8) = pa;
    *reinterpret_cast<uint4*>(Bs + tid*8) = pb0;
    *reinterpret_cast<uint4*>(Bs + (tid+256)*8) = pb1;
    __syncthreads();
    if (k0+32 < K){
      if (tid < ASLOT) pa = *reinterpret_cast<const uint4*>(A + aAddr + k0 + 32);
      pb0 = *reinterpret_cast<const uint4*>(B + bAddr[0] + k0 + 32);
      pb1 = *reinterpret_cast<const uint4*>(B + bAddr[1] + k0 + 32);
    }
    short8 bf0 = *reinterpret_cast<const short8*>(Bs + bslot[0]*8);
    short8 bf1 = *reinterpret_cast<const short8*>(Bs + bslot[1]*8);
    #pragma unroll
    for (int mt=0;mt<MTM;++mt){
      short8 af = *reinterpret_cast<const short8*>(As + aslot[mt]*8);
      acc[mt][0] = __builtin_amdgcn_mfma_f32_16x16x32_bf16(af, bf0, acc[mt][0],0,0,0);
      acc[mt][1] = __builtin_amdgcn_mfma_f32_16x16x32_bf16(af, bf1, acc[mt][1],0,0,0);
    }
  }

  if constexpr (MODE==0){
    #pragma unroll
    for (int mt=0;mt<MTM;++mt)
      #pragma unroll
      for (int nt=0;nt<2;++nt){
        int f = fblk + wv*32 + nt*16 + l15;
        float bi = bias[f];
        #pragma unroll
        for (int r=0;r<4;++r){
          int m = m0 + mt*16 + quad*4 + r;
          outf[(size_t)m*1024 + f] =
            fmaxf(acc[mt][nt][r]+bi, 0.f) + b2f(res[(size_t)m*1024 + f]);
        }
      }
  } else if constexpr (MODE==1){
    #pragma unroll
    for (int mt=0;mt<MTM;++mt)
      #pragma unroll
      for (int nt=0;nt<2;++nt){
        int f = fblk + wv*32 + nt*16 + l15;
        #pragma unroll
        for (int r=0;r<4;++r){
          int m = m0 + mt*16 + quad*4 + r;
          if (m < 1568) outf[((size_t)z*1568 + m)*512 + f] = acc[mt][nt][r];
        }
      }
  } else if constexpr (MODE==2){
    int kk = z>>1, ll = z&1;
    #pragma unroll
    for (int mt=0;mt<MTM;++mt)
      #pragma unroll
      for (int nt=0;nt<2;++nt){
        int f = fblk + wv*32 + nt*16 + l15;
        float bi = bias[f];
        #pragma unroll
        for (int r=0;r<4;++r){
          int m = m0 + mt*16 + quad*4 + r;
          int bt = m>>6, p = m&63;
          long orow = (long)bt*256 + (2*(p>>3)+kk)*16 + 2*(p&7)+ll;
          float v = fmaxf(acc[mt][nt][r]+bi, 0.f);
          unsigned short h = f2bu(v);
          unsigned short l = f2bu(v - b2f(h));
          unsigned short* rp = outs + (size_t)orow*1536 + f;
          rp[0] = h; rp[512] = l; rp[1024] = h;
        }
      }
  } else if constexpr (MODE==3){
    int kk = z>>1, ll = z&1;
    #pragma unroll
    for (int mt=0;mt<MTM;++mt)
      #pragma unroll
      for (int nt=0;nt<2;++nt){
        int f = fblk + wv*32 + nt*16 + l15;
        float bi = bias[f];
        #pragma unroll
        for (int r=0;r<4;++r){
          int m = m0 + mt*16 + quad*4 + r;
          int bt = m>>8, p = m&255;
          long orow = (long)bt*1024 + (2*(p>>4)+kk)*32 + 2*(p&15)+ll;
          outf[(size_t)orow*512 + f] = acc[mt][nt][r] + bi;
        }
      }
  } else {  // MODE 4: weff bf16 out, no bias
    #pragma unroll
    for (int mt=0;mt<MTM;++mt)
      #pragma unroll
      for (int nt=0;nt<2;++nt){
        int f = fblk + wv*32 + nt*16 + l15;
        #pragma unroll
        for (int r=0;r<4;++r){
          int m = m0 + mt*16 + quad*4 + r;
          outs[(size_t)m*1024 + f] = f2bu(acc[mt][nt][r]);
        }
      }
  }
}

// ---------------- BN column stats: part[slice][2][1024] ---------------------------------
__launch_bounds__(256)
__global__ void stats2_k(const float* __restrict__ y, float* __restrict__ part){
  int cb = blockIdx.x;   // 8 x 128 c
  int sl = blockIdx.y;   // 16 x 256 rows
  int tid = threadIdx.x;
  int c = cb*128 + (tid & 127);
  int h = tid >> 7;
  float s=0.f, s2=0.f;
  for (int i=0;i<128;i++){
    int r = sl*256 + h*128 + i;
    float v = y[(size_t)r*1024 + c];
    s += v; s2 += v*v;
  }
  __shared__ float rA[256], rB[256];
  rA[tid]=s; rB[tid]=s2; __syncthreads();
  if (tid < 128){
    part[(size_t)sl*2048 + c] = rA[tid]+rA[tid+128];
    part[(size_t)sl*2048 + 1024 + c] = rB[tid]+rB[tid+128];
  }
}

__global__ void stats_comb(const float* __restrict__ part, const float* __restrict__ g,
                           const float* __restrict__ beta, float* __restrict__ mv){
  int c = blockIdx.x*256 + threadIdx.x;   // 1024
  float S=0.f, S2=0.f;
  #pragma unroll
  for (int s=0;s<16;s++){ S += part[(size_t)s*2048 + c]; S2 += part[(size_t)s*2048 + 1024 + c]; }
  float m = S * (1.f/4096.f);
  float var = S2 * (1.f/4096.f) - m*m;
  float inv = rsqrtf(var + 1e-5f);
  float sc = inv * g[c];
  mv[c] = sc;
  mv[1024 + c] = beta[c] - m*sc;
}

__global__ void norm2_k(const float* __restrict__ y, const float* __restrict__ mv,
                        unsigned short* __restrict__ xcl){
  int idx = blockIdx.x*256 + threadIdx.x;
  int c = idx & 1023;
  xcl[idx] = f2bu(y[idx]*mv[c] + mv[1024+c]);
}

// ---------------- weight permute: wtt[f][j*1024+c] = tp_w[f][c*27+j]  (fp32->bf16) ------
__launch_bounds__(256)
__global__ void wperm_k(const float* __restrict__ w, unsigned short* __restrict__ wtt){
  __shared__ float ls[3456];
  int f = blockIdx.x;
  const float* src = w + (size_t)f*27648;
  unsigned short* dst = wtt + (size_t)f*27648;
  for (int cc=0; cc<8; ++cc){
    __syncthreads();
    for (int i=threadIdx.x; i<3456; i+=256) ls[i] = src[cc*3456 + i];
    __syncthreads();
    for (int u=threadIdx.x; u<3456; u+=256){
      int j = u >> 7, c = u & 127;
      dst[(size_t)j*1024 + cc*128 + c] = f2bu(ls[c*27 + j]);
    }
  }
}

// ---------------- goal_pre = mean over 392 pos of relu(sum9 parts + bias) ---------------
__launch_bounds__(256)
__global__ void gp2_k(const float* __restrict__ part9, const float* __restrict__ tpb,
                      float* __restrict__ gp){
  int b = blockIdx.x;
  int fc = blockIdx.y;
  int fi = threadIdx.x & 31, pi = threadIdx.x >> 5;
  int f = fc*32 + fi;
  float bias = tpb[f];
  float a = 0.f;
  for (int p = pi; p < 392; p += 8){
    size_t base = ((size_t)(b*392 + p))*512 + f;
    float v = bias;
    #pragma unroll
    for (int i=0;i<9;i++) v += part9[(size_t)i*802816 + base];
    a += fmaxf(v, 0.f);
  }
  __shared__ float red[256];
  red[threadIdx.x] = a; __syncthreads();
  for (int st=4; st>0; st>>=1){
    if (pi < st) red[pi*32+fi] += red[(pi+st)*32+fi];
    __syncthreads();
  }
  if (pi==0) gp[b*512 + f] = red[fi] * (1.f/392.f);
}

// ---------------- PE table: peN[n][c] ---------------------------------------------------
__global__ void pen_k(float* __restrict__ peN){
  int idx = blockIdx.x*256 + threadIdx.x;   // 524288
  int n = idx >> 9, c = idx & 511;
  float div = expf(-0.035977892f * (float)(c>>1));   // 2*ln(10000)/512
  float ang = (float)n * div;
  peN[idx] = (c & 1) ? cosf(ang) : sinf(ang);
}

// ---------------- SG[bt][n] = dot(scl[bt*1024+n][:], gp[bt/6][:]) -----------------------
__launch_bounds__(256)
__global__ void sg2_k(const float* __restrict__ scl, const float* __restrict__ gp,
                      float* __restrict__ SG){
  int bt = blockIdx.x, nb = blockIdx.y;   // 24 x 16
  int tid = threadIdx.x;
  int wv = tid >> 6, lane = tid & 63;
  __shared__ float gs[512];
  gs[tid] = gp[(bt/6)*512 + tid];
  gs[tid+256] = gp[(bt/6)*512 + 256 + tid];
  __syncthreads();
  for (int i=0;i<16;i++){
    int n = nb*64 + wv*16 + i;
    const float* row = scl + ((size_t)bt*1024 + n)*512 + lane*8;
    float4 a = *reinterpret_cast<const float4*>(row);
    float4 b = *reinterpret_cast<const float4*>(row+4);
    const float* g = &gs[lane*8];
    float s = a.x*g[0] + a.y*g[1] + a.z*g[2] + a.w*g[3]
            + b.x*g[4] + b.y*g[5] + b.z*g[6] + b.w*g[7];
    #pragma unroll
    for (int off=32; off; off>>=1) s += __shfl_xor(s, off);
    if (lane==0) SG[bt*1024 + n] = s;
  }
}

// ---------------- softmax over n: attn[bt][n] normalized --------------------------------
__launch_bounds__(256)
__global__ void softmax_k(const float* __restrict__ SG, float* __restrict__ attn){
  int bt = blockIdx.x; int tid = threadIdx.x;
  float4 v = *reinterpret_cast<const float4*>(SG + bt*1024 + tid*4);
  float mx = fmaxf(fmaxf(v.x,v.y), fmaxf(v.z,v.w));
  __shared__ float red[256];
  red[tid] = mx; __syncthreads();
  for (int st=128; st>0; st>>=1){
    if (tid<st) red[tid] = fmaxf(red[tid], red[tid+st]);
    __syncthreads();
  }
  float m = red[0]; __syncthreads();
  float4 e;
  e.x = expf(v.x-m); e.y = expf(v.y-m); e.z = expf(v.z-m); e.w = expf(v.w-m);
  red[tid] = e.x+e.y+e.z+e.w; __syncthreads();
  for (int st=128; st>0; st>>=1){
    if (tid<st) red[tid] += red[tid+st];
    __syncthreads();
  }
  float inv = 1.0f/red[0];
  e.x*=inv; e.y*=inv; e.z*=inv; e.w*=inv;
  *reinterpret_cast<float4*>(attn + bt*1024 + tid*4) = e;
}

// ---------------- part_sga[bt][sl][c] = sum_{n in slice} attn[n]*(scl[n][c]+pe[n][c]) ---
__launch_bounds__(256)
__global__ void sga2_k(const float* __restrict__ scl, const float* __restrict__ peN,
                       const float* __restrict__ attn, float* __restrict__ part){
  int bt = blockIdx.x, sl = blockIdx.y;   // 24 x 8
  int tid = threadIdx.x;
  __shared__ float at[128];
  if (tid < 128) at[tid] = attn[bt*1024 + sl*128 + tid];
  __syncthreads();
  float acc0 = 0.f, acc1 = 0.f;
  for (int j=0;j<128;j++){
    int n = sl*128 + j;
    float a = at[j];
    const float* row = scl + ((size_t)bt*1024 + n)*512;
    const float* pe  = peN + (size_t)n*512;
    acc0 += a * (row[tid] + pe[tid]);
    acc1 += a * (row[tid+256] + pe[tid+256]);
  }
  part[((size_t)bt*8 + sl)*512 + tid] = acc0;
  part[((size_t)bt*8 + sl)*512 + tid + 256] = acc1;
}

__global__ void sga_red(const float* __restrict__ part, float* __restrict__ sga){
  int bt = blockIdx.x; int tid = threadIdx.x;
  #pragma unroll
  for (int h=0; h<2; ++h){
    int c = tid + h*256;
    float s = 0.f;
    #pragma unroll
    for (int sl=0; sl<8; ++sl) s += part[((size_t)bt*8 + sl)*512 + c];
    sga[(size_t)bt*512 + c] = s;
  }
}

// ---------------- 512->512(relu)->128 MLP head (fp32 weights) ---------------------------
__launch_bounds__(256)
__global__ void mlp_k(const float* __restrict__ in, const float* __restrict__ w1,
                      const float* __restrict__ b1, const float* __restrict__ w2,
                      const float* __restrict__ b2, float* __restrict__ out){
  int bb = blockIdx.x; int tid = threadIdx.x;
  __shared__ float xv[512]; __shared__ float h[512];
  xv[tid] = in[(size_t)bb*512 + tid];
  xv[tid+256] = in[(size_t)bb*512 + 256 + tid];
  __syncthreads();
  #pragma unroll
  for (int oo=0;oo<2;oo++){
    int o = tid + oo*256;
    const float* wr = w1 + (size_t)o*512;
    float a=0.f;
    for (int c=0;c<512;c+=4){
      float4 q = *reinterpret_cast<const float4*>(wr+c);
      a += xv[c]*q.x + xv[c+1]*q.y + xv[c+2]*q.z + xv[c+3]*q.w;
    }
    h[o] = fmaxf(a + b1[o], 0.f);
  }
  __syncthreads();
  if (tid < 128){
    const float* wr = w2 + (size_t)tid*512;
    float a=0.f;
    for (int c=0;c<512;c+=4){
      float4 q = *reinterpret_cast<const float4*>(wr+c);
      a += h[c]*q.x + h[c+1]*q.y + h[c+2]*q.z + h[c+3]*q.w;
    }
    out[(size_t)bb*128+tid] = a + b2[tid];
  }
}

extern "C" void kernel_launch(void* const* d_in, const int* in_sizes, int n_in,
                              void* d_out, int out_size, void* d_ws, size_t ws_size,
                              hipStream_t stream){
  (void)in_sizes; (void)n_in; (void)out_size; (void)ws_size;
  const float* ctx   = (const float*)d_in[0];
  const float* frame = (const float*)d_in[1];
  const float* nl_vw[2] = {(const float*)d_in[4],  (const float*)d_in[11]};
  const float* nl_ow[2] = {(const float*)d_in[5],  (const float*)d_in[12]};
  const float* nl_ob[2] = {(const float*)d_in[6],  (const float*)d_in[13]};
  const float* nl_g[2]  = {(const float*)d_in[7],  (const float*)d_in[14]};
  const float* nl_be[2] = {(const float*)d_in[8],  (const float*)d_in[15]};
  const float* tp_w = (const float*)d_in[16]; const float* tp_b = (const float*)d_in[17];
  const float* up1w = (const float*)d_in[18]; const float* up1b = (const float*)d_in[19];
  const float* up2w = (const float*)d_in[20]; const float* up2b = (const float*)d_in[21];
  const float* og1w = (const float*)d_in[22]; const float* og1b = (const float*)d_in[23];
  const float* og2w = (const float*)d_in[24]; const float* og2b = (const float*)d_in[25];
  const float* os1w = (const float*)d_in[26]; const float* os1b = (const float*)d_in[27];
  const float* os2w = (const float*)d_in[28]; const float* os2b = (const float*)d_in[29];
  float* out = (float*)d_out;

  char* wsp = (char*)d_ws;
  // ---- persistent region (~23.9 MB) ----
  float* part_bn = (float*)(wsp);                 // 131072  [16][2048]
  float* mv      = (float*)(wsp + 131072);        // 8192
  float* gp      = (float*)(wsp + 139264);        // 8192
  float* SG      = (float*)(wsp + 147456);        // 98304
  float* attn    = (float*)(wsp + 245760);        // 98304
  float* sga     = (float*)(wsp + 344064);        // 49152
  float* psga    = (float*)(wsp + 393216);        // 393216 [24][8][512]
  float* peN     = (float*)(wsp + 786432);        // 2097152 [1024][512]
  bf16*  weff    = (bf16*) (wsp + 2883584);       // 2097152 [1024][1024] bf16
  unsigned short* w1sp = (unsigned short*)(wsp + 4980736);   // 12582912 [4][512][3072]
  unsigned short* w2sp = (unsigned short*)(wsp + 17563648);  // 6291456  [4][512][1536]
  char* ov = wsp + 23855104;
  // phase 1 (nonlocal):
  bf16*  xcl  = (bf16*) (ov);                     // 8 MB [4096][1024]
  float* ybuf = (float*)(ov + 8388608);           // 16 MB [4096][1024]
  // phase 1 split-weight staging: lives in the (dead until phase 2) part9 region
  unsigned short* Asp = (unsigned short*)(ov + 36700160);            // 3 MB [1024][1536]
  unsigned short* Bsp = (unsigned short*)(ov + 36700160 + 3145728);  // 3 MB [1024][1536]
  // phase 2 (conv): wtt aliases ybuf (written after last norm2)
  unsigned short* wtt = (unsigned short*)(ov + 8388608);   // 28.3 MB [512][27648]
  float* part9 = (float*)(ov + 36700160);         // 28.9 MB [9][1568][512]
  // frame staging: aliases part9 (written after gp2_k reads part9)
  unsigned short* Fsp = (unsigned short*)(ov + 36700160);  // 9.4 MB [1536][3072]
  // phase 3 (after gp2_k; xcl/wtt dead):
  unsigned short* s1sp = (unsigned short*)(ov);   // 18.9 MB [6144][1536]
  float* scl  = (float*)(ov + 18874368);          // 50.3 MB [24576][512]

  // prep (independent)
  permT_k<bf16><<<dim3(4,16,16),256,0,stream>>>(ctx, xcl, 256, 1024, 1, 1, 262144L, 262144L);
  permTsplit3_k<1><<<dim3(32,16,1),256,0,stream>>>(up1w, w1sp, 2048, 1024, 4, 512, 0L, 0L);
  permTsplit3_k<1><<<dim3(32,8,1),256,0,stream>>>(up2w, w2sp, 2048, 512, 4, 512, 0L, 0L);
  pen_k<<<2048,256,0,stream>>>(peN);

  // nonlocal layers
  for (int l=0;l<2;l++){
    // weff = ow @ vw via split-bf16 MFMA (fp32-accurate products)
    splitA_k<<<2048,256,0,stream>>>(nl_ow[l], Asp);
    permTsplit3_k<1><<<dim3(16,8,1),256,0,stream>>>(nl_vw[l], Bsp, 1024, 512, 1, 1, 0L, 0L);
    mmL_k<2,4><<<dim3(32,8,1),256,0,stream>>>(Asp, Bsp, nullptr, nullptr,
        nullptr, (unsigned short*)weff, 1536);
    mmL_k<2,0><<<dim3(128,8,1),256,0,stream>>>((const unsigned short*)xcl,
        (const unsigned short*)weff, nl_ob[l], (const unsigned short*)xcl,
        ybuf, nullptr, 1024);
    stats2_k<<<dim3(8,16),256,0,stream>>>(ybuf, part_bn);
    stats_comb<<<4,256,0,stream>>>(part_bn, nl_g[l], nl_be[l], mv);
    norm2_k<<<16384,256,0,stream>>>(ybuf, mv, (unsigned short*)xcl);
  }

  // temporal-pool conv (im2col GEMM, K-split 9)
  wperm_k<<<512,256,0,stream>>>(tp_w, wtt);
  mmL_k<2,1><<<dim3(49,4,9),256,0,stream>>>((const unsigned short*)xcl, wtt,
      nullptr, nullptr, part9, nullptr, 3072);
  gp2_k<<<dim3(4,16),256,0,stream>>>(part9, tp_b, gp);

  // frame path (3-block split-bf16 == fp32-accurate); Fsp aliases part9 -> after gp2_k
  permTsplit3_k<0><<<dim3(1,16,24),256,0,stream>>>(frame, Fsp, 64, 1024, 1, 1, 65536L, 196608L);
  mmL_k<2,2><<<dim3(48,4,4),256,0,stream>>>(Fsp, w1sp, up1b, nullptr,
      nullptr, s1sp, 3072);
  mmL_k<4,3><<<dim3(96,4,4),256,0,stream>>>(s1sp, w2sp, up2b, nullptr,
      scl, nullptr, 1536);

  // attention tail
  sg2_k<<<dim3(24,16),256,0,stream>>>(scl, gp, SG);
  softmax_k<<<24,256,0,stream>>>(SG, attn);
  sga2_k<<<dim3(24,8),256,0,stream>>>(scl, peN, attn, psga);
  sga_red<<<24,256,0,stream>>>(psga, sga);

  // heads
  mlp_k<<<4,256,0,stream>>>(gp, og1w, og1b, og2w, og2b, out);
  mlp_k<<<24,256,0,stream>>>(sga, os1w, os1b, os2w, os2b, out + 512);
}

// Round 3
// 785.055 us; speedup vs baseline: 1.0379x; 1.0379x over previous
//
#include <hip/hip_runtime.h>
#include <hip/hip_bf16.h>

using bf16 = __hip_bfloat16;
typedef short short8 __attribute__((ext_vector_type(8)));
typedef float float4v __attribute__((ext_vector_type(4)));

__device__ __forceinline__ float b2f(unsigned short u){
  unsigned int x = ((unsigned int)u) << 16; float f;
  __builtin_memcpy(&f, &x, 4); return f;
}
__device__ __forceinline__ float b2f(bf16 v){ return __bfloat162float(v); }
__device__ __forceinline__ unsigned short f2bu(float x){
  bf16 h = __float2bfloat16(x); unsigned short u;
  __builtin_memcpy(&u, &h, 2); return u;
}

// async global->LDS, 16B per lane, dest = wave-uniform base + lane*16
#define GLDS16(g, l) __builtin_amdgcn_global_load_lds( \
    (const __attribute__((address_space(1))) void*)(g), \
    (__attribute__((address_space(3))) void*)(l), 16, 0, 0)

// -------- batched permuted transpose fp32->bf16: per z, in[R][Cc] -> out[(q%D)*G+q/D][R] -
template<class TO>
__launch_bounds__(256)
__global__ void permT_k(const float* __restrict__ inp, TO* __restrict__ outp,
                        int Cc, int R, int D, int G, long inS, long outS){
  __shared__ float t[64][65];
  int z = blockIdx.z;
  const float* in = inp + (size_t)z*inS;
  TO* out = outp + (size_t)z*outS;
  int c0 = blockIdx.x*64, r0 = blockIdx.y*64;
  int tid = threadIdx.x;
  int rr = tid>>2, c4 = (tid&3)*16;
  const float* p = in + (size_t)(r0+rr)*Cc + c0 + c4;
  #pragma unroll
  for (int j=0;j<16;j+=4){
    float4 q = *reinterpret_cast<const float4*>(p+j);
    t[rr][c4+j]=q.x; t[rr][c4+j+1]=q.y; t[rr][c4+j+2]=q.z; t[rr][c4+j+3]=q.w;
  }
  __syncthreads();
  int ql = tid>>2;
  int q = c0 + ql;
  int orow = (q % D)*G + q / D;
  TO* op = out + (size_t)orow*R + r0 + c4;
  #pragma unroll
  for (int j=0;j<16;j++){
    if constexpr (sizeof(TO)==2) op[j] = __float2bfloat16(t[c4+j][ql]);
    else op[j] = t[c4+j][ql];
  }
}

// -------- 3-block split transpose: rows of length 3R.
// PAT=0 (A-side): blocks (hi, lo, hi).  PAT=1 (B-side): blocks (hi, hi, lo).
// Paired dot over 3R gives ah*bh + al*bh + ah*bl  == fp32-accurate product.
template<int PAT>
__launch_bounds__(256)
__global__ void permTsplit3_k(const float* __restrict__ inp, unsigned short* __restrict__ outp,
                              int Cc, int R, int D, int G, long inS, long outS){
  __shared__ float t[64][65];
  int z = blockIdx.z;
  const float* in = inp + (size_t)z*inS;
  unsigned short* out = outp + (size_t)z*outS;
  int c0 = blockIdx.x*64, r0 = blockIdx.y*64;
  int tid = threadIdx.x;
  int rr = tid>>2, c4 = (tid&3)*16;
  const float* p = in + (size_t)(r0+rr)*Cc + c0 + c4;
  #pragma unroll
  for (int j=0;j<16;j+=4){
    float4 q = *reinterpret_cast<const float4*>(p+j);
    t[rr][c4+j]=q.x; t[rr][c4+j+1]=q.y; t[rr][c4+j+2]=q.z; t[rr][c4+j+3]=q.w;
  }
  __syncthreads();
  int ql = tid>>2;
  int q = c0 + ql;
  int orow = (q % D)*G + q / D;
  unsigned short* op = out + (size_t)orow*(3*R);
  #pragma unroll
  for (int j=0;j<16;j++){
    float v = t[c4+j][ql];
    unsigned short h = f2bu(v);
    unsigned short l = f2bu(v - b2f(h));
    int idx = r0 + c4 + j;
    if constexpr (PAT==0){
      op[idx] = h; op[R+idx] = l; op[2*R+idx] = h;
    } else {
      op[idx] = h; op[R+idx] = h; op[2*R+idx] = l;
    }
  }
}

// -------- row split (no transpose): in[1024][512] fp32 -> out[1024][1536] bf16 (h,l,h) --
__launch_bounds__(256)
__global__ void splitA_k(const float* __restrict__ in, unsigned short* __restrict__ out){
  int idx = blockIdx.x*256 + threadIdx.x;   // 1024*512
  int m = idx >> 9, j = idx & 511;
  float v = in[idx];
  unsigned short h = f2bu(v);
  unsigned short l = f2bu(v - b2f(h));
  unsigned short* op = out + (size_t)m*1536 + j;
  op[0] = h; op[512] = l; op[1024] = h;
}

// ================= unified MFMA GEMM: global_load_lds + dbuf + counted vmcnt =============
// C[m][f] = sum_k A[m][k]*B[f][k], bf16, BK=32, f-tile 128 (4 waves x 2 n-frags).
// LDS image identical to reg-staged version: linear dest slot = tid (16B), source address
// carries the XOR swizzle (c ^ ((row>>1)&3)) -> fragment ds_read_b128 hits <=2-way banks.
// Pipeline (T3/T4 minimal 2-phase): stage tile t+1 into buf^1 BEFORE waiting vmcnt(3) for
// tile t -> loads stay in flight across both raw s_barriers; never drained to 0 in-loop.
// MODE 0: nonlocal (relu(acc+bias)+residual -> fp32), 1: conv3d im2col K-split z,
// MODE 2: up1 (relu+bias, convT scatter, 3-block h/l/h out), 3: up2 (bias, scatter, fp32)
// MODE 4: weff = split-A . split-B -> bf16 [m][1024]
// MODE 1/2: XCD-aware bijective swizzle (z-major / x / y-minor) -> B slice L2-resident.
template<int MTM, int MODE>
__launch_bounds__(256)
__global__ void mmL_k(const unsigned short* __restrict__ A,
                      const unsigned short* __restrict__ B,
                      const float* __restrict__ bias,
                      const unsigned short* __restrict__ res,
                      float* __restrict__ outf,
                      unsigned short* __restrict__ outs,
                      int K){
  constexpr int AR = MTM*16;
  constexpr int ASLOT = AR*4;          // 16B slots in A tile
  __shared__ __align__(16) short As[2*AR*32];
  __shared__ __align__(16) short Bs[2*128*32];
  const int tid = threadIdx.x;
  const int wv = tid>>6, lane = tid&63, l15 = lane&15, quad = lane>>4;
  const int wbase = wv<<6;             // wave-uniform LDS slot base

  int bx = blockIdx.x, by = blockIdx.y, bz = blockIdx.z;
  if constexpr (MODE==1 || MODE==2){
    const int gx = gridDim.x, gy = gridDim.y, gz = gridDim.z;
    const int n = gx*gy*gz;
    const int lin = bx + gx*(by + gy*bz);
    const int q = n >> 3, r = n & 7;
    const int xcd = lin & 7, j = lin >> 3;
    const int work = (xcd < r ? xcd*(q+1) : r*(q+1) + (xcd-r)*q) + j;
    by = work % gy;                 // y minor
    const int t = work / gy;
    bx = t % gx;                    // x middle
    bz = t / gx;                    // z major (chunk == one kt/kh slice)
  }
  const int m0 = bx*AR;
  const int fblk = by*128;
  const int z = bz;

  // ---- staging addresses (source-side swizzle; LDS dest is linear slot=tid) ----
  size_t aAddr = 0;
  {
    int arow = tid>>2, acs = tid&3;
    int ac = acs ^ ((arow>>1)&3);
    if (tid < ASLOT){
      int m = m0 + arow;
      if constexpr (MODE==1){
        int mm = m < 1568 ? m : 1567;
        int b = mm/392, r = mm%392;
        int t = r/196, r2 = r%196;
        int hh = r2/14, ww = r2%14;
        int kt = z/3, kh = z%3;
        int sp = ((b*4 + t + kt)*16 + hh + kh)*16 + ww;
        aAddr = (size_t)sp*1024 + ac*8;
      } else {
        aAddr = (size_t)m*K + ac*8;
      }
    }
  }
  size_t bAddr[2];
  #pragma unroll
  for (int it=0; it<2; ++it){
    int s = tid + it*256;
    int row = s>>2, cs = s&3;
    int c = cs ^ ((row>>1)&3);
    int f = fblk + row;
    if constexpr (MODE==0)      bAddr[it] = (size_t)f*1024 + c*8;
    else if constexpr (MODE==1) bAddr[it] = (size_t)f*27648 + (size_t)z*3072 + c*8;
    else                        bAddr[it] = ((size_t)z*512 + f)*(size_t)K + c*8;
  }
  // ---- fragment LDS slots (swizzled) ----
  int aslot[MTM];
  #pragma unroll
  for (int mt=0;mt<MTM;++mt){
    int row = mt*16 + l15;
    aslot[mt] = row*4 + (quad ^ ((row>>1)&3));
  }
  int bslot[2];
  #pragma unroll
  for (int nt=0;nt<2;++nt){
    int row = wv*32 + nt*16 + l15;
    bslot[nt] = row*4 + (quad ^ ((row>>1)&3));
  }

  float4v acc[MTM][2];
  #pragma unroll
  for (int i=0;i<MTM;i++){ acc[i][0]=(float4v){0,0,0,0}; acc[i][1]=(float4v){0,0,0,0}; }

  auto stage = [&](int buf, int k0){
    if constexpr (ASLOT >= 256){
      GLDS16(A + aAddr + k0, As + buf*(AR*32) + wbase*8);
    } else {
      if (tid < ASLOT) GLDS16(A + aAddr + k0, As + buf*(AR*32) + wbase*8);
    }
    GLDS16(B + bAddr[0] + k0, Bs + buf*4096 + wbase*8);
    GLDS16(B + bAddr[1] + k0, Bs + buf*4096 + (256+wbase)*8);
  };
  auto computeTile = [&](int buf){
    const short* ap = As + buf*(AR*32);
    const short* bp = Bs + buf*4096;
    short8 bf0 = *reinterpret_cast<const short8*>(bp + bslot[0]*8);
    short8 bf1 = *reinterpret_cast<const short8*>(bp + bslot[1]*8);
    #pragma unroll
    for (int mt=0;mt<MTM;++mt){
      short8 af = *reinterpret_cast<const short8*>(ap + aslot[mt]*8);
      acc[mt][0] = __builtin_amdgcn_mfma_f32_16x16x32_bf16(af, bf0, acc[mt][0],0,0,0);
      acc[mt][1] = __builtin_amdgcn_mfma_f32_16x16x32_bf16(af, bf1, acc[mt][1],0,0,0);
    }
  };

  stage(0, 0);
  int cur = 0;
  for (int k0 = 0; k0 < K-32; k0 += 32){
    stage(cur^1, k0+32);               // tile t+1 in flight across the wait+barriers
    if constexpr (ASLOT >= 256){
      asm volatile("s_waitcnt vmcnt(3)" ::: "memory");
    } else {
      if (tid < ASLOT) asm volatile("s_waitcnt vmcnt(3)" ::: "memory");
      else             asm volatile("s_waitcnt vmcnt(2)" ::: "memory");
    }
    __builtin_amdgcn_sched_barrier(0);
    __builtin_amdgcn_s_barrier();      // all waves' tile-t loads landed
    computeTile(cur);
    asm volatile("s_waitcnt lgkmcnt(0)" ::: "memory");
    __builtin_amdgcn_sched_barrier(0);
    __builtin_amdgcn_s_barrier();      // all waves' ds_reads done before buf reuse
    cur ^= 1;
  }
  asm volatile("s_waitcnt vmcnt(0)" ::: "memory");
  __builtin_amdgcn_sched_barrier(0);
  __builtin_amdgcn_s_barrier();
  computeTile(cur);

  if constexpr (MODE==0){
    #pragma unroll
    for (int mt=0;mt<MTM;++mt)
      #pragma unroll
      for (int nt=0;nt<2;++nt){
        int f = fblk + wv*32 + nt*16 + l15;
        float bi = bias[f];
        #pragma unroll
        for (int r=0;r<4;++r){
          int m = m0 + mt*16 + quad*4 + r;
          outf[(size_t)m*1024 + f] =
            fmaxf(acc[mt][nt][r]+bi, 0.f) + b2f(res[(size_t)m*1024 + f]);
        }
      }
  } else if constexpr (MODE==1){
    #pragma unroll
    for (int mt=0;mt<MTM;++mt)
      #pragma unroll
      for (int nt=0;nt<2;++nt){
        int f = fblk + wv*32 + nt*16 + l15;
        #pragma unroll
        for (int r=0;r<4;++r){
          int m = m0 + mt*16 + quad*4 + r;
          if (m < 1568) outf[((size_t)z*1568 + m)*512 + f] = acc[mt][nt][r];
        }
      }
  } else if constexpr (MODE==2){
    int kk = z>>1, ll = z&1;
    #pragma unroll
    for (int mt=0;mt<MTM;++mt)
      #pragma unroll
      for (int nt=0;nt<2;++nt){
        int f = fblk + wv*32 + nt*16 + l15;
        float bi = bias[f];
        #pragma unroll
        for (int r=0;r<4;++r){
          int m = m0 + mt*16 + quad*4 + r;
          int bt = m>>6, p = m&63;
          long orow = (long)bt*256 + (2*(p>>3)+kk)*16 + 2*(p&7)+ll;
          float v = fmaxf(acc[mt][nt][r]+bi, 0.f);
          unsigned short h = f2bu(v);
          unsigned short l = f2bu(v - b2f(h));
          unsigned short* rp = outs + (size_t)orow*1536 + f;
          rp[0] = h; rp[512] = l; rp[1024] = h;
        }
      }
  } else if constexpr (MODE==3){
    int kk = z>>1, ll = z&1;
    #pragma unroll
    for (int mt=0;mt<MTM;++mt)
      #pragma unroll
      for (int nt=0;nt<2;++nt){
        int f = fblk + wv*32 + nt*16 + l15;
        float bi = bias[f];
        #pragma unroll
        for (int r=0;r<4;++r){
          int m = m0 + mt*16 + quad*4 + r;
          int bt = m>>8, p = m&255;
          long orow = (long)bt*1024 + (2*(p>>4)+kk)*32 + 2*(p&15)+ll;
          outf[(size_t)orow*512 + f] = acc[mt][nt][r] + bi;
        }
      }
  } else {  // MODE 4: weff bf16 out, no bias
    #pragma unroll
    for (int mt=0;mt<MTM;++mt)
      #pragma unroll
      for (int nt=0;nt<2;++nt){
        int f = fblk + wv*32 + nt*16 + l15;
        #pragma unroll
        for (int r=0;r<4;++r){
          int m = m0 + mt*16 + quad*4 + r;
          outs[(size_t)m*1024 + f] = f2bu(acc[mt][nt][r]);
        }
      }
  }
}

// ---------------- BN column stats: part[slice][2][1024] ---------------------------------
__launch_bounds__(256)
__global__ void stats2_k(const float* __restrict__ y, float* __restrict__ part){
  int cb = blockIdx.x;   // 8 x 128 c
  int sl = blockIdx.y;   // 16 x 256 rows
  int tid = threadIdx.x;
  int c = cb*128 + (tid & 127);
  int h = tid >> 7;
  float s=0.f, s2=0.f;
  for (int i=0;i<128;i++){
    int r = sl*256 + h*128 + i;
    float v = y[(size_t)r*1024 + c];
    s += v; s2 += v*v;
  }
  __shared__ float rA[256], rB[256];
  rA[tid]=s; rB[tid]=s2; __syncthreads();
  if (tid < 128){
    part[(size_t)sl*2048 + c] = rA[tid]+rA[tid+128];
    part[(size_t)sl*2048 + 1024 + c] = rB[tid]+rB[tid+128];
  }
}

__global__ void stats_comb(const float* __restrict__ part, const float* __restrict__ g,
                           const float* __restrict__ beta, float* __restrict__ mv){
  int c = blockIdx.x*256 + threadIdx.x;   // 1024
  float S=0.f, S2=0.f;
  #pragma unroll
  for (int s=0;s<16;s++){ S += part[(size_t)s*2048 + c]; S2 += part[(size_t)s*2048 + 1024 + c]; }
  float m = S * (1.f/4096.f);
  float var = S2 * (1.f/4096.f) - m*m;
  float inv = rsqrtf(var + 1e-5f);
  float sc = inv * g[c];
  mv[c] = sc;
  mv[1024 + c] = beta[c] - m*sc;
}

__global__ void norm2_k(const float* __restrict__ y, const float* __restrict__ mv,
                        unsigned short* __restrict__ xcl){
  int idx = blockIdx.x*256 + threadIdx.x;
  int c = idx & 1023;
  xcl[idx] = f2bu(y[idx]*mv[c] + mv[1024+c]);
}

// ---------------- weight permute: wtt[f][j*1024+c] = tp_w[f][c*27+j]  (fp32->bf16) ------
__launch_bounds__(256)
__global__ void wperm_k(const float* __restrict__ w, unsigned short* __restrict__ wtt){
  __shared__ float ls[3456];
  int f = blockIdx.x;
  const float* src = w + (size_t)f*27648;
  unsigned short* dst = wtt + (size_t)f*27648;
  for (int cc=0; cc<8; ++cc){
    __syncthreads();
    for (int i=threadIdx.x; i<3456; i+=256) ls[i] = src[cc*3456 + i];
    __syncthreads();
    for (int u=threadIdx.x; u<3456; u+=256){
      int j = u >> 7, c = u & 127;
      dst[(size_t)j*1024 + cc*128 + c] = f2bu(ls[c*27 + j]);
    }
  }
}

// ---------------- goal_pre = mean over 392 pos of relu(sum9 parts + bias) ---------------
__launch_bounds__(256)
__global__ void gp2_k(const float* __restrict__ part9, const float* __restrict__ tpb,
                      float* __restrict__ gp){
  int b = blockIdx.x;
  int fc = blockIdx.y;
  int fi = threadIdx.x & 31, pi = threadIdx.x >> 5;
  int f = fc*32 + fi;
  float bias = tpb[f];
  float a = 0.f;
  for (int p = pi; p < 392; p += 8){
    size_t base = ((size_t)(b*392 + p))*512 + f;
    float v = bias;
    #pragma unroll
    for (int i=0;i<9;i++) v += part9[(size_t)i*802816 + base];
    a += fmaxf(v, 0.f);
  }
  __shared__ float red[256];
  red[threadIdx.x] = a; __syncthreads();
  for (int st=4; st>0; st>>=1){
    if (pi < st) red[pi*32+fi] += red[(pi+st)*32+fi];
    __syncthreads();
  }
  if (pi==0) gp[b*512 + f] = red[fi] * (1.f/392.f);
}

// ---------------- PE table: peN[n][c] ---------------------------------------------------
__global__ void pen_k(float* __restrict__ peN){
  int idx = blockIdx.x*256 + threadIdx.x;   // 524288
  int n = idx >> 9, c = idx & 511;
  float div = expf(-0.035977892f * (float)(c>>1));   // 2*ln(10000)/512
  float ang = (float)n * div;
  peN[idx] = (c & 1) ? cosf(ang) : sinf(ang);
}

// ---------------- SG[bt][n] = dot(scl[bt*1024+n][:], gp[bt/6][:]) -----------------------
__launch_bounds__(256)
__global__ void sg2_k(const float* __restrict__ scl, const float* __restrict__ gp,
                      float* __restrict__ SG){
  int bt = blockIdx.x, nb = blockIdx.y;   // 24 x 16
  int tid = threadIdx.x;
  int wv = tid >> 6, lane = tid & 63;
  __shared__ float gs[512];
  gs[tid] = gp[(bt/6)*512 + tid];
  gs[tid+256] = gp[(bt/6)*512 + 256 + tid];
  __syncthreads();
  for (int i=0;i<16;i++){
    int n = nb*64 + wv*16 + i;
    const float* row = scl + ((size_t)bt*1024 + n)*512 + lane*8;
    float4 a = *reinterpret_cast<const float4*>(row);
    float4 b = *reinterpret_cast<const float4*>(row+4);
    const float* g = &gs[lane*8];
    float s = a.x*g[0] + a.y*g[1] + a.z*g[2] + a.w*g[3]
            + b.x*g[4] + b.y*g[5] + b.z*g[6] + b.w*g[7];
    #pragma unroll
    for (int off=32; off; off>>=1) s += __shfl_xor(s, off);
    if (lane==0) SG[bt*1024 + n] = s;
  }
}

// ---------------- softmax over n: attn[bt][n] normalized --------------------------------
__launch_bounds__(256)
__global__ void softmax_k(const float* __restrict__ SG, float* __restrict__ attn){
  int bt = blockIdx.x; int tid = threadIdx.x;
  float4 v = *reinterpret_cast<const float4*>(SG + bt*1024 + tid*4);
  float mx = fmaxf(fmaxf(v.x,v.y), fmaxf(v.z,v.w));
  __shared__ float red[256];
  red[tid] = mx; __syncthreads();
  for (int st=128; st>0; st>>=1){
    if (tid<st) red[tid] = fmaxf(red[tid], red[tid+st]);
    __syncthreads();
  }
  float m = red[0]; __syncthreads();
  float4 e;
  e.x = expf(v.x-m); e.y = expf(v.y-m); e.z = expf(v.z-m); e.w = expf(v.w-m);
  red[tid] = e.x+e.y+e.z+e.w; __syncthreads();
  for (int st=128; st>0; st>>=1){
    if (tid<st) red[tid] += red[tid+st];
    __syncthreads();
  }
  float inv = 1.0f/red[0];
  e.x*=inv; e.y*=inv; e.z*=inv; e.w*=inv;
  *reinterpret_cast<float4*>(attn + bt*1024 + tid*4) = e;
}

// ---------------- part_sga[bt][sl][c] = sum_{n in slice} attn[n]*(scl[n][c]+pe[n][c]) ---
__launch_bounds__(256)
__global__ void sga2_k(const float* __restrict__ scl, const float* __restrict__ peN,
                       const float* __restrict__ attn, float* __restrict__ part){
  int bt = blockIdx.x, sl = blockIdx.y;   // 24 x 8
  int tid = threadIdx.x;
  __shared__ float at[128];
  if (tid < 128) at[tid] = attn[bt*1024 + sl*128 + tid];
  __syncthreads();
  float acc0 = 0.f, acc1 = 0.f;
  for (int j=0;j<128;j++){
    int n = sl*128 + j;
    float a = at[j];
    const float* row = scl + ((size_t)bt*1024 + n)*512;
    const float* pe  = peN + (size_t)n*512;
    acc0 += a * (row[tid] + pe[tid]);
    acc1 += a * (row[tid+256] + pe[tid+256]);
  }
  part[((size_t)bt*8 + sl)*512 + tid] = acc0;
  part[((size_t)bt*8 + sl)*512 + tid + 256] = acc1;
}

__global__ void sga_red(const float* __restrict__ part, float* __restrict__ sga){
  int bt = blockIdx.x; int tid = threadIdx.x;
  #pragma unroll
  for (int h=0; h<2; ++h){
    int c = tid + h*256;
    float s = 0.f;
    #pragma unroll
    for (int sl=0; sl<8; ++sl) s += part[((size_t)bt*8 + sl)*512 + c];
    sga[(size_t)bt*512 + c] = s;
  }
}

// ---------------- 512->512(relu)->128 MLP head (fp32 weights) ---------------------------
__launch_bounds__(256)
__global__ void mlp_k(const float* __restrict__ in, const float* __restrict__ w1,
                      const float* __restrict__ b1, const float* __restrict__ w2,
                      const float* __restrict__ b2, float* __restrict__ out){
  int bb = blockIdx.x; int tid = threadIdx.x;
  __shared__ float xv[512]; __shared__ float h[512];
  xv[tid] = in[(size_t)bb*512 + tid];
  xv[tid+256] = in[(size_t)bb*512 + 256 + tid];
  __syncthreads();
  #pragma unroll
  for (int oo=0;oo<2;oo++){
    int o = tid + oo*256;
    const float* wr = w1 + (size_t)o*512;
    float a=0.f;
    for (int c=0;c<512;c+=4){
      float4 q = *reinterpret_cast<const float4*>(wr+c);
      a += xv[c]*q.x + xv[c+1]*q.y + xv[c+2]*q.z + xv[c+3]*q.w;
    }
    h[o] = fmaxf(a + b1[o], 0.f);
  }
  __syncthreads();
  if (tid < 128){
    const float* wr = w2 + (size_t)tid*512;
    float a=0.f;
    for (int c=0;c<512;c+=4){
      float4 q = *reinterpret_cast<const float4*>(wr+c);
      a += h[c]*q.x + h[c+1]*q.y + h[c+2]*q.z + h[c+3]*q.w;
    }
    out[(size_t)bb*128+tid] = a + b2[tid];
  }
}

extern "C" void kernel_launch(void* const* d_in, const int* in_sizes, int n_in,
                              void* d_out, int out_size, void* d_ws, size_t ws_size,
                              hipStream_t stream){
  (void)in_sizes; (void)n_in; (void)out_size; (void)ws_size;
  const float* ctx   = (const float*)d_in[0];
  const float* frame = (const float*)d_in[1];
  const float* nl_vw[2] = {(const float*)d_in[4],  (const float*)d_in[11]};
  const float* nl_ow[2] = {(const float*)d_in[5],  (const float*)d_in[12]};
  const float* nl_ob[2] = {(const float*)d_in[6],  (const float*)d_in[13]};
  const float* nl_g[2]  = {(const float*)d_in[7],  (const float*)d_in[14]};
  const float* nl_be[2] = {(const float*)d_in[8],  (const float*)d_in[15]};
  const float* tp_w = (const float*)d_in[16]; const float* tp_b = (const float*)d_in[17];
  const float* up1w = (const float*)d_in[18]; const float* up1b = (const float*)d_in[19];
  const float* up2w = (const float*)d_in[20]; const float* up2b = (const float*)d_in[21];
  const float* og1w = (const float*)d_in[22]; const float* og1b = (const float*)d_in[23];
  const float* og2w = (const float*)d_in[24]; const float* og2b = (const float*)d_in[25];
  const float* os1w = (const float*)d_in[26]; const float* os1b = (const float*)d_in[27];
  const float* os2w = (const float*)d_in[28]; const float* os2b = (const float*)d_in[29];
  float* out = (float*)d_out;

  char* wsp = (char*)d_ws;
  // ---- persistent region (~23.9 MB) ----
  float* part_bn = (float*)(wsp);                 // 131072  [16][2048]
  float* mv      = (float*)(wsp + 131072);        // 8192
  float* gp      = (float*)(wsp + 139264);        // 8192
  float* SG      = (float*)(wsp + 147456);        // 98304
  float* attn    = (float*)(wsp + 245760);        // 98304
  float* sga     = (float*)(wsp + 344064);        // 49152
  float* psga    = (float*)(wsp + 393216);        // 393216 [24][8][512]
  float* peN     = (float*)(wsp + 786432);        // 2097152 [1024][512]
  bf16*  weff    = (bf16*) (wsp + 2883584);       // 2097152 [1024][1024] bf16
  unsigned short* w1sp = (unsigned short*)(wsp + 4980736);   // 12582912 [4][512][3072]
  unsigned short* w2sp = (unsigned short*)(wsp + 17563648);  // 6291456  [4][512][1536]
  char* ov = wsp + 23855104;
  // phase 1 (nonlocal):
  bf16*  xcl  = (bf16*) (ov);                     // 8 MB [4096][1024]
  float* ybuf = (float*)(ov + 8388608);           // 16 MB [4096][1024]
  // phase 1 split-weight staging: lives in the (dead until phase 2) part9 region
  unsigned short* Asp = (unsigned short*)(ov + 36700160);            // 3 MB [1024][1536]
  unsigned short* Bsp = (unsigned short*)(ov + 36700160 + 3145728);  // 3 MB [1024][1536]
  // phase 2 (conv): wtt aliases ybuf (written after last norm2)
  unsigned short* wtt = (unsigned short*)(ov + 8388608);   // 28.3 MB [512][27648]
  float* part9 = (float*)(ov + 36700160);         // 28.9 MB [9][1568][512]
  // frame staging: aliases part9 (written after gp2_k reads part9)
  unsigned short* Fsp = (unsigned short*)(ov + 36700160);  // 9.4 MB [1536][3072]
  // phase 3 (after gp2_k; xcl/wtt dead):
  unsigned short* s1sp = (unsigned short*)(ov);   // 18.9 MB [6144][1536]
  float* scl  = (float*)(ov + 18874368);          // 50.3 MB [24576][512]

  // prep (independent)
  permT_k<bf16><<<dim3(4,16,16),256,0,stream>>>(ctx, xcl, 256, 1024, 1, 1, 262144L, 262144L);
  permTsplit3_k<1><<<dim3(32,16,1),256,0,stream>>>(up1w, w1sp, 2048, 1024, 4, 512, 0L, 0L);
  permTsplit3_k<1><<<dim3(32,8,1),256,0,stream>>>(up2w, w2sp, 2048, 512, 4, 512, 0L, 0L);
  pen_k<<<2048,256,0,stream>>>(peN);

  // nonlocal layers
  for (int l=0;l<2;l++){
    // weff = ow @ vw via split-bf16 MFMA (fp32-accurate products)
    splitA_k<<<2048,256,0,stream>>>(nl_ow[l], Asp);
    permTsplit3_k<1><<<dim3(16,8,1),256,0,stream>>>(nl_vw[l], Bsp, 1024, 512, 1, 1, 0L, 0L);
    mmL_k<2,4><<<dim3(32,8,1),256,0,stream>>>(Asp, Bsp, nullptr, nullptr,
        nullptr, (unsigned short*)weff, 1536);
    mmL_k<4,0><<<dim3(64,8,1),256,0,stream>>>((const unsigned short*)xcl,
        (const unsigned short*)weff, nl_ob[l], (const unsigned short*)xcl,
        ybuf, nullptr, 1024);
    stats2_k<<<dim3(8,16),256,0,stream>>>(ybuf, part_bn);
    stats_comb<<<4,256,0,stream>>>(part_bn, nl_g[l], nl_be[l], mv);
    norm2_k<<<16384,256,0,stream>>>(ybuf, mv, (unsigned short*)xcl);
  }

  // temporal-pool conv (im2col GEMM, K-split 9)
  wperm_k<<<512,256,0,stream>>>(tp_w, wtt);
  mmL_k<4,1><<<dim3(25,4,9),256,0,stream>>>((const unsigned short*)xcl, wtt,
      nullptr, nullptr, part9, nullptr, 3072);
  gp2_k<<<dim3(4,16),256,0,stream>>>(part9, tp_b, gp);

  // frame path (3-block split-bf16 == fp32-accurate); Fsp aliases part9 -> after gp2_k
  permTsplit3_k<0><<<dim3(1,16,24),256,0,stream>>>(frame, Fsp, 64, 1024, 1, 1, 65536L, 196608L);
  mmL_k<2,2><<<dim3(48,4,4),256,0,stream>>>(Fsp, w1sp, up1b, nullptr,
      nullptr, s1sp, 3072);
  mmL_k<4,3><<<dim3(96,4,4),256,0,stream>>>(s1sp, w2sp, up2b, nullptr,
      scl, nullptr, 1536);

  // attention tail
  sg2_k<<<dim3(24,16),256,0,stream>>>(scl, gp, SG);
  softmax_k<<<24,256,0,stream>>>(SG, attn);
  sga2_k<<<dim3(24,8),256,0,stream>>>(scl, peN, attn, psga);
  sga_red<<<24,256,0,stream>>>(psga, sga);

  // heads
  mlp_k<<<4,256,0,stream>>>(gp, og1w, og1b, og2w, og2b, out);
  mlp_k<<<24,256,0,stream>>>(sga, os1w, os1b, os2w, os2b, out + 512);
}

// Round 4
// 730.010 us; speedup vs baseline: 1.1161x; 1.0754x over previous
//
#include <hip/hip_runtime.h>
#include <hip/hip_bf16.h>

using bf16 = __hip_bfloat16;
typedef short short8 __attribute__((ext_vector_type(8)));
typedef float float4v __attribute__((ext_vector_type(4)));

__device__ __forceinline__ float b2f(unsigned short u){
  unsigned int x = ((unsigned int)u) << 16; float f;
  __builtin_memcpy(&f, &x, 4); return f;
}
__device__ __forceinline__ float b2f(bf16 v){ return __bfloat162float(v); }
__device__ __forceinline__ unsigned short f2bu(float x){
  bf16 h = __float2bfloat16(x); unsigned short u;
  __builtin_memcpy(&u, &h, 2); return u;
}

// async global->LDS, 16B per lane, dest = wave-uniform base + lane*16
#define GLDS16(g, l) __builtin_amdgcn_global_load_lds( \
    (const __attribute__((address_space(1))) void*)(g), \
    (__attribute__((address_space(3))) void*)(l), 16, 0, 0)

// -------- batched permuted transpose fp32->bf16: per z, in[R][Cc] -> out[(q%D)*G+q/D][R] -
template<class TO>
__launch_bounds__(256)
__global__ void permT_k(const float* __restrict__ inp, TO* __restrict__ outp,
                        int Cc, int R, int D, int G, long inS, long outS){
  __shared__ float t[64][65];
  int z = blockIdx.z;
  const float* in = inp + (size_t)z*inS;
  TO* out = outp + (size_t)z*outS;
  int c0 = blockIdx.x*64, r0 = blockIdx.y*64;
  int tid = threadIdx.x;
  int rr = tid>>2, c4 = (tid&3)*16;
  const float* p = in + (size_t)(r0+rr)*Cc + c0 + c4;
  #pragma unroll
  for (int j=0;j<16;j+=4){
    float4 q = *reinterpret_cast<const float4*>(p+j);
    t[rr][c4+j]=q.x; t[rr][c4+j+1]=q.y; t[rr][c4+j+2]=q.z; t[rr][c4+j+3]=q.w;
  }
  __syncthreads();
  int ql = tid>>2;
  int q = c0 + ql;
  int orow = (q % D)*G + q / D;
  TO* op = out + (size_t)orow*R + r0 + c4;
  #pragma unroll
  for (int j=0;j<16;j++){
    if constexpr (sizeof(TO)==2) op[j] = __float2bfloat16(t[c4+j][ql]);
    else op[j] = t[c4+j][ql];
  }
}

// -------- 3-block split transpose: rows of length 3R.
// PAT=0 (A-side): blocks (hi, lo, hi).  PAT=1 (B-side): blocks (hi, hi, lo).
// Paired dot over 3R gives ah*bh + al*bh + ah*bl  == fp32-accurate product.
template<int PAT>
__launch_bounds__(256)
__global__ void permTsplit3_k(const float* __restrict__ inp, unsigned short* __restrict__ outp,
                              int Cc, int R, int D, int G, long inS, long outS){
  __shared__ float t[64][65];
  int z = blockIdx.z;
  const float* in = inp + (size_t)z*inS;
  unsigned short* out = outp + (size_t)z*outS;
  int c0 = blockIdx.x*64, r0 = blockIdx.y*64;
  int tid = threadIdx.x;
  int rr = tid>>2, c4 = (tid&3)*16;
  const float* p = in + (size_t)(r0+rr)*Cc + c0 + c4;
  #pragma unroll
  for (int j=0;j<16;j+=4){
    float4 q = *reinterpret_cast<const float4*>(p+j);
    t[rr][c4+j]=q.x; t[rr][c4+j+1]=q.y; t[rr][c4+j+2]=q.z; t[rr][c4+j+3]=q.w;
  }
  __syncthreads();
  int ql = tid>>2;
  int q = c0 + ql;
  int orow = (q % D)*G + q / D;
  unsigned short* op = out + (size_t)orow*(3*R);
  #pragma unroll
  for (int j=0;j<16;j++){
    float v = t[c4+j][ql];
    unsigned short h = f2bu(v);
    unsigned short l = f2bu(v - b2f(h));
    int idx = r0 + c4 + j;
    if constexpr (PAT==0){
      op[idx] = h; op[R+idx] = l; op[2*R+idx] = h;
    } else {
      op[idx] = h; op[R+idx] = h; op[2*R+idx] = l;
    }
  }
}

// -------- row split (no transpose): in[1024][512] fp32 -> out[1024][1536] bf16 (h,l,h) --
__launch_bounds__(256)
__global__ void splitA_k(const float* __restrict__ in, unsigned short* __restrict__ out){
  int idx = blockIdx.x*256 + threadIdx.x;   // 1024*512
  int m = idx >> 9, j = idx & 511;
  float v = in[idx];
  unsigned short h = f2bu(v);
  unsigned short l = f2bu(v - b2f(h));
  unsigned short* op = out + (size_t)m*1536 + j;
  op[0] = h; op[512] = l; op[1024] = h;
}

// ================= unified MFMA GEMM: global_load_lds + dbuf + counted vmcnt, BK=64 ======
// C[m][f] = sum_k A[m][k]*B[f][k], bf16, BK=64, f-tile 128 (4 waves x 2 n-frags).
// LDS image: linear dest slot (16B) = row*8 + chunk'; content swizzle chunk' = c ^ (row&7)
// applied on the GLOBAL source address (m104-safe). Row stride 128B = 32 banks, so the
// (row&7) XOR spreads the 16 fragment lanes over 8 chunk-slots -> 2-way banks (free).
// Pipeline (T3/T4 2-phase, BK=64 to amortize per-step barriers): stage tile t+1 into buf^1
// BEFORE waiting vmcnt(LPT) for tile t; loads stay in flight across both raw s_barriers.
// MODE 0: nonlocal (relu(acc+bias)+residual -> fp32), 1: conv3d im2col K-split z,
// MODE 2: up1 (relu+bias, convT scatter, 3-block h/l/h out), 3: up2 (bias, scatter, fp32)
// MODE 4: weff = split-A . split-B -> bf16 [m][1024]
// MODE 1/2: XCD-aware bijective swizzle (z-major / x / y-minor) -> B slice L2-resident.
template<int MTM, int MODE>
__launch_bounds__(256)
__global__ void mmL_k(const unsigned short* __restrict__ A,
                      const unsigned short* __restrict__ B,
                      const float* __restrict__ bias,
                      const unsigned short* __restrict__ res,
                      float* __restrict__ outf,
                      unsigned short* __restrict__ outs,
                      int K){
  constexpr int AR = MTM*16;
  constexpr int ACH = AR*8;            // 16B chunks per A tile (BK=64)
  constexpr int AIT = ACH/256;         // A chunks per thread (1 or 2)
  constexpr int LPT = AIT + 4;         // loads per thread per stage
  __shared__ __align__(16) short As[2*AR*64];
  __shared__ __align__(16) short Bs[2*128*64];
  const int tid = threadIdx.x;
  const int wv = tid>>6, lane = tid&63, l15 = lane&15, quad = lane>>4;
  const int wbase = wv<<6;             // wave-uniform LDS slot base (64 slots/wave)

  int bx = blockIdx.x, by = blockIdx.y, bz = blockIdx.z;
  if constexpr (MODE==1 || MODE==2){
    const int gx = gridDim.x, gy = gridDim.y, gz = gridDim.z;
    const int n = gx*gy*gz;
    const int lin = bx + gx*(by + gy*bz);
    const int q = n >> 3, r = n & 7;
    const int xcd = lin & 7, j = lin >> 3;
    const int work = (xcd < r ? xcd*(q+1) : r*(q+1) + (xcd-r)*q) + j;
    by = work % gy;                 // y minor
    const int t = work / gy;
    bx = t % gx;                    // x middle
    bz = t / gx;                    // z major (chunk == one kt/kh slice)
  }
  const int m0 = bx*AR;
  const int fblk = by*128;
  const int z = bz;

  // ---- staging addresses (source-side swizzle; LDS dest linear: slot = it*256+tid) ----
  size_t aAddr[AIT];
  #pragma unroll
  for (int it=0; it<AIT; ++it){
    int s = tid + it*256;
    int arow = s>>3;
    int ac = (s&7) ^ (arow&7);
    int m = m0 + arow;
    if constexpr (MODE==1){
      int mm = m < 1568 ? m : 1567;
      int b = mm/392, r = mm%392;
      int t = r/196, r2 = r%196;
      int hh = r2/14, ww = r2%14;
      int kt = z/3, kh = z%3;
      int sp = ((b*4 + t + kt)*16 + hh + kh)*16 + ww;
      aAddr[it] = (size_t)sp*1024 + ac*8;
    } else {
      aAddr[it] = (size_t)m*K + ac*8;
    }
  }
  size_t bAddr[4];
  #pragma unroll
  for (int it=0; it<4; ++it){
    int s = tid + it*256;
    int row = s>>3;
    int c = (s&7) ^ (row&7);
    int f = fblk + row;
    if constexpr (MODE==0)      bAddr[it] = (size_t)f*1024 + c*8;
    else if constexpr (MODE==1) bAddr[it] = (size_t)f*27648 + (size_t)z*3072 + c*8;
    else                        bAddr[it] = ((size_t)z*512 + f)*(size_t)K + c*8;
  }
  // ---- fragment LDS slots (swizzled), per k-subtile ----
  int aslot[MTM][2];
  #pragma unroll
  for (int mt=0;mt<MTM;++mt)
    #pragma unroll
    for (int ks=0;ks<2;++ks){
      int row = mt*16 + l15;
      aslot[mt][ks] = row*8 + ((ks*4 + quad) ^ (row&7));
    }
  int bslot[2][2];
  #pragma unroll
  for (int nt=0;nt<2;++nt)
    #pragma unroll
    for (int ks=0;ks<2;++ks){
      int row = wv*32 + nt*16 + l15;
      bslot[nt][ks] = row*8 + ((ks*4 + quad) ^ (row&7));
    }

  float4v acc[MTM][2];
  #pragma unroll
  for (int i=0;i<MTM;i++){ acc[i][0]=(float4v){0,0,0,0}; acc[i][1]=(float4v){0,0,0,0}; }

  auto stage = [&](int buf, int k0){
    #pragma unroll
    for (int it=0; it<AIT; ++it)
      GLDS16(A + aAddr[it] + k0, As + buf*(AR*64) + (it*256 + wbase)*8);
    #pragma unroll
    for (int it=0; it<4; ++it)
      GLDS16(B + bAddr[it] + k0, Bs + buf*8192 + (it*256 + wbase)*8);
  };
  auto computeTile = [&](int buf){
    const short* ap = As + buf*(AR*64);
    const short* bp = Bs + buf*8192;
    #pragma unroll
    for (int ks=0; ks<2; ++ks){
      short8 bf0 = *reinterpret_cast<const short8*>(bp + bslot[0][ks]*8);
      short8 bf1 = *reinterpret_cast<const short8*>(bp + bslot[1][ks]*8);
      #pragma unroll
      for (int mt=0;mt<MTM;++mt){
        short8 af = *reinterpret_cast<const short8*>(ap + aslot[mt][ks]*8);
        acc[mt][0] = __builtin_amdgcn_mfma_f32_16x16x32_bf16(af, bf0, acc[mt][0],0,0,0);
        acc[mt][1] = __builtin_amdgcn_mfma_f32_16x16x32_bf16(af, bf1, acc[mt][1],0,0,0);
      }
    }
  };

  stage(0, 0);
  int cur = 0;
  for (int k0 = 0; k0 < K-64; k0 += 64){
    stage(cur^1, k0+64);               // tile t+1 in flight across the wait+barriers
    if constexpr (LPT==6){
      asm volatile("s_waitcnt vmcnt(6)" ::: "memory");
    } else {
      asm volatile("s_waitcnt vmcnt(5)" ::: "memory");
    }
    __builtin_amdgcn_sched_barrier(0);
    __builtin_amdgcn_s_barrier();      // all waves' tile-t loads landed
    computeTile(cur);
    asm volatile("s_waitcnt lgkmcnt(0)" ::: "memory");
    __builtin_amdgcn_sched_barrier(0);
    __builtin_amdgcn_s_barrier();      // all waves' ds_reads done before buf reuse
    cur ^= 1;
  }
  asm volatile("s_waitcnt vmcnt(0)" ::: "memory");
  __builtin_amdgcn_sched_barrier(0);
  __builtin_amdgcn_s_barrier();
  computeTile(cur);

  if constexpr (MODE==0){
    #pragma unroll
    for (int mt=0;mt<MTM;++mt)
      #pragma unroll
      for (int nt=0;nt<2;++nt){
        int f = fblk + wv*32 + nt*16 + l15;
        float bi = bias[f];
        #pragma unroll
        for (int r=0;r<4;++r){
          int m = m0 + mt*16 + quad*4 + r;
          outf[(size_t)m*1024 + f] =
            fmaxf(acc[mt][nt][r]+bi, 0.f) + b2f(res[(size_t)m*1024 + f]);
        }
      }
  } else if constexpr (MODE==1){
    #pragma unroll
    for (int mt=0;mt<MTM;++mt)
      #pragma unroll
      for (int nt=0;nt<2;++nt){
        int f = fblk + wv*32 + nt*16 + l15;
        #pragma unroll
        for (int r=0;r<4;++r){
          int m = m0 + mt*16 + quad*4 + r;
          if (m < 1568) outf[((size_t)z*1568 + m)*512 + f] = acc[mt][nt][r];
        }
      }
  } else if constexpr (MODE==2){
    int kk = z>>1, ll = z&1;
    #pragma unroll
    for (int mt=0;mt<MTM;++mt)
      #pragma unroll
      for (int nt=0;nt<2;++nt){
        int f = fblk + wv*32 + nt*16 + l15;
        float bi = bias[f];
        #pragma unroll
        for (int r=0;r<4;++r){
          int m = m0 + mt*16 + quad*4 + r;
          int bt = m>>6, p = m&63;
          long orow = (long)bt*256 + (2*(p>>3)+kk)*16 + 2*(p&7)+ll;
          float v = fmaxf(acc[mt][nt][r]+bi, 0.f);
          unsigned short h = f2bu(v);
          unsigned short l = f2bu(v - b2f(h));
          unsigned short* rp = outs + (size_t)orow*1536 + f;
          rp[0] = h; rp[512] = l; rp[1024] = h;
        }
      }
  } else if constexpr (MODE==3){
    int kk = z>>1, ll = z&1;
    #pragma unroll
    for (int mt=0;mt<MTM;++mt)
      #pragma unroll
      for (int nt=0;nt<2;++nt){
        int f = fblk + wv*32 + nt*16 + l15;
        float bi = bias[f];
        #pragma unroll
        for (int r=0;r<4;++r){
          int m = m0 + mt*16 + quad*4 + r;
          int bt = m>>8, p = m&255;
          long orow = (long)bt*1024 + (2*(p>>4)+kk)*32 + 2*(p&15)+ll;
          outf[(size_t)orow*512 + f] = acc[mt][nt][r] + bi;
        }
      }
  } else {  // MODE 4: weff bf16 out, no bias
    #pragma unroll
    for (int mt=0;mt<MTM;++mt)
      #pragma unroll
      for (int nt=0;nt<2;++nt){
        int f = fblk + wv*32 + nt*16 + l15;
        #pragma unroll
        for (int r=0;r<4;++r){
          int m = m0 + mt*16 + quad*4 + r;
          outs[(size_t)m*1024 + f] = f2bu(acc[mt][nt][r]);
        }
      }
  }
}

// ---------------- BN column stats: part[slice][2][1024] ---------------------------------
__launch_bounds__(256)
__global__ void stats2_k(const float* __restrict__ y, float* __restrict__ part){
  int cb = blockIdx.x;   // 8 x 128 c
  int sl = blockIdx.y;   // 16 x 256 rows
  int tid = threadIdx.x;
  int c = cb*128 + (tid & 127);
  int h = tid >> 7;
  float s=0.f, s2=0.f;
  for (int i=0;i<128;i++){
    int r = sl*256 + h*128 + i;
    float v = y[(size_t)r*1024 + c];
    s += v; s2 += v*v;
  }
  __shared__ float rA[256], rB[256];
  rA[tid]=s; rB[tid]=s2; __syncthreads();
  if (tid < 128){
    part[(size_t)sl*2048 + c] = rA[tid]+rA[tid+128];
    part[(size_t)sl*2048 + 1024 + c] = rB[tid]+rB[tid+128];
  }
}

__global__ void stats_comb(const float* __restrict__ part, const float* __restrict__ g,
                           const float* __restrict__ beta, float* __restrict__ mv){
  int c = blockIdx.x*256 + threadIdx.x;   // 1024
  float S=0.f, S2=0.f;
  #pragma unroll
  for (int s=0;s<16;s++){ S += part[(size_t)s*2048 + c]; S2 += part[(size_t)s*2048 + 1024 + c]; }
  float m = S * (1.f/4096.f);
  float var = S2 * (1.f/4096.f) - m*m;
  float inv = rsqrtf(var + 1e-5f);
  float sc = inv * g[c];
  mv[c] = sc;
  mv[1024 + c] = beta[c] - m*sc;
}

__global__ void norm2_k(const float* __restrict__ y, const float* __restrict__ mv,
                        unsigned short* __restrict__ xcl){
  int idx = blockIdx.x*256 + threadIdx.x;
  int c = idx & 1023;
  xcl[idx] = f2bu(y[idx]*mv[c] + mv[1024+c]);
}

// ---------------- weight permute: wtt[f][j*1024+c] = tp_w[f][c*27+j]  (fp32->bf16) ------
__launch_bounds__(256)
__global__ void wperm_k(const float* __restrict__ w, unsigned short* __restrict__ wtt){
  __shared__ float ls[3456];
  int f = blockIdx.x;
  const float* src = w + (size_t)f*27648;
  unsigned short* dst = wtt + (size_t)f*27648;
  for (int cc=0; cc<8; ++cc){
    __syncthreads();
    for (int i=threadIdx.x; i<3456; i+=256) ls[i] = src[cc*3456 + i];
    __syncthreads();
    for (int u=threadIdx.x; u<3456; u+=256){
      int j = u >> 7, c = u & 127;
      dst[(size_t)j*1024 + cc*128 + c] = f2bu(ls[c*27 + j]);
    }
  }
}

// ---------------- goal_pre = mean over 392 pos of relu(sum9 parts + bias) ---------------
__launch_bounds__(256)
__global__ void gp2_k(const float* __restrict__ part9, const float* __restrict__ tpb,
                      float* __restrict__ gp){
  int b = blockIdx.x;
  int fc = blockIdx.y;
  int fi = threadIdx.x & 31, pi = threadIdx.x >> 5;
  int f = fc*32 + fi;
  float bias = tpb[f];
  float a = 0.f;
  for (int p = pi; p < 392; p += 8){
    size_t base = ((size_t)(b*392 + p))*512 + f;
    float v = bias;
    #pragma unroll
    for (int i=0;i<9;i++) v += part9[(size_t)i*802816 + base];
    a += fmaxf(v, 0.f);
  }
  __shared__ float red[256];
  red[threadIdx.x] = a; __syncthreads();
  for (int st=4; st>0; st>>=1){
    if (pi < st) red[pi*32+fi] += red[(pi+st)*32+fi];
    __syncthreads();
  }
  if (pi==0) gp[b*512 + f] = red[fi] * (1.f/392.f);
}

// ---------------- PE table: peN[n][c] ---------------------------------------------------
__global__ void pen_k(float* __restrict__ peN){
  int idx = blockIdx.x*256 + threadIdx.x;   // 524288
  int n = idx >> 9, c = idx & 511;
  float div = expf(-0.035977892f * (float)(c>>1));   // 2*ln(10000)/512
  float ang = (float)n * div;
  peN[idx] = (c & 1) ? cosf(ang) : sinf(ang);
}

// ---------------- SG[bt][n] = dot(scl[bt*1024+n][:], gp[bt/6][:]) -----------------------
__launch_bounds__(256)
__global__ void sg2_k(const float* __restrict__ scl, const float* __restrict__ gp,
                      float* __restrict__ SG){
  int bt = blockIdx.x, nb = blockIdx.y;   // 24 x 16
  int tid = threadIdx.x;
  int wv = tid >> 6, lane = tid & 63;
  __shared__ float gs[512];
  gs[tid] = gp[(bt/6)*512 + tid];
  gs[tid+256] = gp[(bt/6)*512 + 256 + tid];
  __syncthreads();
  for (int i=0;i<16;i++){
    int n = nb*64 + wv*16 + i;
    const float* row = scl + ((size_t)bt*1024 + n)*512 + lane*8;
    float4 a = *reinterpret_cast<const float4*>(row);
    float4 b = *reinterpret_cast<const float4*>(row+4);
    const float* g = &gs[lane*8];
    float s = a.x*g[0] + a.y*g[1] + a.z*g[2] + a.w*g[3]
            + b.x*g[4] + b.y*g[5] + b.z*g[6] + b.w*g[7];
    #pragma unroll
    for (int off=32; off; off>>=1) s += __shfl_xor(s, off);
    if (lane==0) SG[bt*1024 + n] = s;
  }
}

// ---------------- softmax over n: attn[bt][n] normalized --------------------------------
__launch_bounds__(256)
__global__ void softmax_k(const float* __restrict__ SG, float* __restrict__ attn){
  int bt = blockIdx.x; int tid = threadIdx.x;
  float4 v = *reinterpret_cast<const float4*>(SG + bt*1024 + tid*4);
  float mx = fmaxf(fmaxf(v.x,v.y), fmaxf(v.z,v.w));
  __shared__ float red[256];
  red[tid] = mx; __syncthreads();
  for (int st=128; st>0; st>>=1){
    if (tid<st) red[tid] = fmaxf(red[tid], red[tid+st]);
    __syncthreads();
  }
  float m = red[0]; __syncthreads();
  float4 e;
  e.x = expf(v.x-m); e.y = expf(v.y-m); e.z = expf(v.z-m); e.w = expf(v.w-m);
  red[tid] = e.x+e.y+e.z+e.w; __syncthreads();
  for (int st=128; st>0; st>>=1){
    if (tid<st) red[tid] += red[tid+st];
    __syncthreads();
  }
  float inv = 1.0f/red[0];
  e.x*=inv; e.y*=inv; e.z*=inv; e.w*=inv;
  *reinterpret_cast<float4*>(attn + bt*1024 + tid*4) = e;
}

// ---------------- part_sga[bt][sl][c] = sum_{n in slice} attn[n]*(scl[n][c]+pe[n][c]) ---
__launch_bounds__(256)
__global__ void sga2_k(const float* __restrict__ scl, const float* __restrict__ peN,
                       const float* __restrict__ attn, float* __restrict__ part){
  int bt = blockIdx.x, sl = blockIdx.y;   // 24 x 8
  int tid = threadIdx.x;
  __shared__ float at[128];
  if (tid < 128) at[tid] = attn[bt*1024 + sl*128 + tid];
  __syncthreads();
  float acc0 = 0.f, acc1 = 0.f;
  for (int j=0;j<128;j++){
    int n = sl*128 + j;
    float a = at[j];
    const float* row = scl + ((size_t)bt*1024 + n)*512;
    const float* pe  = peN + (size_t)n*512;
    acc0 += a * (row[tid] + pe[tid]);
    acc1 += a * (row[tid+256] + pe[tid+256]);
  }
  part[((size_t)bt*8 + sl)*512 + tid] = acc0;
  part[((size_t)bt*8 + sl)*512 + tid + 256] = acc1;
}

__global__ void sga_red(const float* __restrict__ part, float* __restrict__ sga){
  int bt = blockIdx.x; int tid = threadIdx.x;
  #pragma unroll
  for (int h=0; h<2; ++h){
    int c = tid + h*256;
    float s = 0.f;
    #pragma unroll
    for (int sl=0; sl<8; ++sl) s += part[((size_t)bt*8 + sl)*512 + c];
    sga[(size_t)bt*512 + c] = s;
  }
}

// ---------------- 512->512(relu)->128 MLP head (fp32 weights) ---------------------------
__launch_bounds__(256)
__global__ void mlp_k(const float* __restrict__ in, const float* __restrict__ w1,
                      const float* __restrict__ b1, const float* __restrict__ w2,
                      const float* __restrict__ b2, float* __restrict__ out){
  int bb = blockIdx.x; int tid = threadIdx.x;
  __shared__ float xv[512]; __shared__ float h[512];
  xv[tid] = in[(size_t)bb*512 + tid];
  xv[tid+256] = in[(size_t)bb*512 + 256 + tid];
  __syncthreads();
  #pragma unroll
  for (int oo=0;oo<2;oo++){
    int o = tid + oo*256;
    const float* wr = w1 + (size_t)o*512;
    float a=0.f;
    for (int c=0;c<512;c+=4){
      float4 q = *reinterpret_cast<const float4*>(wr+c);
      a += xv[c]*q.x + xv[c+1]*q.y + xv[c+2]*q.z + xv[c+3]*q.w;
    }
    h[o] = fmaxf(a + b1[o], 0.f);
  }
  __syncthreads();
  if (tid < 128){
    const float* wr = w2 + (size_t)tid*512;
    float a=0.f;
    for (int c=0;c<512;c+=4){
      float4 q = *reinterpret_cast<const float4*>(wr+c);
      a += h[c]*q.x + h[c+1]*q.y + h[c+2]*q.z + h[c+3]*q.w;
    }
    out[(size_t)bb*128+tid] = a + b2[tid];
  }
}

extern "C" void kernel_launch(void* const* d_in, const int* in_sizes, int n_in,
                              void* d_out, int out_size, void* d_ws, size_t ws_size,
                              hipStream_t stream){
  (void)in_sizes; (void)n_in; (void)out_size; (void)ws_size;
  const float* ctx   = (const float*)d_in[0];
  const float* frame = (const float*)d_in[1];
  const float* nl_vw[2] = {(const float*)d_in[4],  (const float*)d_in[11]};
  const float* nl_ow[2] = {(const float*)d_in[5],  (const float*)d_in[12]};
  const float* nl_ob[2] = {(const float*)d_in[6],  (const float*)d_in[13]};
  const float* nl_g[2]  = {(const float*)d_in[7],  (const float*)d_in[14]};
  const float* nl_be[2] = {(const float*)d_in[8],  (const float*)d_in[15]};
  const float* tp_w = (const float*)d_in[16]; const float* tp_b = (const float*)d_in[17];
  const float* up1w = (const float*)d_in[18]; const float* up1b = (const float*)d_in[19];
  const float* up2w = (const float*)d_in[20]; const float* up2b = (const float*)d_in[21];
  const float* og1w = (const float*)d_in[22]; const float* og1b = (const float*)d_in[23];
  const float* og2w = (const float*)d_in[24]; const float* og2b = (const float*)d_in[25];
  const float* os1w = (const float*)d_in[26]; const float* os1b = (const float*)d_in[27];
  const float* os2w = (const float*)d_in[28]; const float* os2b = (const float*)d_in[29];
  float* out = (float*)d_out;

  char* wsp = (char*)d_ws;
  // ---- persistent region (~23.9 MB) ----
  float* part_bn = (float*)(wsp);                 // 131072  [16][2048]
  float* mv      = (float*)(wsp + 131072);        // 8192
  float* gp      = (float*)(wsp + 139264);        // 8192
  float* SG      = (float*)(wsp + 147456);        // 98304
  float* attn    = (float*)(wsp + 245760);        // 98304
  float* sga     = (float*)(wsp + 344064);        // 49152
  float* psga    = (float*)(wsp + 393216);        // 393216 [24][8][512]
  float* peN     = (float*)(wsp + 786432);        // 2097152 [1024][512]
  bf16*  weff    = (bf16*) (wsp + 2883584);       // 2097152 [1024][1024] bf16
  unsigned short* w1sp = (unsigned short*)(wsp + 4980736);   // 12582912 [4][512][3072]
  unsigned short* w2sp = (unsigned short*)(wsp + 17563648);  // 6291456  [4][512][1536]
  char* ov = wsp + 23855104;
  // phase 1 (nonlocal):
  bf16*  xcl  = (bf16*) (ov);                     // 8 MB [4096][1024]
  float* ybuf = (float*)(ov + 8388608);           // 16 MB [4096][1024]
  // phase 1 split-weight staging: lives in the (dead until phase 2) part9 region
  unsigned short* Asp = (unsigned short*)(ov + 36700160);            // 3 MB [1024][1536]
  unsigned short* Bsp = (unsigned short*)(ov + 36700160 + 3145728);  // 3 MB [1024][1536]
  // phase 2 (conv): wtt aliases ybuf (written after last norm2)
  unsigned short* wtt = (unsigned short*)(ov + 8388608);   // 28.3 MB [512][27648]
  float* part9 = (float*)(ov + 36700160);         // 28.9 MB [9][1568][512]
  // frame staging: aliases part9 (written after gp2_k reads part9)
  unsigned short* Fsp = (unsigned short*)(ov + 36700160);  // 9.4 MB [1536][3072]
  // phase 3 (after gp2_k; xcl/wtt dead):
  unsigned short* s1sp = (unsigned short*)(ov);   // 18.9 MB [6144][1536]
  float* scl  = (float*)(ov + 18874368);          // 50.3 MB [24576][512]

  // prep (independent)
  permT_k<bf16><<<dim3(4,16,16),256,0,stream>>>(ctx, xcl, 256, 1024, 1, 1, 262144L, 262144L);
  permTsplit3_k<1><<<dim3(32,16,1),256,0,stream>>>(up1w, w1sp, 2048, 1024, 4, 512, 0L, 0L);
  permTsplit3_k<1><<<dim3(32,8,1),256,0,stream>>>(up2w, w2sp, 2048, 512, 4, 512, 0L, 0L);
  pen_k<<<2048,256,0,stream>>>(peN);

  // nonlocal layers
  for (int l=0;l<2;l++){
    // weff = ow @ vw via split-bf16 MFMA (fp32-accurate products)
    splitA_k<<<2048,256,0,stream>>>(nl_ow[l], Asp);
    permTsplit3_k<1><<<dim3(16,8,1),256,0,stream>>>(nl_vw[l], Bsp, 1024, 512, 1, 1, 0L, 0L);
    mmL_k<2,4><<<dim3(32,8,1),256,0,stream>>>(Asp, Bsp, nullptr, nullptr,
        nullptr, (unsigned short*)weff, 1536);
    mmL_k<4,0><<<dim3(64,8,1),256,0,stream>>>((const unsigned short*)xcl,
        (const unsigned short*)weff, nl_ob[l], (const unsigned short*)xcl,
        ybuf, nullptr, 1024);
    stats2_k<<<dim3(8,16),256,0,stream>>>(ybuf, part_bn);
    stats_comb<<<4,256,0,stream>>>(part_bn, nl_g[l], nl_be[l], mv);
    norm2_k<<<16384,256,0,stream>>>(ybuf, mv, (unsigned short*)xcl);
  }

  // temporal-pool conv (im2col GEMM, K-split 9)
  wperm_k<<<512,256,0,stream>>>(tp_w, wtt);
  mmL_k<4,1><<<dim3(25,4,9),256,0,stream>>>((const unsigned short*)xcl, wtt,
      nullptr, nullptr, part9, nullptr, 3072);
  gp2_k<<<dim3(4,16),256,0,stream>>>(part9, tp_b, gp);

  // frame path (3-block split-bf16 == fp32-accurate); Fsp aliases part9 -> after gp2_k
  permTsplit3_k<0><<<dim3(1,16,24),256,0,stream>>>(frame, Fsp, 64, 1024, 1, 1, 65536L, 196608L);
  mmL_k<2,2><<<dim3(48,4,4),256,0,stream>>>(Fsp, w1sp, up1b, nullptr,
      nullptr, s1sp, 3072);
  mmL_k<4,3><<<dim3(96,4,4),256,0,stream>>>(s1sp, w2sp, up2b, nullptr,
      scl, nullptr, 1536);

  // attention tail
  sg2_k<<<dim3(24,16),256,0,stream>>>(scl, gp, SG);
  softmax_k<<<24,256,0,stream>>>(SG, attn);
  sga2_k<<<dim3(24,8),256,0,stream>>>(scl, peN, attn, psga);
  sga_red<<<24,256,0,stream>>>(psga, sga);

  // heads
  mlp_k<<<4,256,0,stream>>>(gp, og1w, og1b, og2w, og2b, out);
  mlp_k<<<24,256,0,stream>>>(sga, os1w, os1b, os2w, os2b, out + 512);
}

// Round 5
// 713.758 us; speedup vs baseline: 1.1415x; 1.0228x over previous
//
#include <hip/hip_runtime.h>
#include <hip/hip_bf16.h>

using bf16 = __hip_bfloat16;
typedef short short8 __attribute__((ext_vector_type(8)));
typedef float float4v __attribute__((ext_vector_type(4)));

__device__ __forceinline__ float b2f(unsigned short u){
  unsigned int x = ((unsigned int)u) << 16; float f;
  __builtin_memcpy(&f, &x, 4); return f;
}
__device__ __forceinline__ float b2f(bf16 v){ return __bfloat162float(v); }
__device__ __forceinline__ unsigned short f2bu(float x){
  bf16 h = __float2bfloat16(x); unsigned short u;
  __builtin_memcpy(&u, &h, 2); return u;
}

// async global->LDS, 16B per lane, dest = wave-uniform base + lane*16
#define GLDS16(g, l) __builtin_amdgcn_global_load_lds( \
    (const __attribute__((address_space(1))) void*)(g), \
    (__attribute__((address_space(3))) void*)(l), 16, 0, 0)

// -------- batched permuted transpose fp32->bf16: per z, in[R][Cc] -> out[(q%D)*G+q/D][R] -
template<class TO>
__launch_bounds__(256)
__global__ void permT_k(const float* __restrict__ inp, TO* __restrict__ outp,
                        int Cc, int R, int D, int G, long inS, long outS){
  __shared__ float t[64][65];
  int z = blockIdx.z;
  const float* in = inp + (size_t)z*inS;
  TO* out = outp + (size_t)z*outS;
  int c0 = blockIdx.x*64, r0 = blockIdx.y*64;
  int tid = threadIdx.x;
  int rr = tid>>2, c4 = (tid&3)*16;
  const float* p = in + (size_t)(r0+rr)*Cc + c0 + c4;
  #pragma unroll
  for (int j=0;j<16;j+=4){
    float4 q = *reinterpret_cast<const float4*>(p+j);
    t[rr][c4+j]=q.x; t[rr][c4+j+1]=q.y; t[rr][c4+j+2]=q.z; t[rr][c4+j+3]=q.w;
  }
  __syncthreads();
  int ql = tid>>2;
  int q = c0 + ql;
  int orow = (q % D)*G + q / D;
  TO* op = out + (size_t)orow*R + r0 + c4;
  #pragma unroll
  for (int j=0;j<16;j++){
    if constexpr (sizeof(TO)==2) op[j] = __float2bfloat16(t[c4+j][ql]);
    else op[j] = t[c4+j][ql];
  }
}

// -------- 3-block split transpose: rows of length 3R.
// PAT=0 (A-side): blocks (hi, lo, hi).  PAT=1 (B-side): blocks (hi, hi, lo).
// Paired dot over 3R gives ah*bh + al*bh + ah*bl  == fp32-accurate product.
template<int PAT>
__launch_bounds__(256)
__global__ void permTsplit3_k(const float* __restrict__ inp, unsigned short* __restrict__ outp,
                              int Cc, int R, int D, int G, long inS, long outS){
  __shared__ float t[64][65];
  int z = blockIdx.z;
  const float* in = inp + (size_t)z*inS;
  unsigned short* out = outp + (size_t)z*outS;
  int c0 = blockIdx.x*64, r0 = blockIdx.y*64;
  int tid = threadIdx.x;
  int rr = tid>>2, c4 = (tid&3)*16;
  const float* p = in + (size_t)(r0+rr)*Cc + c0 + c4;
  #pragma unroll
  for (int j=0;j<16;j+=4){
    float4 q = *reinterpret_cast<const float4*>(p+j);
    t[rr][c4+j]=q.x; t[rr][c4+j+1]=q.y; t[rr][c4+j+2]=q.z; t[rr][c4+j+3]=q.w;
  }
  __syncthreads();
  int ql = tid>>2;
  int q = c0 + ql;
  int orow = (q % D)*G + q / D;
  unsigned short* op = out + (size_t)orow*(3*R);
  #pragma unroll
  for (int j=0;j<16;j++){
    float v = t[c4+j][ql];
    unsigned short h = f2bu(v);
    unsigned short l = f2bu(v - b2f(h));
    int idx = r0 + c4 + j;
    if constexpr (PAT==0){
      op[idx] = h; op[R+idx] = l; op[2*R+idx] = h;
    } else {
      op[idx] = h; op[R+idx] = h; op[2*R+idx] = l;
    }
  }
}

// -------- row split (no transpose): in[1024][512] fp32 -> out[1024][1536] bf16 (h,l,h) --
__launch_bounds__(256)
__global__ void splitA_k(const float* __restrict__ in, unsigned short* __restrict__ out){
  int idx = blockIdx.x*256 + threadIdx.x;   // 1024*512
  int m = idx >> 9, j = idx & 511;
  float v = in[idx];
  unsigned short h = f2bu(v);
  unsigned short l = f2bu(v - b2f(h));
  unsigned short* op = out + (size_t)m*1536 + j;
  op[0] = h; op[512] = l; op[1024] = h;
}

// ================= unified MFMA GEMM: global_load_lds + dbuf + counted vmcnt =============
// C[m][f] = sum_k A[m][k]*B[f][k], bf16, f-tile 128 (4 waves x 2 n-frags). BK templated:
//   BK=64 for grid-limited kernels (per-step barrier amortization; LDS 40-48KB ok since
//   grid <= 2-3 blocks/CU anyway); BK=32 (24KB LDS -> 6 blocks/CU) for high-grid kernels
//   (conv 3.5/CU, up2 6/CU) where 48KB LDS capped residency at ~2 and cost more than the
//   barrier amortization gained (round-4 lesson).
// LDS image: linear dest slot (16B) = row*CPR + chunk'; swizzle chunk' = c ^ swz(row)
// applied on the GLOBAL source address (m104-safe); swz = (row>>1)&3 @BK32, row&7 @BK64.
// Pipeline (T3/T4 2-phase): stage tile t+1 into buf^1 BEFORE waiting vmcnt(LPT) for tile
// t; loads stay in flight across both raw s_barriers; never drained to 0 in-loop.
// MODE 0: nonlocal (relu(acc+bias)+residual -> fp32, + BN partial col-stats to bnp),
// MODE 1: conv3d im2col K-split z, 2: up1 (relu+bias, convT scatter, 3-block h/l/h out),
// MODE 3: up2 (bias, scatter, fp32), 4: weff = split-A . split-B -> bf16
// MODE 1/2: XCD-aware bijective swizzle (z-major / x / y-minor) -> B slice L2-resident.
template<int MTM, int MODE, int BK>
__launch_bounds__(256)
__global__ void mmL_k(const unsigned short* __restrict__ A,
                      const unsigned short* __restrict__ B,
                      const float* __restrict__ bias,
                      const unsigned short* __restrict__ res,
                      float* __restrict__ outf,
                      unsigned short* __restrict__ outs,
                      float* __restrict__ bnp,
                      int K){
  constexpr int AR  = MTM*16;
  constexpr int CPR = BK/8;            // 16B chunks per row
  constexpr int KS  = BK/32;           // k-subtiles per step
  constexpr int AIT = (AR*CPR)/256;    // A chunks per thread (all used combos >=1)
  constexpr int NB  = (128*CPR)/256;   // B chunks per thread (2 or 4)
  constexpr int LPT = AIT + NB;        // loads in flight per thread per stage
  __shared__ __align__(16) short As[2*AR*BK];
  __shared__ __align__(16) short Bs[2*128*BK];
  const int tid = threadIdx.x;
  const int wv = tid>>6, lane = tid&63, l15 = lane&15, quad = lane>>4;
  const int wbase = wv<<6;             // wave-uniform LDS slot base (64 slots/wave)

  int bx = blockIdx.x, by = blockIdx.y, bz = blockIdx.z;
  if constexpr (MODE==1 || MODE==2){
    const int gx = gridDim.x, gy = gridDim.y, gz = gridDim.z;
    const int n = gx*gy*gz;
    const int lin = bx + gx*(by + gy*bz);
    const int q = n >> 3, r = n & 7;
    const int xcd = lin & 7, j = lin >> 3;
    const int work = (xcd < r ? xcd*(q+1) : r*(q+1) + (xcd-r)*q) + j;
    by = work % gy;                 // y minor
    const int t = work / gy;
    bx = t % gx;                    // x middle
    bz = t / gx;                    // z major (chunk == one kt/kh slice)
  }
  const int m0 = bx*AR;
  const int fblk = by*128;
  const int z = bz;

  auto swz = [](int row){ if constexpr (BK==32) return (row>>1)&3; else return row&7; };

  // ---- staging addresses (source-side swizzle; LDS dest linear: slot = it*256+tid) ----
  size_t aAddr[AIT];
  #pragma unroll
  for (int it=0; it<AIT; ++it){
    int s = tid + it*256;
    int arow = s/CPR;
    int ac = (s&(CPR-1)) ^ swz(arow);
    int m = m0 + arow;
    if constexpr (MODE==1){
      int mm = m < 1568 ? m : 1567;
      int b = mm/392, r = mm%392;
      int t = r/196, r2 = r%196;
      int hh = r2/14, ww = r2%14;
      int kt = z/3, kh = z%3;
      int sp = ((b*4 + t + kt)*16 + hh + kh)*16 + ww;
      aAddr[it] = (size_t)sp*1024 + ac*8;
    } else {
      aAddr[it] = (size_t)m*K + ac*8;
    }
  }
  size_t bAddr[NB];
  #pragma unroll
  for (int it=0; it<NB; ++it){
    int s = tid + it*256;
    int row = s/CPR;
    int c = (s&(CPR-1)) ^ swz(row);
    int f = fblk + row;
    if constexpr (MODE==0)      bAddr[it] = (size_t)f*1024 + c*8;
    else if constexpr (MODE==1) bAddr[it] = (size_t)f*27648 + (size_t)z*3072 + c*8;
    else                        bAddr[it] = ((size_t)z*512 + f)*(size_t)K + c*8;
  }
  // ---- fragment LDS slots (swizzled), per k-subtile ----
  int aslot[MTM][KS];
  #pragma unroll
  for (int mt=0;mt<MTM;++mt)
    #pragma unroll
    for (int ks=0;ks<KS;++ks){
      int row = mt*16 + l15;
      aslot[mt][ks] = row*CPR + ((ks*4 + quad) ^ swz(row));
    }
  int bslot[2][KS];
  #pragma unroll
  for (int nt=0;nt<2;++nt)
    #pragma unroll
    for (int ks=0;ks<KS;++ks){
      int row = wv*32 + nt*16 + l15;
      bslot[nt][ks] = row*CPR + ((ks*4 + quad) ^ swz(row));
    }

  float4v acc[MTM][2];
  #pragma unroll
  for (int i=0;i<MTM;i++){ acc[i][0]=(float4v){0,0,0,0}; acc[i][1]=(float4v){0,0,0,0}; }

  auto stage = [&](int buf, int k0){
    #pragma unroll
    for (int it=0; it<AIT; ++it)
      GLDS16(A + aAddr[it] + k0, As + buf*(AR*BK) + (it*256 + wbase)*8);
    #pragma unroll
    for (int it=0; it<NB; ++it)
      GLDS16(B + bAddr[it] + k0, Bs + buf*(128*BK) + (it*256 + wbase)*8);
  };
  auto computeTile = [&](int buf){
    const short* ap = As + buf*(AR*BK);
    const short* bp = Bs + buf*(128*BK);
    #pragma unroll
    for (int ks=0; ks<KS; ++ks){
      short8 bf0 = *reinterpret_cast<const short8*>(bp + bslot[0][ks]*8);
      short8 bf1 = *reinterpret_cast<const short8*>(bp + bslot[1][ks]*8);
      #pragma unroll
      for (int mt=0;mt<MTM;++mt){
        short8 af = *reinterpret_cast<const short8*>(ap + aslot[mt][ks]*8);
        acc[mt][0] = __builtin_amdgcn_mfma_f32_16x16x32_bf16(af, bf0, acc[mt][0],0,0,0);
        acc[mt][1] = __builtin_amdgcn_mfma_f32_16x16x32_bf16(af, bf1, acc[mt][1],0,0,0);
      }
    }
  };

  stage(0, 0);
  int cur = 0;
  for (int k0 = 0; k0 < K-BK; k0 += BK){
    stage(cur^1, k0+BK);               // tile t+1 in flight across the wait+barriers
    if constexpr (LPT==6)      asm volatile("s_waitcnt vmcnt(6)" ::: "memory");
    else if constexpr (LPT==5) asm volatile("s_waitcnt vmcnt(5)" ::: "memory");
    else                       asm volatile("s_waitcnt vmcnt(3)" ::: "memory");
    __builtin_amdgcn_sched_barrier(0);
    __builtin_amdgcn_s_barrier();      // all waves' tile-t loads landed
    computeTile(cur);
    asm volatile("s_waitcnt lgkmcnt(0)" ::: "memory");
    __builtin_amdgcn_sched_barrier(0);
    __builtin_amdgcn_s_barrier();      // all waves' ds_reads done before buf reuse
    cur ^= 1;
  }
  asm volatile("s_waitcnt vmcnt(0)" ::: "memory");
  __builtin_amdgcn_sched_barrier(0);
  __builtin_amdgcn_s_barrier();
  computeTile(cur);

  if constexpr (MODE==0){
    float sacc[2] = {0.f, 0.f}, s2acc[2] = {0.f, 0.f};
    #pragma unroll
    for (int mt=0;mt<MTM;++mt)
      #pragma unroll
      for (int nt=0;nt<2;++nt){
        int f = fblk + wv*32 + nt*16 + l15;
        float bi = bias[f];
        #pragma unroll
        for (int r=0;r<4;++r){
          int m = m0 + mt*16 + quad*4 + r;
          float v = fmaxf(acc[mt][nt][r]+bi, 0.f) + b2f(res[(size_t)m*1024 + f]);
          outf[(size_t)m*1024 + f] = v;
          sacc[nt] += v; s2acc[nt] += v*v;
        }
      }
    // per-block BN column partials: reduce the 4 quads (m = 64 rows) per f
    #pragma unroll
    for (int nt=0;nt<2;++nt){
      float s = sacc[nt], s2 = s2acc[nt];
      s  += __shfl_xor(s, 16);  s  += __shfl_xor(s, 32);
      s2 += __shfl_xor(s2, 16); s2 += __shfl_xor(s2, 32);
      if (quad==0){
        int f = fblk + wv*32 + nt*16 + l15;
        bnp[(size_t)bx*2048 + f] = s;
        bnp[(size_t)bx*2048 + 1024 + f] = s2;
      }
    }
  } else if constexpr (MODE==1){
    #pragma unroll
    for (int mt=0;mt<MTM;++mt)
      #pragma unroll
      for (int nt=0;nt<2;++nt){
        int f = fblk + wv*32 + nt*16 + l15;
        #pragma unroll
        for (int r=0;r<4;++r){
          int m = m0 + mt*16 + quad*4 + r;
          if (m < 1568) outf[((size_t)z*1568 + m)*512 + f] = acc[mt][nt][r];
        }
      }
  } else if constexpr (MODE==2){
    int kk = z>>1, ll = z&1;
    #pragma unroll
    for (int mt=0;mt<MTM;++mt)
      #pragma unroll
      for (int nt=0;nt<2;++nt){
        int f = fblk + wv*32 + nt*16 + l15;
        float bi = bias[f];
        #pragma unroll
        for (int r=0;r<4;++r){
          int m = m0 + mt*16 + quad*4 + r;
          int bt = m>>6, p = m&63;
          long orow = (long)bt*256 + (2*(p>>3)+kk)*16 + 2*(p&7)+ll;
          float v = fmaxf(acc[mt][nt][r]+bi, 0.f);
          unsigned short h = f2bu(v);
          unsigned short l = f2bu(v - b2f(h));
          unsigned short* rp = outs + (size_t)orow*1536 + f;
          rp[0] = h; rp[512] = l; rp[1024] = h;
        }
      }
  } else if constexpr (MODE==3){
    int kk = z>>1, ll = z&1;
    #pragma unroll
    for (int mt=0;mt<MTM;++mt)
      #pragma unroll
      for (int nt=0;nt<2;++nt){
        int f = fblk + wv*32 + nt*16 + l15;
        float bi = bias[f];
        #pragma unroll
        for (int r=0;r<4;++r){
          int m = m0 + mt*16 + quad*4 + r;
          int bt = m>>8, p = m&255;
          long orow = (long)bt*1024 + (2*(p>>4)+kk)*32 + 2*(p&15)+ll;
          outf[(size_t)orow*512 + f] = acc[mt][nt][r] + bi;
        }
      }
  } else {  // MODE 4: weff bf16 out, no bias
    #pragma unroll
    for (int mt=0;mt<MTM;++mt)
      #pragma unroll
      for (int nt=0;nt<2;++nt){
        int f = fblk + wv*32 + nt*16 + l15;
        #pragma unroll
        for (int r=0;r<4;++r){
          int m = m0 + mt*16 + quad*4 + r;
          outs[(size_t)m*1024 + f] = f2bu(acc[mt][nt][r]);
        }
      }
  }
}

// ---------------- BN stats combine: bnp[64][2][1024] -> scale/shift ---------------------
__global__ void stats_comb(const float* __restrict__ bnp, const float* __restrict__ g,
                           const float* __restrict__ beta, float* __restrict__ mv){
  int c = blockIdx.x*256 + threadIdx.x;   // 1024
  float S=0.f, S2=0.f;
  #pragma unroll 8
  for (int s=0;s<64;s++){ S += bnp[(size_t)s*2048 + c]; S2 += bnp[(size_t)s*2048 + 1024 + c]; }
  float m = S * (1.f/4096.f);
  float var = S2 * (1.f/4096.f) - m*m;
  float inv = rsqrtf(var + 1e-5f);
  float sc = inv * g[c];
  mv[c] = sc;
  mv[1024 + c] = beta[c] - m*sc;
}

__global__ void norm2_k(const float* __restrict__ y, const float* __restrict__ mv,
                        unsigned short* __restrict__ xcl){
  int idx = blockIdx.x*256 + threadIdx.x;
  int c = idx & 1023;
  xcl[idx] = f2bu(y[idx]*mv[c] + mv[1024+c]);
}

// ---------------- weight permute: wtt[f][j*1024+c] = tp_w[f][c*27+j]  (fp32->bf16) ------
__launch_bounds__(256)
__global__ void wperm_k(const float* __restrict__ w, unsigned short* __restrict__ wtt){
  __shared__ float ls[3456];
  int f = blockIdx.x;
  const float* src = w + (size_t)f*27648;
  unsigned short* dst = wtt + (size_t)f*27648;
  for (int cc=0; cc<8; ++cc){
    __syncthreads();
    for (int i=threadIdx.x; i<3456; i+=256) ls[i] = src[cc*3456 + i];
    __syncthreads();
    for (int u=threadIdx.x; u<3456; u+=256){
      int j = u >> 7, c = u & 127;
      dst[(size_t)j*1024 + cc*128 + c] = f2bu(ls[c*27 + j]);
    }
  }
}

// ---------------- goal_pre partials: z splits the 392 positions 4-ways ------------------
__launch_bounds__(256)
__global__ void gp2_k(const float* __restrict__ part9, const float* __restrict__ tpb,
                      float* __restrict__ gpp){
  int b = blockIdx.x;
  int fc = blockIdx.y;
  int z = blockIdx.z;          // 4 p-chunks of 98
  int fi = threadIdx.x & 31, pi = threadIdx.x >> 5;
  int f = fc*32 + fi;
  float bias = tpb[f];
  float a = 0.f;
  for (int p = z*98 + pi; p < z*98 + 98; p += 8){
    size_t base = ((size_t)(b*392 + p))*512 + f;
    float v = bias;
    #pragma unroll
    for (int i=0;i<9;i++) v += part9[(size_t)i*802816 + base];
    a += fmaxf(v, 0.f);
  }
  __shared__ float red[256];
  red[threadIdx.x] = a; __syncthreads();
  for (int st=4; st>0; st>>=1){
    if (pi < st) red[pi*32+fi] += red[(pi+st)*32+fi];
    __syncthreads();
  }
  if (pi==0) gpp[(size_t)z*2048 + b*512 + f] = red[fi];
}

__global__ void gp_comb(const float* __restrict__ gpp, float* __restrict__ gp){
  int idx = blockIdx.x*256 + threadIdx.x;   // 2048
  float s = gpp[idx] + gpp[2048+idx] + gpp[4096+idx] + gpp[6144+idx];
  gp[idx] = s * (1.f/392.f);
}

// ---------------- PE table: peN[n][c] ---------------------------------------------------
__global__ void pen_k(float* __restrict__ peN){
  int idx = blockIdx.x*256 + threadIdx.x;   // 524288
  int n = idx >> 9, c = idx & 511;
  float div = expf(-0.035977892f * (float)(c>>1));   // 2*ln(10000)/512
  float ang = (float)n * div;
  peN[idx] = (c & 1) ? cosf(ang) : sinf(ang);
}

// ---------------- SG[bt][n] = dot(scl[bt*1024+n][:], gp[bt/6][:]) -----------------------
__launch_bounds__(256)
__global__ void sg2_k(const float* __restrict__ scl, const float* __restrict__ gp,
                      float* __restrict__ SG){
  int bt = blockIdx.x, nb = blockIdx.y;   // 24 x 16
  int tid = threadIdx.x;
  int wv = tid >> 6, lane = tid & 63;
  __shared__ float gs[512];
  gs[tid] = gp[(bt/6)*512 + tid];
  gs[tid+256] = gp[(bt/6)*512 + 256 + tid];
  __syncthreads();
  for (int i=0;i<16;i++){
    int n = nb*64 + wv*16 + i;
    const float* row = scl + ((size_t)bt*1024 + n)*512 + lane*8;
    float4 a = *reinterpret_cast<const float4*>(row);
    float4 b = *reinterpret_cast<const float4*>(row+4);
    const float* g = &gs[lane*8];
    float s = a.x*g[0] + a.y*g[1] + a.z*g[2] + a.w*g[3]
            + b.x*g[4] + b.y*g[5] + b.z*g[6] + b.w*g[7];
    #pragma unroll
    for (int off=32; off; off>>=1) s += __shfl_xor(s, off);
    if (lane==0) SG[bt*1024 + n] = s;
  }
}

// ---------------- softmax over n: attn[bt][n] normalized --------------------------------
__launch_bounds__(256)
__global__ void softmax_k(const float* __restrict__ SG, float* __restrict__ attn){
  int bt = blockIdx.x; int tid = threadIdx.x;
  float4 v = *reinterpret_cast<const float4*>(SG + bt*1024 + tid*4);
  float mx = fmaxf(fmaxf(v.x,v.y), fmaxf(v.z,v.w));
  __shared__ float red[256];
  red[tid] = mx; __syncthreads();
  for (int st=128; st>0; st>>=1){
    if (tid<st) red[tid] = fmaxf(red[tid], red[tid+st]);
    __syncthreads();
  }
  float m = red[0]; __syncthreads();
  float4 e;
  e.x = expf(v.x-m); e.y = expf(v.y-m); e.z = expf(v.z-m); e.w = expf(v.w-m);
  red[tid] = e.x+e.y+e.z+e.w; __syncthreads();
  for (int st=128; st>0; st>>=1){
    if (tid<st) red[tid] += red[tid+st];
    __syncthreads();
  }
  float inv = 1.0f/red[0];
  e.x*=inv; e.y*=inv; e.z*=inv; e.w*=inv;
  *reinterpret_cast<float4*>(attn + bt*1024 + tid*4) = e;
}

// ---------------- part_sga[bt][sl][c] = sum_{n in slice} attn[n]*(scl[n][c]+pe[n][c]) ---
__launch_bounds__(256)
__global__ void sga2_k(const float* __restrict__ scl, const float* __restrict__ peN,
                       const float* __restrict__ attn, float* __restrict__ part){
  int bt = blockIdx.x, sl = blockIdx.y;   // 24 x 8
  int tid = threadIdx.x;
  __shared__ float at[128];
  if (tid < 128) at[tid] = attn[bt*1024 + sl*128 + tid];
  __syncthreads();
  float acc0 = 0.f, acc1 = 0.f;
  for (int j=0;j<128;j++){
    int n = sl*128 + j;
    float a = at[j];
    const float* row = scl + ((size_t)bt*1024 + n)*512;
    const float* pe  = peN + (size_t)n*512;
    acc0 += a * (row[tid] + pe[tid]);
    acc1 += a * (row[tid+256] + pe[tid+256]);
  }
  part[((size_t)bt*8 + sl)*512 + tid] = acc0;
  part[((size_t)bt*8 + sl)*512 + tid + 256] = acc1;
}

__global__ void sga_red(const float* __restrict__ part, float* __restrict__ sga){
  int bt = blockIdx.x; int tid = threadIdx.x;
  #pragma unroll
  for (int h=0; h<2; ++h){
    int c = tid + h*256;
    float s = 0.f;
    #pragma unroll
    for (int sl=0; sl<8; ++sl) s += part[((size_t)bt*8 + sl)*512 + c];
    sga[(size_t)bt*512 + c] = s;
  }
}

// ---------------- 512->512(relu)->128 MLP head (fp32 weights) ---------------------------
__launch_bounds__(256)
__global__ void mlp_k(const float* __restrict__ in, const float* __restrict__ w1,
                      const float* __restrict__ b1, const float* __restrict__ w2,
                      const float* __restrict__ b2, float* __restrict__ out){
  int bb = blockIdx.x; int tid = threadIdx.x;
  __shared__ float xv[512]; __shared__ float h[512];
  xv[tid] = in[(size_t)bb*512 + tid];
  xv[tid+256] = in[(size_t)bb*512 + 256 + tid];
  __syncthreads();
  #pragma unroll
  for (int oo=0;oo<2;oo++){
    int o = tid + oo*256;
    const float* wr = w1 + (size_t)o*512;
    float a=0.f;
    for (int c=0;c<512;c+=4){
      float4 q = *reinterpret_cast<const float4*>(wr+c);
      a += xv[c]*q.x + xv[c+1]*q.y + xv[c+2]*q.z + xv[c+3]*q.w;
    }
    h[o] = fmaxf(a + b1[o], 0.f);
  }
  __syncthreads();
  if (tid < 128){
    const float* wr = w2 + (size_t)tid*512;
    float a=0.f;
    for (int c=0;c<512;c+=4){
      float4 q = *reinterpret_cast<const float4*>(wr+c);
      a += h[c]*q.x + h[c+1]*q.y + h[c+2]*q.z + h[c+3]*q.w;
    }
    out[(size_t)bb*128+tid] = a + b2[tid];
  }
}

extern "C" void kernel_launch(void* const* d_in, const int* in_sizes, int n_in,
                              void* d_out, int out_size, void* d_ws, size_t ws_size,
                              hipStream_t stream){
  (void)in_sizes; (void)n_in; (void)out_size; (void)ws_size;
  const float* ctx   = (const float*)d_in[0];
  const float* frame = (const float*)d_in[1];
  const float* nl_vw[2] = {(const float*)d_in[4],  (const float*)d_in[11]};
  const float* nl_ow[2] = {(const float*)d_in[5],  (const float*)d_in[12]};
  const float* nl_ob[2] = {(const float*)d_in[6],  (const float*)d_in[13]};
  const float* nl_g[2]  = {(const float*)d_in[7],  (const float*)d_in[14]};
  const float* nl_be[2] = {(const float*)d_in[8],  (const float*)d_in[15]};
  const float* tp_w = (const float*)d_in[16]; const float* tp_b = (const float*)d_in[17];
  const float* up1w = (const float*)d_in[18]; const float* up1b = (const float*)d_in[19];
  const float* up2w = (const float*)d_in[20]; const float* up2b = (const float*)d_in[21];
  const float* og1w = (const float*)d_in[22]; const float* og1b = (const float*)d_in[23];
  const float* og2w = (const float*)d_in[24]; const float* og2b = (const float*)d_in[25];
  const float* os1w = (const float*)d_in[26]; const float* os1b = (const float*)d_in[27];
  const float* os2w = (const float*)d_in[28]; const float* os2b = (const float*)d_in[29];
  float* out = (float*)d_out;

  char* wsp = (char*)d_ws;
  // ---- persistent region (~23.9 MB) ----
  float* gpp     = (float*)(wsp);                 // 32768 [4][4][512] (old part_bn slot)
  float* mv      = (float*)(wsp + 131072);        // 8192
  float* gp      = (float*)(wsp + 139264);        // 8192
  float* SG      = (float*)(wsp + 147456);        // 98304
  float* attn    = (float*)(wsp + 245760);        // 98304
  float* sga     = (float*)(wsp + 344064);        // 49152
  float* psga    = (float*)(wsp + 393216);        // 393216 [24][8][512]
  float* peN     = (float*)(wsp + 786432);        // 2097152 [1024][512]
  bf16*  weff    = (bf16*) (wsp + 2883584);       // 2097152 [1024][1024] bf16
  unsigned short* w1sp = (unsigned short*)(wsp + 4980736);   // 12582912 [4][512][3072]
  unsigned short* w2sp = (unsigned short*)(wsp + 17563648);  // 6291456  [4][512][1536]
  char* ov = wsp + 23855104;
  // phase 1 (nonlocal):
  bf16*  xcl  = (bf16*) (ov);                     // 8 MB [4096][1024]
  float* ybuf = (float*)(ov + 8388608);           // 16 MB [4096][1024]
  // phase 1 staging in the (dead until phase 2) part9 region:
  unsigned short* Asp = (unsigned short*)(ov + 36700160);            // 3 MB [1024][1536]
  unsigned short* Bsp = (unsigned short*)(ov + 36700160 + 3145728);  // 3 MB [1024][1536]
  float* bnp = (float*)(ov + 36700160 + 6291456); // 512 KB [64][2][1024] BN partials
  // phase 2 (conv): wtt aliases ybuf (written after last norm2)
  unsigned short* wtt = (unsigned short*)(ov + 8388608);   // 28.3 MB [512][27648]
  float* part9 = (float*)(ov + 36700160);         // 28.9 MB [9][1568][512]
  // frame staging: aliases part9 (written after gp2_k reads part9)
  unsigned short* Fsp = (unsigned short*)(ov + 36700160);  // 9.4 MB [1536][3072]
  // phase 3 (after gp2_k; xcl/wtt dead):
  unsigned short* s1sp = (unsigned short*)(ov);   // 18.9 MB [6144][1536]
  float* scl  = (float*)(ov + 18874368);          // 50.3 MB [24576][512]

  // prep (independent)
  permT_k<bf16><<<dim3(4,16,16),256,0,stream>>>(ctx, xcl, 256, 1024, 1, 1, 262144L, 262144L);
  permTsplit3_k<1><<<dim3(32,16,1),256,0,stream>>>(up1w, w1sp, 2048, 1024, 4, 512, 0L, 0L);
  permTsplit3_k<1><<<dim3(32,8,1),256,0,stream>>>(up2w, w2sp, 2048, 512, 4, 512, 0L, 0L);
  pen_k<<<2048,256,0,stream>>>(peN);

  // nonlocal layers
  for (int l=0;l<2;l++){
    // weff = ow @ vw via split-bf16 MFMA (fp32-accurate products)
    splitA_k<<<2048,256,0,stream>>>(nl_ow[l], Asp);
    permTsplit3_k<1><<<dim3(16,8,1),256,0,stream>>>(nl_vw[l], Bsp, 1024, 512, 1, 1, 0L, 0L);
    mmL_k<2,4,64><<<dim3(32,8,1),256,0,stream>>>(Asp, Bsp, nullptr, nullptr,
        nullptr, (unsigned short*)weff, nullptr, 1536);
    mmL_k<4,0,64><<<dim3(64,8,1),256,0,stream>>>((const unsigned short*)xcl,
        (const unsigned short*)weff, nl_ob[l], (const unsigned short*)xcl,
        ybuf, nullptr, bnp, 1024);
    stats_comb<<<4,256,0,stream>>>(bnp, nl_g[l], nl_be[l], mv);
    norm2_k<<<16384,256,0,stream>>>(ybuf, mv, (unsigned short*)xcl);
  }

  // temporal-pool conv (im2col GEMM, K-split 9) -- BK=32: 24KB LDS keeps 3.5 blocks/CU resident
  wperm_k<<<512,256,0,stream>>>(tp_w, wtt);
  mmL_k<4,1,32><<<dim3(25,4,9),256,0,stream>>>((const unsigned short*)xcl, wtt,
      nullptr, nullptr, part9, nullptr, nullptr, 3072);
  gp2_k<<<dim3(4,16,4),256,0,stream>>>(part9, tp_b, gpp);
  gp_comb<<<8,256,0,stream>>>(gpp, gp);

  // frame path (3-block split-bf16 == fp32-accurate); Fsp aliases part9 -> after gp2_k
  permTsplit3_k<0><<<dim3(1,16,24),256,0,stream>>>(frame, Fsp, 64, 1024, 1, 1, 65536L, 196608L);
  mmL_k<2,2,64><<<dim3(48,4,4),256,0,stream>>>(Fsp, w1sp, up1b, nullptr,
      nullptr, s1sp, nullptr, 3072);
  mmL_k<4,3,32><<<dim3(96,4,4),256,0,stream>>>(s1sp, w2sp, up2b, nullptr,
      scl, nullptr, nullptr, 1536);

  // attention tail
  sg2_k<<<dim3(24,16),256,0,stream>>>(scl, gp, SG);
  softmax_k<<<24,256,0,stream>>>(SG, attn);
  sga2_k<<<dim3(24,8),256,0,stream>>>(scl, peN, attn, psga);
  sga_red<<<24,256,0,stream>>>(psga, sga);

  // heads
  mlp_k<<<4,256,0,stream>>>(gp, og1w, og1b, og2w, og2b, out);
  mlp_k<<<24,256,0,stream>>>(sga, os1w, os1b, os2w, os2b, out + 512);
}

// Round 6
// 682.042 us; speedup vs baseline: 1.1946x; 1.0465x over previous
//
#include <hip/hip_runtime.h>
#include <hip/hip_bf16.h>

using bf16 = __hip_bfloat16;
typedef short short8 __attribute__((ext_vector_type(8)));
typedef float float4v __attribute__((ext_vector_type(4)));

__device__ __forceinline__ float b2f(unsigned short u){
  unsigned int x = ((unsigned int)u) << 16; float f;
  __builtin_memcpy(&f, &x, 4); return f;
}
__device__ __forceinline__ float b2f(bf16 v){ return __bfloat162float(v); }
__device__ __forceinline__ unsigned short f2bu(float x){
  bf16 h = __float2bfloat16(x); unsigned short u;
  __builtin_memcpy(&u, &h, 2); return u;
}

// async global->LDS, 16B per lane, dest = wave-uniform base + lane*16
#define GLDS16(g, l) __builtin_amdgcn_global_load_lds( \
    (const __attribute__((address_space(1))) void*)(g), \
    (__attribute__((address_space(3))) void*)(l), 16, 0, 0)

// -------- batched permuted transpose fp32->bf16: per z, in[R][Cc] -> out[(q%D)*G+q/D][R] -
template<class TO>
__launch_bounds__(256)
__global__ void permT_k(const float* __restrict__ inp, TO* __restrict__ outp,
                        int Cc, int R, int D, int G, long inS, long outS){
  __shared__ float t[64][65];
  int z = blockIdx.z;
  const float* in = inp + (size_t)z*inS;
  TO* out = outp + (size_t)z*outS;
  int c0 = blockIdx.x*64, r0 = blockIdx.y*64;
  int tid = threadIdx.x;
  int rr = tid>>2, c4 = (tid&3)*16;
  const float* p = in + (size_t)(r0+rr)*Cc + c0 + c4;
  #pragma unroll
  for (int j=0;j<16;j+=4){
    float4 q = *reinterpret_cast<const float4*>(p+j);
    t[rr][c4+j]=q.x; t[rr][c4+j+1]=q.y; t[rr][c4+j+2]=q.z; t[rr][c4+j+3]=q.w;
  }
  __syncthreads();
  int ql = tid>>2;
  int q = c0 + ql;
  int orow = (q % D)*G + q / D;
  TO* op = out + (size_t)orow*R + r0 + c4;
  #pragma unroll
  for (int j=0;j<16;j++){
    if constexpr (sizeof(TO)==2) op[j] = __float2bfloat16(t[c4+j][ql]);
    else op[j] = t[c4+j][ql];
  }
}

// -------- 3-block split transpose: rows of length 3R.
// PAT=0 (A-side): blocks (hi, lo, hi).  PAT=1 (B-side): blocks (hi, hi, lo).
// Paired dot over 3R gives ah*bh + al*bh + ah*bl  == fp32-accurate product.
template<int PAT>
__launch_bounds__(256)
__global__ void permTsplit3_k(const float* __restrict__ inp, unsigned short* __restrict__ outp,
                              int Cc, int R, int D, int G, long inS, long outS){
  __shared__ float t[64][65];
  int z = blockIdx.z;
  const float* in = inp + (size_t)z*inS;
  unsigned short* out = outp + (size_t)z*outS;
  int c0 = blockIdx.x*64, r0 = blockIdx.y*64;
  int tid = threadIdx.x;
  int rr = tid>>2, c4 = (tid&3)*16;
  const float* p = in + (size_t)(r0+rr)*Cc + c0 + c4;
  #pragma unroll
  for (int j=0;j<16;j+=4){
    float4 q = *reinterpret_cast<const float4*>(p+j);
    t[rr][c4+j]=q.x; t[rr][c4+j+1]=q.y; t[rr][c4+j+2]=q.z; t[rr][c4+j+3]=q.w;
  }
  __syncthreads();
  int ql = tid>>2;
  int q = c0 + ql;
  int orow = (q % D)*G + q / D;
  unsigned short* op = out + (size_t)orow*(3*R);
  #pragma unroll
  for (int j=0;j<16;j++){
    float v = t[c4+j][ql];
    unsigned short h = f2bu(v);
    unsigned short l = f2bu(v - b2f(h));
    int idx = r0 + c4 + j;
    if constexpr (PAT==0){
      op[idx] = h; op[R+idx] = l; op[2*R+idx] = h;
    } else {
      op[idx] = h; op[R+idx] = h; op[2*R+idx] = l;
    }
  }
}

// -------- row split (no transpose): in[1024][512] fp32 -> out[1024][1536] bf16 (h,l,h) --
__launch_bounds__(256)
__global__ void splitA_k(const float* __restrict__ in, unsigned short* __restrict__ out){
  int idx = blockIdx.x*256 + threadIdx.x;   // 1024*512
  int m = idx >> 9, j = idx & 511;
  float v = in[idx];
  unsigned short h = f2bu(v);
  unsigned short l = f2bu(v - b2f(h));
  unsigned short* op = out + (size_t)m*1536 + j;
  op[0] = h; op[512] = l; op[1024] = h;
}

__global__ void zero_k(float* __restrict__ p){
  p[blockIdx.x*256 + threadIdx.x] = 0.f;
}

// ================= unified MFMA GEMM: global_load_lds + dbuf + counted vmcnt =============
// C[m][f] = sum_k A[m][k]*B[f][k], bf16. Wave layout templated: WM x WN waves, each wave
// owns a (MTM*16) x (NTN*16) output tile. Block tile BM=WM*MTM*16, BN=WN*NTN*16.
//   1x4 waves / 64x32 per wave for M- or f-rich kernels needing many blocks;
//   2x2 waves / 64x64 per wave (128x128 block) for LDS-read-bound kernels (conv, up2):
//   LDS bytes/MFMA drops 0.75 -> 0.5 KB (round-5 analysis: conv is LDS-throughput-bound).
// LDS image: linear dest slot (16B) = row*CPR + chunk'; swizzle chunk' = c ^ swz(row)
// applied on the GLOBAL source address (m104-safe); swz = (row>>1)&3 @BK32, row&7 @BK64.
// Pipeline (T3/T4 2-phase): stage tile t+1 into buf^1 BEFORE waiting vmcnt(LPT) for tile
// t; loads stay in flight across both raw s_barriers; never drained to 0 in-loop.
// MODE 0: nonlocal (relu(acc+bias)+residual -> fp32, + BN partial col-stats to aux),
// MODE 1: conv3d im2col K-split z, 2: up1 (relu+bias, convT scatter, 3-block h/l/h out),
// MODE 4: weff = split-A . split-B -> bf16
// MODE 5: up2 (bias, scatter, fp32) + fused SG partial dot vs gpf -> atomicAdd aux
// MODE 1: XCD-aware bijective swizzle (z-major / x / y-minor) -> B slice L2-resident.
template<int WM, int WN, int MTM, int NTN, int MODE, int BK>
__launch_bounds__(256)
__global__ void mmL_k(const unsigned short* __restrict__ A,
                      const unsigned short* __restrict__ B,
                      const float* __restrict__ bias,
                      const unsigned short* __restrict__ res,
                      const float* __restrict__ gpf,
                      float* __restrict__ outf,
                      unsigned short* __restrict__ outs,
                      float* __restrict__ aux,
                      int K){
  constexpr int BM  = WM*MTM*16;
  constexpr int BN  = WN*NTN*16;
  constexpr int CPR = BK/8;            // 16B chunks per row
  constexpr int KS  = BK/32;           // k-subtiles per step
  constexpr int AIT = (BM*CPR)/256;    // A chunks per thread (>=1 in all instantiations)
  constexpr int NBC = (BN*CPR)/256;    // B chunks per thread
  constexpr int LPT = AIT + NBC;       // loads in flight per thread per stage
  __shared__ __align__(16) short As[2*BM*BK];
  __shared__ __align__(16) short Bs[2*BN*BK];
  const int tid = threadIdx.x;
  const int wv = tid>>6, lane = tid&63, l15 = lane&15, quad = lane>>4;
  const int wvm = wv / WN, wvf = wv % WN;
  const int wbase = wv<<6;             // wave-uniform LDS slot base (64 slots/wave)

  int bx = blockIdx.x, by = blockIdx.y, bz = blockIdx.z;
  if constexpr (MODE==1){
    const int gx = gridDim.x, gy = gridDim.y, gz = gridDim.z;
    const int n = gx*gy*gz;
    const int lin = bx + gx*(by + gy*bz);
    const int q = n >> 3, r = n & 7;
    const int xcd = lin & 7, j = lin >> 3;
    const int work = (xcd < r ? xcd*(q+1) : r*(q+1) + (xcd-r)*q) + j;
    by = work % gy;                 // y minor
    const int t = work / gy;
    bx = t % gx;                    // x middle
    bz = t / gx;                    // z major (chunk == one kt/kh slice)
  }
  const int m0 = bx*BM;
  const int fblk = by*BN;
  const int z = bz;

  auto swz = [](int row){ if constexpr (BK==32) return (row>>1)&3; else return row&7; };

  // ---- staging addresses (source-side swizzle; LDS dest linear: slot = it*256+tid) ----
  size_t aAddr[AIT];
  #pragma unroll
  for (int it=0; it<AIT; ++it){
    int s = tid + it*256;
    int arow = s/CPR;
    int ac = (s&(CPR-1)) ^ swz(arow);
    int m = m0 + arow;
    if constexpr (MODE==1){
      int mm = m < 1568 ? m : 1567;
      int b = mm/392, r = mm%392;
      int t = r/196, r2 = r%196;
      int hh = r2/14, ww = r2%14;
      int kt = z/3, kh = z%3;
      int sp = ((b*4 + t + kt)*16 + hh + kh)*16 + ww;
      aAddr[it] = (size_t)sp*1024 + ac*8;
    } else {
      aAddr[it] = (size_t)m*K + ac*8;
    }
  }
  size_t bAddr[NBC];
  #pragma unroll
  for (int it=0; it<NBC; ++it){
    int s = tid + it*256;
    int row = s/CPR;
    int c = (s&(CPR-1)) ^ swz(row);
    int f = fblk + row;
    if constexpr (MODE==0)      bAddr[it] = (size_t)f*1024 + c*8;
    else if constexpr (MODE==1) bAddr[it] = (size_t)f*27648 + (size_t)z*3072 + c*8;
    else                        bAddr[it] = ((size_t)z*512 + f)*(size_t)K + c*8;
  }
  // ---- fragment LDS slots (swizzled), per k-subtile ----
  int aslot[MTM][KS];
  #pragma unroll
  for (int mt=0;mt<MTM;++mt)
    #pragma unroll
    for (int ks=0;ks<KS;++ks){
      int row = wvm*MTM*16 + mt*16 + l15;
      aslot[mt][ks] = row*CPR + ((ks*4 + quad) ^ swz(row));
    }
  int bslot[NTN][KS];
  #pragma unroll
  for (int nt=0;nt<NTN;++nt)
    #pragma unroll
    for (int ks=0;ks<KS;++ks){
      int row = wvf*NTN*16 + nt*16 + l15;
      bslot[nt][ks] = row*CPR + ((ks*4 + quad) ^ swz(row));
    }

  float4v acc[MTM][NTN];
  #pragma unroll
  for (int i=0;i<MTM;i++)
    #pragma unroll
    for (int j=0;j<NTN;j++) acc[i][j]=(float4v){0,0,0,0};

  auto stage = [&](int buf, int k0){
    #pragma unroll
    for (int it=0; it<AIT; ++it)
      GLDS16(A + aAddr[it] + k0, As + buf*(BM*BK) + (it*256 + wbase)*8);
    #pragma unroll
    for (int it=0; it<NBC; ++it)
      GLDS16(B + bAddr[it] + k0, Bs + buf*(BN*BK) + (it*256 + wbase)*8);
  };
  auto computeTile = [&](int buf){
    const short* ap = As + buf*(BM*BK);
    const short* bp = Bs + buf*(BN*BK);
    #pragma unroll
    for (int ks=0; ks<KS; ++ks){
      short8 bf[NTN];
      #pragma unroll
      for (int nt=0;nt<NTN;++nt)
        bf[nt] = *reinterpret_cast<const short8*>(bp + bslot[nt][ks]*8);
      #pragma unroll
      for (int mt=0;mt<MTM;++mt){
        short8 af = *reinterpret_cast<const short8*>(ap + aslot[mt][ks]*8);
        #pragma unroll
        for (int nt=0;nt<NTN;++nt)
          acc[mt][nt] = __builtin_amdgcn_mfma_f32_16x16x32_bf16(af, bf[nt], acc[mt][nt],0,0,0);
      }
    }
  };

  stage(0, 0);
  int cur = 0;
  for (int k0 = 0; k0 < K-BK; k0 += BK){
    stage(cur^1, k0+BK);               // tile t+1 in flight across the wait+barriers
    if constexpr (LPT==6)      asm volatile("s_waitcnt vmcnt(6)" ::: "memory");
    else if constexpr (LPT==5) asm volatile("s_waitcnt vmcnt(5)" ::: "memory");
    else if constexpr (LPT==4) asm volatile("s_waitcnt vmcnt(4)" ::: "memory");
    else                       asm volatile("s_waitcnt vmcnt(3)" ::: "memory");
    __builtin_amdgcn_sched_barrier(0);
    __builtin_amdgcn_s_barrier();      // all waves' tile-t loads landed
    computeTile(cur);
    asm volatile("s_waitcnt lgkmcnt(0)" ::: "memory");
    __builtin_amdgcn_sched_barrier(0);
    __builtin_amdgcn_s_barrier();      // all waves' ds_reads done before buf reuse
    cur ^= 1;
  }
  asm volatile("s_waitcnt vmcnt(0)" ::: "memory");
  __builtin_amdgcn_sched_barrier(0);
  __builtin_amdgcn_s_barrier();
  computeTile(cur);

  if constexpr (MODE==0){
    float sacc[NTN] = {}, s2acc[NTN] = {};
    #pragma unroll
    for (int mt=0;mt<MTM;++mt)
      #pragma unroll
      for (int nt=0;nt<NTN;++nt){
        int f = fblk + wvf*NTN*16 + nt*16 + l15;
        float bi = bias[f];
        #pragma unroll
        for (int r=0;r<4;++r){
          int m = m0 + wvm*MTM*16 + mt*16 + quad*4 + r;
          float v = fmaxf(acc[mt][nt][r]+bi, 0.f) + b2f(res[(size_t)m*1024 + f]);
          outf[(size_t)m*1024 + f] = v;
          sacc[nt] += v; s2acc[nt] += v*v;
        }
      }
    // per-block BN column partials: reduce the 4 quads (64 rows) per f
    #pragma unroll
    for (int nt=0;nt<NTN;++nt){
      float s = sacc[nt], s2 = s2acc[nt];
      s  += __shfl_xor(s, 16);  s  += __shfl_xor(s, 32);
      s2 += __shfl_xor(s2, 16); s2 += __shfl_xor(s2, 32);
      if (quad==0){
        int f = fblk + wvf*NTN*16 + nt*16 + l15;
        aux[(size_t)bx*2048 + f] = s;
        aux[(size_t)bx*2048 + 1024 + f] = s2;
      }
    }
  } else if constexpr (MODE==1){
    #pragma unroll
    for (int mt=0;mt<MTM;++mt)
      #pragma unroll
      for (int nt=0;nt<NTN;++nt){
        int f = fblk + wvf*NTN*16 + nt*16 + l15;
        #pragma unroll
        for (int r=0;r<4;++r){
          int m = m0 + wvm*MTM*16 + mt*16 + quad*4 + r;
          if (m < 1568) outf[((size_t)z*1568 + m)*512 + f] = acc[mt][nt][r];
        }
      }
  } else if constexpr (MODE==2){
    int kk = z>>1, ll = z&1;
    #pragma unroll
    for (int mt=0;mt<MTM;++mt)
      #pragma unroll
      for (int nt=0;nt<NTN;++nt){
        int f = fblk + wvf*NTN*16 + nt*16 + l15;
        float bi = bias[f];
        #pragma unroll
        for (int r=0;r<4;++r){
          int m = m0 + wvm*MTM*16 + mt*16 + quad*4 + r;
          int bt = m>>6, p = m&63;
          long orow = (long)bt*256 + (2*(p>>3)+kk)*16 + 2*(p&7)+ll;
          float v = fmaxf(acc[mt][nt][r]+bi, 0.f);
          unsigned short h = f2bu(v);
          unsigned short l = f2bu(v - b2f(h));
          unsigned short* rp = outs + (size_t)orow*1536 + f;
          rp[0] = h; rp[512] = l; rp[1024] = h;
        }
      }
  } else if constexpr (MODE==5){
    int kk = z>>1, ll = z&1;
    #pragma unroll
    for (int mt=0;mt<MTM;++mt){
      int mbase = m0 + wvm*MTM*16 + mt*16;
      int bt = mbase>>8, b6 = bt/6, p0 = mbase&255;
      float gv[NTN], bv[NTN];
      #pragma unroll
      for (int nt=0;nt<NTN;++nt){
        int f = fblk + wvf*NTN*16 + nt*16 + l15;
        gv[nt] = gpf[b6*512 + f];
        bv[nt] = bias[f];
      }
      #pragma unroll
      for (int r=0;r<4;++r){
        int p = p0 + quad*4 + r;
        long orow = (long)bt*1024 + (2*(p>>4)+kk)*32 + 2*(p&15)+ll;
        float sdot = 0.f;
        #pragma unroll
        for (int nt=0;nt<NTN;++nt){
          int f = fblk + wvf*NTN*16 + nt*16 + l15;
          float v = acc[mt][nt][r] + bv[nt];
          outf[(size_t)orow*512 + f] = v;
          sdot += v * gv[nt];
        }
        sdot += __shfl_xor(sdot, 1); sdot += __shfl_xor(sdot, 2);
        sdot += __shfl_xor(sdot, 4); sdot += __shfl_xor(sdot, 8);
        if (l15==0) atomicAdd(aux + orow, sdot);
      }
    }
  } else {  // MODE 4: weff bf16 out, no bias
    #pragma unroll
    for (int mt=0;mt<MTM;++mt)
      #pragma unroll
      for (int nt=0;nt<NTN;++nt){
        int f = fblk + wvf*NTN*16 + nt*16 + l15;
        #pragma unroll
        for (int r=0;r<4;++r){
          int m = m0 + wvm*MTM*16 + mt*16 + quad*4 + r;
          outs[(size_t)m*1024 + f] = f2bu(acc[mt][nt][r]);
        }
      }
  }
}

// ---------------- BN stats combine: bnp[64][2][1024] -> scale/shift ---------------------
__global__ void stats_comb(const float* __restrict__ bnp, const float* __restrict__ g,
                           const float* __restrict__ beta, float* __restrict__ mv){
  int c = blockIdx.x*256 + threadIdx.x;   // 1024
  float S=0.f, S2=0.f;
  #pragma unroll 8
  for (int s=0;s<64;s++){ S += bnp[(size_t)s*2048 + c]; S2 += bnp[(size_t)s*2048 + 1024 + c]; }
  float m = S * (1.f/4096.f);
  float var = S2 * (1.f/4096.f) - m*m;
  float inv = rsqrtf(var + 1e-5f);
  float sc = inv * g[c];
  mv[c] = sc;
  mv[1024 + c] = beta[c] - m*sc;
}

__global__ void norm2_k(const float* __restrict__ y, const float* __restrict__ mv,
                        unsigned short* __restrict__ xcl){
  int idx = blockIdx.x*256 + threadIdx.x;
  int c = idx & 1023;
  xcl[idx] = f2bu(y[idx]*mv[c] + mv[1024+c]);
}

// ---------------- weight permute: wtt[f][j*1024+c] = tp_w[f][c*27+j]  (fp32->bf16) ------
__launch_bounds__(256)
__global__ void wperm_k(const float* __restrict__ w, unsigned short* __restrict__ wtt){
  __shared__ float ls[3456];
  int f = blockIdx.x;
  const float* src = w + (size_t)f*27648;
  unsigned short* dst = wtt + (size_t)f*27648;
  for (int cc=0; cc<8; ++cc){
    __syncthreads();
    for (int i=threadIdx.x; i<3456; i+=256) ls[i] = src[cc*3456 + i];
    __syncthreads();
    for (int u=threadIdx.x; u<3456; u+=256){
      int j = u >> 7, c = u & 127;
      dst[(size_t)j*1024 + cc*128 + c] = f2bu(ls[c*27 + j]);
    }
  }
}

// ---------------- goal_pre partials: z splits the 392 positions 4-ways ------------------
__launch_bounds__(256)
__global__ void gp2_k(const float* __restrict__ part9, const float* __restrict__ tpb,
                      float* __restrict__ gpp){
  int b = blockIdx.x;
  int fc = blockIdx.y;
  int z = blockIdx.z;          // 4 p-chunks of 98
  int fi = threadIdx.x & 31, pi = threadIdx.x >> 5;
  int f = fc*32 + fi;
  float bias = tpb[f];
  float a = 0.f;
  for (int p = z*98 + pi; p < z*98 + 98; p += 8){
    size_t base = ((size_t)(b*392 + p))*512 + f;
    float v = bias;
    #pragma unroll
    for (int i=0;i<9;i++) v += part9[(size_t)i*802816 + base];
    a += fmaxf(v, 0.f);
  }
  __shared__ float red[256];
  red[threadIdx.x] = a; __syncthreads();
  for (int st=4; st>0; st>>=1){
    if (pi < st) red[pi*32+fi] += red[(pi+st)*32+fi];
    __syncthreads();
  }
  if (pi==0) gpp[(size_t)z*2048 + b*512 + f] = red[fi];
}

__global__ void gp_comb(const float* __restrict__ gpp, float* __restrict__ gp){
  int idx = blockIdx.x*256 + threadIdx.x;   // 2048
  float s = gpp[idx] + gpp[2048+idx] + gpp[4096+idx] + gpp[6144+idx];
  gp[idx] = s * (1.f/392.f);
}

// ---------------- PE table: peN[n][c] ---------------------------------------------------
__global__ void pen_k(float* __restrict__ peN){
  int idx = blockIdx.x*256 + threadIdx.x;   // 524288
  int n = idx >> 9, c = idx & 511;
  float div = expf(-0.035977892f * (float)(c>>1));   // 2*ln(10000)/512
  float ang = (float)n * div;
  peN[idx] = (c & 1) ? cosf(ang) : sinf(ang);
}

// ---------------- softmax over n: attn[bt][n] normalized --------------------------------
__launch_bounds__(256)
__global__ void softmax_k(const float* __restrict__ SG, float* __restrict__ attn){
  int bt = blockIdx.x; int tid = threadIdx.x;
  float4 v = *reinterpret_cast<const float4*>(SG + bt*1024 + tid*4);
  float mx = fmaxf(fmaxf(v.x,v.y), fmaxf(v.z,v.w));
  __shared__ float red[256];
  red[tid] = mx; __syncthreads();
  for (int st=128; st>0; st>>=1){
    if (tid<st) red[tid] = fmaxf(red[tid], red[tid+st]);
    __syncthreads();
  }
  float m = red[0]; __syncthreads();
  float4 e;
  e.x = expf(v.x-m); e.y = expf(v.y-m); e.z = expf(v.z-m); e.w = expf(v.w-m);
  red[tid] = e.x+e.y+e.z+e.w; __syncthreads();
  for (int st=128; st>0; st>>=1){
    if (tid<st) red[tid] += red[tid+st];
    __syncthreads();
  }
  float inv = 1.0f/red[0];
  e.x*=inv; e.y*=inv; e.z*=inv; e.w*=inv;
  *reinterpret_cast<float4*>(attn + bt*1024 + tid*4) = e;
}

// ---------------- part_sga[bt][sl][c] = sum_{n in slice} attn[n]*(scl[n][c]+pe[n][c]) ---
__launch_bounds__(256)
__global__ void sga2_k(const float* __restrict__ scl, const float* __restrict__ peN,
                       const float* __restrict__ attn, float* __restrict__ part){
  int bt = blockIdx.x, sl = blockIdx.y;   // 24 x 8
  int tid = threadIdx.x;
  __shared__ float at[128];
  if (tid < 128) at[tid] = attn[bt*1024 + sl*128 + tid];
  __syncthreads();
  float acc0 = 0.f, acc1 = 0.f;
  for (int j=0;j<128;j++){
    int n = sl*128 + j;
    float a = at[j];
    const float* row = scl + ((size_t)bt*1024 + n)*512;
    const float* pe  = peN + (size_t)n*512;
    acc0 += a * (row[tid] + pe[tid]);
    acc1 += a * (row[tid+256] + pe[tid+256]);
  }
  part[((size_t)bt*8 + sl)*512 + tid] = acc0;
  part[((size_t)bt*8 + sl)*512 + tid + 256] = acc1;
}

__global__ void sga_red(const float* __restrict__ part, float* __restrict__ sga){
  int bt = blockIdx.x; int tid = threadIdx.x;
  #pragma unroll
  for (int h=0; h<2; ++h){
    int c = tid + h*256;
    float s = 0.f;
    #pragma unroll
    for (int sl=0; sl<8; ++sl) s += part[((size_t)bt*8 + sl)*512 + c];
    sga[(size_t)bt*512 + c] = s;
  }
}

// ---------------- 512->512(relu)->128 MLP head (fp32 weights) ---------------------------
__launch_bounds__(256)
__global__ void mlp_k(const float* __restrict__ in, const float* __restrict__ w1,
                      const float* __restrict__ b1, const float* __restrict__ w2,
                      const float* __restrict__ b2, float* __restrict__ out){
  int bb = blockIdx.x; int tid = threadIdx.x;
  __shared__ float xv[512]; __shared__ float h[512];
  xv[tid] = in[(size_t)bb*512 + tid];
  xv[tid+256] = in[(size_t)bb*512 + 256 + tid];
  __syncthreads();
  #pragma unroll
  for (int oo=0;oo<2;oo++){
    int o = tid + oo*256;
    const float* wr = w1 + (size_t)o*512;
    float a=0.f;
    for (int c=0;c<512;c+=4){
      float4 q = *reinterpret_cast<const float4*>(wr+c);
      a += xv[c]*q.x + xv[c+1]*q.y + xv[c+2]*q.z + xv[c+3]*q.w;
    }
    h[o] = fmaxf(a + b1[o], 0.f);
  }
  __syncthreads();
  if (tid < 128){
    const float* wr = w2 + (size_t)tid*512;
    float a=0.f;
    for (int c=0;c<512;c+=4){
      float4 q = *reinterpret_cast<const float4*>(wr+c);
      a += h[c]*q.x + h[c+1]*q.y + h[c+2]*q.z + h[c+3]*q.w;
    }
    out[(size_t)bb*128+tid] = a + b2[tid];
  }
}

extern "C" void kernel_launch(void* const* d_in, const int* in_sizes, int n_in,
                              void* d_out, int out_size, void* d_ws, size_t ws_size,
                              hipStream_t stream){
  (void)in_sizes; (void)n_in; (void)out_size; (void)ws_size;
  const float* ctx   = (const float*)d_in[0];
  const float* frame = (const float*)d_in[1];
  const float* nl_vw[2] = {(const float*)d_in[4],  (const float*)d_in[11]};
  const float* nl_ow[2] = {(const float*)d_in[5],  (const float*)d_in[12]};
  const float* nl_ob[2] = {(const float*)d_in[6],  (const float*)d_in[13]};
  const float* nl_g[2]  = {(const float*)d_in[7],  (const float*)d_in[14]};
  const float* nl_be[2] = {(const float*)d_in[8],  (const float*)d_in[15]};
  const float* tp_w = (const float*)d_in[16]; const float* tp_b = (const float*)d_in[17];
  const float* up1w = (const float*)d_in[18]; const float* up1b = (const float*)d_in[19];
  const float* up2w = (const float*)d_in[20]; const float* up2b = (const float*)d_in[21];
  const float* og1w = (const float*)d_in[22]; const float* og1b = (const float*)d_in[23];
  const float* og2w = (const float*)d_in[24]; const float* og2b = (const float*)d_in[25];
  const float* os1w = (const float*)d_in[26]; const float* os1b = (const float*)d_in[27];
  const float* os2w = (const float*)d_in[28]; const float* os2b = (const float*)d_in[29];
  float* out = (float*)d_out;

  char* wsp = (char*)d_ws;
  // ---- persistent region (~23.9 MB) ----
  float* gpp     = (float*)(wsp);                 // 32768 [4][4][512]
  float* mv      = (float*)(wsp + 131072);        // 8192
  float* gp      = (float*)(wsp + 139264);        // 8192
  float* SG      = (float*)(wsp + 147456);        // 98304
  float* attn    = (float*)(wsp + 245760);        // 98304
  float* sga     = (float*)(wsp + 344064);        // 49152
  float* psga    = (float*)(wsp + 393216);        // 393216 [24][8][512]
  float* peN     = (float*)(wsp + 786432);        // 2097152 [1024][512]
  bf16*  weff    = (bf16*) (wsp + 2883584);       // 2097152 [1024][1024] bf16
  unsigned short* w1sp = (unsigned short*)(wsp + 4980736);   // 12582912 [4][512][3072]
  unsigned short* w2sp = (unsigned short*)(wsp + 17563648);  // 6291456  [4][512][1536]
  char* ov = wsp + 23855104;
  // phase 1 (nonlocal):
  bf16*  xcl  = (bf16*) (ov);                     // 8 MB [4096][1024]
  float* ybuf = (float*)(ov + 8388608);           // 16 MB [4096][1024]
  // phase 1 staging in the (dead until phase 2) part9 region:
  unsigned short* Asp = (unsigned short*)(ov + 36700160);            // 3 MB [1024][1536]
  unsigned short* Bsp = (unsigned short*)(ov + 36700160 + 3145728);  // 3 MB [1024][1536]
  float* bnp = (float*)(ov + 36700160 + 6291456); // 512 KB [64][2][1024] BN partials
  // phase 2 (conv): wtt aliases ybuf (written after last norm2)
  unsigned short* wtt = (unsigned short*)(ov + 8388608);   // 28.3 MB [512][27648]
  float* part9 = (float*)(ov + 36700160);         // 28.9 MB [9][1568][512]
  // frame staging: aliases part9 (written after gp2_k reads part9)
  unsigned short* Fsp = (unsigned short*)(ov + 36700160);  // 9.4 MB [1536][3072]
  // phase 3 (after gp2_k; xcl/wtt dead):
  unsigned short* s1sp = (unsigned short*)(ov);   // 18.9 MB [6144][1536]
  float* scl  = (float*)(ov + 18874368);          // 50.3 MB [24576][512]

  // prep (independent)
  permT_k<bf16><<<dim3(4,16,16),256,0,stream>>>(ctx, xcl, 256, 1024, 1, 1, 262144L, 262144L);
  permTsplit3_k<1><<<dim3(32,16,1),256,0,stream>>>(up1w, w1sp, 2048, 1024, 4, 512, 0L, 0L);
  permTsplit3_k<1><<<dim3(32,8,1),256,0,stream>>>(up2w, w2sp, 2048, 512, 4, 512, 0L, 0L);
  pen_k<<<2048,256,0,stream>>>(peN);
  zero_k<<<96,256,0,stream>>>(SG);   // accumulated by MODE5 atomics

  // nonlocal layers
  for (int l=0;l<2;l++){
    // weff = ow @ vw via split-bf16 MFMA (fp32-accurate products)
    splitA_k<<<2048,256,0,stream>>>(nl_ow[l], Asp);
    permTsplit3_k<1><<<dim3(16,8,1),256,0,stream>>>(nl_vw[l], Bsp, 1024, 512, 1, 1, 0L, 0L);
    mmL_k<1,4,2,2,4,64><<<dim3(32,8,1),256,0,stream>>>(Asp, Bsp, nullptr, nullptr, nullptr,
        nullptr, (unsigned short*)weff, nullptr, 1536);
    mmL_k<1,4,4,2,0,64><<<dim3(64,8,1),256,0,stream>>>((const unsigned short*)xcl,
        (const unsigned short*)weff, nl_ob[l], (const unsigned short*)xcl, nullptr,
        ybuf, nullptr, bnp, 1024);
    stats_comb<<<4,256,0,stream>>>(bnp, nl_g[l], nl_be[l], mv);
    norm2_k<<<16384,256,0,stream>>>(ybuf, mv, (unsigned short*)xcl);
  }

  // temporal-pool conv (im2col GEMM, K-split 9) -- 128x128 block (2x2 waves of 64x64):
  // -33% LDS-read bytes/FLOP vs 64x128; grid (13,4,9)=468 blocks, 32KB LDS -> 5 blocks/CU
  wperm_k<<<512,256,0,stream>>>(tp_w, wtt);
  mmL_k<2,2,4,4,1,32><<<dim3(13,4,9),256,0,stream>>>((const unsigned short*)xcl, wtt,
      nullptr, nullptr, nullptr, part9, nullptr, nullptr, 3072);
  gp2_k<<<dim3(4,16,4),256,0,stream>>>(part9, tp_b, gpp);
  gp_comb<<<8,256,0,stream>>>(gpp, gp);

  // frame path (3-block split-bf16 == fp32-accurate); Fsp aliases part9 -> after gp2_k
  permTsplit3_k<0><<<dim3(1,16,24),256,0,stream>>>(frame, Fsp, 64, 1024, 1, 1, 65536L, 196608L);
  mmL_k<1,4,2,2,2,64><<<dim3(48,4,4),256,0,stream>>>(Fsp, w1sp, up1b, nullptr, nullptr,
      nullptr, s1sp, nullptr, 3072);
  // up2 + fused SG partial dot (replaces sg2_k): 128x128 block, SG += scl-row . gp
  mmL_k<2,2,4,4,5,32><<<dim3(48,4,4),256,0,stream>>>(s1sp, w2sp, up2b, nullptr, gp,
      scl, nullptr, SG, 1536);

  // attention tail
  softmax_k<<<24,256,0,stream>>>(SG, attn);
  sga2_k<<<dim3(24,8),256,0,stream>>>(scl, peN, attn, psga);
  sga_red<<<24,256,0,stream>>>(psga, sga);

  // heads
  mlp_k<<<4,256,0,stream>>>(gp, og1w, og1b, og2w, og2b, out);
  mlp_k<<<24,256,0,stream>>>(sga, os1w, os1b, os2w, os2b, out + 512);
}

// Round 7
// 666.417 us; speedup vs baseline: 1.2226x; 1.0234x over previous
//
#include <hip/hip_runtime.h>
#include <hip/hip_bf16.h>

using bf16 = __hip_bfloat16;
typedef short short8 __attribute__((ext_vector_type(8)));
typedef float float4v __attribute__((ext_vector_type(4)));

__device__ __forceinline__ float b2f(unsigned short u){
  unsigned int x = ((unsigned int)u) << 16; float f;
  __builtin_memcpy(&f, &x, 4); return f;
}
__device__ __forceinline__ float b2f(bf16 v){ return __bfloat162float(v); }
__device__ __forceinline__ unsigned short f2bu(float x){
  bf16 h = __float2bfloat16(x); unsigned short u;
  __builtin_memcpy(&u, &h, 2); return u;
}

// async global->LDS, 16B per lane, dest = wave-uniform base + lane*16
#define GLDS16(g, l) __builtin_amdgcn_global_load_lds( \
    (const __attribute__((address_space(1))) void*)(g), \
    (__attribute__((address_space(3))) void*)(l), 16, 0, 0)

// -------- batched permuted transpose fp32->bf16: per z, in[R][Cc] -> out[(q%D)*G+q/D][R] -
template<class TO>
__launch_bounds__(256)
__global__ void permT_k(const float* __restrict__ inp, TO* __restrict__ outp,
                        int Cc, int R, int D, int G, long inS, long outS){
  __shared__ float t[64][65];
  int z = blockIdx.z;
  const float* in = inp + (size_t)z*inS;
  TO* out = outp + (size_t)z*outS;
  int c0 = blockIdx.x*64, r0 = blockIdx.y*64;
  int tid = threadIdx.x;
  int rr = tid>>2, c4 = (tid&3)*16;
  const float* p = in + (size_t)(r0+rr)*Cc + c0 + c4;
  #pragma unroll
  for (int j=0;j<16;j+=4){
    float4 q = *reinterpret_cast<const float4*>(p+j);
    t[rr][c4+j]=q.x; t[rr][c4+j+1]=q.y; t[rr][c4+j+2]=q.z; t[rr][c4+j+3]=q.w;
  }
  __syncthreads();
  int ql = tid>>2;
  int q = c0 + ql;
  int orow = (q % D)*G + q / D;
  TO* op = out + (size_t)orow*R + r0 + c4;
  #pragma unroll
  for (int j=0;j<16;j++){
    if constexpr (sizeof(TO)==2) op[j] = __float2bfloat16(t[c4+j][ql]);
    else op[j] = t[c4+j][ql];
  }
}

// -------- 3-block split transpose: rows of length 3R.
// PAT=0 (A-side): blocks (hi, lo, hi).  PAT=1 (B-side): blocks (hi, hi, lo).
// Paired dot over 3R gives ah*bh + al*bh + ah*bl  == fp32-accurate product.
template<int PAT>
__launch_bounds__(256)
__global__ void permTsplit3_k(const float* __restrict__ inp, unsigned short* __restrict__ outp,
                              int Cc, int R, int D, int G, long inS, long outS){
  __shared__ float t[64][65];
  int z = blockIdx.z;
  const float* in = inp + (size_t)z*inS;
  unsigned short* out = outp + (size_t)z*outS;
  int c0 = blockIdx.x*64, r0 = blockIdx.y*64;
  int tid = threadIdx.x;
  int rr = tid>>2, c4 = (tid&3)*16;
  const float* p = in + (size_t)(r0+rr)*Cc + c0 + c4;
  #pragma unroll
  for (int j=0;j<16;j+=4){
    float4 q = *reinterpret_cast<const float4*>(p+j);
    t[rr][c4+j]=q.x; t[rr][c4+j+1]=q.y; t[rr][c4+j+2]=q.z; t[rr][c4+j+3]=q.w;
  }
  __syncthreads();
  int ql = tid>>2;
  int q = c0 + ql;
  int orow = (q % D)*G + q / D;
  unsigned short* op = out + (size_t)orow*(3*R);
  #pragma unroll
  for (int j=0;j<16;j++){
    float v = t[c4+j][ql];
    unsigned short h = f2bu(v);
    unsigned short l = f2bu(v - b2f(h));
    int idx = r0 + c4 + j;
    if constexpr (PAT==0){
      op[idx] = h; op[R+idx] = l; op[2*R+idx] = h;
    } else {
      op[idx] = h; op[R+idx] = h; op[2*R+idx] = l;
    }
  }
}

// -------- row split (no transpose): in[1024][512] fp32 -> out[1024][1536] bf16 (h,l,h) --
__launch_bounds__(256)
__global__ void splitA_k(const float* __restrict__ in, unsigned short* __restrict__ out){
  int idx = blockIdx.x*256 + threadIdx.x;   // 1024*512
  int m = idx >> 9, j = idx & 511;
  float v = in[idx];
  unsigned short h = f2bu(v);
  unsigned short l = f2bu(v - b2f(h));
  unsigned short* op = out + (size_t)m*1536 + j;
  op[0] = h; op[512] = l; op[1024] = h;
}

__global__ void zero_k(float* __restrict__ p){
  p[blockIdx.x*256 + threadIdx.x] = 0.f;
}

// ================= unified MFMA GEMM: global_load_lds + dbuf + counted vmcnt =============
// C[m][f] = sum_k A[m][k]*B[f][k], bf16. WM x WN waves, each owns (MTM*16) x (NTN*16).
// BK=64 for grid-limited kernels; BK=32 (24-32KB LDS) for high-grid kernels (round-4/5).
// LDS image: linear dest slot (16B) = row*CPR + chunk'; swizzle chunk' = c ^ swz(row)
// applied on the GLOBAL source address (m104-safe). 2-phase T3/T4 pipeline: stage t+1
// before vmcnt(LPT) for t; loads in flight across both raw s_barriers, never drained.
// BN-FOLD (round 7): BatchNorm x_norm = y*sc+sh is folded into consumers:
//   MODE 4 (weff): if gpf, scale weff columns by sc0[k] and atomicAdd sum_k sh0[k]*weff
//     into aux[m] (bias fold). MODE 0: bi = bias + biasAdd(outf); residual read scaled by
//     gpf (sc0/sh0); writes bf16 xcl DIRECTLY (outs) + BN col-partials to aux. ybuf and
//     both norm2 passes are gone. In/out xcl ping-pong (no in-place race).
// MODE 1: conv3d im2col K-split z (XCD-bijective z-major swizzle -> B L2-resident),
// MODE 2: up1 (relu+bias, convT scatter, 3-block h/l/h), MODE 5: up2 + fused SG dot.
template<int WM, int WN, int MTM, int NTN, int MODE, int BK>
__launch_bounds__(256)
__global__ void mmL_k(const unsigned short* __restrict__ A,
                      const unsigned short* __restrict__ B,
                      const float* __restrict__ bias,
                      const unsigned short* __restrict__ res,
                      const float* __restrict__ gpf,
                      float* __restrict__ outf,
                      unsigned short* __restrict__ outs,
                      float* __restrict__ aux,
                      int K){
  constexpr int BM  = WM*MTM*16;
  constexpr int BN  = WN*NTN*16;
  constexpr int CPR = BK/8;            // 16B chunks per row
  constexpr int KS  = BK/32;           // k-subtiles per step
  constexpr int AIT = (BM*CPR)/256;    // A chunks per thread
  constexpr int NBC = (BN*CPR)/256;    // B chunks per thread
  constexpr int LPT = AIT + NBC;       // loads in flight per thread per stage
  __shared__ __align__(16) short As[2*BM*BK];
  __shared__ __align__(16) short Bs[2*BN*BK];
  const int tid = threadIdx.x;
  const int wv = tid>>6, lane = tid&63, l15 = lane&15, quad = lane>>4;
  const int wvm = wv / WN, wvf = wv % WN;
  const int wbase = wv<<6;             // wave-uniform LDS slot base (64 slots/wave)

  int bx = blockIdx.x, by = blockIdx.y, bz = blockIdx.z;
  if constexpr (MODE==1){
    const int gx = gridDim.x, gy = gridDim.y, gz = gridDim.z;
    const int n = gx*gy*gz;
    const int lin = bx + gx*(by + gy*bz);
    const int q = n >> 3, r = n & 7;
    const int xcd = lin & 7, j = lin >> 3;
    const int work = (xcd < r ? xcd*(q+1) : r*(q+1) + (xcd-r)*q) + j;
    by = work % gy;                 // y minor
    const int t = work / gy;
    bx = t % gx;                    // x middle
    bz = t / gx;                    // z major (chunk == one kt/kh slice)
  }
  const int m0 = bx*BM;
  const int fblk = by*BN;
  const int z = bz;

  auto swz = [](int row){ if constexpr (BK==32) return (row>>1)&3; else return row&7; };

  // ---- staging addresses (source-side swizzle; LDS dest linear: slot = it*256+tid) ----
  size_t aAddr[AIT];
  #pragma unroll
  for (int it=0; it<AIT; ++it){
    int s = tid + it*256;
    int arow = s/CPR;
    int ac = (s&(CPR-1)) ^ swz(arow);
    int m = m0 + arow;
    if constexpr (MODE==1){
      int mm = m < 1568 ? m : 1567;
      int b = mm/392, r = mm%392;
      int t = r/196, r2 = r%196;
      int hh = r2/14, ww = r2%14;
      int kt = z/3, kh = z%3;
      int sp = ((b*4 + t + kt)*16 + hh + kh)*16 + ww;
      aAddr[it] = (size_t)sp*1024 + ac*8;
    } else {
      aAddr[it] = (size_t)m*K + ac*8;
    }
  }
  size_t bAddr[NBC];
  #pragma unroll
  for (int it=0; it<NBC; ++it){
    int s = tid + it*256;
    int row = s/CPR;
    int c = (s&(CPR-1)) ^ swz(row);
    int f = fblk + row;
    if constexpr (MODE==0)      bAddr[it] = (size_t)f*1024 + c*8;
    else if constexpr (MODE==1) bAddr[it] = (size_t)f*27648 + (size_t)z*3072 + c*8;
    else                        bAddr[it] = ((size_t)z*512 + f)*(size_t)K + c*8;
  }
  // ---- fragment LDS slots (swizzled), per k-subtile ----
  int aslot[MTM][KS];
  #pragma unroll
  for (int mt=0;mt<MTM;++mt)
    #pragma unroll
    for (int ks=0;ks<KS;++ks){
      int row = wvm*MTM*16 + mt*16 + l15;
      aslot[mt][ks] = row*CPR + ((ks*4 + quad) ^ swz(row));
    }
  int bslot[NTN][KS];
  #pragma unroll
  for (int nt=0;nt<NTN;++nt)
    #pragma unroll
    for (int ks=0;ks<KS;++ks){
      int row = wvf*NTN*16 + nt*16 + l15;
      bslot[nt][ks] = row*CPR + ((ks*4 + quad) ^ swz(row));
    }

  float4v acc[MTM][NTN];
  #pragma unroll
  for (int i=0;i<MTM;i++)
    #pragma unroll
    for (int j=0;j<NTN;j++) acc[i][j]=(float4v){0,0,0,0};

  auto stage = [&](int buf, int k0){
    #pragma unroll
    for (int it=0; it<AIT; ++it)
      GLDS16(A + aAddr[it] + k0, As + buf*(BM*BK) + (it*256 + wbase)*8);
    #pragma unroll
    for (int it=0; it<NBC; ++it)
      GLDS16(B + bAddr[it] + k0, Bs + buf*(BN*BK) + (it*256 + wbase)*8);
  };
  auto computeTile = [&](int buf){
    const short* ap = As + buf*(BM*BK);
    const short* bp = Bs + buf*(BN*BK);
    #pragma unroll
    for (int ks=0; ks<KS; ++ks){
      short8 bf[NTN];
      #pragma unroll
      for (int nt=0;nt<NTN;++nt)
        bf[nt] = *reinterpret_cast<const short8*>(bp + bslot[nt][ks]*8);
      #pragma unroll
      for (int mt=0;mt<MTM;++mt){
        short8 af = *reinterpret_cast<const short8*>(ap + aslot[mt][ks]*8);
        #pragma unroll
        for (int nt=0;nt<NTN;++nt)
          acc[mt][nt] = __builtin_amdgcn_mfma_f32_16x16x32_bf16(af, bf[nt], acc[mt][nt],0,0,0);
      }
    }
  };

  stage(0, 0);
  int cur = 0;
  for (int k0 = 0; k0 < K-BK; k0 += BK){
    stage(cur^1, k0+BK);               // tile t+1 in flight across the wait+barriers
    if constexpr (LPT==6)      asm volatile("s_waitcnt vmcnt(6)" ::: "memory");
    else if constexpr (LPT==5) asm volatile("s_waitcnt vmcnt(5)" ::: "memory");
    else if constexpr (LPT==4) asm volatile("s_waitcnt vmcnt(4)" ::: "memory");
    else                       asm volatile("s_waitcnt vmcnt(3)" ::: "memory");
    __builtin_amdgcn_sched_barrier(0);
    __builtin_amdgcn_s_barrier();      // all waves' tile-t loads landed
    computeTile(cur);
    asm volatile("s_waitcnt lgkmcnt(0)" ::: "memory");
    __builtin_amdgcn_sched_barrier(0);
    __builtin_amdgcn_s_barrier();      // all waves' ds_reads done before buf reuse
    cur ^= 1;
  }
  asm volatile("s_waitcnt vmcnt(0)" ::: "memory");
  __builtin_amdgcn_sched_barrier(0);
  __builtin_amdgcn_s_barrier();
  computeTile(cur);

  if constexpr (MODE==0){
    // BN-folded nonlocal epilogue: v = relu(acc+bias+biasAdd) + res*sc + sh -> bf16 xcl,
    // plus per-block column stats (sum, sum^2) into aux.
    const float* badd = outf;          // bias-fold accumulator (l=1) or nullptr (l=0)
    float sacc[NTN] = {}, s2acc[NTN] = {};
    #pragma unroll
    for (int nt=0;nt<NTN;++nt){
      int f = fblk + wvf*NTN*16 + nt*16 + l15;
      float bi = bias[f] + (badd ? badd[f] : 0.f);
      float rsc = 1.f, rsh = 0.f;
      if (gpf){ rsc = gpf[f]; rsh = gpf[1024+f]; }
      #pragma unroll
      for (int mt=0;mt<MTM;++mt){
        #pragma unroll
        for (int r=0;r<4;++r){
          int m = m0 + wvm*MTM*16 + mt*16 + quad*4 + r;
          float v = fmaxf(acc[mt][nt][r]+bi, 0.f) + b2f(res[(size_t)m*1024 + f])*rsc + rsh;
          outs[(size_t)m*1024 + f] = f2bu(v);
          sacc[nt] += v; s2acc[nt] += v*v;
        }
      }
    }
    #pragma unroll
    for (int nt=0;nt<NTN;++nt){
      float s = sacc[nt], s2 = s2acc[nt];
      s  += __shfl_xor(s, 16);  s  += __shfl_xor(s, 32);
      s2 += __shfl_xor(s2, 16); s2 += __shfl_xor(s2, 32);
      if (quad==0){
        int f = fblk + wvf*NTN*16 + nt*16 + l15;
        aux[(size_t)bx*2048 + f] = s;
        aux[(size_t)bx*2048 + 1024 + f] = s2;
      }
    }
  } else if constexpr (MODE==1){
    #pragma unroll
    for (int mt=0;mt<MTM;++mt)
      #pragma unroll
      for (int nt=0;nt<NTN;++nt){
        int f = fblk + wvf*NTN*16 + nt*16 + l15;
        #pragma unroll
        for (int r=0;r<4;++r){
          int m = m0 + wvm*MTM*16 + mt*16 + quad*4 + r;
          if (m < 1568) outf[((size_t)z*1568 + m)*512 + f] = acc[mt][nt][r];
        }
      }
  } else if constexpr (MODE==2){
    int kk = z>>1, ll = z&1;
    #pragma unroll
    for (int mt=0;mt<MTM;++mt)
      #pragma unroll
      for (int nt=0;nt<NTN;++nt){
        int f = fblk + wvf*NTN*16 + nt*16 + l15;
        float bi = bias[f];
        #pragma unroll
        for (int r=0;r<4;++r){
          int m = m0 + wvm*MTM*16 + mt*16 + quad*4 + r;
          int bt = m>>6, p = m&63;
          long orow = (long)bt*256 + (2*(p>>3)+kk)*16 + 2*(p&7)+ll;
          float v = fmaxf(acc[mt][nt][r]+bi, 0.f);
          unsigned short h = f2bu(v);
          unsigned short l = f2bu(v - b2f(h));
          unsigned short* rp = outs + (size_t)orow*1536 + f;
          rp[0] = h; rp[512] = l; rp[1024] = h;
        }
      }
  } else if constexpr (MODE==5){
    int kk = z>>1, ll = z&1;
    #pragma unroll
    for (int mt=0;mt<MTM;++mt){
      int mbase = m0 + wvm*MTM*16 + mt*16;
      int bt = mbase>>8, b6 = bt/6, p0 = mbase&255;
      float gv[NTN], bv[NTN];
      #pragma unroll
      for (int nt=0;nt<NTN;++nt){
        int f = fblk + wvf*NTN*16 + nt*16 + l15;
        gv[nt] = gpf[b6*512 + f];
        bv[nt] = bias[f];
      }
      #pragma unroll
      for (int r=0;r<4;++r){
        int p = p0 + quad*4 + r;
        long orow = (long)bt*1024 + (2*(p>>4)+kk)*32 + 2*(p&15)+ll;
        float sdot = 0.f;
        #pragma unroll
        for (int nt=0;nt<NTN;++nt){
          int f = fblk + wvf*NTN*16 + nt*16 + l15;
          float v = acc[mt][nt][r] + bv[nt];
          outf[(size_t)orow*512 + f] = v;
          sdot += v * gv[nt];
        }
        sdot += __shfl_xor(sdot, 1); sdot += __shfl_xor(sdot, 2);
        sdot += __shfl_xor(sdot, 4); sdot += __shfl_xor(sdot, 8);
        if (l15==0) atomicAdd(aux + orow, sdot);
      }
    }
  } else {  // MODE 4: weff bf16 out; BN-fold: scale cols by sc0, bias partials via sh0
    if (gpf){
      float sc[NTN], sh[NTN];
      #pragma unroll
      for (int nt=0;nt<NTN;++nt){
        int f = fblk + wvf*NTN*16 + nt*16 + l15;
        sc[nt] = gpf[f]; sh[nt] = gpf[1024+f];
      }
      #pragma unroll
      for (int mt=0;mt<MTM;++mt){
        #pragma unroll
        for (int r=0;r<4;++r){
          int m = m0 + wvm*MTM*16 + mt*16 + quad*4 + r;
          float part = 0.f;
          #pragma unroll
          for (int nt=0;nt<NTN;++nt){
            int f = fblk + wvf*NTN*16 + nt*16 + l15;
            float a = acc[mt][nt][r];
            part += a * sh[nt];
            outs[(size_t)m*1024 + f] = f2bu(a * sc[nt]);
          }
          part += __shfl_xor(part, 1); part += __shfl_xor(part, 2);
          part += __shfl_xor(part, 4); part += __shfl_xor(part, 8);
          if (l15==0) atomicAdd(aux + m, part);
        }
      }
    } else {
      #pragma unroll
      for (int mt=0;mt<MTM;++mt)
        #pragma unroll
        for (int nt=0;nt<NTN;++nt){
          int f = fblk + wvf*NTN*16 + nt*16 + l15;
          #pragma unroll
          for (int r=0;r<4;++r){
            int m = m0 + wvm*MTM*16 + mt*16 + quad*4 + r;
            outs[(size_t)m*1024 + f] = f2bu(acc[mt][nt][r]);
          }
        }
    }
  }
}

// ---------------- BN stats combine: bnp[64][2][1024] -> scale/shift mv ------------------
__global__ void stats_comb(const float* __restrict__ bnp, const float* __restrict__ g,
                           const float* __restrict__ beta, float* __restrict__ mv){
  int c = blockIdx.x*256 + threadIdx.x;   // 1024
  float S=0.f, S2=0.f;
  #pragma unroll 8
  for (int s=0;s<64;s++){ S += bnp[(size_t)s*2048 + c]; S2 += bnp[(size_t)s*2048 + 1024 + c]; }
  float m = S * (1.f/4096.f);
  float var = S2 * (1.f/4096.f) - m*m;
  float inv = rsqrtf(var + 1e-5f);
  float sc = inv * g[c];
  mv[c] = sc;
  mv[1024 + c] = beta[c] - m*sc;
}

// ---- weight permute + BN fold: wtt[f][j*1024+c] = bf16(tp_w[f][c*27+j]*sc1[c]),
//      tpb2[f] = tp_b[f] + sum_{j,c} tp_w[f][c*27+j]*sh1[c] ------------------------------
__launch_bounds__(256)
__global__ void wperm_k(const float* __restrict__ w, const float* __restrict__ mv1,
                        const float* __restrict__ tpb,
                        unsigned short* __restrict__ wtt, float* __restrict__ tpb2){
  __shared__ float ls[3456];
  __shared__ float rs[256];
  int f = blockIdx.x;
  const float* src = w + (size_t)f*27648;
  unsigned short* dst = wtt + (size_t)f*27648;
  float part = 0.f;
  for (int cc=0; cc<8; ++cc){
    __syncthreads();
    for (int i=threadIdx.x; i<3456; i+=256) ls[i] = src[cc*3456 + i];
    __syncthreads();
    for (int u=threadIdx.x; u<3456; u+=256){
      int j = u >> 7, c = u & 127;
      int ch = cc*128 + c;
      float wv = ls[c*27 + j];
      dst[(size_t)j*1024 + ch] = f2bu(wv * mv1[ch]);
      part += wv * mv1[1024 + ch];
    }
  }
  rs[threadIdx.x] = part; __syncthreads();
  for (int st=128; st>0; st>>=1){
    if (threadIdx.x < st) rs[threadIdx.x] += rs[threadIdx.x+st];
    __syncthreads();
  }
  if (threadIdx.x==0) tpb2[f] = tpb[f] + rs[0];
}

// ---------------- goal_pre partials: z splits the 392 positions 4-ways ------------------
__launch_bounds__(256)
__global__ void gp2_k(const float* __restrict__ part9, const float* __restrict__ tpb,
                      float* __restrict__ gpp){
  int b = blockIdx.x;
  int fc = blockIdx.y;
  int z = blockIdx.z;          // 4 p-chunks of 98
  int fi = threadIdx.x & 31, pi = threadIdx.x >> 5;
  int f = fc*32 + fi;
  float bias = tpb[f];
  float a = 0.f;
  for (int p = z*98 + pi; p < z*98 + 98; p += 8){
    size_t base = ((size_t)(b*392 + p))*512 + f;
    float v = bias;
    #pragma unroll
    for (int i=0;i<9;i++) v += part9[(size_t)i*802816 + base];
    a += fmaxf(v, 0.f);
  }
  __shared__ float red[256];
  red[threadIdx.x] = a; __syncthreads();
  for (int st=4; st>0; st>>=1){
    if (pi < st) red[pi*32+fi] += red[(pi+st)*32+fi];
    __syncthreads();
  }
  if (pi==0) gpp[(size_t)z*2048 + b*512 + f] = red[fi];
}

__global__ void gp_comb(const float* __restrict__ gpp, float* __restrict__ gp){
  int idx = blockIdx.x*256 + threadIdx.x;   // 2048
  float s = gpp[idx] + gpp[2048+idx] + gpp[4096+idx] + gpp[6144+idx];
  gp[idx] = s * (1.f/392.f);
}

// ---------------- PE table: peN[n][c] ---------------------------------------------------
__global__ void pen_k(float* __restrict__ peN){
  int idx = blockIdx.x*256 + threadIdx.x;   // 524288
  int n = idx >> 9, c = idx & 511;
  float div = expf(-0.035977892f * (float)(c>>1));   // 2*ln(10000)/512
  float ang = (float)n * div;
  peN[idx] = (c & 1) ? cosf(ang) : sinf(ang);
}

// ---------------- softmax over n: attn[bt][n] normalized --------------------------------
__launch_bounds__(256)
__global__ void softmax_k(const float* __restrict__ SG, float* __restrict__ attn){
  int bt = blockIdx.x; int tid = threadIdx.x;
  float4 v = *reinterpret_cast<const float4*>(SG + bt*1024 + tid*4);
  float mx = fmaxf(fmaxf(v.x,v.y), fmaxf(v.z,v.w));
  __shared__ float red[256];
  red[tid] = mx; __syncthreads();
  for (int st=128; st>0; st>>=1){
    if (tid<st) red[tid] = fmaxf(red[tid], red[tid+st]);
    __syncthreads();
  }
  float m = red[0]; __syncthreads();
  float4 e;
  e.x = expf(v.x-m); e.y = expf(v.y-m); e.z = expf(v.z-m); e.w = expf(v.w-m);
  red[tid] = e.x+e.y+e.z+e.w; __syncthreads();
  for (int st=128; st>0; st>>=1){
    if (tid<st) red[tid] += red[tid+st];
    __syncthreads();
  }
  float inv = 1.0f/red[0];
  e.x*=inv; e.y*=inv; e.z*=inv; e.w*=inv;
  *reinterpret_cast<float4*>(attn + bt*1024 + tid*4) = e;
}

// ---------------- part_sga[bt][sl][c] = sum_{n in slice} attn[n]*(scl[n][c]+pe[n][c]) ---
__launch_bounds__(256)
__global__ void sga2_k(const float* __restrict__ scl, const float* __restrict__ peN,
                       const float* __restrict__ attn, float* __restrict__ part){
  int bt = blockIdx.x, sl = blockIdx.y;   // 24 x 8
  int tid = threadIdx.x;
  __shared__ float at[128];
  if (tid < 128) at[tid] = attn[bt*1024 + sl*128 + tid];
  __syncthreads();
  float acc0 = 0.f, acc1 = 0.f;
  for (int j=0;j<128;j++){
    int n = sl*128 + j;
    float a = at[j];
    const float* row = scl + ((size_t)bt*1024 + n)*512;
    const float* pe  = peN + (size_t)n*512;
    acc0 += a * (row[tid] + pe[tid]);
    acc1 += a * (row[tid+256] + pe[tid+256]);
  }
  part[((size_t)bt*8 + sl)*512 + tid] = acc0;
  part[((size_t)bt*8 + sl)*512 + tid + 256] = acc1;
}

__global__ void sga_red(const float* __restrict__ part, float* __restrict__ sga){
  int bt = blockIdx.x; int tid = threadIdx.x;
  #pragma unroll
  for (int h=0; h<2; ++h){
    int c = tid + h*256;
    float s = 0.f;
    #pragma unroll
    for (int sl=0; sl<8; ++sl) s += part[((size_t)bt*8 + sl)*512 + c];
    sga[(size_t)bt*512 + c] = s;
  }
}

// ---------------- 512->512(relu)->128 MLP head (fp32 weights) ---------------------------
__launch_bounds__(256)
__global__ void mlp_k(const float* __restrict__ in, const float* __restrict__ w1,
                      const float* __restrict__ b1, const float* __restrict__ w2,
                      const float* __restrict__ b2, float* __restrict__ out){
  int bb = blockIdx.x; int tid = threadIdx.x;
  __shared__ float xv[512]; __shared__ float h[512];
  xv[tid] = in[(size_t)bb*512 + tid];
  xv[tid+256] = in[(size_t)bb*512 + 256 + tid];
  __syncthreads();
  #pragma unroll
  for (int oo=0;oo<2;oo++){
    int o = tid + oo*256;
    const float* wr = w1 + (size_t)o*512;
    float a=0.f;
    for (int c=0;c<512;c+=4){
      float4 q = *reinterpret_cast<const float4*>(wr+c);
      a += xv[c]*q.x + xv[c+1]*q.y + xv[c+2]*q.z + xv[c+3]*q.w;
    }
    h[o] = fmaxf(a + b1[o], 0.f);
  }
  __syncthreads();
  if (tid < 128){
    const float* wr = w2 + (size_t)tid*512;
    float a=0.f;
    for (int c=0;c<512;c+=4){
      float4 q = *reinterpret_cast<const float4*>(wr+c);
      a += h[c]*q.x + h[c+1]*q.y + h[c+2]*q.z + h[c+3]*q.w;
    }
    out[(size_t)bb*128+tid] = a + b2[tid];
  }
}

extern "C" void kernel_launch(void* const* d_in, const int* in_sizes, int n_in,
                              void* d_out, int out_size, void* d_ws, size_t ws_size,
                              hipStream_t stream){
  (void)in_sizes; (void)n_in; (void)out_size; (void)ws_size;
  const float* ctx   = (const float*)d_in[0];
  const float* frame = (const float*)d_in[1];
  const float* nl_vw[2] = {(const float*)d_in[4],  (const float*)d_in[11]};
  const float* nl_ow[2] = {(const float*)d_in[5],  (const float*)d_in[12]};
  const float* nl_ob[2] = {(const float*)d_in[6],  (const float*)d_in[13]};
  const float* nl_g[2]  = {(const float*)d_in[7],  (const float*)d_in[14]};
  const float* nl_be[2] = {(const float*)d_in[8],  (const float*)d_in[15]};
  const float* tp_w = (const float*)d_in[16]; const float* tp_b = (const float*)d_in[17];
  const float* up1w = (const float*)d_in[18]; const float* up1b = (const float*)d_in[19];
  const float* up2w = (const float*)d_in[20]; const float* up2b = (const float*)d_in[21];
  const float* og1w = (const float*)d_in[22]; const float* og1b = (const float*)d_in[23];
  const float* og2w = (const float*)d_in[24]; const float* og2b = (const float*)d_in[25];
  const float* os1w = (const float*)d_in[26]; const float* os1b = (const float*)d_in[27];
  const float* os2w = (const float*)d_in[28]; const float* os2b = (const float*)d_in[29];
  float* out = (float*)d_out;

  char* wsp = (char*)d_ws;
  // ---- persistent region ----
  float* gpp     = (float*)(wsp);                 // 32KB [4][4][512]
  float* bias2   = (float*)(wsp + 65536);         // 4KB  [1024] weff bias-fold acc
  float* tpb2    = (float*)(wsp + 69632);         // 2KB  [512] conv bias-fold
  float* gp      = (float*)(wsp + 73728);         // 8KB  [4][512]
  float* mv0     = (float*)(wsp + 131072);        // 8KB  BN scale/shift layer 0
  float* mv1     = (float*)(wsp + 139264);        // 8KB  BN scale/shift layer 1
  float* SG      = (float*)(wsp + 147456);        // 98304
  float* attn    = (float*)(wsp + 245760);        // 98304
  float* sga     = (float*)(wsp + 344064);        // 49152
  float* psga    = (float*)(wsp + 393216);        // 393216 [24][8][512]
  float* peN     = (float*)(wsp + 786432);        // 2097152 [1024][512]
  bf16*  weff    = (bf16*) (wsp + 2883584);       // 2097152 [1024][1024] bf16
  unsigned short* w1sp = (unsigned short*)(wsp + 4980736);   // 12582912 [4][512][3072]
  unsigned short* w2sp = (unsigned short*)(wsp + 17563648);  // 6291456  [4][512][1536]
  char* ov = wsp + 23855104;
  // phase 1 (nonlocal, BN folded -> xcl ping-pong, no ybuf):
  bf16*  xclA = (bf16*) (ov);                     // 8 MB [4096][1024]
  bf16*  xclB = (bf16*) (ov + 8388608);           // 8 MB (dead after l=1 reads it)
  // phase 1 staging in the (dead until phase 2) part9 region:
  unsigned short* Asp = (unsigned short*)(ov + 36700160);            // 3 MB [1024][1536]
  unsigned short* Bsp = (unsigned short*)(ov + 36700160 + 3145728);  // 3 MB [1024][1536]
  float* bnp = (float*)(ov + 36700160 + 6291456); // 512 KB [64][2][1024] BN partials
  // phase 2 (conv): wtt aliases xclB region (written after l=1 MODE0 consumed xclB)
  unsigned short* wtt = (unsigned short*)(ov + 8388608);   // 28.3 MB [512][27648]
  float* part9 = (float*)(ov + 36700160);         // 28.9 MB [9][1568][512]
  // frame staging: aliases part9 (written after gp2_k reads part9)
  unsigned short* Fsp = (unsigned short*)(ov + 36700160);  // 9.4 MB [1536][3072]
  // phase 3 (after gp2_k; xclA/wtt dead):
  unsigned short* s1sp = (unsigned short*)(ov);   // 18.9 MB [6144][1536]
  float* scl  = (float*)(ov + 18874368);          // 50.3 MB [24576][512]

  // prep (independent)
  permT_k<bf16><<<dim3(4,16,16),256,0,stream>>>(ctx, xclA, 256, 1024, 1, 1, 262144L, 262144L);
  permTsplit3_k<1><<<dim3(32,16,1),256,0,stream>>>(up1w, w1sp, 2048, 1024, 4, 512, 0L, 0L);
  permTsplit3_k<1><<<dim3(32,8,1),256,0,stream>>>(up2w, w2sp, 2048, 512, 4, 512, 0L, 0L);
  pen_k<<<2048,256,0,stream>>>(peN);
  zero_k<<<96,256,0,stream>>>(SG);     // accumulated by MODE5 atomics
  zero_k<<<4,256,0,stream>>>(bias2);   // accumulated by MODE4 (l=1) atomics

  // nonlocal layer 0: xclA -> xclB (BN deferred via fold into layer-1 consumers)
  splitA_k<<<2048,256,0,stream>>>(nl_ow[0], Asp);
  permTsplit3_k<1><<<dim3(16,8,1),256,0,stream>>>(nl_vw[0], Bsp, 1024, 512, 1, 1, 0L, 0L);
  mmL_k<1,4,2,2,4,64><<<dim3(32,8,1),256,0,stream>>>(Asp, Bsp, nullptr, nullptr, nullptr,
      nullptr, (unsigned short*)weff, nullptr, 1536);
  mmL_k<1,4,4,2,0,64><<<dim3(64,8,1),256,0,stream>>>((const unsigned short*)xclA,
      (const unsigned short*)weff, nl_ob[0], (const unsigned short*)xclA, nullptr,
      nullptr, (unsigned short*)xclB, bnp, 1024);
  stats_comb<<<4,256,0,stream>>>(bnp, nl_g[0], nl_be[0], mv0);

  // nonlocal layer 1: xclB -> xclA; weff cols scaled by sc0, sh0 folded to bias2
  splitA_k<<<2048,256,0,stream>>>(nl_ow[1], Asp);
  permTsplit3_k<1><<<dim3(16,8,1),256,0,stream>>>(nl_vw[1], Bsp, 1024, 512, 1, 1, 0L, 0L);
  mmL_k<1,4,2,2,4,64><<<dim3(32,8,1),256,0,stream>>>(Asp, Bsp, nullptr, nullptr, mv0,
      nullptr, (unsigned short*)weff, bias2, 1536);
  mmL_k<1,4,4,2,0,64><<<dim3(64,8,1),256,0,stream>>>((const unsigned short*)xclB,
      (const unsigned short*)weff, nl_ob[1], (const unsigned short*)xclB, mv0,
      bias2, (unsigned short*)xclA, bnp, 1024);
  stats_comb<<<4,256,0,stream>>>(bnp, nl_g[1], nl_be[1], mv1);

  // temporal-pool conv (im2col GEMM, K-split 9); BN-1 folded into wtt (sc1) + tpb2 (sh1)
  wperm_k<<<512,256,0,stream>>>(tp_w, mv1, tp_b, wtt, tpb2);
  mmL_k<2,2,4,4,1,32><<<dim3(13,4,9),256,0,stream>>>((const unsigned short*)xclA, wtt,
      nullptr, nullptr, nullptr, part9, nullptr, nullptr, 3072);
  gp2_k<<<dim3(4,16,4),256,0,stream>>>(part9, tpb2, gpp);
  gp_comb<<<8,256,0,stream>>>(gpp, gp);

  // frame path (3-block split-bf16 == fp32-accurate); Fsp aliases part9 -> after gp2_k
  permTsplit3_k<0><<<dim3(1,16,24),256,0,stream>>>(frame, Fsp, 64, 1024, 1, 1, 65536L, 196608L);
  mmL_k<1,4,2,2,2,64><<<dim3(48,4,4),256,0,stream>>>(Fsp, w1sp, up1b, nullptr, nullptr,
      nullptr, s1sp, nullptr, 3072);
  // up2 + fused SG partial dot: 128x128 block, SG += scl-row . gp
  mmL_k<2,2,4,4,5,32><<<dim3(48,4,4),256,0,stream>>>(s1sp, w2sp, up2b, nullptr, gp,
      scl, nullptr, SG, 1536);

  // attention tail
  softmax_k<<<24,256,0,stream>>>(SG, attn);
  sga2_k<<<dim3(24,8),256,0,stream>>>(scl, peN, attn, psga);
  sga_red<<<24,256,0,stream>>>(psga, sga);

  // heads
  mlp_k<<<4,256,0,stream>>>(gp, og1w, og1b, og2w, og2b, out);
  mlp_k<<<24,256,0,stream>>>(sga, os1w, os1b, os2w, os2b, out + 512);
}

// Round 8
// 660.644 us; speedup vs baseline: 1.2333x; 1.0087x over previous
//
#include <hip/hip_runtime.h>
#include <hip/hip_bf16.h>

using bf16 = __hip_bfloat16;
typedef short short8 __attribute__((ext_vector_type(8)));
typedef float float4v __attribute__((ext_vector_type(4)));

__device__ __forceinline__ float b2f(unsigned short u){
  unsigned int x = ((unsigned int)u) << 16; float f;
  __builtin_memcpy(&f, &x, 4); return f;
}
__device__ __forceinline__ float b2f(bf16 v){ return __bfloat162float(v); }
__device__ __forceinline__ unsigned short f2bu(float x){
  bf16 h = __float2bfloat16(x); unsigned short u;
  __builtin_memcpy(&u, &h, 2); return u;
}

// async global->LDS, 16B per lane, dest = wave-uniform base + lane*16
#define GLDS16(g, l) __builtin_amdgcn_global_load_lds( \
    (const __attribute__((address_space(1))) void*)(g), \
    (__attribute__((address_space(3))) void*)(l), 16, 0, 0)

// -------- batched permuted transpose fp32->bf16: per z, in[R][Cc] -> out[(q%D)*G+q/D][R] -
template<class TO>
__launch_bounds__(256)
__global__ void permT_k(const float* __restrict__ inp, TO* __restrict__ outp,
                        int Cc, int R, int D, int G, long inS, long outS){
  __shared__ float t[64][65];
  int z = blockIdx.z;
  const float* in = inp + (size_t)z*inS;
  TO* out = outp + (size_t)z*outS;
  int c0 = blockIdx.x*64, r0 = blockIdx.y*64;
  int tid = threadIdx.x;
  int rr = tid>>2, c4 = (tid&3)*16;
  const float* p = in + (size_t)(r0+rr)*Cc + c0 + c4;
  #pragma unroll
  for (int j=0;j<16;j+=4){
    float4 q = *reinterpret_cast<const float4*>(p+j);
    t[rr][c4+j]=q.x; t[rr][c4+j+1]=q.y; t[rr][c4+j+2]=q.z; t[rr][c4+j+3]=q.w;
  }
  __syncthreads();
  int ql = tid>>2;
  int q = c0 + ql;
  int orow = (q % D)*G + q / D;
  TO* op = out + (size_t)orow*R + r0 + c4;
  #pragma unroll
  for (int j=0;j<16;j++){
    if constexpr (sizeof(TO)==2) op[j] = __float2bfloat16(t[c4+j][ql]);
    else op[j] = t[c4+j][ql];
  }
}

// -------- 3-block split transpose: rows of length 3R.
// PAT=0 (A-side): blocks (hi, lo, hi).  PAT=1 (B-side): blocks (hi, hi, lo).
// Paired dot over 3R gives ah*bh + al*bh + ah*bl  == fp32-accurate product.
template<int PAT>
__launch_bounds__(256)
__global__ void permTsplit3_k(const float* __restrict__ inp, unsigned short* __restrict__ outp,
                              int Cc, int R, int D, int G, long inS, long outS){
  __shared__ float t[64][65];
  int z = blockIdx.z;
  const float* in = inp + (size_t)z*inS;
  unsigned short* out = outp + (size_t)z*outS;
  int c0 = blockIdx.x*64, r0 = blockIdx.y*64;
  int tid = threadIdx.x;
  int rr = tid>>2, c4 = (tid&3)*16;
  const float* p = in + (size_t)(r0+rr)*Cc + c0 + c4;
  #pragma unroll
  for (int j=0;j<16;j+=4){
    float4 q = *reinterpret_cast<const float4*>(p+j);
    t[rr][c4+j]=q.x; t[rr][c4+j+1]=q.y; t[rr][c4+j+2]=q.z; t[rr][c4+j+3]=q.w;
  }
  __syncthreads();
  int ql = tid>>2;
  int q = c0 + ql;
  int orow = (q % D)*G + q / D;
  unsigned short* op = out + (size_t)orow*(3*R);
  #pragma unroll
  for (int j=0;j<16;j++){
    float v = t[c4+j][ql];
    unsigned short h = f2bu(v);
    unsigned short l = f2bu(v - b2f(h));
    int idx = r0 + c4 + j;
    if constexpr (PAT==0){
      op[idx] = h; op[R+idx] = l; op[2*R+idx] = h;
    } else {
      op[idx] = h; op[R+idx] = h; op[2*R+idx] = l;
    }
  }
}

// -------- row split (no transpose): in[1024][512] fp32 -> out[1024][1536] bf16 (h,l,h) --
__launch_bounds__(256)
__global__ void splitA_k(const float* __restrict__ in, unsigned short* __restrict__ out){
  int idx = blockIdx.x*256 + threadIdx.x;   // 1024*512
  int m = idx >> 9, j = idx & 511;
  float v = in[idx];
  unsigned short h = f2bu(v);
  unsigned short l = f2bu(v - b2f(h));
  unsigned short* op = out + (size_t)m*1536 + j;
  op[0] = h; op[512] = l; op[1024] = h;
}

__global__ void zero_k(float* __restrict__ p){
  p[blockIdx.x*256 + threadIdx.x] = 0.f;
}

// ================= unified MFMA GEMM: global_load_lds + dbuf + counted vmcnt =============
// C[m][f] = sum_k A[m][k]*B[f][k], bf16. WM x WN waves, each owns (MTM*16) x (NTN*16).
// BK choice per kernel (round-4/7 lesson): BK=64 only where LDS-capped residency still
// covers the grid's blocks/CU demand (conv 128²: 468 blocks = 1.8/CU <= 2 @64KB); BK=32
// where demand is higher (up2: 3/CU). Accumulation order is identical across BK.
// LDS image: linear dest slot (16B) = row*CPR + chunk'; swizzle chunk' = c ^ swz(row)
// applied on the GLOBAL source address (m104-safe). 2-phase T3/T4 pipeline: stage t+1
// before vmcnt(LPT) for t; loads in flight across both raw s_barriers, never drained.
// BN-FOLD: MODE 4 (weff): if gpf, scale cols by sc0 + atomicAdd sh0-dot into aux (bias
// fold). MODE 0: bias+biasAdd, residual scaled by gpf, writes bf16 xcl + BN partials.
// MODE 1: conv3d im2col K-split z (XCD-bijective z-major swizzle -> B L2-resident),
// MODE 2: up1 (relu+bias, convT scatter, 3-block h/l/h), MODE 5: up2 + fused SG dot.
template<int WM, int WN, int MTM, int NTN, int MODE, int BK>
__launch_bounds__(256)
__global__ void mmL_k(const unsigned short* __restrict__ A,
                      const unsigned short* __restrict__ B,
                      const float* __restrict__ bias,
                      const unsigned short* __restrict__ res,
                      const float* __restrict__ gpf,
                      float* __restrict__ outf,
                      unsigned short* __restrict__ outs,
                      float* __restrict__ aux,
                      int K){
  constexpr int BM  = WM*MTM*16;
  constexpr int BN  = WN*NTN*16;
  constexpr int CPR = BK/8;            // 16B chunks per row
  constexpr int KS  = BK/32;           // k-subtiles per step
  constexpr int AIT = (BM*CPR)/256;    // A chunks per thread
  constexpr int NBC = (BN*CPR)/256;    // B chunks per thread
  constexpr int LPT = AIT + NBC;       // loads in flight per thread per stage
  __shared__ __align__(16) short As[2*BM*BK];
  __shared__ __align__(16) short Bs[2*BN*BK];
  const int tid = threadIdx.x;
  const int wv = tid>>6, lane = tid&63, l15 = lane&15, quad = lane>>4;
  const int wvm = wv / WN, wvf = wv % WN;
  const int wbase = wv<<6;             // wave-uniform LDS slot base (64 slots/wave)

  int bx = blockIdx.x, by = blockIdx.y, bz = blockIdx.z;
  if constexpr (MODE==1){
    const int gx = gridDim.x, gy = gridDim.y, gz = gridDim.z;
    const int n = gx*gy*gz;
    const int lin = bx + gx*(by + gy*bz);
    const int q = n >> 3, r = n & 7;
    const int xcd = lin & 7, j = lin >> 3;
    const int work = (xcd < r ? xcd*(q+1) : r*(q+1) + (xcd-r)*q) + j;
    by = work % gy;                 // y minor
    const int t = work / gy;
    bx = t % gx;                    // x middle
    bz = t / gx;                    // z major (chunk == one kt/kh slice)
  }
  const int m0 = bx*BM;
  const int fblk = by*BN;
  const int z = bz;

  auto swz = [](int row){ if constexpr (BK==32) return (row>>1)&3; else return row&7; };

  // ---- staging addresses (source-side swizzle; LDS dest linear: slot = it*256+tid) ----
  size_t aAddr[AIT];
  #pragma unroll
  for (int it=0; it<AIT; ++it){
    int s = tid + it*256;
    int arow = s/CPR;
    int ac = (s&(CPR-1)) ^ swz(arow);
    int m = m0 + arow;
    if constexpr (MODE==1){
      int mm = m < 1568 ? m : 1567;
      int b = mm/392, r = mm%392;
      int t = r/196, r2 = r%196;
      int hh = r2/14, ww = r2%14;
      int kt = z/3, kh = z%3;
      int sp = ((b*4 + t + kt)*16 + hh + kh)*16 + ww;
      aAddr[it] = (size_t)sp*1024 + ac*8;
    } else {
      aAddr[it] = (size_t)m*K + ac*8;
    }
  }
  size_t bAddr[NBC];
  #pragma unroll
  for (int it=0; it<NBC; ++it){
    int s = tid + it*256;
    int row = s/CPR;
    int c = (s&(CPR-1)) ^ swz(row);
    int f = fblk + row;
    if constexpr (MODE==0)      bAddr[it] = (size_t)f*1024 + c*8;
    else if constexpr (MODE==1) bAddr[it] = (size_t)f*27648 + (size_t)z*3072 + c*8;
    else                        bAddr[it] = ((size_t)z*512 + f)*(size_t)K + c*8;
  }
  // ---- fragment LDS slots (swizzled), per k-subtile ----
  int aslot[MTM][KS];
  #pragma unroll
  for (int mt=0;mt<MTM;++mt)
    #pragma unroll
    for (int ks=0;ks<KS;++ks){
      int row = wvm*MTM*16 + mt*16 + l15;
      aslot[mt][ks] = row*CPR + ((ks*4 + quad) ^ swz(row));
    }
  int bslot[NTN][KS];
  #pragma unroll
  for (int nt=0;nt<NTN;++nt)
    #pragma unroll
    for (int ks=0;ks<KS;++ks){
      int row = wvf*NTN*16 + nt*16 + l15;
      bslot[nt][ks] = row*CPR + ((ks*4 + quad) ^ swz(row));
    }

  float4v acc[MTM][NTN];
  #pragma unroll
  for (int i=0;i<MTM;i++)
    #pragma unroll
    for (int j=0;j<NTN;j++) acc[i][j]=(float4v){0,0,0,0};

  auto stage = [&](int buf, int k0){
    #pragma unroll
    for (int it=0; it<AIT; ++it)
      GLDS16(A + aAddr[it] + k0, As + buf*(BM*BK) + (it*256 + wbase)*8);
    #pragma unroll
    for (int it=0; it<NBC; ++it)
      GLDS16(B + bAddr[it] + k0, Bs + buf*(BN*BK) + (it*256 + wbase)*8);
  };
  auto computeTile = [&](int buf){
    const short* ap = As + buf*(BM*BK);
    const short* bp = Bs + buf*(BN*BK);
    #pragma unroll
    for (int ks=0; ks<KS; ++ks){
      short8 bf[NTN];
      #pragma unroll
      for (int nt=0;nt<NTN;++nt)
        bf[nt] = *reinterpret_cast<const short8*>(bp + bslot[nt][ks]*8);
      #pragma unroll
      for (int mt=0;mt<MTM;++mt){
        short8 af = *reinterpret_cast<const short8*>(ap + aslot[mt][ks]*8);
        #pragma unroll
        for (int nt=0;nt<NTN;++nt)
          acc[mt][nt] = __builtin_amdgcn_mfma_f32_16x16x32_bf16(af, bf[nt], acc[mt][nt],0,0,0);
      }
    }
  };

  stage(0, 0);
  int cur = 0;
  for (int k0 = 0; k0 < K-BK; k0 += BK){
    stage(cur^1, k0+BK);               // tile t+1 in flight across the wait+barriers
    if constexpr (LPT==8)      asm volatile("s_waitcnt vmcnt(8)" ::: "memory");
    else if constexpr (LPT==6) asm volatile("s_waitcnt vmcnt(6)" ::: "memory");
    else if constexpr (LPT==5) asm volatile("s_waitcnt vmcnt(5)" ::: "memory");
    else if constexpr (LPT==4) asm volatile("s_waitcnt vmcnt(4)" ::: "memory");
    else                       asm volatile("s_waitcnt vmcnt(3)" ::: "memory");
    __builtin_amdgcn_sched_barrier(0);
    __builtin_amdgcn_s_barrier();      // all waves' tile-t loads landed
    computeTile(cur);
    asm volatile("s_waitcnt lgkmcnt(0)" ::: "memory");
    __builtin_amdgcn_sched_barrier(0);
    __builtin_amdgcn_s_barrier();      // all waves' ds_reads done before buf reuse
    cur ^= 1;
  }
  asm volatile("s_waitcnt vmcnt(0)" ::: "memory");
  __builtin_amdgcn_sched_barrier(0);
  __builtin_amdgcn_s_barrier();
  computeTile(cur);

  if constexpr (MODE==0){
    // BN-folded nonlocal epilogue: v = relu(acc+bias+biasAdd) + res*sc + sh -> bf16 xcl,
    // plus per-block column stats (sum, sum^2) into aux.
    const float* badd = outf;          // bias-fold accumulator (l=1) or nullptr (l=0)
    float sacc[NTN] = {}, s2acc[NTN] = {};
    #pragma unroll
    for (int nt=0;nt<NTN;++nt){
      int f = fblk + wvf*NTN*16 + nt*16 + l15;
      float bi = bias[f] + (badd ? badd[f] : 0.f);
      float rsc = 1.f, rsh = 0.f;
      if (gpf){ rsc = gpf[f]; rsh = gpf[1024+f]; }
      #pragma unroll
      for (int mt=0;mt<MTM;++mt){
        #pragma unroll
        for (int r=0;r<4;++r){
          int m = m0 + wvm*MTM*16 + mt*16 + quad*4 + r;
          float v = fmaxf(acc[mt][nt][r]+bi, 0.f) + b2f(res[(size_t)m*1024 + f])*rsc + rsh;
          outs[(size_t)m*1024 + f] = f2bu(v);
          sacc[nt] += v; s2acc[nt] += v*v;
        }
      }
    }
    #pragma unroll
    for (int nt=0;nt<NTN;++nt){
      float s = sacc[nt], s2 = s2acc[nt];
      s  += __shfl_xor(s, 16);  s  += __shfl_xor(s, 32);
      s2 += __shfl_xor(s2, 16); s2 += __shfl_xor(s2, 32);
      if (quad==0){
        int f = fblk + wvf*NTN*16 + nt*16 + l15;
        aux[(size_t)bx*2048 + f] = s;
        aux[(size_t)bx*2048 + 1024 + f] = s2;
      }
    }
  } else if constexpr (MODE==1){
    #pragma unroll
    for (int mt=0;mt<MTM;++mt)
      #pragma unroll
      for (int nt=0;nt<NTN;++nt){
        int f = fblk + wvf*NTN*16 + nt*16 + l15;
        #pragma unroll
        for (int r=0;r<4;++r){
          int m = m0 + wvm*MTM*16 + mt*16 + quad*4 + r;
          if (m < 1568) outf[((size_t)z*1568 + m)*512 + f] = acc[mt][nt][r];
        }
      }
  } else if constexpr (MODE==2){
    int kk = z>>1, ll = z&1;
    #pragma unroll
    for (int mt=0;mt<MTM;++mt)
      #pragma unroll
      for (int nt=0;nt<NTN;++nt){
        int f = fblk + wvf*NTN*16 + nt*16 + l15;
        float bi = bias[f];
        #pragma unroll
        for (int r=0;r<4;++r){
          int m = m0 + wvm*MTM*16 + mt*16 + quad*4 + r;
          int bt = m>>6, p = m&63;
          long orow = (long)bt*256 + (2*(p>>3)+kk)*16 + 2*(p&7)+ll;
          float v = fmaxf(acc[mt][nt][r]+bi, 0.f);
          unsigned short h = f2bu(v);
          unsigned short l = f2bu(v - b2f(h));
          unsigned short* rp = outs + (size_t)orow*1536 + f;
          rp[0] = h; rp[512] = l; rp[1024] = h;
        }
      }
  } else if constexpr (MODE==5){
    int kk = z>>1, ll = z&1;
    #pragma unroll
    for (int mt=0;mt<MTM;++mt){
      int mbase = m0 + wvm*MTM*16 + mt*16;
      int bt = mbase>>8, b6 = bt/6, p0 = mbase&255;
      float gv[NTN], bv[NTN];
      #pragma unroll
      for (int nt=0;nt<NTN;++nt){
        int f = fblk + wvf*NTN*16 + nt*16 + l15;
        gv[nt] = gpf[b6*512 + f];
        bv[nt] = bias[f];
      }
      #pragma unroll
      for (int r=0;r<4;++r){
        int p = p0 + quad*4 + r;
        long orow = (long)bt*1024 + (2*(p>>4)+kk)*32 + 2*(p&15)+ll;
        float sdot = 0.f;
        #pragma unroll
        for (int nt=0;nt<NTN;++nt){
          int f = fblk + wvf*NTN*16 + nt*16 + l15;
          float v = acc[mt][nt][r] + bv[nt];
          outf[(size_t)orow*512 + f] = v;
          sdot += v * gv[nt];
        }
        sdot += __shfl_xor(sdot, 1); sdot += __shfl_xor(sdot, 2);
        sdot += __shfl_xor(sdot, 4); sdot += __shfl_xor(sdot, 8);
        if (l15==0) atomicAdd(aux + orow, sdot);
      }
    }
  } else {  // MODE 4: weff bf16 out; BN-fold: scale cols by sc0, bias partials via sh0
    if (gpf){
      float sc[NTN], sh[NTN];
      #pragma unroll
      for (int nt=0;nt<NTN;++nt){
        int f = fblk + wvf*NTN*16 + nt*16 + l15;
        sc[nt] = gpf[f]; sh[nt] = gpf[1024+f];
      }
      #pragma unroll
      for (int mt=0;mt<MTM;++mt){
        #pragma unroll
        for (int r=0;r<4;++r){
          int m = m0 + wvm*MTM*16 + mt*16 + quad*4 + r;
          float part = 0.f;
          #pragma unroll
          for (int nt=0;nt<NTN;++nt){
            int f = fblk + wvf*NTN*16 + nt*16 + l15;
            float a = acc[mt][nt][r];
            part += a * sh[nt];
            outs[(size_t)m*1024 + f] = f2bu(a * sc[nt]);
          }
          part += __shfl_xor(part, 1); part += __shfl_xor(part, 2);
          part += __shfl_xor(part, 4); part += __shfl_xor(part, 8);
          if (l15==0) atomicAdd(aux + m, part);
        }
      }
    } else {
      #pragma unroll
      for (int mt=0;mt<MTM;++mt)
        #pragma unroll
        for (int nt=0;nt<NTN;++nt){
          int f = fblk + wvf*NTN*16 + nt*16 + l15;
          #pragma unroll
          for (int r=0;r<4;++r){
            int m = m0 + wvm*MTM*16 + mt*16 + quad*4 + r;
            outs[(size_t)m*1024 + f] = f2bu(acc[mt][nt][r]);
          }
        }
    }
  }
}

// ---------------- BN stats combine: bnp[64][2][1024] -> scale/shift mv ------------------
__global__ void stats_comb(const float* __restrict__ bnp, const float* __restrict__ g,
                           const float* __restrict__ beta, float* __restrict__ mv){
  int c = blockIdx.x*256 + threadIdx.x;   // 1024
  float S=0.f, S2=0.f;
  #pragma unroll 8
  for (int s=0;s<64;s++){ S += bnp[(size_t)s*2048 + c]; S2 += bnp[(size_t)s*2048 + 1024 + c]; }
  float m = S * (1.f/4096.f);
  float var = S2 * (1.f/4096.f) - m*m;
  float inv = rsqrtf(var + 1e-5f);
  float sc = inv * g[c];
  mv[c] = sc;
  mv[1024 + c] = beta[c] - m*sc;
}

// ---- weight permute + BN fold: wtt[f][j*1024+c] = bf16(tp_w[f][c*27+j]*sc1[c]),
//      tpb2[f] = tp_b[f] + sum_{j,c} tp_w[f][c*27+j]*sh1[c] ------------------------------
__launch_bounds__(256)
__global__ void wperm_k(const float* __restrict__ w, const float* __restrict__ mv1,
                        const float* __restrict__ tpb,
                        unsigned short* __restrict__ wtt, float* __restrict__ tpb2){
  __shared__ float ls[3456];
  __shared__ float rs[256];
  int f = blockIdx.x;
  const float* src = w + (size_t)f*27648;
  unsigned short* dst = wtt + (size_t)f*27648;
  float part = 0.f;
  for (int cc=0; cc<8; ++cc){
    __syncthreads();
    for (int i=threadIdx.x; i<3456; i+=256) ls[i] = src[cc*3456 + i];
    __syncthreads();
    for (int u=threadIdx.x; u<3456; u+=256){
      int j = u >> 7, c = u & 127;
      int ch = cc*128 + c;
      float wv = ls[c*27 + j];
      dst[(size_t)j*1024 + ch] = f2bu(wv * mv1[ch]);
      part += wv * mv1[1024 + ch];
    }
  }
  rs[threadIdx.x] = part; __syncthreads();
  for (int st=128; st>0; st>>=1){
    if (threadIdx.x < st) rs[threadIdx.x] += rs[threadIdx.x+st];
    __syncthreads();
  }
  if (threadIdx.x==0) tpb2[f] = tpb[f] + rs[0];
}

// ---------------- goal_pre: z splits the 392 positions 4-ways; atomicAdd into gp --------
__launch_bounds__(256)
__global__ void gp2_k(const float* __restrict__ part9, const float* __restrict__ tpb,
                      float* __restrict__ gp){
  int b = blockIdx.x;
  int fc = blockIdx.y;
  int z = blockIdx.z;          // 4 p-chunks of 98
  int fi = threadIdx.x & 31, pi = threadIdx.x >> 5;
  int f = fc*32 + fi;
  float bias = tpb[f];
  float a = 0.f;
  for (int p = z*98 + pi; p < z*98 + 98; p += 8){
    size_t base = ((size_t)(b*392 + p))*512 + f;
    float v = bias;
    #pragma unroll
    for (int i=0;i<9;i++) v += part9[(size_t)i*802816 + base];
    a += fmaxf(v, 0.f);
  }
  __shared__ float red[256];
  red[threadIdx.x] = a; __syncthreads();
  for (int st=4; st>0; st>>=1){
    if (pi < st) red[pi*32+fi] += red[(pi+st)*32+fi];
    __syncthreads();
  }
  if (pi==0) atomicAdd(gp + b*512 + f, red[fi] * (1.f/392.f));
}

// ---------------- PE table: peN[n][c] ---------------------------------------------------
__global__ void pen_k(float* __restrict__ peN){
  int idx = blockIdx.x*256 + threadIdx.x;   // 524288
  int n = idx >> 9, c = idx & 511;
  float div = expf(-0.035977892f * (float)(c>>1));   // 2*ln(10000)/512
  float ang = (float)n * div;
  peN[idx] = (c & 1) ? cosf(ang) : sinf(ang);
}

// ---------------- softmax over n: attn[bt][n] normalized --------------------------------
__launch_bounds__(256)
__global__ void softmax_k(const float* __restrict__ SG, float* __restrict__ attn){
  int bt = blockIdx.x; int tid = threadIdx.x;
  float4 v = *reinterpret_cast<const float4*>(SG + bt*1024 + tid*4);
  float mx = fmaxf(fmaxf(v.x,v.y), fmaxf(v.z,v.w));
  __shared__ float red[256];
  red[tid] = mx; __syncthreads();
  for (int st=128; st>0; st>>=1){
    if (tid<st) red[tid] = fmaxf(red[tid], red[tid+st]);
    __syncthreads();
  }
  float m = red[0]; __syncthreads();
  float4 e;
  e.x = expf(v.x-m); e.y = expf(v.y-m); e.z = expf(v.z-m); e.w = expf(v.w-m);
  red[tid] = e.x+e.y+e.z+e.w; __syncthreads();
  for (int st=128; st>0; st>>=1){
    if (tid<st) red[tid] += red[tid+st];
    __syncthreads();
  }
  float inv = 1.0f/red[0];
  e.x*=inv; e.y*=inv; e.z*=inv; e.w*=inv;
  *reinterpret_cast<float4*>(attn + bt*1024 + tid*4) = e;
}

// ---- sga[bt][c] += sum_{n in slice} attn[n]*(scl[n][c]+pe[n][c])  (atomic, 8 slices) ---
__launch_bounds__(256)
__global__ void sga2_k(const float* __restrict__ scl, const float* __restrict__ peN,
                       const float* __restrict__ attn, float* __restrict__ sga){
  int bt = blockIdx.x, sl = blockIdx.y;   // 24 x 8
  int tid = threadIdx.x;
  __shared__ float at[128];
  if (tid < 128) at[tid] = attn[bt*1024 + sl*128 + tid];
  __syncthreads();
  float acc0 = 0.f, acc1 = 0.f;
  for (int j=0;j<128;j++){
    int n = sl*128 + j;
    float a = at[j];
    const float* row = scl + ((size_t)bt*1024 + n)*512;
    const float* pe  = peN + (size_t)n*512;
    acc0 += a * (row[tid] + pe[tid]);
    acc1 += a * (row[tid+256] + pe[tid+256]);
  }
  atomicAdd(sga + (size_t)bt*512 + tid, acc0);
  atomicAdd(sga + (size_t)bt*512 + 256 + tid, acc1);
}

// ---------------- 512->512(relu)->128 MLP head (fp32 weights) ---------------------------
__launch_bounds__(256)
__global__ void mlp_k(const float* __restrict__ in, const float* __restrict__ w1,
                      const float* __restrict__ b1, const float* __restrict__ w2,
                      const float* __restrict__ b2, float* __restrict__ out){
  int bb = blockIdx.x; int tid = threadIdx.x;
  __shared__ float xv[512]; __shared__ float h[512];
  xv[tid] = in[(size_t)bb*512 + tid];
  xv[tid+256] = in[(size_t)bb*512 + 256 + tid];
  __syncthreads();
  #pragma unroll
  for (int oo=0;oo<2;oo++){
    int o = tid + oo*256;
    const float* wr = w1 + (size_t)o*512;
    float a=0.f;
    for (int c=0;c<512;c+=4){
      float4 q = *reinterpret_cast<const float4*>(wr+c);
      a += xv[c]*q.x + xv[c+1]*q.y + xv[c+2]*q.z + xv[c+3]*q.w;
    }
    h[o] = fmaxf(a + b1[o], 0.f);
  }
  __syncthreads();
  if (tid < 128){
    const float* wr = w2 + (size_t)tid*512;
    float a=0.f;
    for (int c=0;c<512;c+=4){
      float4 q = *reinterpret_cast<const float4*>(wr+c);
      a += h[c]*q.x + h[c+1]*q.y + h[c+2]*q.z + h[c+3]*q.w;
    }
    out[(size_t)bb*128+tid] = a + b2[tid];
  }
}

extern "C" void kernel_launch(void* const* d_in, const int* in_sizes, int n_in,
                              void* d_out, int out_size, void* d_ws, size_t ws_size,
                              hipStream_t stream){
  (void)in_sizes; (void)n_in; (void)out_size; (void)ws_size;
  const float* ctx   = (const float*)d_in[0];
  const float* frame = (const float*)d_in[1];
  const float* nl_vw[2] = {(const float*)d_in[4],  (const float*)d_in[11]};
  const float* nl_ow[2] = {(const float*)d_in[5],  (const float*)d_in[12]};
  const float* nl_ob[2] = {(const float*)d_in[6],  (const float*)d_in[13]};
  const float* nl_g[2]  = {(const float*)d_in[7],  (const float*)d_in[14]};
  const float* nl_be[2] = {(const float*)d_in[8],  (const float*)d_in[15]};
  const float* tp_w = (const float*)d_in[16]; const float* tp_b = (const float*)d_in[17];
  const float* up1w = (const float*)d_in[18]; const float* up1b = (const float*)d_in[19];
  const float* up2w = (const float*)d_in[20]; const float* up2b = (const float*)d_in[21];
  const float* og1w = (const float*)d_in[22]; const float* og1b = (const float*)d_in[23];
  const float* og2w = (const float*)d_in[24]; const float* og2b = (const float*)d_in[25];
  const float* os1w = (const float*)d_in[26]; const float* os1b = (const float*)d_in[27];
  const float* os2w = (const float*)d_in[28]; const float* os2b = (const float*)d_in[29];
  float* out = (float*)d_out;

  char* wsp = (char*)d_ws;
  // ---- persistent region ----
  float* bias2   = (float*)(wsp + 65536);         // 4KB  [1024] weff bias-fold acc
  float* tpb2    = (float*)(wsp + 69632);         // 2KB  [512] conv bias-fold
  float* gp      = (float*)(wsp + 73728);         // 8KB  [4][512] (atomic-accumulated)
  float* mv0     = (float*)(wsp + 131072);        // 8KB  BN scale/shift layer 0
  float* mv1     = (float*)(wsp + 139264);        // 8KB  BN scale/shift layer 1
  float* SG      = (float*)(wsp + 147456);        // 98304 (atomic-accumulated)
  float* attn    = (float*)(wsp + 245760);        // 98304
  float* sga     = (float*)(wsp + 344064);        // 49152 (atomic-accumulated)
  float* peN     = (float*)(wsp + 786432);        // 2097152 [1024][512]
  bf16*  weff    = (bf16*) (wsp + 2883584);       // 2097152 [1024][1024] bf16
  unsigned short* w1sp = (unsigned short*)(wsp + 4980736);   // 12582912 [4][512][3072]
  unsigned short* w2sp = (unsigned short*)(wsp + 17563648);  // 6291456  [4][512][1536]
  char* ov = wsp + 23855104;
  // phase 1 (nonlocal, BN folded -> xcl ping-pong):
  bf16*  xclA = (bf16*) (ov);                     // 8 MB [4096][1024]
  bf16*  xclB = (bf16*) (ov + 8388608);           // 8 MB (dead after l=1 reads it)
  // phase 1 staging in the (dead until phase 2) part9 region:
  unsigned short* Asp = (unsigned short*)(ov + 36700160);            // 3 MB [1024][1536]
  unsigned short* Bsp = (unsigned short*)(ov + 36700160 + 3145728);  // 3 MB [1024][1536]
  float* bnp = (float*)(ov + 36700160 + 6291456); // 512 KB [64][2][1024] BN partials
  // phase 2 (conv): wtt aliases xclB region (written after l=1 MODE0 consumed xclB)
  unsigned short* wtt = (unsigned short*)(ov + 8388608);   // 28.3 MB [512][27648]
  float* part9 = (float*)(ov + 36700160);         // 28.9 MB [9][1568][512]
  // frame staging: aliases part9 (written after gp2_k reads part9)
  unsigned short* Fsp = (unsigned short*)(ov + 36700160);  // 9.4 MB [1536][3072]
  // phase 3 (after gp2_k; xclA/wtt dead):
  unsigned short* s1sp = (unsigned short*)(ov);   // 18.9 MB [6144][1536]
  float* scl  = (float*)(ov + 18874368);          // 50.3 MB [24576][512]

  // prep (independent). One range-zero covers bias2/gp/SG/sga (all atomic-accumulated)
  // plus scratch (tpb2/mv0/mv1/attn are fully rewritten before use).
  permT_k<bf16><<<dim3(4,16,16),256,0,stream>>>(ctx, xclA, 256, 1024, 1, 1, 262144L, 262144L);
  permTsplit3_k<1><<<dim3(32,16,1),256,0,stream>>>(up1w, w1sp, 2048, 1024, 4, 512, 0L, 0L);
  permTsplit3_k<1><<<dim3(32,8,1),256,0,stream>>>(up2w, w2sp, 2048, 512, 4, 512, 0L, 0L);
  pen_k<<<2048,256,0,stream>>>(peN);
  zero_k<<<320,256,0,stream>>>((float*)(wsp + 65536));   // bytes 65536..393216

  // nonlocal layer 0: xclA -> xclB (BN deferred via fold into layer-1 consumers)
  splitA_k<<<2048,256,0,stream>>>(nl_ow[0], Asp);
  permTsplit3_k<1><<<dim3(16,8,1),256,0,stream>>>(nl_vw[0], Bsp, 1024, 512, 1, 1, 0L, 0L);
  mmL_k<1,4,2,2,4,64><<<dim3(32,8,1),256,0,stream>>>(Asp, Bsp, nullptr, nullptr, nullptr,
      nullptr, (unsigned short*)weff, nullptr, 1536);
  mmL_k<1,4,4,2,0,64><<<dim3(64,8,1),256,0,stream>>>((const unsigned short*)xclA,
      (const unsigned short*)weff, nl_ob[0], (const unsigned short*)xclA, nullptr,
      nullptr, (unsigned short*)xclB, bnp, 1024);
  stats_comb<<<4,256,0,stream>>>(bnp, nl_g[0], nl_be[0], mv0);

  // nonlocal layer 1: xclB -> xclA; weff cols scaled by sc0, sh0 folded to bias2
  splitA_k<<<2048,256,0,stream>>>(nl_ow[1], Asp);
  permTsplit3_k<1><<<dim3(16,8,1),256,0,stream>>>(nl_vw[1], Bsp, 1024, 512, 1, 1, 0L, 0L);
  mmL_k<1,4,2,2,4,64><<<dim3(32,8,1),256,0,stream>>>(Asp, Bsp, nullptr, nullptr, mv0,
      nullptr, (unsigned short*)weff, bias2, 1536);
  mmL_k<1,4,4,2,0,64><<<dim3(64,8,1),256,0,stream>>>((const unsigned short*)xclB,
      (const unsigned short*)weff, nl_ob[1], (const unsigned short*)xclB, mv0,
      bias2, (unsigned short*)xclA, bnp, 1024);
  stats_comb<<<4,256,0,stream>>>(bnp, nl_g[1], nl_be[1], mv1);

  // temporal-pool conv (im2col GEMM, K-split 9); BN-1 folded into wtt (sc1) + tpb2 (sh1)
  // 128x128 / BK=64: 64KB LDS -> 2 blocks/CU >= grid demand 468/256=1.8 (round-4 trap
  // does not apply); halves per-K-step barrier+wait fixed cost vs BK=32.
  wperm_k<<<512,256,0,stream>>>(tp_w, mv1, tp_b, wtt, tpb2);
  mmL_k<2,2,4,4,1,64><<<dim3(13,4,9),256,0,stream>>>((const unsigned short*)xclA, wtt,
      nullptr, nullptr, nullptr, part9, nullptr, nullptr, 3072);
  gp2_k<<<dim3(4,16,4),256,0,stream>>>(part9, tpb2, gp);

  // frame path (3-block split-bf16 == fp32-accurate); Fsp aliases part9 -> after gp2_k
  permTsplit3_k<0><<<dim3(1,16,24),256,0,stream>>>(frame, Fsp, 64, 1024, 1, 1, 65536L, 196608L);
  mmL_k<1,4,2,2,2,64><<<dim3(48,4,4),256,0,stream>>>(Fsp, w1sp, up1b, nullptr, nullptr,
      nullptr, s1sp, nullptr, 3072);
  // up2 + fused SG partial dot (BK=32: grid demand 3/CU > 64KB residency 2 -> keep 32KB)
  mmL_k<2,2,4,4,5,32><<<dim3(48,4,4),256,0,stream>>>(s1sp, w2sp, up2b, nullptr, gp,
      scl, nullptr, SG, 1536);

  // attention tail
  softmax_k<<<24,256,0,stream>>>(SG, attn);
  sga2_k<<<dim3(24,8),256,0,stream>>>(scl, peN, attn, sga);

  // heads
  mlp_k<<<4,256,0,stream>>>(gp, og1w, og1b, og2w, og2b, out);
  mlp_k<<<24,256,0,stream>>>(sga, os1w, os1b, os2w, os2b, out + 512);
}

// Round 9
// 616.985 us; speedup vs baseline: 1.3206x; 1.0708x over previous
//
#include <hip/hip_runtime.h>
#include <hip/hip_bf16.h>

using bf16 = __hip_bfloat16;
typedef short short8 __attribute__((ext_vector_type(8)));
typedef float float4v __attribute__((ext_vector_type(4)));

__device__ __forceinline__ float b2f(unsigned short u){
  unsigned int x = ((unsigned int)u) << 16; float f;
  __builtin_memcpy(&f, &x, 4); return f;
}
__device__ __forceinline__ float b2f(bf16 v){ return __bfloat162float(v); }
__device__ __forceinline__ unsigned short f2bu(float x){
  bf16 h = __float2bfloat16(x); unsigned short u;
  __builtin_memcpy(&u, &h, 2); return u;
}

// async global->LDS, 16B per lane, dest = wave-uniform base + lane*16
#define GLDS16(g, l) __builtin_amdgcn_global_load_lds( \
    (const __attribute__((address_space(1))) void*)(g), \
    (__attribute__((address_space(3))) void*)(l), 16, 0, 0)

// -------- batched permuted transpose fp32->bf16: per z, in[R][Cc] -> out[(q%D)*G+q/D][R] -
template<class TO>
__launch_bounds__(256)
__global__ void permT_k(const float* __restrict__ inp, TO* __restrict__ outp,
                        int Cc, int R, int D, int G, long inS, long outS){
  __shared__ float t[64][65];
  int z = blockIdx.z;
  const float* in = inp + (size_t)z*inS;
  TO* out = outp + (size_t)z*outS;
  int c0 = blockIdx.x*64, r0 = blockIdx.y*64;
  int tid = threadIdx.x;
  int rr = tid>>2, c4 = (tid&3)*16;
  const float* p = in + (size_t)(r0+rr)*Cc + c0 + c4;
  #pragma unroll
  for (int j=0;j<16;j+=4){
    float4 q = *reinterpret_cast<const float4*>(p+j);
    t[rr][c4+j]=q.x; t[rr][c4+j+1]=q.y; t[rr][c4+j+2]=q.z; t[rr][c4+j+3]=q.w;
  }
  __syncthreads();
  int ql = tid>>2;
  int q = c0 + ql;
  int orow = (q % D)*G + q / D;
  TO* op = out + (size_t)orow*R + r0 + c4;
  #pragma unroll
  for (int j=0;j<16;j++){
    if constexpr (sizeof(TO)==2) op[j] = __float2bfloat16(t[c4+j][ql]);
    else op[j] = t[c4+j][ql];
  }
}

// -------- 3-block split transpose: rows of length 3R.
// PAT=0 (A-side): blocks (hi, lo, hi).  PAT=1 (B-side): blocks (hi, hi, lo).
// Paired dot over 3R gives ah*bh + al*bh + ah*bl  == fp32-accurate product.
template<int PAT>
__launch_bounds__(256)
__global__ void permTsplit3_k(const float* __restrict__ inp, unsigned short* __restrict__ outp,
                              int Cc, int R, int D, int G, long inS, long outS){
  __shared__ float t[64][65];
  int z = blockIdx.z;
  const float* in = inp + (size_t)z*inS;
  unsigned short* out = outp + (size_t)z*outS;
  int c0 = blockIdx.x*64, r0 = blockIdx.y*64;
  int tid = threadIdx.x;
  int rr = tid>>2, c4 = (tid&3)*16;
  const float* p = in + (size_t)(r0+rr)*Cc + c0 + c4;
  #pragma unroll
  for (int j=0;j<16;j+=4){
    float4 q = *reinterpret_cast<const float4*>(p+j);
    t[rr][c4+j]=q.x; t[rr][c4+j+1]=q.y; t[rr][c4+j+2]=q.z; t[rr][c4+j+3]=q.w;
  }
  __syncthreads();
  int ql = tid>>2;
  int q = c0 + ql;
  int orow = (q % D)*G + q / D;
  unsigned short* op = out + (size_t)orow*(3*R);
  #pragma unroll
  for (int j=0;j<16;j++){
    float v = t[c4+j][ql];
    unsigned short h = f2bu(v);
    unsigned short l = f2bu(v - b2f(h));
    int idx = r0 + c4 + j;
    if constexpr (PAT==0){
      op[idx] = h; op[R+idx] = l; op[2*R+idx] = h;
    } else {
      op[idx] = h; op[R+idx] = h; op[2*R+idx] = l;
    }
  }
}

// -------- row split (no transpose): in[1024][512] fp32 -> out[1024][1536] bf16 (h,l,h) --
__launch_bounds__(256)
__global__ void splitA_k(const float* __restrict__ in, unsigned short* __restrict__ out){
  int idx = blockIdx.x*256 + threadIdx.x;   // 1024*512
  int m = idx >> 9, j = idx & 511;
  float v = in[idx];
  unsigned short h = f2bu(v);
  unsigned short l = f2bu(v - b2f(h));
  unsigned short* op = out + (size_t)m*1536 + j;
  op[0] = h; op[512] = l; op[1024] = h;
}

__global__ void zero_k(float* __restrict__ p){
  p[blockIdx.x*256 + threadIdx.x] = 0.f;
}

// ================= unified MFMA GEMM: global_load_lds + dbuf + counted vmcnt =============
// C[m][f] = sum_k A[m][k]*B[f][k], bf16. WM x WN waves, each owns (MTM*16) x (NTN*16).
// BK choice per kernel (round-4/7 lesson): BK=64 only where LDS-capped residency still
// covers the grid's blocks/CU demand (conv 128²: 468 blocks = 1.8/CU <= 2 @64KB); BK=32
// where demand is higher (up2: 3/CU). Accumulation order is identical across BK.
// LDS image: linear dest slot (16B) = row*CPR + chunk'; swizzle chunk' = c ^ swz(row)
// applied on the GLOBAL source address (m104-safe). 2-phase T3/T4 pipeline: stage t+1
// before vmcnt(LPT) for t; loads in flight across both raw s_barriers, never drained.
// BN-FOLD: MODE 4 (weff): if gpf, scale cols by sc0 + atomicAdd sh0-dot into aux (bias
// fold). MODE 0: bias+biasAdd, residual scaled by gpf, writes bf16 xcl + BN partials.
// MODE 1: conv3d im2col K-split z (XCD-bijective z-major swizzle -> B L2-resident),
// MODE 2: up1 (relu+bias, convT scatter, 3-block h/l/h), MODE 5: up2 + fused SG dot.
template<int WM, int WN, int MTM, int NTN, int MODE, int BK>
__launch_bounds__(256)
__global__ void mmL_k(const unsigned short* __restrict__ A,
                      const unsigned short* __restrict__ B,
                      const float* __restrict__ bias,
                      const unsigned short* __restrict__ res,
                      const float* __restrict__ gpf,
                      float* __restrict__ outf,
                      unsigned short* __restrict__ outs,
                      float* __restrict__ aux,
                      int K){
  constexpr int BM  = WM*MTM*16;
  constexpr int BN  = WN*NTN*16;
  constexpr int CPR = BK/8;            // 16B chunks per row
  constexpr int KS  = BK/32;           // k-subtiles per step
  constexpr int AIT = (BM*CPR)/256;    // A chunks per thread
  constexpr int NBC = (BN*CPR)/256;    // B chunks per thread
  constexpr int LPT = AIT + NBC;       // loads in flight per thread per stage
  __shared__ __align__(16) short As[2*BM*BK];
  __shared__ __align__(16) short Bs[2*BN*BK];
  const int tid = threadIdx.x;
  const int wv = tid>>6, lane = tid&63, l15 = lane&15, quad = lane>>4;
  const int wvm = wv / WN, wvf = wv % WN;
  const int wbase = wv<<6;             // wave-uniform LDS slot base (64 slots/wave)

  int bx = blockIdx.x, by = blockIdx.y, bz = blockIdx.z;
  if constexpr (MODE==1){
    const int gx = gridDim.x, gy = gridDim.y, gz = gridDim.z;
    const int n = gx*gy*gz;
    const int lin = bx + gx*(by + gy*bz);
    const int q = n >> 3, r = n & 7;
    const int xcd = lin & 7, j = lin >> 3;
    const int work = (xcd < r ? xcd*(q+1) : r*(q+1) + (xcd-r)*q) + j;
    by = work % gy;                 // y minor
    const int t = work / gy;
    bx = t % gx;                    // x middle
    bz = t / gx;                    // z major (chunk == one kt/kh slice)
  }
  const int m0 = bx*BM;
  const int fblk = by*BN;
  const int z = bz;

  auto swz = [](int row){ if constexpr (BK==32) return (row>>1)&3; else return row&7; };

  // ---- staging addresses (source-side swizzle; LDS dest linear: slot = it*256+tid) ----
  size_t aAddr[AIT];
  #pragma unroll
  for (int it=0; it<AIT; ++it){
    int s = tid + it*256;
    int arow = s/CPR;
    int ac = (s&(CPR-1)) ^ swz(arow);
    int m = m0 + arow;
    if constexpr (MODE==1){
      int mm = m < 1568 ? m : 1567;
      int b = mm/392, r = mm%392;
      int t = r/196, r2 = r%196;
      int hh = r2/14, ww = r2%14;
      int kt = z/3, kh = z%3;
      int sp = ((b*4 + t + kt)*16 + hh + kh)*16 + ww;
      aAddr[it] = (size_t)sp*1024 + ac*8;
    } else {
      aAddr[it] = (size_t)m*K + ac*8;
    }
  }
  size_t bAddr[NBC];
  #pragma unroll
  for (int it=0; it<NBC; ++it){
    int s = tid + it*256;
    int row = s/CPR;
    int c = (s&(CPR-1)) ^ swz(row);
    int f = fblk + row;
    if constexpr (MODE==0)      bAddr[it] = (size_t)f*1024 + c*8;
    else if constexpr (MODE==1) bAddr[it] = (size_t)f*27648 + (size_t)z*3072 + c*8;
    else                        bAddr[it] = ((size_t)z*512 + f)*(size_t)K + c*8;
  }
  // ---- fragment LDS slots (swizzled), per k-subtile ----
  int aslot[MTM][KS];
  #pragma unroll
  for (int mt=0;mt<MTM;++mt)
    #pragma unroll
    for (int ks=0;ks<KS;++ks){
      int row = wvm*MTM*16 + mt*16 + l15;
      aslot[mt][ks] = row*CPR + ((ks*4 + quad) ^ swz(row));
    }
  int bslot[NTN][KS];
  #pragma unroll
  for (int nt=0;nt<NTN;++nt)
    #pragma unroll
    for (int ks=0;ks<KS;++ks){
      int row = wvf*NTN*16 + nt*16 + l15;
      bslot[nt][ks] = row*CPR + ((ks*4 + quad) ^ swz(row));
    }

  float4v acc[MTM][NTN];
  #pragma unroll
  for (int i=0;i<MTM;i++)
    #pragma unroll
    for (int j=0;j<NTN;j++) acc[i][j]=(float4v){0,0,0,0};

  auto stage = [&](int buf, int k0){
    #pragma unroll
    for (int it=0; it<AIT; ++it)
      GLDS16(A + aAddr[it] + k0, As + buf*(BM*BK) + (it*256 + wbase)*8);
    #pragma unroll
    for (int it=0; it<NBC; ++it)
      GLDS16(B + bAddr[it] + k0, Bs + buf*(BN*BK) + (it*256 + wbase)*8);
  };
  auto computeTile = [&](int buf){
    const short* ap = As + buf*(BM*BK);
    const short* bp = Bs + buf*(BN*BK);
    #pragma unroll
    for (int ks=0; ks<KS; ++ks){
      short8 bf[NTN];
      #pragma unroll
      for (int nt=0;nt<NTN;++nt)
        bf[nt] = *reinterpret_cast<const short8*>(bp + bslot[nt][ks]*8);
      #pragma unroll
      for (int mt=0;mt<MTM;++mt){
        short8 af = *reinterpret_cast<const short8*>(ap + aslot[mt][ks]*8);
        #pragma unroll
        for (int nt=0;nt<NTN;++nt)
          acc[mt][nt] = __builtin_amdgcn_mfma_f32_16x16x32_bf16(af, bf[nt], acc[mt][nt],0,0,0);
      }
    }
  };

  stage(0, 0);
  int cur = 0;
  for (int k0 = 0; k0 < K-BK; k0 += BK){
    stage(cur^1, k0+BK);               // tile t+1 in flight across the wait+barriers
    if constexpr (LPT==8)      asm volatile("s_waitcnt vmcnt(8)" ::: "memory");
    else if constexpr (LPT==6) asm volatile("s_waitcnt vmcnt(6)" ::: "memory");
    else if constexpr (LPT==5) asm volatile("s_waitcnt vmcnt(5)" ::: "memory");
    else if constexpr (LPT==4) asm volatile("s_waitcnt vmcnt(4)" ::: "memory");
    else                       asm volatile("s_waitcnt vmcnt(3)" ::: "memory");
    __builtin_amdgcn_sched_barrier(0);
    __builtin_amdgcn_s_barrier();      // all waves' tile-t loads landed
    computeTile(cur);
    asm volatile("s_waitcnt lgkmcnt(0)" ::: "memory");
    __builtin_amdgcn_sched_barrier(0);
    __builtin_amdgcn_s_barrier();      // all waves' ds_reads done before buf reuse
    cur ^= 1;
  }
  asm volatile("s_waitcnt vmcnt(0)" ::: "memory");
  __builtin_amdgcn_sched_barrier(0);
  __builtin_amdgcn_s_barrier();
  computeTile(cur);

  if constexpr (MODE==0){
    // BN-folded nonlocal epilogue: v = relu(acc+bias+biasAdd) + res*sc + sh -> bf16 xcl,
    // plus per-block column stats (sum, sum^2) into aux.
    const float* badd = outf;          // bias-fold accumulator (l=1) or nullptr (l=0)
    float sacc[NTN] = {}, s2acc[NTN] = {};
    #pragma unroll
    for (int nt=0;nt<NTN;++nt){
      int f = fblk + wvf*NTN*16 + nt*16 + l15;
      float bi = bias[f] + (badd ? badd[f] : 0.f);
      float rsc = 1.f, rsh = 0.f;
      if (gpf){ rsc = gpf[f]; rsh = gpf[1024+f]; }
      #pragma unroll
      for (int mt=0;mt<MTM;++mt){
        #pragma unroll
        for (int r=0;r<4;++r){
          int m = m0 + wvm*MTM*16 + mt*16 + quad*4 + r;
          float v = fmaxf(acc[mt][nt][r]+bi, 0.f) + b2f(res[(size_t)m*1024 + f])*rsc + rsh;
          outs[(size_t)m*1024 + f] = f2bu(v);
          sacc[nt] += v; s2acc[nt] += v*v;
        }
      }
    }
    #pragma unroll
    for (int nt=0;nt<NTN;++nt){
      float s = sacc[nt], s2 = s2acc[nt];
      s  += __shfl_xor(s, 16);  s  += __shfl_xor(s, 32);
      s2 += __shfl_xor(s2, 16); s2 += __shfl_xor(s2, 32);
      if (quad==0){
        int f = fblk + wvf*NTN*16 + nt*16 + l15;
        aux[(size_t)bx*2048 + f] = s;
        aux[(size_t)bx*2048 + 1024 + f] = s2;
      }
    }
  } else if constexpr (MODE==1){
    #pragma unroll
    for (int mt=0;mt<MTM;++mt)
      #pragma unroll
      for (int nt=0;nt<NTN;++nt){
        int f = fblk + wvf*NTN*16 + nt*16 + l15;
        #pragma unroll
        for (int r=0;r<4;++r){
          int m = m0 + wvm*MTM*16 + mt*16 + quad*4 + r;
          if (m < 1568) outf[((size_t)z*1568 + m)*512 + f] = acc[mt][nt][r];
        }
      }
  } else if constexpr (MODE==2){
    int kk = z>>1, ll = z&1;
    #pragma unroll
    for (int mt=0;mt<MTM;++mt)
      #pragma unroll
      for (int nt=0;nt<NTN;++nt){
        int f = fblk + wvf*NTN*16 + nt*16 + l15;
        float bi = bias[f];
        #pragma unroll
        for (int r=0;r<4;++r){
          int m = m0 + wvm*MTM*16 + mt*16 + quad*4 + r;
          int bt = m>>6, p = m&63;
          long orow = (long)bt*256 + (2*(p>>3)+kk)*16 + 2*(p&7)+ll;
          float v = fmaxf(acc[mt][nt][r]+bi, 0.f);
          unsigned short h = f2bu(v);
          unsigned short l = f2bu(v - b2f(h));
          unsigned short* rp = outs + (size_t)orow*1536 + f;
          rp[0] = h; rp[512] = l; rp[1024] = h;
        }
      }
  } else if constexpr (MODE==5){
    int kk = z>>1, ll = z&1;
    #pragma unroll
    for (int mt=0;mt<MTM;++mt){
      int mbase = m0 + wvm*MTM*16 + mt*16;
      int bt = mbase>>8, b6 = bt/6, p0 = mbase&255;
      float gv[NTN], bv[NTN];
      #pragma unroll
      for (int nt=0;nt<NTN;++nt){
        int f = fblk + wvf*NTN*16 + nt*16 + l15;
        gv[nt] = gpf[b6*512 + f];
        bv[nt] = bias[f];
      }
      #pragma unroll
      for (int r=0;r<4;++r){
        int p = p0 + quad*4 + r;
        long orow = (long)bt*1024 + (2*(p>>4)+kk)*32 + 2*(p&15)+ll;
        float sdot = 0.f;
        #pragma unroll
        for (int nt=0;nt<NTN;++nt){
          int f = fblk + wvf*NTN*16 + nt*16 + l15;
          float v = acc[mt][nt][r] + bv[nt];
          outf[(size_t)orow*512 + f] = v;
          sdot += v * gv[nt];
        }
        sdot += __shfl_xor(sdot, 1); sdot += __shfl_xor(sdot, 2);
        sdot += __shfl_xor(sdot, 4); sdot += __shfl_xor(sdot, 8);
        if (l15==0) atomicAdd(aux + orow, sdot);
      }
    }
  } else {  // MODE 4: weff bf16 out; BN-fold: scale cols by sc0, bias partials via sh0
    if (gpf){
      float sc[NTN], sh[NTN];
      #pragma unroll
      for (int nt=0;nt<NTN;++nt){
        int f = fblk + wvf*NTN*16 + nt*16 + l15;
        sc[nt] = gpf[f]; sh[nt] = gpf[1024+f];
      }
      #pragma unroll
      for (int mt=0;mt<MTM;++mt){
        #pragma unroll
        for (int r=0;r<4;++r){
          int m = m0 + wvm*MTM*16 + mt*16 + quad*4 + r;
          float part = 0.f;
          #pragma unroll
          for (int nt=0;nt<NTN;++nt){
            int f = fblk + wvf*NTN*16 + nt*16 + l15;
            float a = acc[mt][nt][r];
            part += a * sh[nt];
            outs[(size_t)m*1024 + f] = f2bu(a * sc[nt]);
          }
          part += __shfl_xor(part, 1); part += __shfl_xor(part, 2);
          part += __shfl_xor(part, 4); part += __shfl_xor(part, 8);
          if (l15==0) atomicAdd(aux + m, part);
        }
      }
    } else {
      #pragma unroll
      for (int mt=0;mt<MTM;++mt)
        #pragma unroll
        for (int nt=0;nt<NTN;++nt){
          int f = fblk + wvf*NTN*16 + nt*16 + l15;
          #pragma unroll
          for (int r=0;r<4;++r){
            int m = m0 + wvm*MTM*16 + mt*16 + quad*4 + r;
            outs[(size_t)m*1024 + f] = f2bu(acc[mt][nt][r]);
          }
        }
    }
  }
}

// ---------------- BN stats combine: bnp[64][2][1024] -> scale/shift mv ------------------
__global__ void stats_comb(const float* __restrict__ bnp, const float* __restrict__ g,
                           const float* __restrict__ beta, float* __restrict__ mv){
  int c = blockIdx.x*256 + threadIdx.x;   // 1024
  float S=0.f, S2=0.f;
  #pragma unroll 8
  for (int s=0;s<64;s++){ S += bnp[(size_t)s*2048 + c]; S2 += bnp[(size_t)s*2048 + 1024 + c]; }
  float m = S * (1.f/4096.f);
  float var = S2 * (1.f/4096.f) - m*m;
  float inv = rsqrtf(var + 1e-5f);
  float sc = inv * g[c];
  mv[c] = sc;
  mv[1024 + c] = beta[c] - m*sc;
}

// ---- weight permute + BN fold, cc-parallel (round 9: was latency-bound at 2 blocks/CU
// with a serial 8-phase loop; now one phase per block, 4096 blocks):
//   wtt[f][j*1024+cc*128+c] = bf16(tp_w[f][(cc*128+c)*27+j]*sc1), atomicAdd sh1-dot tpb2.
__launch_bounds__(256)
__global__ void wperm_k(const float* __restrict__ w, const float* __restrict__ mv1,
                        unsigned short* __restrict__ wtt, float* __restrict__ tpb2){
  __shared__ float ls[3456];
  __shared__ float rs[256];
  int f = blockIdx.x, cc = blockIdx.y;
  const float* src = w + (size_t)f*27648 + cc*3456;
  unsigned short* dst = wtt + (size_t)f*27648;
  for (int i=threadIdx.x; i<3456; i+=256) ls[i] = src[i];
  __syncthreads();
  float part = 0.f;
  for (int u=threadIdx.x; u<3456; u+=256){
    int j = u >> 7, c = u & 127;
    int ch = cc*128 + c;
    float wv = ls[c*27 + j];
    dst[(size_t)j*1024 + ch] = f2bu(wv * mv1[ch]);
    part += wv * mv1[1024 + ch];
  }
  rs[threadIdx.x] = part; __syncthreads();
  for (int st=128; st>0; st>>=1){
    if (threadIdx.x < st) rs[threadIdx.x] += rs[threadIdx.x+st];
    __syncthreads();
  }
  if (threadIdx.x==0) atomicAdd(tpb2 + f, rs[0]);
}

// ---------------- goal_pre: z splits the 392 positions 4-ways; atomicAdd into gp --------
// bias = tp_b[f] + tpb2[f] (tpb2 = atomic-accumulated BN-shift fold from wperm_k)
__launch_bounds__(256)
__global__ void gp2_k(const float* __restrict__ part9, const float* __restrict__ tpb,
                      const float* __restrict__ tpbA, float* __restrict__ gp){
  int b = blockIdx.x;
  int fc = blockIdx.y;
  int z = blockIdx.z;          // 4 p-chunks of 98
  int fi = threadIdx.x & 31, pi = threadIdx.x >> 5;
  int f = fc*32 + fi;
  float bias = tpb[f] + tpbA[f];
  float a = 0.f;
  for (int p = z*98 + pi; p < z*98 + 98; p += 8){
    size_t base = ((size_t)(b*392 + p))*512 + f;
    float v = bias;
    #pragma unroll
    for (int i=0;i<9;i++) v += part9[(size_t)i*802816 + base];
    a += fmaxf(v, 0.f);
  }
  __shared__ float red[256];
  red[threadIdx.x] = a; __syncthreads();
  for (int st=4; st>0; st>>=1){
    if (pi < st) red[pi*32+fi] += red[(pi+st)*32+fi];
    __syncthreads();
  }
  if (pi==0) atomicAdd(gp + b*512 + f, red[fi] * (1.f/392.f));
}

// ---------------- PE table: peN[n][c] ---------------------------------------------------
__global__ void pen_k(float* __restrict__ peN){
  int idx = blockIdx.x*256 + threadIdx.x;   // 524288
  int n = idx >> 9, c = idx & 511;
  float div = expf(-0.035977892f * (float)(c>>1));   // 2*ln(10000)/512
  float ang = (float)n * div;
  peN[idx] = (c & 1) ? cosf(ang) : sinf(ang);
}

// ---------------- softmax over n: attn[bt][n] normalized --------------------------------
__launch_bounds__(256)
__global__ void softmax_k(const float* __restrict__ SG, float* __restrict__ attn){
  int bt = blockIdx.x; int tid = threadIdx.x;
  float4 v = *reinterpret_cast<const float4*>(SG + bt*1024 + tid*4);
  float mx = fmaxf(fmaxf(v.x,v.y), fmaxf(v.z,v.w));
  __shared__ float red[256];
  red[tid] = mx; __syncthreads();
  for (int st=128; st>0; st>>=1){
    if (tid<st) red[tid] = fmaxf(red[tid], red[tid+st]);
    __syncthreads();
  }
  float m = red[0]; __syncthreads();
  float4 e;
  e.x = expf(v.x-m); e.y = expf(v.y-m); e.z = expf(v.z-m); e.w = expf(v.w-m);
  red[tid] = e.x+e.y+e.z+e.w; __syncthreads();
  for (int st=128; st>0; st>>=1){
    if (tid<st) red[tid] += red[tid+st];
    __syncthreads();
  }
  float inv = 1.0f/red[0];
  e.x*=inv; e.y*=inv; e.z*=inv; e.w*=inv;
  *reinterpret_cast<float4*>(attn + bt*1024 + tid*4) = e;
}

// ---- sga[bt][c] += sum_{n in slice} attn[n]*(scl[n][c]+pe[n][c])  (atomic, 8 slices) ---
__launch_bounds__(256)
__global__ void sga2_k(const float* __restrict__ scl, const float* __restrict__ peN,
                       const float* __restrict__ attn, float* __restrict__ sga){
  int bt = blockIdx.x, sl = blockIdx.y;   // 24 x 8
  int tid = threadIdx.x;
  __shared__ float at[128];
  if (tid < 128) at[tid] = attn[bt*1024 + sl*128 + tid];
  __syncthreads();
  float acc0 = 0.f, acc1 = 0.f;
  for (int j=0;j<128;j++){
    int n = sl*128 + j;
    float a = at[j];
    const float* row = scl + ((size_t)bt*1024 + n)*512;
    const float* pe  = peN + (size_t)n*512;
    acc0 += a * (row[tid] + pe[tid]);
    acc1 += a * (row[tid+256] + pe[tid+256]);
  }
  atomicAdd(sga + (size_t)bt*512 + tid, acc0);
  atomicAdd(sga + (size_t)bt*512 + 256 + tid, acc1);
}

// ---------------- 512->512(relu)->128 MLP head (fp32 weights) ---------------------------
__launch_bounds__(256)
__global__ void mlp_k(const float* __restrict__ in, const float* __restrict__ w1,
                      const float* __restrict__ b1, const float* __restrict__ w2,
                      const float* __restrict__ b2, float* __restrict__ out){
  int bb = blockIdx.x; int tid = threadIdx.x;
  __shared__ float xv[512]; __shared__ float h[512];
  xv[tid] = in[(size_t)bb*512 + tid];
  xv[tid+256] = in[(size_t)bb*512 + 256 + tid];
  __syncthreads();
  #pragma unroll
  for (int oo=0;oo<2;oo++){
    int o = tid + oo*256;
    const float* wr = w1 + (size_t)o*512;
    float a=0.f;
    for (int c=0;c<512;c+=4){
      float4 q = *reinterpret_cast<const float4*>(wr+c);
      a += xv[c]*q.x + xv[c+1]*q.y + xv[c+2]*q.z + xv[c+3]*q.w;
    }
    h[o] = fmaxf(a + b1[o], 0.f);
  }
  __syncthreads();
  if (tid < 128){
    const float* wr = w2 + (size_t)tid*512;
    float a=0.f;
    for (int c=0;c<512;c+=4){
      float4 q = *reinterpret_cast<const float4*>(wr+c);
      a += h[c]*q.x + h[c+1]*q.y + h[c+2]*q.z + h[c+3]*q.w;
    }
    out[(size_t)bb*128+tid] = a + b2[tid];
  }
}

extern "C" void kernel_launch(void* const* d_in, const int* in_sizes, int n_in,
                              void* d_out, int out_size, void* d_ws, size_t ws_size,
                              hipStream_t stream){
  (void)in_sizes; (void)n_in; (void)out_size; (void)ws_size;
  const float* ctx   = (const float*)d_in[0];
  const float* frame = (const float*)d_in[1];
  const float* nl_vw[2] = {(const float*)d_in[4],  (const float*)d_in[11]};
  const float* nl_ow[2] = {(const float*)d_in[5],  (const float*)d_in[12]};
  const float* nl_ob[2] = {(const float*)d_in[6],  (const float*)d_in[13]};
  const float* nl_g[2]  = {(const float*)d_in[7],  (const float*)d_in[14]};
  const float* nl_be[2] = {(const float*)d_in[8],  (const float*)d_in[15]};
  const float* tp_w = (const float*)d_in[16]; const float* tp_b = (const float*)d_in[17];
  const float* up1w = (const float*)d_in[18]; const float* up1b = (const float*)d_in[19];
  const float* up2w = (const float*)d_in[20]; const float* up2b = (const float*)d_in[21];
  const float* og1w = (const float*)d_in[22]; const float* og1b = (const float*)d_in[23];
  const float* og2w = (const float*)d_in[24]; const float* og2b = (const float*)d_in[25];
  const float* os1w = (const float*)d_in[26]; const float* os1b = (const float*)d_in[27];
  const float* os2w = (const float*)d_in[28]; const float* os2b = (const float*)d_in[29];
  float* out = (float*)d_out;

  char* wsp = (char*)d_ws;
  // ---- persistent region ----
  float* bias2   = (float*)(wsp + 65536);         // 4KB  [1024] weff bias-fold acc
  float* tpb2    = (float*)(wsp + 69632);         // 2KB  [512] conv bias-fold (atomic)
  float* gp      = (float*)(wsp + 73728);         // 8KB  [4][512] (atomic-accumulated)
  float* mv0     = (float*)(wsp + 131072);        // 8KB  BN scale/shift layer 0
  float* mv1     = (float*)(wsp + 139264);        // 8KB  BN scale/shift layer 1
  float* SG      = (float*)(wsp + 147456);        // 98304 (atomic-accumulated)
  float* attn    = (float*)(wsp + 245760);        // 98304
  float* sga     = (float*)(wsp + 344064);        // 49152 (atomic-accumulated)
  float* peN     = (float*)(wsp + 786432);        // 2097152 [1024][512]
  bf16*  weff    = (bf16*) (wsp + 2883584);       // 2097152 [1024][1024] bf16
  unsigned short* w1sp = (unsigned short*)(wsp + 4980736);   // 12582912 [4][512][3072]
  unsigned short* w2sp = (unsigned short*)(wsp + 17563648);  // 6291456  [4][512][1536]
  char* ov = wsp + 23855104;
  // phase 1 (nonlocal, BN folded -> xcl ping-pong):
  bf16*  xclA = (bf16*) (ov);                     // 8 MB [4096][1024]
  bf16*  xclB = (bf16*) (ov + 8388608);           // 8 MB (dead after l=1 reads it)
  // phase 1 staging in the (dead until phase 2) part9 region:
  unsigned short* Asp = (unsigned short*)(ov + 36700160);            // 3 MB [1024][1536]
  unsigned short* Bsp = (unsigned short*)(ov + 36700160 + 3145728);  // 3 MB [1024][1536]
  float* bnp = (float*)(ov + 36700160 + 6291456); // 512 KB [64][2][1024] BN partials
  // phase 2 (conv): wtt aliases xclB region (written after l=1 MODE0 consumed xclB)
  unsigned short* wtt = (unsigned short*)(ov + 8388608);   // 28.3 MB [512][27648]
  float* part9 = (float*)(ov + 36700160);         // 28.9 MB [9][1568][512]
  // frame staging: aliases part9 (written after gp2_k reads part9)
  unsigned short* Fsp = (unsigned short*)(ov + 36700160);  // 9.4 MB [1536][3072]
  // phase 3 (after gp2_k; xclA/wtt dead):
  unsigned short* s1sp = (unsigned short*)(ov);   // 18.9 MB [6144][1536]
  float* scl  = (float*)(ov + 18874368);          // 50.3 MB [24576][512]

  // prep (independent). One range-zero covers bias2/tpb2/gp/SG/sga (atomic-accumulated).
  permT_k<bf16><<<dim3(4,16,16),256,0,stream>>>(ctx, xclA, 256, 1024, 1, 1, 262144L, 262144L);
  permTsplit3_k<1><<<dim3(32,16,1),256,0,stream>>>(up1w, w1sp, 2048, 1024, 4, 512, 0L, 0L);
  permTsplit3_k<1><<<dim3(32,8,1),256,0,stream>>>(up2w, w2sp, 2048, 512, 4, 512, 0L, 0L);
  pen_k<<<2048,256,0,stream>>>(peN);
  zero_k<<<320,256,0,stream>>>((float*)(wsp + 65536));   // bytes 65536..393216

  // nonlocal layer 0: xclA -> xclB (BN deferred via fold into layer-1 consumers)
  splitA_k<<<2048,256,0,stream>>>(nl_ow[0], Asp);
  permTsplit3_k<1><<<dim3(16,8,1),256,0,stream>>>(nl_vw[0], Bsp, 1024, 512, 1, 1, 0L, 0L);
  mmL_k<1,4,2,2,4,64><<<dim3(32,8,1),256,0,stream>>>(Asp, Bsp, nullptr, nullptr, nullptr,
      nullptr, (unsigned short*)weff, nullptr, 1536);
  mmL_k<1,4,4,2,0,64><<<dim3(64,8,1),256,0,stream>>>((const unsigned short*)xclA,
      (const unsigned short*)weff, nl_ob[0], (const unsigned short*)xclA, nullptr,
      nullptr, (unsigned short*)xclB, bnp, 1024);
  stats_comb<<<4,256,0,stream>>>(bnp, nl_g[0], nl_be[0], mv0);

  // nonlocal layer 1: xclB -> xclA; weff cols scaled by sc0, sh0 folded to bias2
  splitA_k<<<2048,256,0,stream>>>(nl_ow[1], Asp);
  permTsplit3_k<1><<<dim3(16,8,1),256,0,stream>>>(nl_vw[1], Bsp, 1024, 512, 1, 1, 0L, 0L);
  mmL_k<1,4,2,2,4,64><<<dim3(32,8,1),256,0,stream>>>(Asp, Bsp, nullptr, nullptr, mv0,
      nullptr, (unsigned short*)weff, bias2, 1536);
  mmL_k<1,4,4,2,0,64><<<dim3(64,8,1),256,0,stream>>>((const unsigned short*)xclB,
      (const unsigned short*)weff, nl_ob[1], (const unsigned short*)xclB, mv0,
      bias2, (unsigned short*)xclA, bnp, 1024);
  stats_comb<<<4,256,0,stream>>>(bnp, nl_g[1], nl_be[1], mv1);

  // temporal-pool conv (im2col GEMM, K-split 9); BN-1 folded into wtt (sc1) + tpb2 (sh1)
  // wperm: cc-parallel (4096 blocks) -- was latency-bound at 2 blocks/CU (round-8 PMC)
  wperm_k<<<dim3(512,8),256,0,stream>>>(tp_w, mv1, wtt, tpb2);
  mmL_k<2,2,4,4,1,64><<<dim3(13,4,9),256,0,stream>>>((const unsigned short*)xclA, wtt,
      nullptr, nullptr, nullptr, part9, nullptr, nullptr, 3072);
  gp2_k<<<dim3(4,16,4),256,0,stream>>>(part9, tp_b, tpb2, gp);

  // frame path (3-block split-bf16 == fp32-accurate); Fsp aliases part9 -> after gp2_k
  permTsplit3_k<0><<<dim3(1,16,24),256,0,stream>>>(frame, Fsp, 64, 1024, 1, 1, 65536L, 196608L);
  mmL_k<1,4,2,2,2,64><<<dim3(48,4,4),256,0,stream>>>(Fsp, w1sp, up1b, nullptr, nullptr,
      nullptr, s1sp, nullptr, 3072);
  // up2 + fused SG partial dot (BK=32: grid demand 3/CU > 64KB residency 2 -> keep 32KB)
  mmL_k<2,2,4,4,5,32><<<dim3(48,4,4),256,0,stream>>>(s1sp, w2sp, up2b, nullptr, gp,
      scl, nullptr, SG, 1536);

  // attention tail
  softmax_k<<<24,256,0,stream>>>(SG, attn);
  sga2_k<<<dim3(24,8),256,0,stream>>>(scl, peN, attn, sga);

  // heads
  mlp_k<<<4,256,0,stream>>>(gp, og1w, og1b, og2w, og2b, out);
  mlp_k<<<24,256,0,stream>>>(sga, os1w, os1b, os2w, os2b, out + 512);
}

// Round 10
// 602.787 us; speedup vs baseline: 1.3517x; 1.0236x over previous
//
#include <hip/hip_runtime.h>
#include <hip/hip_bf16.h>

using bf16 = __hip_bfloat16;
typedef short short8 __attribute__((ext_vector_type(8)));
typedef float float4v __attribute__((ext_vector_type(4)));

__device__ __forceinline__ float b2f(unsigned short u){
  unsigned int x = ((unsigned int)u) << 16; float f;
  __builtin_memcpy(&f, &x, 4); return f;
}
__device__ __forceinline__ float b2f(bf16 v){ return __bfloat162float(v); }
__device__ __forceinline__ unsigned short f2bu(float x){
  bf16 h = __float2bfloat16(x); unsigned short u;
  __builtin_memcpy(&u, &h, 2); return u;
}

// async global->LDS, 16B per lane, dest = wave-uniform base + lane*16
#define GLDS16(g, l) __builtin_amdgcn_global_load_lds( \
    (const __attribute__((address_space(1))) void*)(g), \
    (__attribute__((address_space(3))) void*)(l), 16, 0, 0)

template<int N> __device__ __forceinline__ void vwait(){
  if constexpr (N==0)       asm volatile("s_waitcnt vmcnt(0)" ::: "memory");
  else if constexpr (N==3)  asm volatile("s_waitcnt vmcnt(3)" ::: "memory");
  else if constexpr (N==4)  asm volatile("s_waitcnt vmcnt(4)" ::: "memory");
  else if constexpr (N==5)  asm volatile("s_waitcnt vmcnt(5)" ::: "memory");
  else if constexpr (N==6)  asm volatile("s_waitcnt vmcnt(6)" ::: "memory");
  else if constexpr (N==8)  asm volatile("s_waitcnt vmcnt(8)" ::: "memory");
  else if constexpr (N==10) asm volatile("s_waitcnt vmcnt(10)" ::: "memory");
  else                      asm volatile("s_waitcnt vmcnt(12)" ::: "memory");
}

// -------- batched permuted transpose fp32->bf16: per z, in[R][Cc] -> out[(q%D)*G+q/D][R] -
template<class TO>
__launch_bounds__(256)
__global__ void permT_k(const float* __restrict__ inp, TO* __restrict__ outp,
                        int Cc, int R, int D, int G, long inS, long outS){
  __shared__ float t[64][65];
  int z = blockIdx.z;
  const float* in = inp + (size_t)z*inS;
  TO* out = outp + (size_t)z*outS;
  int c0 = blockIdx.x*64, r0 = blockIdx.y*64;
  int tid = threadIdx.x;
  int rr = tid>>2, c4 = (tid&3)*16;
  const float* p = in + (size_t)(r0+rr)*Cc + c0 + c4;
  #pragma unroll
  for (int j=0;j<16;j+=4){
    float4 q = *reinterpret_cast<const float4*>(p+j);
    t[rr][c4+j]=q.x; t[rr][c4+j+1]=q.y; t[rr][c4+j+2]=q.z; t[rr][c4+j+3]=q.w;
  }
  __syncthreads();
  int ql = tid>>2;
  int q = c0 + ql;
  int orow = (q % D)*G + q / D;
  TO* op = out + (size_t)orow*R + r0 + c4;
  #pragma unroll
  for (int j=0;j<16;j++){
    if constexpr (sizeof(TO)==2) op[j] = __float2bfloat16(t[c4+j][ql]);
    else op[j] = t[c4+j][ql];
  }
}

// -------- 3-block split transpose: rows of length 3R.
// PAT=0 (A-side): blocks (hi, lo, hi).  PAT=1 (B-side): blocks (hi, hi, lo).
// Paired dot over 3R gives ah*bh + al*bh + ah*bl  == fp32-accurate product.
template<int PAT>
__launch_bounds__(256)
__global__ void permTsplit3_k(const float* __restrict__ inp, unsigned short* __restrict__ outp,
                              int Cc, int R, int D, int G, long inS, long outS){
  __shared__ float t[64][65];
  int z = blockIdx.z;
  const float* in = inp + (size_t)z*inS;
  unsigned short* out = outp + (size_t)z*outS;
  int c0 = blockIdx.x*64, r0 = blockIdx.y*64;
  int tid = threadIdx.x;
  int rr = tid>>2, c4 = (tid&3)*16;
  const float* p = in + (size_t)(r0+rr)*Cc + c0 + c4;
  #pragma unroll
  for (int j=0;j<16;j+=4){
    float4 q = *reinterpret_cast<const float4*>(p+j);
    t[rr][c4+j]=q.x; t[rr][c4+j+1]=q.y; t[rr][c4+j+2]=q.z; t[rr][c4+j+3]=q.w;
  }
  __syncthreads();
  int ql = tid>>2;
  int q = c0 + ql;
  int orow = (q % D)*G + q / D;
  unsigned short* op = out + (size_t)orow*(3*R);
  #pragma unroll
  for (int j=0;j<16;j++){
    float v = t[c4+j][ql];
    unsigned short h = f2bu(v);
    unsigned short l = f2bu(v - b2f(h));
    int idx = r0 + c4 + j;
    if constexpr (PAT==0){
      op[idx] = h; op[R+idx] = l; op[2*R+idx] = h;
    } else {
      op[idx] = h; op[R+idx] = h; op[2*R+idx] = l;
    }
  }
}

// -------- row split (no transpose): in[1024][512] fp32 -> out[1024][1536] bf16 (h,l,h) --
__launch_bounds__(256)
__global__ void splitA_k(const float* __restrict__ in, unsigned short* __restrict__ out){
  int idx = blockIdx.x*256 + threadIdx.x;   // 1024*512
  int m = idx >> 9, j = idx & 511;
  float v = in[idx];
  unsigned short h = f2bu(v);
  unsigned short l = f2bu(v - b2f(h));
  unsigned short* op = out + (size_t)m*1536 + j;
  op[0] = h; op[512] = l; op[1024] = h;
}

__global__ void zero_k(float* __restrict__ p){
  p[blockIdx.x*256 + threadIdx.x] = 0.f;
}

// ================= unified MFMA GEMM: global_load_lds + TRIPLE-buffer + counted vmcnt ====
// C[m][f] = sum_k A[m][k]*B[f][k], bf16. WM x WN waves, each owns (MTM*16) x (NTN*16).
// ROUND-10 pipeline: 3 LDS buffers, 1-ahead staging -> ONE barrier per K-step, NO lgkm
// drain. Safety: stage(t+1) writes buf (t+1)%3, last READ at compute(t-2); every wave
// finished compute(t-2) (MFMA data-deps force ds_read completion) before BAR(t-1), and
// stage(t+1) is issued after BAR(t-1) -> race-free. vmcnt(LPT) = 1 stage in flight.
// The old 2-buf scheme needed lgkmcnt(0)+2nd barrier per step (writer hit last step's
// reader buffer) -> that rendezvous+drain was ~half the unaccounted step cost (r9 PMC).
// LDS 1.5x of 2-buf: per-kernel BK/BM re-derived for the round-4 residency rule
// (blocks/CU from LDS >= grid demand): conv BK32 48KB->3/CU, MODE0 BK64 72KB->2/CU,
// up1 BM64/BK64 72KB grid(24,..)->1.5 demand, up2 BK32 48KB->3/CU.
// LDS image: linear dest slot (16B) = row*CPR + chunk'; swizzle chunk' = c ^ swz(row)
// on the GLOBAL source address (m104-safe); swz = (row>>1)&3 @BK32, row&7 @BK64.
// BN-FOLD: MODE 4 (weff): if gpf, scale cols by sc0 + atomicAdd sh0-dot into aux.
// MODE 0: bias+biasAdd, residual scaled by gpf, writes bf16 xcl + BN partials.
// MODE 1: conv3d im2col K-split z (XCD-bijective z-major swizzle -> B L2-resident),
// MODE 2: up1 (relu+bias, convT scatter, 3-block h/l/h), MODE 5: up2 + fused SG dot.
template<int WM, int WN, int MTM, int NTN, int MODE, int BK>
__launch_bounds__(256)
__global__ void mmL_k(const unsigned short* __restrict__ A,
                      const unsigned short* __restrict__ B,
                      const float* __restrict__ bias,
                      const unsigned short* __restrict__ res,
                      const float* __restrict__ gpf,
                      float* __restrict__ outf,
                      unsigned short* __restrict__ outs,
                      float* __restrict__ aux,
                      int K){
  constexpr int BM  = WM*MTM*16;
  constexpr int BN  = WN*NTN*16;
  constexpr int CPR = BK/8;            // 16B chunks per row
  constexpr int KS  = BK/32;           // k-subtiles per step
  constexpr int AIT = (BM*CPR)/256;    // A chunks per thread (>=1 in all instantiations)
  constexpr int NBC = (BN*CPR)/256;    // B chunks per thread
  constexpr int LPT = AIT + NBC;       // loads in flight per thread per stage
  __shared__ __align__(16) short As[3*BM*BK];
  __shared__ __align__(16) short Bs[3*BN*BK];
  const int tid = threadIdx.x;
  const int wv = tid>>6, lane = tid&63, l15 = lane&15, quad = lane>>4;
  const int wvm = wv / WN, wvf = wv % WN;
  const int wbase = wv<<6;             // wave-uniform LDS slot base (64 slots/wave)

  int bx = blockIdx.x, by = blockIdx.y, bz = blockIdx.z;
  if constexpr (MODE==1){
    const int gx = gridDim.x, gy = gridDim.y, gz = gridDim.z;
    const int n = gx*gy*gz;
    const int lin = bx + gx*(by + gy*bz);
    const int q = n >> 3, r = n & 7;
    const int xcd = lin & 7, j = lin >> 3;
    const int work = (xcd < r ? xcd*(q+1) : r*(q+1) + (xcd-r)*q) + j;
    by = work % gy;                 // y minor
    const int t = work / gy;
    bx = t % gx;                    // x middle
    bz = t / gx;                    // z major (chunk == one kt/kh slice)
  }
  const int m0 = bx*BM;
  const int fblk = by*BN;
  const int z = bz;

  auto swz = [](int row){ if constexpr (BK==32) return (row>>1)&3; else return row&7; };

  // ---- staging addresses (source-side swizzle; LDS dest linear: slot = it*256+tid) ----
  size_t aAddr[AIT];
  #pragma unroll
  for (int it=0; it<AIT; ++it){
    int s = tid + it*256;
    int arow = s/CPR;
    int ac = (s&(CPR-1)) ^ swz(arow);
    int m = m0 + arow;
    if constexpr (MODE==1){
      int mm = m < 1568 ? m : 1567;
      int b = mm/392, r = mm%392;
      int t = r/196, r2 = r%196;
      int hh = r2/14, ww = r2%14;
      int kt = z/3, kh = z%3;
      int sp = ((b*4 + t + kt)*16 + hh + kh)*16 + ww;
      aAddr[it] = (size_t)sp*1024 + ac*8;
    } else {
      aAddr[it] = (size_t)m*K + ac*8;
    }
  }
  size_t bAddr[NBC];
  #pragma unroll
  for (int it=0; it<NBC; ++it){
    int s = tid + it*256;
    int row = s/CPR;
    int c = (s&(CPR-1)) ^ swz(row);
    int f = fblk + row;
    if constexpr (MODE==0)      bAddr[it] = (size_t)f*1024 + c*8;
    else if constexpr (MODE==1) bAddr[it] = (size_t)f*27648 + (size_t)z*3072 + c*8;
    else                        bAddr[it] = ((size_t)z*512 + f)*(size_t)K + c*8;
  }
  // ---- fragment LDS slots (swizzled), per k-subtile ----
  int aslot[MTM][KS];
  #pragma unroll
  for (int mt=0;mt<MTM;++mt)
    #pragma unroll
    for (int ks=0;ks<KS;++ks){
      int row = wvm*MTM*16 + mt*16 + l15;
      aslot[mt][ks] = row*CPR + ((ks*4 + quad) ^ swz(row));
    }
  int bslot[NTN][KS];
  #pragma unroll
  for (int nt=0;nt<NTN;++nt)
    #pragma unroll
    for (int ks=0;ks<KS;++ks){
      int row = wvf*NTN*16 + nt*16 + l15;
      bslot[nt][ks] = row*CPR + ((ks*4 + quad) ^ swz(row));
    }

  float4v acc[MTM][NTN];
  #pragma unroll
  for (int i=0;i<MTM;i++)
    #pragma unroll
    for (int j=0;j<NTN;j++) acc[i][j]=(float4v){0,0,0,0};

  auto stage = [&](int buf, int k0){
    #pragma unroll
    for (int it=0; it<AIT; ++it)
      GLDS16(A + aAddr[it] + k0, As + buf*(BM*BK) + (it*256 + wbase)*8);
    #pragma unroll
    for (int it=0; it<NBC; ++it)
      GLDS16(B + bAddr[it] + k0, Bs + buf*(BN*BK) + (it*256 + wbase)*8);
  };
  auto computeTile = [&](int buf){
    const short* ap = As + buf*(BM*BK);
    const short* bp = Bs + buf*(BN*BK);
    #pragma unroll
    for (int ks=0; ks<KS; ++ks){
      short8 bf[NTN];
      #pragma unroll
      for (int nt=0;nt<NTN;++nt)
        bf[nt] = *reinterpret_cast<const short8*>(bp + bslot[nt][ks]*8);
      #pragma unroll
      for (int mt=0;mt<MTM;++mt){
        short8 af = *reinterpret_cast<const short8*>(ap + aslot[mt][ks]*8);
        #pragma unroll
        for (int nt=0;nt<NTN;++nt)
          acc[mt][nt] = __builtin_amdgcn_mfma_f32_16x16x32_bf16(af, bf[nt], acc[mt][nt],0,0,0);
      }
    }
  };

  const int nt = K/BK;
  int b0=0, b1=1, b2=2;
  stage(b0, 0);
  for (int t=0; t<nt-1; ++t){
    stage(b1, (t+1)*BK);               // tile t+1 in flight across the barrier
    vwait<LPT>();
    __builtin_amdgcn_sched_barrier(0);
    __builtin_amdgcn_s_barrier();      // all waves' tile-t loads landed
    __builtin_amdgcn_sched_barrier(0);
    computeTile(b0);                   // reads consumed by MFMA before next stage issues
    int tmp=b0; b0=b1; b1=b2; b2=tmp;
  }
  vwait<0>();
  __builtin_amdgcn_sched_barrier(0);
  __builtin_amdgcn_s_barrier();
  __builtin_amdgcn_sched_barrier(0);
  computeTile(b0);

  if constexpr (MODE==0){
    // BN-folded nonlocal epilogue: v = relu(acc+bias+biasAdd) + res*sc + sh -> bf16 xcl,
    // plus per-block column stats (sum, sum^2) into aux.
    const float* badd = outf;          // bias-fold accumulator (l=1) or nullptr (l=0)
    float sacc[NTN] = {}, s2acc[NTN] = {};
    #pragma unroll
    for (int nt2=0;nt2<NTN;++nt2){
      int f = fblk + wvf*NTN*16 + nt2*16 + l15;
      float bi = bias[f] + (badd ? badd[f] : 0.f);
      float rsc = 1.f, rsh = 0.f;
      if (gpf){ rsc = gpf[f]; rsh = gpf[1024+f]; }
      #pragma unroll
      for (int mt=0;mt<MTM;++mt){
        #pragma unroll
        for (int r=0;r<4;++r){
          int m = m0 + wvm*MTM*16 + mt*16 + quad*4 + r;
          float v = fmaxf(acc[mt][nt2][r]+bi, 0.f) + b2f(res[(size_t)m*1024 + f])*rsc + rsh;
          outs[(size_t)m*1024 + f] = f2bu(v);
          sacc[nt2] += v; s2acc[nt2] += v*v;
        }
      }
    }
    #pragma unroll
    for (int nt2=0;nt2<NTN;++nt2){
      float s = sacc[nt2], s2 = s2acc[nt2];
      s  += __shfl_xor(s, 16);  s  += __shfl_xor(s, 32);
      s2 += __shfl_xor(s2, 16); s2 += __shfl_xor(s2, 32);
      if (quad==0){
        int f = fblk + wvf*NTN*16 + nt2*16 + l15;
        aux[(size_t)bx*2048 + f] = s;
        aux[(size_t)bx*2048 + 1024 + f] = s2;
      }
    }
  } else if constexpr (MODE==1){
    #pragma unroll
    for (int mt=0;mt<MTM;++mt)
      #pragma unroll
      for (int nt2=0;nt2<NTN;++nt2){
        int f = fblk + wvf*NTN*16 + nt2*16 + l15;
        #pragma unroll
        for (int r=0;r<4;++r){
          int m = m0 + wvm*MTM*16 + mt*16 + quad*4 + r;
          if (m < 1568) outf[((size_t)z*1568 + m)*512 + f] = acc[mt][nt2][r];
        }
      }
  } else if constexpr (MODE==2){
    int kk = z>>1, ll = z&1;
    #pragma unroll
    for (int mt=0;mt<MTM;++mt)
      #pragma unroll
      for (int nt2=0;nt2<NTN;++nt2){
        int f = fblk + wvf*NTN*16 + nt2*16 + l15;
        float bi = bias[f];
        #pragma unroll
        for (int r=0;r<4;++r){
          int m = m0 + wvm*MTM*16 + mt*16 + quad*4 + r;
          int bt = m>>6, p = m&63;
          long orow = (long)bt*256 + (2*(p>>3)+kk)*16 + 2*(p&7)+ll;
          float v = fmaxf(acc[mt][nt2][r]+bi, 0.f);
          unsigned short h = f2bu(v);
          unsigned short l = f2bu(v - b2f(h));
          unsigned short* rp = outs + (size_t)orow*1536 + f;
          rp[0] = h; rp[512] = l; rp[1024] = h;
        }
      }
  } else if constexpr (MODE==5){
    int kk = z>>1, ll = z&1;
    #pragma unroll
    for (int mt=0;mt<MTM;++mt){
      int mbase = m0 + wvm*MTM*16 + mt*16;
      int bt = mbase>>8, b6 = bt/6, p0 = mbase&255;
      float gv[NTN], bv[NTN];
      #pragma unroll
      for (int nt2=0;nt2<NTN;++nt2){
        int f = fblk + wvf*NTN*16 + nt2*16 + l15;
        gv[nt2] = gpf[b6*512 + f];
        bv[nt2] = bias[f];
      }
      #pragma unroll
      for (int r=0;r<4;++r){
        int p = p0 + quad*4 + r;
        long orow = (long)bt*1024 + (2*(p>>4)+kk)*32 + 2*(p&15)+ll;
        float sdot = 0.f;
        #pragma unroll
        for (int nt2=0;nt2<NTN;++nt2){
          int f = fblk + wvf*NTN*16 + nt2*16 + l15;
          float v = acc[mt][nt2][r] + bv[nt2];
          outf[(size_t)orow*512 + f] = v;
          sdot += v * gv[nt2];
        }
        sdot += __shfl_xor(sdot, 1); sdot += __shfl_xor(sdot, 2);
        sdot += __shfl_xor(sdot, 4); sdot += __shfl_xor(sdot, 8);
        if (l15==0) atomicAdd(aux + orow, sdot);
      }
    }
  } else {  // MODE 4: weff bf16 out; BN-fold: scale cols by sc0, bias partials via sh0
    if (gpf){
      float sc[NTN], sh[NTN];
      #pragma unroll
      for (int nt2=0;nt2<NTN;++nt2){
        int f = fblk + wvf*NTN*16 + nt2*16 + l15;
        sc[nt2] = gpf[f]; sh[nt2] = gpf[1024+f];
      }
      #pragma unroll
      for (int mt=0;mt<MTM;++mt){
        #pragma unroll
        for (int r=0;r<4;++r){
          int m = m0 + wvm*MTM*16 + mt*16 + quad*4 + r;
          float part = 0.f;
          #pragma unroll
          for (int nt2=0;nt2<NTN;++nt2){
            int f = fblk + wvf*NTN*16 + nt2*16 + l15;
            float a = acc[mt][nt2][r];
            part += a * sh[nt2];
            outs[(size_t)m*1024 + f] = f2bu(a * sc[nt2]);
          }
          part += __shfl_xor(part, 1); part += __shfl_xor(part, 2);
          part += __shfl_xor(part, 4); part += __shfl_xor(part, 8);
          if (l15==0) atomicAdd(aux + m, part);
        }
      }
    } else {
      #pragma unroll
      for (int mt=0;mt<MTM;++mt)
        #pragma unroll
        for (int nt2=0;nt2<NTN;++nt2){
          int f = fblk + wvf*NTN*16 + nt2*16 + l15;
          #pragma unroll
          for (int r=0;r<4;++r){
            int m = m0 + wvm*MTM*16 + mt*16 + quad*4 + r;
            outs[(size_t)m*1024 + f] = f2bu(acc[mt][nt2][r]);
          }
        }
    }
  }
}

// ---------------- BN stats combine: bnp[64][2][1024] -> scale/shift mv ------------------
__global__ void stats_comb(const float* __restrict__ bnp, const float* __restrict__ g,
                           const float* __restrict__ beta, float* __restrict__ mv){
  int c = blockIdx.x*256 + threadIdx.x;   // 1024
  float S=0.f, S2=0.f;
  #pragma unroll 8
  for (int s=0;s<64;s++){ S += bnp[(size_t)s*2048 + c]; S2 += bnp[(size_t)s*2048 + 1024 + c]; }
  float m = S * (1.f/4096.f);
  float var = S2 * (1.f/4096.f) - m*m;
  float inv = rsqrtf(var + 1e-5f);
  float sc = inv * g[c];
  mv[c] = sc;
  mv[1024 + c] = beta[c] - m*sc;
}

// ---- weight permute + BN fold, cc-parallel: one load->scatter phase per block ----------
__launch_bounds__(256)
__global__ void wperm_k(const float* __restrict__ w, const float* __restrict__ mv1,
                        unsigned short* __restrict__ wtt, float* __restrict__ tpb2){
  __shared__ float ls[3456];
  __shared__ float rs[256];
  int f = blockIdx.x, cc = blockIdx.y;
  const float* src = w + (size_t)f*27648 + cc*3456;
  unsigned short* dst = wtt + (size_t)f*27648;
  for (int i=threadIdx.x; i<3456; i+=256) ls[i] = src[i];
  __syncthreads();
  float part = 0.f;
  for (int u=threadIdx.x; u<3456; u+=256){
    int j = u >> 7, c = u & 127;
    int ch = cc*128 + c;
    float wv = ls[c*27 + j];
    dst[(size_t)j*1024 + ch] = f2bu(wv * mv1[ch]);
    part += wv * mv1[1024 + ch];
  }
  rs[threadIdx.x] = part; __syncthreads();
  for (int st=128; st>0; st>>=1){
    if (threadIdx.x < st) rs[threadIdx.x] += rs[threadIdx.x+st];
    __syncthreads();
  }
  if (threadIdx.x==0) atomicAdd(tpb2 + f, rs[0]);
}

// ---------------- goal_pre: z splits the 392 positions 8-ways; atomicAdd into gp --------
__launch_bounds__(256)
__global__ void gp2_k(const float* __restrict__ part9, const float* __restrict__ tpb,
                      const float* __restrict__ tpbA, float* __restrict__ gp){
  int b = blockIdx.x;
  int fc = blockIdx.y;
  int z = blockIdx.z;          // 8 p-chunks of 49
  int fi = threadIdx.x & 31, pi = threadIdx.x >> 5;
  int f = fc*32 + fi;
  float bias = tpb[f] + tpbA[f];
  float a = 0.f;
  for (int p = z*49 + pi; p < z*49 + 49; p += 8){
    size_t base = ((size_t)(b*392 + p))*512 + f;
    float v = bias;
    #pragma unroll
    for (int i=0;i<9;i++) v += part9[(size_t)i*802816 + base];
    a += fmaxf(v, 0.f);
  }
  __shared__ float red[256];
  red[threadIdx.x] = a; __syncthreads();
  for (int st=4; st>0; st>>=1){
    if (pi < st) red[pi*32+fi] += red[(pi+st)*32+fi];
    __syncthreads();
  }
  if (pi==0) atomicAdd(gp + b*512 + f, red[fi] * (1.f/392.f));
}

// ---------------- PE table: peN[n][c] ---------------------------------------------------
__global__ void pen_k(float* __restrict__ peN){
  int idx = blockIdx.x*256 + threadIdx.x;   // 524288
  int n = idx >> 9, c = idx & 511;
  float div = expf(-0.035977892f * (float)(c>>1));   // 2*ln(10000)/512
  float ang = (float)n * div;
  peN[idx] = (c & 1) ? cosf(ang) : sinf(ang);
}

// ---------------- softmax over n: attn[bt][n] normalized --------------------------------
__launch_bounds__(256)
__global__ void softmax_k(const float* __restrict__ SG, float* __restrict__ attn){
  int bt = blockIdx.x; int tid = threadIdx.x;
  float4 v = *reinterpret_cast<const float4*>(SG + bt*1024 + tid*4);
  float mx = fmaxf(fmaxf(v.x,v.y), fmaxf(v.z,v.w));
  __shared__ float red[256];
  red[tid] = mx; __syncthreads();
  for (int st=128; st>0; st>>=1){
    if (tid<st) red[tid] = fmaxf(red[tid], red[tid+st]);
    __syncthreads();
  }
  float m = red[0]; __syncthreads();
  float4 e;
  e.x = expf(v.x-m); e.y = expf(v.y-m); e.z = expf(v.z-m); e.w = expf(v.w-m);
  red[tid] = e.x+e.y+e.z+e.w; __syncthreads();
  for (int st=128; st>0; st>>=1){
    if (tid<st) red[tid] += red[tid+st];
    __syncthreads();
  }
  float inv = 1.0f/red[0];
  e.x*=inv; e.y*=inv; e.z*=inv; e.w*=inv;
  *reinterpret_cast<float4*>(attn + bt*1024 + tid*4) = e;
}

// ---- sga[bt][c] += sum_{n in slice} attn[n]*(scl[n][c]+pe[n][c])  (32 slices of 32) ----
// round 10: 8 slices (192 blocks = 0.75/CU) was latency-bound; 32 slices -> 768 blocks.
__launch_bounds__(256)
__global__ void sga2_k(const float* __restrict__ scl, const float* __restrict__ peN,
                       const float* __restrict__ attn, float* __restrict__ sga){
  int bt = blockIdx.x, sl = blockIdx.y;   // 24 x 32
  int tid = threadIdx.x;
  __shared__ float at[32];
  if (tid < 32) at[tid] = attn[bt*1024 + sl*32 + tid];
  __syncthreads();
  float acc0 = 0.f, acc1 = 0.f;
  for (int j=0;j<32;j++){
    int n = sl*32 + j;
    float a = at[j];
    const float* row = scl + ((size_t)bt*1024 + n)*512;
    const float* pe  = peN + (size_t)n*512;
    acc0 += a * (row[tid] + pe[tid]);
    acc1 += a * (row[tid+256] + pe[tid+256]);
  }
  atomicAdd(sga + (size_t)bt*512 + tid, acc0);
  atomicAdd(sga + (size_t)bt*512 + 256 + tid, acc1);
}

// ---------------- 512->512(relu)->128 MLP head (fp32 weights) ---------------------------
__launch_bounds__(256)
__global__ void mlp_k(const float* __restrict__ in, const float* __restrict__ w1,
                      const float* __restrict__ b1, const float* __restrict__ w2,
                      const float* __restrict__ b2, float* __restrict__ out){
  int bb = blockIdx.x; int tid = threadIdx.x;
  __shared__ float xv[512]; __shared__ float h[512];
  xv[tid] = in[(size_t)bb*512 + tid];
  xv[tid+256] = in[(size_t)bb*512 + 256 + tid];
  __syncthreads();
  #pragma unroll
  for (int oo=0;oo<2;oo++){
    int o = tid + oo*256;
    const float* wr = w1 + (size_t)o*512;
    float a=0.f;
    for (int c=0;c<512;c+=4){
      float4 q = *reinterpret_cast<const float4*>(wr+c);
      a += xv[c]*q.x + xv[c+1]*q.y + xv[c+2]*q.z + xv[c+3]*q.w;
    }
    h[o] = fmaxf(a + b1[o], 0.f);
  }
  __syncthreads();
  if (tid < 128){
    const float* wr = w2 + (size_t)tid*512;
    float a=0.f;
    for (int c=0;c<512;c+=4){
      float4 q = *reinterpret_cast<const float4*>(wr+c);
      a += h[c]*q.x + h[c+1]*q.y + h[c+2]*q.z + h[c+3]*q.w;
    }
    out[(size_t)bb*128+tid] = a + b2[tid];
  }
}

extern "C" void kernel_launch(void* const* d_in, const int* in_sizes, int n_in,
                              void* d_out, int out_size, void* d_ws, size_t ws_size,
                              hipStream_t stream){
  (void)in_sizes; (void)n_in; (void)out_size; (void)ws_size;
  const float* ctx   = (const float*)d_in[0];
  const float* frame = (const float*)d_in[1];
  const float* nl_vw[2] = {(const float*)d_in[4],  (const float*)d_in[11]};
  const float* nl_ow[2] = {(const float*)d_in[5],  (const float*)d_in[12]};
  const float* nl_ob[2] = {(const float*)d_in[6],  (const float*)d_in[13]};
  const float* nl_g[2]  = {(const float*)d_in[7],  (const float*)d_in[14]};
  const float* nl_be[2] = {(const float*)d_in[8],  (const float*)d_in[15]};
  const float* tp_w = (const float*)d_in[16]; const float* tp_b = (const float*)d_in[17];
  const float* up1w = (const float*)d_in[18]; const float* up1b = (const float*)d_in[19];
  const float* up2w = (const float*)d_in[20]; const float* up2b = (const float*)d_in[21];
  const float* og1w = (const float*)d_in[22]; const float* og1b = (const float*)d_in[23];
  const float* og2w = (const float*)d_in[24]; const float* og2b = (const float*)d_in[25];
  const float* os1w = (const float*)d_in[26]; const float* os1b = (const float*)d_in[27];
  const float* os2w = (const float*)d_in[28]; const float* os2b = (const float*)d_in[29];
  float* out = (float*)d_out;

  char* wsp = (char*)d_ws;
  // ---- persistent region ----
  float* bias2   = (float*)(wsp + 65536);         // 4KB  [1024] weff bias-fold acc
  float* tpb2    = (float*)(wsp + 69632);         // 2KB  [512] conv bias-fold (atomic)
  float* gp      = (float*)(wsp + 73728);         // 8KB  [4][512] (atomic-accumulated)
  float* mv0     = (float*)(wsp + 131072);        // 8KB  BN scale/shift layer 0
  float* mv1     = (float*)(wsp + 139264);        // 8KB  BN scale/shift layer 1
  float* SG      = (float*)(wsp + 147456);        // 98304 (atomic-accumulated)
  float* attn    = (float*)(wsp + 245760);        // 98304
  float* sga     = (float*)(wsp + 344064);        // 49152 (atomic-accumulated)
  float* peN     = (float*)(wsp + 786432);        // 2097152 [1024][512]
  bf16*  weff    = (bf16*) (wsp + 2883584);       // 2097152 [1024][1024] bf16
  unsigned short* w1sp = (unsigned short*)(wsp + 4980736);   // 12582912 [4][512][3072]
  unsigned short* w2sp = (unsigned short*)(wsp + 17563648);  // 6291456  [4][512][1536]
  char* ov = wsp + 23855104;
  // phase 1 (nonlocal, BN folded -> xcl ping-pong):
  bf16*  xclA = (bf16*) (ov);                     // 8 MB [4096][1024]
  bf16*  xclB = (bf16*) (ov + 8388608);           // 8 MB (dead after l=1 reads it)
  // phase 1 staging in the (dead until phase 2) part9 region:
  unsigned short* Asp = (unsigned short*)(ov + 36700160);            // 3 MB [1024][1536]
  unsigned short* Bsp = (unsigned short*)(ov + 36700160 + 3145728);  // 3 MB [1024][1536]
  float* bnp = (float*)(ov + 36700160 + 6291456); // 512 KB [64][2][1024] BN partials
  // phase 2 (conv): wtt aliases xclB region (written after l=1 MODE0 consumed xclB)
  unsigned short* wtt = (unsigned short*)(ov + 8388608);   // 28.3 MB [512][27648]
  float* part9 = (float*)(ov + 36700160);         // 28.9 MB [9][1568][512]
  // frame staging: aliases part9 (written after gp2_k reads part9)
  unsigned short* Fsp = (unsigned short*)(ov + 36700160);  // 9.4 MB [1536][3072]
  // phase 3 (after gp2_k; xclA/wtt dead):
  unsigned short* s1sp = (unsigned short*)(ov);   // 18.9 MB [6144][1536]
  float* scl  = (float*)(ov + 18874368);          // 50.3 MB [24576][512]

  // prep (independent). One range-zero covers bias2/tpb2/gp/SG/sga (atomic-accumulated).
  permT_k<bf16><<<dim3(4,16,16),256,0,stream>>>(ctx, xclA, 256, 1024, 1, 1, 262144L, 262144L);
  permTsplit3_k<1><<<dim3(32,16,1),256,0,stream>>>(up1w, w1sp, 2048, 1024, 4, 512, 0L, 0L);
  permTsplit3_k<1><<<dim3(32,8,1),256,0,stream>>>(up2w, w2sp, 2048, 512, 4, 512, 0L, 0L);
  pen_k<<<2048,256,0,stream>>>(peN);
  zero_k<<<320,256,0,stream>>>((float*)(wsp + 65536));   // bytes 65536..393216

  // nonlocal layer 0: xclA -> xclB (BN deferred via fold into layer-1 consumers)
  splitA_k<<<2048,256,0,stream>>>(nl_ow[0], Asp);
  permTsplit3_k<1><<<dim3(16,8,1),256,0,stream>>>(nl_vw[0], Bsp, 1024, 512, 1, 1, 0L, 0L);
  mmL_k<1,4,2,2,4,64><<<dim3(32,8,1),256,0,stream>>>(Asp, Bsp, nullptr, nullptr, nullptr,
      nullptr, (unsigned short*)weff, nullptr, 1536);
  mmL_k<1,4,4,2,0,64><<<dim3(64,8,1),256,0,stream>>>((const unsigned short*)xclA,
      (const unsigned short*)weff, nl_ob[0], (const unsigned short*)xclA, nullptr,
      nullptr, (unsigned short*)xclB, bnp, 1024);
  stats_comb<<<4,256,0,stream>>>(bnp, nl_g[0], nl_be[0], mv0);

  // nonlocal layer 1: xclB -> xclA; weff cols scaled by sc0, sh0 folded to bias2
  splitA_k<<<2048,256,0,stream>>>(nl_ow[1], Asp);
  permTsplit3_k<1><<<dim3(16,8,1),256,0,stream>>>(nl_vw[1], Bsp, 1024, 512, 1, 1, 0L, 0L);
  mmL_k<1,4,2,2,4,64><<<dim3(32,8,1),256,0,stream>>>(Asp, Bsp, nullptr, nullptr, mv0,
      nullptr, (unsigned short*)weff, bias2, 1536);
  mmL_k<1,4,4,2,0,64><<<dim3(64,8,1),256,0,stream>>>((const unsigned short*)xclB,
      (const unsigned short*)weff, nl_ob[1], (const unsigned short*)xclB, mv0,
      bias2, (unsigned short*)xclA, bnp, 1024);
  stats_comb<<<4,256,0,stream>>>(bnp, nl_g[1], nl_be[1], mv1);

  // temporal-pool conv (im2col GEMM, K-split 9); BN-1 folded into wtt (sc1) + tpb2 (sh1)
  // 3-buf BK=32: 48KB LDS -> 3 blocks/CU >= 1.8 demand; one barrier per K-step.
  wperm_k<<<dim3(512,8),256,0,stream>>>(tp_w, mv1, wtt, tpb2);
  mmL_k<2,2,4,4,1,32><<<dim3(13,4,9),256,0,stream>>>((const unsigned short*)xclA, wtt,
      nullptr, nullptr, nullptr, part9, nullptr, nullptr, 3072);
  gp2_k<<<dim3(4,16,8),256,0,stream>>>(part9, tp_b, tpb2, gp);

  // frame path (3-block split-bf16 == fp32-accurate); Fsp aliases part9 -> after gp2_k
  permTsplit3_k<0><<<dim3(1,16,24),256,0,stream>>>(frame, Fsp, 64, 1024, 1, 1, 65536L, 196608L);
  // up1: BM=64 (3-buf 72KB -> 2/CU; grid 384 = 1.5/CU demand)
  mmL_k<1,4,4,2,2,64><<<dim3(24,4,4),256,0,stream>>>(Fsp, w1sp, up1b, nullptr, nullptr,
      nullptr, s1sp, nullptr, 3072);
  // up2 + fused SG partial dot (3-buf BK=32: 48KB -> 3/CU = demand)
  mmL_k<2,2,4,4,5,32><<<dim3(48,4,4),256,0,stream>>>(s1sp, w2sp, up2b, nullptr, gp,
      scl, nullptr, SG, 1536);

  // attention tail
  softmax_k<<<24,256,0,stream>>>(SG, attn);
  sga2_k<<<dim3(24,32),256,0,stream>>>(scl, peN, attn, sga);

  // heads
  mlp_k<<<4,256,0,stream>>>(gp, og1w, og1b, og2w, og2b, out);
  mlp_k<<<24,256,0,stream>>>(sga, os1w, os1b, os2w, os2b, out + 512);
}

// Round 11
// 568.524 us; speedup vs baseline: 1.4332x; 1.0603x over previous
//
#include <hip/hip_runtime.h>
#include <hip/hip_bf16.h>

using bf16 = __hip_bfloat16;
typedef short short8 __attribute__((ext_vector_type(8)));
typedef float float4v __attribute__((ext_vector_type(4)));

__device__ __forceinline__ float b2f(unsigned short u){
  unsigned int x = ((unsigned int)u) << 16; float f;
  __builtin_memcpy(&f, &x, 4); return f;
}
__device__ __forceinline__ float b2f(bf16 v){ return __bfloat162float(v); }
__device__ __forceinline__ unsigned short f2bu(float x){
  bf16 h = __float2bfloat16(x); unsigned short u;
  __builtin_memcpy(&u, &h, 2); return u;
}

// async global->LDS, 16B per lane, dest = wave-uniform base + lane*16
#define GLDS16(g, l) __builtin_amdgcn_global_load_lds( \
    (const __attribute__((address_space(1))) void*)(g), \
    (__attribute__((address_space(3))) void*)(l), 16, 0, 0)

template<int N> __device__ __forceinline__ void vwait(){
  if constexpr (N==0)       asm volatile("s_waitcnt vmcnt(0)" ::: "memory");
  else if constexpr (N==3)  asm volatile("s_waitcnt vmcnt(3)" ::: "memory");
  else if constexpr (N==4)  asm volatile("s_waitcnt vmcnt(4)" ::: "memory");
  else if constexpr (N==5)  asm volatile("s_waitcnt vmcnt(5)" ::: "memory");
  else if constexpr (N==6)  asm volatile("s_waitcnt vmcnt(6)" ::: "memory");
  else if constexpr (N==8)  asm volatile("s_waitcnt vmcnt(8)" ::: "memory");
  else if constexpr (N==10) asm volatile("s_waitcnt vmcnt(10)" ::: "memory");
  else                      asm volatile("s_waitcnt vmcnt(12)" ::: "memory");
}

// ================= device bodies (shared by standalone kernels and prep_k) ==============
__device__ __forceinline__ void permT_body(const float* inp, bf16* outp,
    int Cc, int R, int D, int G, long inS, long outS,
    int bx, int by, int bz, int tid, float (*t)[65]){
  const float* in = inp + (size_t)bz*inS;
  bf16* out = outp + (size_t)bz*outS;
  int c0 = bx*64, r0 = by*64;
  int rr = tid>>2, c4 = (tid&3)*16;
  const float* p = in + (size_t)(r0+rr)*Cc + c0 + c4;
  #pragma unroll
  for (int j=0;j<16;j+=4){
    float4 q = *reinterpret_cast<const float4*>(p+j);
    t[rr][c4+j]=q.x; t[rr][c4+j+1]=q.y; t[rr][c4+j+2]=q.z; t[rr][c4+j+3]=q.w;
  }
  __syncthreads();
  int ql = tid>>2;
  int q = c0 + ql;
  int orow = (q % D)*G + q / D;
  bf16* op = out + (size_t)orow*R + r0 + c4;
  #pragma unroll
  for (int j=0;j<16;j++) op[j] = __float2bfloat16(t[c4+j][ql]);
}

// PAT=0 (A-side): blocks (hi, lo, hi). PAT=1 (B-side): blocks (hi, hi, lo).
// Paired dot over 3R gives ah*bh + al*bh + ah*bl == fp32-accurate product.
template<int PAT>
__device__ __forceinline__ void permTsplit3_body(const float* inp, unsigned short* outp,
    int Cc, int R, int D, int G, long inS, long outS,
    int bx, int by, int bz, int tid, float (*t)[65]){
  const float* in = inp + (size_t)bz*inS;
  unsigned short* out = outp + (size_t)bz*outS;
  int c0 = bx*64, r0 = by*64;
  int rr = tid>>2, c4 = (tid&3)*16;
  const float* p = in + (size_t)(r0+rr)*Cc + c0 + c4;
  #pragma unroll
  for (int j=0;j<16;j+=4){
    float4 q = *reinterpret_cast<const float4*>(p+j);
    t[rr][c4+j]=q.x; t[rr][c4+j+1]=q.y; t[rr][c4+j+2]=q.z; t[rr][c4+j+3]=q.w;
  }
  __syncthreads();
  int ql = tid>>2;
  int q = c0 + ql;
  int orow = (q % D)*G + q / D;
  unsigned short* op = out + (size_t)orow*(3*R);
  #pragma unroll
  for (int j=0;j<16;j++){
    float v = t[c4+j][ql];
    unsigned short h = f2bu(v);
    unsigned short l = f2bu(v - b2f(h));
    int idx = r0 + c4 + j;
    if constexpr (PAT==0){
      op[idx] = h; op[R+idx] = l; op[2*R+idx] = h;
    } else {
      op[idx] = h; op[R+idx] = h; op[2*R+idx] = l;
    }
  }
}

__device__ __forceinline__ void splitA_body(const float* in, unsigned short* out,
                                            int blk, int tid){
  int idx = blk*256 + tid;   // 1024*512
  int m = idx >> 9, j = idx & 511;
  float v = in[idx];
  unsigned short h = f2bu(v);
  unsigned short l = f2bu(v - b2f(h));
  unsigned short* op = out + (size_t)m*1536 + j;
  op[0] = h; op[512] = l; op[1024] = h;
}

// ---- fused prep: permT(ctx) | split3(up1w) | split3(up2w) | PE table | range-zero ------
// (round 11: 5 serial latency-bound launches -> 1 kernel, 4160 blocks co-scheduled)
__launch_bounds__(256)
__global__ void prep_k(const float* __restrict__ ctx, bf16* __restrict__ xclA,
                       const float* __restrict__ up1w, unsigned short* __restrict__ w1sp,
                       const float* __restrict__ up2w, unsigned short* __restrict__ w2sp,
                       float* __restrict__ peN, float* __restrict__ zbase){
  __shared__ float t[64][65];
  int b = blockIdx.x, tid = threadIdx.x;
  if (b < 1024){
    permT_body(ctx, xclA, 256, 1024, 1, 1, 262144L, 262144L,
               b&3, (b>>2)&15, b>>6, tid, t);
  } else if (b < 1536){
    b -= 1024;
    permTsplit3_body<1>(up1w, w1sp, 2048, 1024, 4, 512, 0L, 0L,
                        b&31, b>>5, 0, tid, t);
  } else if (b < 1792){
    b -= 1536;
    permTsplit3_body<1>(up2w, w2sp, 2048, 512, 4, 512, 0L, 0L,
                        b&31, b>>5, 0, tid, t);
  } else if (b < 3840){
    int idx = (b-1792)*256 + tid;   // 524288 PE entries
    int n = idx >> 9, c = idx & 511;
    float div = expf(-0.035977892f * (float)(c>>1));   // 2*ln(10000)/512
    float ang = (float)n * div;
    peN[idx] = (c & 1) ? cosf(ang) : sinf(ang);
  } else {
    zbase[(b-3840)*256 + tid] = 0.f;   // bytes 65536..393216 of ws
  }
}

// ---- fused layer prep: splitA(ow) | split3(vw) ----------------------------------------
__launch_bounds__(256)
__global__ void layerprep_k(const float* __restrict__ ow, unsigned short* __restrict__ Asp,
                            const float* __restrict__ vw, unsigned short* __restrict__ Bsp){
  __shared__ float t[64][65];
  int b = blockIdx.x, tid = threadIdx.x;
  if (b < 2048){
    splitA_body(ow, Asp, b, tid);
  } else {
    b -= 2048;   // 128 blocks: (16,8)
    permTsplit3_body<1>(vw, Bsp, 1024, 512, 1, 1, 0L, 0L, b&15, b>>4, 0, tid, t);
  }
}

// standalone wrapper (frame staging: must run after gp2_k; aliases part9)
template<int PAT>
__launch_bounds__(256)
__global__ void permTsplit3_k(const float* __restrict__ inp, unsigned short* __restrict__ outp,
                              int Cc, int R, int D, int G, long inS, long outS){
  __shared__ float t[64][65];
  permTsplit3_body<PAT>(inp, outp, Cc, R, D, G, inS, outS,
                        blockIdx.x, blockIdx.y, blockIdx.z, threadIdx.x, t);
}

// ================= unified MFMA GEMM: global_load_lds + N-buffer + counted vmcnt =========
// C[m][f] = sum_k A[m][k]*B[f][k], bf16. WM x WN waves, each owns (MTM*16) x (NTN*16).
// NBUF=3: 1-ahead staging, ONE barrier per K-step, no lgkm drain (round-10; race-free:
//   stage(t+1) writes buf last read at compute(t-2), finished before BAR(t-1)).
// NBUF=4 (round 11, conv): 2-ahead staging -> each stage has ~2 K-steps to land, covering
//   the L2 round-trip that 1-ahead left exposed at 2 blocks/CU. stage(t+2) writes buf
//   last read at compute(t-2) -> same barrier-ordering argument, race-free. Steady-state
//   wait vmcnt(2*LPT); tail: vmcnt(LPT), then vmcnt(0).
// Residency rule (round-4): LDS blocks/CU >= grid demand. conv 4buf BK32 64KB -> 2/CU
// (grid 1.8); MODE0 3buf BK64 72KB -> 2/CU (grid 2); up1 72KB -> 2 (1.5); up2 48KB -> 3 (3).
// LDS image: linear dest slot (16B) = row*CPR + chunk'; swizzle chunk' = c ^ swz(row)
// on the GLOBAL source address (m104-safe); swz = (row>>1)&3 @BK32, row&7 @BK64.
// BN-FOLD: MODE 4 (weff): if gpf, scale cols by sc0 + atomicAdd sh0-dot into aux.
// MODE 0: bias+biasAdd, residual scaled by gpf, writes bf16 xcl + BN partials.
// MODE 1: conv3d im2col K-split z (XCD-bijective z-major swizzle -> B L2-resident),
// MODE 2: up1 (relu+bias, convT scatter, 3-block h/l/h), MODE 5: up2 + fused SG dot.
template<int WM, int WN, int MTM, int NTN, int MODE, int BK, int NBUF=3>
__launch_bounds__(256)
__global__ void mmL_k(const unsigned short* __restrict__ A,
                      const unsigned short* __restrict__ B,
                      const float* __restrict__ bias,
                      const unsigned short* __restrict__ res,
                      const float* __restrict__ gpf,
                      float* __restrict__ outf,
                      unsigned short* __restrict__ outs,
                      float* __restrict__ aux,
                      int K){
  constexpr int BM  = WM*MTM*16;
  constexpr int BN  = WN*NTN*16;
  constexpr int CPR = BK/8;            // 16B chunks per row
  constexpr int KS  = BK/32;           // k-subtiles per step
  constexpr int AIT = (BM*CPR)/256;    // A chunks per thread
  constexpr int NBC = (BN*CPR)/256;    // B chunks per thread
  constexpr int LPT = AIT + NBC;       // loads in flight per thread per stage
  __shared__ __align__(16) short As[NBUF*BM*BK];
  __shared__ __align__(16) short Bs[NBUF*BN*BK];
  const int tid = threadIdx.x;
  const int wv = tid>>6, lane = tid&63, l15 = lane&15, quad = lane>>4;
  const int wvm = wv / WN, wvf = wv % WN;
  const int wbase = wv<<6;             // wave-uniform LDS slot base (64 slots/wave)

  int bx = blockIdx.x, by = blockIdx.y, bz = blockIdx.z;
  if constexpr (MODE==1){
    const int gx = gridDim.x, gy = gridDim.y, gz = gridDim.z;
    const int n = gx*gy*gz;
    const int lin = bx + gx*(by + gy*bz);
    const int q = n >> 3, r = n & 7;
    const int xcd = lin & 7, j = lin >> 3;
    const int work = (xcd < r ? xcd*(q+1) : r*(q+1) + (xcd-r)*q) + j;
    by = work % gy;                 // y minor
    const int t = work / gy;
    bx = t % gx;                    // x middle
    bz = t / gx;                    // z major (chunk == one kt/kh slice)
  }
  const int m0 = bx*BM;
  const int fblk = by*BN;
  const int z = bz;

  auto swz = [](int row){ if constexpr (BK==32) return (row>>1)&3; else return row&7; };

  // ---- staging addresses (source-side swizzle; LDS dest linear: slot = it*256+tid) ----
  size_t aAddr[AIT];
  #pragma unroll
  for (int it=0; it<AIT; ++it){
    int s = tid + it*256;
    int arow = s/CPR;
    int ac = (s&(CPR-1)) ^ swz(arow);
    int m = m0 + arow;
    if constexpr (MODE==1){
      int mm = m < 1568 ? m : 1567;
      int b = mm/392, r = mm%392;
      int t = r/196, r2 = r%196;
      int hh = r2/14, ww = r2%14;
      int kt = z/3, kh = z%3;
      int sp = ((b*4 + t + kt)*16 + hh + kh)*16 + ww;
      aAddr[it] = (size_t)sp*1024 + ac*8;
    } else {
      aAddr[it] = (size_t)m*K + ac*8;
    }
  }
  size_t bAddr[NBC];
  #pragma unroll
  for (int it=0; it<NBC; ++it){
    int s = tid + it*256;
    int row = s/CPR;
    int c = (s&(CPR-1)) ^ swz(row);
    int f = fblk + row;
    if constexpr (MODE==0)      bAddr[it] = (size_t)f*1024 + c*8;
    else if constexpr (MODE==1) bAddr[it] = (size_t)f*27648 + (size_t)z*3072 + c*8;
    else                        bAddr[it] = ((size_t)z*512 + f)*(size_t)K + c*8;
  }
  // ---- fragment LDS slots (swizzled), per k-subtile ----
  int aslot[MTM][KS];
  #pragma unroll
  for (int mt=0;mt<MTM;++mt)
    #pragma unroll
    for (int ks=0;ks<KS;++ks){
      int row = wvm*MTM*16 + mt*16 + l15;
      aslot[mt][ks] = row*CPR + ((ks*4 + quad) ^ swz(row));
    }
  int bslot[NTN][KS];
  #pragma unroll
  for (int nt=0;nt<NTN;++nt)
    #pragma unroll
    for (int ks=0;ks<KS;++ks){
      int row = wvf*NTN*16 + nt*16 + l15;
      bslot[nt][ks] = row*CPR + ((ks*4 + quad) ^ swz(row));
    }

  float4v acc[MTM][NTN];
  #pragma unroll
  for (int i=0;i<MTM;i++)
    #pragma unroll
    for (int j=0;j<NTN;j++) acc[i][j]=(float4v){0,0,0,0};

  auto stage = [&](int buf, int k0){
    #pragma unroll
    for (int it=0; it<AIT; ++it)
      GLDS16(A + aAddr[it] + k0, As + buf*(BM*BK) + (it*256 + wbase)*8);
    #pragma unroll
    for (int it=0; it<NBC; ++it)
      GLDS16(B + bAddr[it] + k0, Bs + buf*(BN*BK) + (it*256 + wbase)*8);
  };
  auto computeTile = [&](int buf){
    const short* ap = As + buf*(BM*BK);
    const short* bp = Bs + buf*(BN*BK);
    #pragma unroll
    for (int ks=0; ks<KS; ++ks){
      short8 bf[NTN];
      #pragma unroll
      for (int nt=0;nt<NTN;++nt)
        bf[nt] = *reinterpret_cast<const short8*>(bp + bslot[nt][ks]*8);
      #pragma unroll
      for (int mt=0;mt<MTM;++mt){
        short8 af = *reinterpret_cast<const short8*>(ap + aslot[mt][ks]*8);
        #pragma unroll
        for (int nt=0;nt<NTN;++nt)
          acc[mt][nt] = __builtin_amdgcn_mfma_f32_16x16x32_bf16(af, bf[nt], acc[mt][nt],0,0,0);
      }
    }
  };

  const int nt = K/BK;
  if constexpr (NBUF==3){
    int b0=0, b1=1, b2=2;
    stage(b0, 0);
    for (int t=0; t<nt-1; ++t){
      stage(b1, (t+1)*BK);             // tile t+1 in flight across the barrier
      vwait<LPT>();
      __builtin_amdgcn_sched_barrier(0);
      __builtin_amdgcn_s_barrier();    // all waves' tile-t loads landed
      __builtin_amdgcn_sched_barrier(0);
      computeTile(b0);
      int tmp=b0; b0=b1; b1=b2; b2=tmp;
    }
    vwait<0>();
    __builtin_amdgcn_sched_barrier(0);
    __builtin_amdgcn_s_barrier();
    __builtin_amdgcn_sched_barrier(0);
    computeTile(b0);
  } else {
    // 4-buffer, 2-ahead
    stage(0, 0);
    stage(1, BK);
    for (int t=0; t<nt; ++t){
      if (t+2 < nt) stage((t+2)&3, (t+2)*BK);
      if (t+2 < nt)      vwait<2*LPT>();
      else if (t+1 < nt) vwait<LPT>();
      else               vwait<0>();
      __builtin_amdgcn_sched_barrier(0);
      __builtin_amdgcn_s_barrier();    // tile-t loads landed
      __builtin_amdgcn_sched_barrier(0);
      computeTile(t&3);
    }
  }

  if constexpr (MODE==0){
    // BN-folded nonlocal epilogue: v = relu(acc+bias+biasAdd) + res*sc + sh -> bf16 xcl,
    // plus per-block column stats (sum, sum^2) into aux.
    const float* badd = outf;          // bias-fold accumulator (l=1) or nullptr (l=0)
    float sacc[NTN] = {}, s2acc[NTN] = {};
    #pragma unroll
    for (int nt2=0;nt2<NTN;++nt2){
      int f = fblk + wvf*NTN*16 + nt2*16 + l15;
      float bi = bias[f] + (badd ? badd[f] : 0.f);
      float rsc = 1.f, rsh = 0.f;
      if (gpf){ rsc = gpf[f]; rsh = gpf[1024+f]; }
      #pragma unroll
      for (int mt=0;mt<MTM;++mt){
        #pragma unroll
        for (int r=0;r<4;++r){
          int m = m0 + wvm*MTM*16 + mt*16 + quad*4 + r;
          float v = fmaxf(acc[mt][nt2][r]+bi, 0.f) + b2f(res[(size_t)m*1024 + f])*rsc + rsh;
          outs[(size_t)m*1024 + f] = f2bu(v);
          sacc[nt2] += v; s2acc[nt2] += v*v;
        }
      }
    }
    #pragma unroll
    for (int nt2=0;nt2<NTN;++nt2){
      float s = sacc[nt2], s2 = s2acc[nt2];
      s  += __shfl_xor(s, 16);  s  += __shfl_xor(s, 32);
      s2 += __shfl_xor(s2, 16); s2 += __shfl_xor(s2, 32);
      if (quad==0){
        int f = fblk + wvf*NTN*16 + nt2*16 + l15;
        aux[(size_t)bx*2048 + f] = s;
        aux[(size_t)bx*2048 + 1024 + f] = s2;
      }
    }
  } else if constexpr (MODE==1){
    #pragma unroll
    for (int mt=0;mt<MTM;++mt)
      #pragma unroll
      for (int nt2=0;nt2<NTN;++nt2){
        int f = fblk + wvf*NTN*16 + nt2*16 + l15;
        #pragma unroll
        for (int r=0;r<4;++r){
          int m = m0 + wvm*MTM*16 + mt*16 + quad*4 + r;
          if (m < 1568) outf[((size_t)z*1568 + m)*512 + f] = acc[mt][nt2][r];
        }
      }
  } else if constexpr (MODE==2){
    int kk = z>>1, ll = z&1;
    #pragma unroll
    for (int mt=0;mt<MTM;++mt)
      #pragma unroll
      for (int nt2=0;nt2<NTN;++nt2){
        int f = fblk + wvf*NTN*16 + nt2*16 + l15;
        float bi = bias[f];
        #pragma unroll
        for (int r=0;r<4;++r){
          int m = m0 + wvm*MTM*16 + mt*16 + quad*4 + r;
          int bt = m>>6, p = m&63;
          long orow = (long)bt*256 + (2*(p>>3)+kk)*16 + 2*(p&7)+ll;
          float v = fmaxf(acc[mt][nt2][r]+bi, 0.f);
          unsigned short h = f2bu(v);
          unsigned short l = f2bu(v - b2f(h));
          unsigned short* rp = outs + (size_t)orow*1536 + f;
          rp[0] = h; rp[512] = l; rp[1024] = h;
        }
      }
  } else if constexpr (MODE==5){
    int kk = z>>1, ll = z&1;
    #pragma unroll
    for (int mt=0;mt<MTM;++mt){
      int mbase = m0 + wvm*MTM*16 + mt*16;
      int bt = mbase>>8, b6 = bt/6, p0 = mbase&255;
      float gv[NTN], bv[NTN];
      #pragma unroll
      for (int nt2=0;nt2<NTN;++nt2){
        int f = fblk + wvf*NTN*16 + nt2*16 + l15;
        gv[nt2] = gpf[b6*512 + f];
        bv[nt2] = bias[f];
      }
      #pragma unroll
      for (int r=0;r<4;++r){
        int p = p0 + quad*4 + r;
        long orow = (long)bt*1024 + (2*(p>>4)+kk)*32 + 2*(p&15)+ll;
        float sdot = 0.f;
        #pragma unroll
        for (int nt2=0;nt2<NTN;++nt2){
          int f = fblk + wvf*NTN*16 + nt2*16 + l15;
          float v = acc[mt][nt2][r] + bv[nt2];
          outf[(size_t)orow*512 + f] = v;
          sdot += v * gv[nt2];
        }
        sdot += __shfl_xor(sdot, 1); sdot += __shfl_xor(sdot, 2);
        sdot += __shfl_xor(sdot, 4); sdot += __shfl_xor(sdot, 8);
        if (l15==0) atomicAdd(aux + orow, sdot);
      }
    }
  } else {  // MODE 4: weff bf16 out; BN-fold: scale cols by sc0, bias partials via sh0
    if (gpf){
      float sc[NTN], sh[NTN];
      #pragma unroll
      for (int nt2=0;nt2<NTN;++nt2){
        int f = fblk + wvf*NTN*16 + nt2*16 + l15;
        sc[nt2] = gpf[f]; sh[nt2] = gpf[1024+f];
      }
      #pragma unroll
      for (int mt=0;mt<MTM;++mt){
        #pragma unroll
        for (int r=0;r<4;++r){
          int m = m0 + wvm*MTM*16 + mt*16 + quad*4 + r;
          float part = 0.f;
          #pragma unroll
          for (int nt2=0;nt2<NTN;++nt2){
            int f = fblk + wvf*NTN*16 + nt2*16 + l15;
            float a = acc[mt][nt2][r];
            part += a * sh[nt2];
            outs[(size_t)m*1024 + f] = f2bu(a * sc[nt2]);
          }
          part += __shfl_xor(part, 1); part += __shfl_xor(part, 2);
          part += __shfl_xor(part, 4); part += __shfl_xor(part, 8);
          if (l15==0) atomicAdd(aux + m, part);
        }
      }
    } else {
      #pragma unroll
      for (int mt=0;mt<MTM;++mt)
        #pragma unroll
        for (int nt2=0;nt2<NTN;++nt2){
          int f = fblk + wvf*NTN*16 + nt2*16 + l15;
          #pragma unroll
          for (int r=0;r<4;++r){
            int m = m0 + wvm*MTM*16 + mt*16 + quad*4 + r;
            outs[(size_t)m*1024 + f] = f2bu(acc[mt][nt2][r]);
          }
        }
    }
  }
}

// ---------------- BN stats combine: bnp[64][2][1024] -> scale/shift mv ------------------
__global__ void stats_comb(const float* __restrict__ bnp, const float* __restrict__ g,
                           const float* __restrict__ beta, float* __restrict__ mv){
  int c = blockIdx.x*256 + threadIdx.x;   // 1024
  float S=0.f, S2=0.f;
  #pragma unroll 8
  for (int s=0;s<64;s++){ S += bnp[(size_t)s*2048 + c]; S2 += bnp[(size_t)s*2048 + 1024 + c]; }
  float m = S * (1.f/4096.f);
  float var = S2 * (1.f/4096.f) - m*m;
  float inv = rsqrtf(var + 1e-5f);
  float sc = inv * g[c];
  mv[c] = sc;
  mv[1024 + c] = beta[c] - m*sc;
}

// ---- weight permute + BN fold, cc-parallel: one load->scatter phase per block ----------
__launch_bounds__(256)
__global__ void wperm_k(const float* __restrict__ w, const float* __restrict__ mv1,
                        unsigned short* __restrict__ wtt, float* __restrict__ tpb2){
  __shared__ float ls[3456];
  __shared__ float rs[256];
  int f = blockIdx.x, cc = blockIdx.y;
  const float* src = w + (size_t)f*27648 + cc*3456;
  unsigned short* dst = wtt + (size_t)f*27648;
  for (int i=threadIdx.x; i<3456; i+=256) ls[i] = src[i];
  __syncthreads();
  float part = 0.f;
  for (int u=threadIdx.x; u<3456; u+=256){
    int j = u >> 7, c = u & 127;
    int ch = cc*128 + c;
    float wv = ls[c*27 + j];
    dst[(size_t)j*1024 + ch] = f2bu(wv * mv1[ch]);
    part += wv * mv1[1024 + ch];
  }
  rs[threadIdx.x] = part; __syncthreads();
  for (int st=128; st>0; st>>=1){
    if (threadIdx.x < st) rs[threadIdx.x] += rs[threadIdx.x+st];
    __syncthreads();
  }
  if (threadIdx.x==0) atomicAdd(tpb2 + f, rs[0]);
}

// ---------------- goal_pre: z splits the 392 positions 8-ways; atomicAdd into gp --------
__launch_bounds__(256)
__global__ void gp2_k(const float* __restrict__ part9, const float* __restrict__ tpb,
                      const float* __restrict__ tpbA, float* __restrict__ gp){
  int b = blockIdx.x;
  int fc = blockIdx.y;
  int z = blockIdx.z;          // 8 p-chunks of 49
  int fi = threadIdx.x & 31, pi = threadIdx.x >> 5;
  int f = fc*32 + fi;
  float bias = tpb[f] + tpbA[f];
  float a = 0.f;
  for (int p = z*49 + pi; p < z*49 + 49; p += 8){
    size_t base = ((size_t)(b*392 + p))*512 + f;
    float v = bias;
    #pragma unroll
    for (int i=0;i<9;i++) v += part9[(size_t)i*802816 + base];
    a += fmaxf(v, 0.f);
  }
  __shared__ float red[256];
  red[threadIdx.x] = a; __syncthreads();
  for (int st=4; st>0; st>>=1){
    if (pi < st) red[pi*32+fi] += red[(pi+st)*32+fi];
    __syncthreads();
  }
  if (pi==0) atomicAdd(gp + b*512 + f, red[fi] * (1.f/392.f));
}

// ---------------- softmax over n: attn[bt][n] normalized --------------------------------
__launch_bounds__(256)
__global__ void softmax_k(const float* __restrict__ SG, float* __restrict__ attn){
  int bt = blockIdx.x; int tid = threadIdx.x;
  float4 v = *reinterpret_cast<const float4*>(SG + bt*1024 + tid*4);
  float mx = fmaxf(fmaxf(v.x,v.y), fmaxf(v.z,v.w));
  __shared__ float red[256];
  red[tid] = mx; __syncthreads();
  for (int st=128; st>0; st>>=1){
    if (tid<st) red[tid] = fmaxf(red[tid], red[tid+st]);
    __syncthreads();
  }
  float m = red[0]; __syncthreads();
  float4 e;
  e.x = expf(v.x-m); e.y = expf(v.y-m); e.z = expf(v.z-m); e.w = expf(v.w-m);
  red[tid] = e.x+e.y+e.z+e.w; __syncthreads();
  for (int st=128; st>0; st>>=1){
    if (tid<st) red[tid] += red[tid+st];
    __syncthreads();
  }
  float inv = 1.0f/red[0];
  e.x*=inv; e.y*=inv; e.z*=inv; e.w*=inv;
  *reinterpret_cast<float4*>(attn + bt*1024 + tid*4) = e;
}

// ---- sga[bt][c] += sum_{n in slice} attn[n]*(scl[n][c]+pe[n][c])  (32 slices of 32) ----
__launch_bounds__(256)
__global__ void sga2_k(const float* __restrict__ scl, const float* __restrict__ peN,
                       const float* __restrict__ attn, float* __restrict__ sga){
  int bt = blockIdx.x, sl = blockIdx.y;   // 24 x 32
  int tid = threadIdx.x;
  __shared__ float at[32];
  if (tid < 32) at[tid] = attn[bt*1024 + sl*32 + tid];
  __syncthreads();
  float acc0 = 0.f, acc1 = 0.f;
  for (int j=0;j<32;j++){
    int n = sl*32 + j;
    float a = at[j];
    const float* row = scl + ((size_t)bt*1024 + n)*512;
    const float* pe  = peN + (size_t)n*512;
    acc0 += a * (row[tid] + pe[tid]);
    acc1 += a * (row[tid+256] + pe[tid+256]);
  }
  atomicAdd(sga + (size_t)bt*512 + tid, acc0);
  atomicAdd(sga + (size_t)bt*512 + 256 + tid, acc1);
}

// ---------------- 512->512(relu)->128 MLP head (fp32 weights) ---------------------------
__launch_bounds__(256)
__global__ void mlp_k(const float* __restrict__ in, const float* __restrict__ w1,
                      const float* __restrict__ b1, const float* __restrict__ w2,
                      const float* __restrict__ b2, float* __restrict__ out){
  int bb = blockIdx.x; int tid = threadIdx.x;
  __shared__ float xv[512]; __shared__ float h[512];
  xv[tid] = in[(size_t)bb*512 + tid];
  xv[tid+256] = in[(size_t)bb*512 + 256 + tid];
  __syncthreads();
  #pragma unroll
  for (int oo=0;oo<2;oo++){
    int o = tid + oo*256;
    const float* wr = w1 + (size_t)o*512;
    float a=0.f;
    for (int c=0;c<512;c+=4){
      float4 q = *reinterpret_cast<const float4*>(wr+c);
      a += xv[c]*q.x + xv[c+1]*q.y + xv[c+2]*q.z + xv[c+3]*q.w;
    }
    h[o] = fmaxf(a + b1[o], 0.f);
  }
  __syncthreads();
  if (tid < 128){
    const float* wr = w2 + (size_t)tid*512;
    float a=0.f;
    for (int c=0;c<512;c+=4){
      float4 q = *reinterpret_cast<const float4*>(wr+c);
      a += h[c]*q.x + h[c+1]*q.y + h[c+2]*q.z + h[c+3]*q.w;
    }
    out[(size_t)bb*128+tid] = a + b2[tid];
  }
}

extern "C" void kernel_launch(void* const* d_in, const int* in_sizes, int n_in,
                              void* d_out, int out_size, void* d_ws, size_t ws_size,
                              hipStream_t stream){
  (void)in_sizes; (void)n_in; (void)out_size; (void)ws_size;
  const float* ctx   = (const float*)d_in[0];
  const float* frame = (const float*)d_in[1];
  const float* nl_vw[2] = {(const float*)d_in[4],  (const float*)d_in[11]};
  const float* nl_ow[2] = {(const float*)d_in[5],  (const float*)d_in[12]};
  const float* nl_ob[2] = {(const float*)d_in[6],  (const float*)d_in[13]};
  const float* nl_g[2]  = {(const float*)d_in[7],  (const float*)d_in[14]};
  const float* nl_be[2] = {(const float*)d_in[8],  (const float*)d_in[15]};
  const float* tp_w = (const float*)d_in[16]; const float* tp_b = (const float*)d_in[17];
  const float* up1w = (const float*)d_in[18]; const float* up1b = (const float*)d_in[19];
  const float* up2w = (const float*)d_in[20]; const float* up2b = (const float*)d_in[21];
  const float* og1w = (const float*)d_in[22]; const float* og1b = (const float*)d_in[23];
  const float* og2w = (const float*)d_in[24]; const float* og2b = (const float*)d_in[25];
  const float* os1w = (const float*)d_in[26]; const float* os1b = (const float*)d_in[27];
  const float* os2w = (const float*)d_in[28]; const float* os2b = (const float*)d_in[29];
  float* out = (float*)d_out;

  char* wsp = (char*)d_ws;
  // ---- persistent region ----
  float* bias2   = (float*)(wsp + 65536);         // 4KB  [1024] weff bias-fold acc
  float* tpb2    = (float*)(wsp + 69632);         // 2KB  [512] conv bias-fold (atomic)
  float* gp      = (float*)(wsp + 73728);         // 8KB  [4][512] (atomic-accumulated)
  float* mv0     = (float*)(wsp + 131072);        // 8KB  BN scale/shift layer 0
  float* mv1     = (float*)(wsp + 139264);        // 8KB  BN scale/shift layer 1
  float* SG      = (float*)(wsp + 147456);        // 98304 (atomic-accumulated)
  float* attn    = (float*)(wsp + 245760);        // 98304
  float* sga     = (float*)(wsp + 344064);        // 49152 (atomic-accumulated)
  float* peN     = (float*)(wsp + 786432);        // 2097152 [1024][512]
  bf16*  weff    = (bf16*) (wsp + 2883584);       // 2097152 [1024][1024] bf16
  unsigned short* w1sp = (unsigned short*)(wsp + 4980736);   // 12582912 [4][512][3072]
  unsigned short* w2sp = (unsigned short*)(wsp + 17563648);  // 6291456  [4][512][1536]
  char* ov = wsp + 23855104;
  // phase 1 (nonlocal, BN folded -> xcl ping-pong):
  bf16*  xclA = (bf16*) (ov);                     // 8 MB [4096][1024]
  bf16*  xclB = (bf16*) (ov + 8388608);           // 8 MB (dead after l=1 reads it)
  // phase 1 staging in the (dead until phase 2) part9 region:
  unsigned short* Asp = (unsigned short*)(ov + 36700160);            // 3 MB [1024][1536]
  unsigned short* Bsp = (unsigned short*)(ov + 36700160 + 3145728);  // 3 MB [1024][1536]
  float* bnp = (float*)(ov + 36700160 + 6291456); // 512 KB [64][2][1024] BN partials
  // phase 2 (conv): wtt aliases xclB region (written after l=1 MODE0 consumed xclB)
  unsigned short* wtt = (unsigned short*)(ov + 8388608);   // 28.3 MB [512][27648]
  float* part9 = (float*)(ov + 36700160);         // 28.9 MB [9][1568][512]
  // frame staging: aliases part9 (written after gp2_k reads part9)
  unsigned short* Fsp = (unsigned short*)(ov + 36700160);  // 9.4 MB [1536][3072]
  // phase 3 (after gp2_k; xclA/wtt dead):
  unsigned short* s1sp = (unsigned short*)(ov);   // 18.9 MB [6144][1536]
  float* scl  = (float*)(ov + 18874368);          // 50.3 MB [24576][512]

  // fused prep: permT(ctx) | split3(up1w) | split3(up2w) | PE | range-zero (1 launch)
  prep_k<<<4160,256,0,stream>>>(ctx, xclA, up1w, w1sp, up2w, w2sp, peN,
                                (float*)(wsp + 65536));

  // nonlocal layer 0: xclA -> xclB (BN deferred via fold into layer-1 consumers)
  layerprep_k<<<2176,256,0,stream>>>(nl_ow[0], Asp, nl_vw[0], Bsp);
  mmL_k<1,4,2,2,4,64><<<dim3(32,8,1),256,0,stream>>>(Asp, Bsp, nullptr, nullptr, nullptr,
      nullptr, (unsigned short*)weff, nullptr, 1536);
  mmL_k<1,4,4,2,0,64><<<dim3(64,8,1),256,0,stream>>>((const unsigned short*)xclA,
      (const unsigned short*)weff, nl_ob[0], (const unsigned short*)xclA, nullptr,
      nullptr, (unsigned short*)xclB, bnp, 1024);
  stats_comb<<<4,256,0,stream>>>(bnp, nl_g[0], nl_be[0], mv0);

  // nonlocal layer 1: xclB -> xclA; weff cols scaled by sc0, sh0 folded to bias2
  layerprep_k<<<2176,256,0,stream>>>(nl_ow[1], Asp, nl_vw[1], Bsp);
  mmL_k<1,4,2,2,4,64><<<dim3(32,8,1),256,0,stream>>>(Asp, Bsp, nullptr, nullptr, mv0,
      nullptr, (unsigned short*)weff, bias2, 1536);
  mmL_k<1,4,4,2,0,64><<<dim3(64,8,1),256,0,stream>>>((const unsigned short*)xclB,
      (const unsigned short*)weff, nl_ob[1], (const unsigned short*)xclB, mv0,
      bias2, (unsigned short*)xclA, bnp, 1024);
  stats_comb<<<4,256,0,stream>>>(bnp, nl_g[1], nl_be[1], mv1);

  // temporal-pool conv (im2col GEMM, K-split 9); BN-1 folded into wtt (sc1) + tpb2 (sh1)
  // 4-buf 2-ahead BK=32: 64KB LDS -> 2/CU >= 1.8 demand; 2 stages in flight cover L2 lat.
  wperm_k<<<dim3(512,8),256,0,stream>>>(tp_w, mv1, wtt, tpb2);
  mmL_k<2,2,4,4,1,32,4><<<dim3(13,4,9),256,0,stream>>>((const unsigned short*)xclA, wtt,
      nullptr, nullptr, nullptr, part9, nullptr, nullptr, 3072);
  gp2_k<<<dim3(4,16,8),256,0,stream>>>(part9, tp_b, tpb2, gp);

  // frame path (3-block split-bf16 == fp32-accurate); Fsp aliases part9 -> after gp2_k
  permTsplit3_k<0><<<dim3(1,16,24),256,0,stream>>>(frame, Fsp, 64, 1024, 1, 1, 65536L, 196608L);
  // up1: BM=64 (3-buf 72KB -> 2/CU; grid 384 = 1.5/CU demand)
  mmL_k<1,4,4,2,2,64><<<dim3(24,4,4),256,0,stream>>>(Fsp, w1sp, up1b, nullptr, nullptr,
      nullptr, s1sp, nullptr, 3072);
  // up2 + fused SG partial dot (3-buf BK=32: 48KB -> 3/CU = demand)
  mmL_k<2,2,4,4,5,32><<<dim3(48,4,4),256,0,stream>>>(s1sp, w2sp, up2b, nullptr, gp,
      scl, nullptr, SG, 1536);

  // attention tail
  softmax_k<<<24,256,0,stream>>>(SG, attn);
  sga2_k<<<dim3(24,32),256,0,stream>>>(scl, peN, attn, sga);

  // heads
  mlp_k<<<4,256,0,stream>>>(gp, og1w, og1b, og2w, og2b, out);
  mlp_k<<<24,256,0,stream>>>(sga, os1w, os1b, os2w, os2b, out + 512);
}

// Round 12
// 535.319 us; speedup vs baseline: 1.5221x; 1.0620x over previous
//
#include <hip/hip_runtime.h>
#include <hip/hip_bf16.h>

using bf16 = __hip_bfloat16;
typedef short short8 __attribute__((ext_vector_type(8)));
typedef float float4v __attribute__((ext_vector_type(4)));

__device__ __forceinline__ float b2f(unsigned short u){
  unsigned int x = ((unsigned int)u) << 16; float f;
  __builtin_memcpy(&f, &x, 4); return f;
}
__device__ __forceinline__ float b2f(bf16 v){ return __bfloat162float(v); }
__device__ __forceinline__ unsigned short f2bu(float x){
  bf16 h = __float2bfloat16(x); unsigned short u;
  __builtin_memcpy(&u, &h, 2); return u;
}

// async global->LDS, 16B per lane, dest = wave-uniform base + lane*16
#define GLDS16(g, l) __builtin_amdgcn_global_load_lds( \
    (const __attribute__((address_space(1))) void*)(g), \
    (__attribute__((address_space(3))) void*)(l), 16, 0, 0)

template<int N> __device__ __forceinline__ void vwait(){
  if constexpr (N==0)       asm volatile("s_waitcnt vmcnt(0)" ::: "memory");
  else if constexpr (N==3)  asm volatile("s_waitcnt vmcnt(3)" ::: "memory");
  else if constexpr (N==4)  asm volatile("s_waitcnt vmcnt(4)" ::: "memory");
  else if constexpr (N==5)  asm volatile("s_waitcnt vmcnt(5)" ::: "memory");
  else if constexpr (N==6)  asm volatile("s_waitcnt vmcnt(6)" ::: "memory");
  else if constexpr (N==8)  asm volatile("s_waitcnt vmcnt(8)" ::: "memory");
  else if constexpr (N==10) asm volatile("s_waitcnt vmcnt(10)" ::: "memory");
  else                      asm volatile("s_waitcnt vmcnt(12)" ::: "memory");
}

// ================= device bodies (shared by standalone kernels and prep_k) ==============
__device__ __forceinline__ void permT_body(const float* inp, bf16* outp,
    int Cc, int R, int D, int G, long inS, long outS,
    int bx, int by, int bz, int tid, float (*t)[65]){
  const float* in = inp + (size_t)bz*inS;
  bf16* out = outp + (size_t)bz*outS;
  int c0 = bx*64, r0 = by*64;
  int rr = tid>>2, c4 = (tid&3)*16;
  const float* p = in + (size_t)(r0+rr)*Cc + c0 + c4;
  #pragma unroll
  for (int j=0;j<16;j+=4){
    float4 q = *reinterpret_cast<const float4*>(p+j);
    t[rr][c4+j]=q.x; t[rr][c4+j+1]=q.y; t[rr][c4+j+2]=q.z; t[rr][c4+j+3]=q.w;
  }
  __syncthreads();
  int ql = tid>>2;
  int q = c0 + ql;
  int orow = (q % D)*G + q / D;
  bf16* op = out + (size_t)orow*R + r0 + c4;
  #pragma unroll
  for (int j=0;j<16;j++) op[j] = __float2bfloat16(t[c4+j][ql]);
}

// PAT=0 (A-side): blocks (hi, lo, hi). PAT=1 (B-side): blocks (hi, hi, lo).
// Paired dot over 3R gives ah*bh + al*bh + ah*bl == fp32-accurate product.
template<int PAT>
__device__ __forceinline__ void permTsplit3_body(const float* inp, unsigned short* outp,
    int Cc, int R, int D, int G, long inS, long outS,
    int bx, int by, int bz, int tid, float (*t)[65]){
  const float* in = inp + (size_t)bz*inS;
  unsigned short* out = outp + (size_t)bz*outS;
  int c0 = bx*64, r0 = by*64;
  int rr = tid>>2, c4 = (tid&3)*16;
  const float* p = in + (size_t)(r0+rr)*Cc + c0 + c4;
  #pragma unroll
  for (int j=0;j<16;j+=4){
    float4 q = *reinterpret_cast<const float4*>(p+j);
    t[rr][c4+j]=q.x; t[rr][c4+j+1]=q.y; t[rr][c4+j+2]=q.z; t[rr][c4+j+3]=q.w;
  }
  __syncthreads();
  int ql = tid>>2;
  int q = c0 + ql;
  int orow = (q % D)*G + q / D;
  unsigned short* op = out + (size_t)orow*(3*R);
  #pragma unroll
  for (int j=0;j<16;j++){
    float v = t[c4+j][ql];
    unsigned short h = f2bu(v);
    unsigned short l = f2bu(v - b2f(h));
    int idx = r0 + c4 + j;
    if constexpr (PAT==0){
      op[idx] = h; op[R+idx] = l; op[2*R+idx] = h;
    } else {
      op[idx] = h; op[R+idx] = h; op[2*R+idx] = l;
    }
  }
}

__device__ __forceinline__ void splitA_body(const float* in, unsigned short* out,
                                            int blk, int tid){
  int idx = blk*256 + tid;   // 1024*512
  int m = idx >> 9, j = idx & 511;
  float v = in[idx];
  unsigned short h = f2bu(v);
  unsigned short l = f2bu(v - b2f(h));
  unsigned short* op = out + (size_t)m*1536 + j;
  op[0] = h; op[512] = l; op[1024] = h;
}

// ---- fused prep: permT(ctx) | split3(up1w) | split3(up2w) | PE table | range-zero ------
__launch_bounds__(256)
__global__ void prep_k(const float* __restrict__ ctx, bf16* __restrict__ xclA,
                       const float* __restrict__ up1w, unsigned short* __restrict__ w1sp,
                       const float* __restrict__ up2w, unsigned short* __restrict__ w2sp,
                       float* __restrict__ peN, float* __restrict__ zbase){
  __shared__ float t[64][65];
  int b = blockIdx.x, tid = threadIdx.x;
  if (b < 1024){
    permT_body(ctx, xclA, 256, 1024, 1, 1, 262144L, 262144L,
               b&3, (b>>2)&15, b>>6, tid, t);
  } else if (b < 1536){
    b -= 1024;
    permTsplit3_body<1>(up1w, w1sp, 2048, 1024, 4, 512, 0L, 0L,
                        b&31, b>>5, 0, tid, t);
  } else if (b < 1792){
    b -= 1536;
    permTsplit3_body<1>(up2w, w2sp, 2048, 512, 4, 512, 0L, 0L,
                        b&31, b>>5, 0, tid, t);
  } else if (b < 3840){
    int idx = (b-1792)*256 + tid;   // 524288 PE entries
    int n = idx >> 9, c = idx & 511;
    float div = expf(-0.035977892f * (float)(c>>1));   // 2*ln(10000)/512
    float ang = (float)n * div;
    peN[idx] = (c & 1) ? cosf(ang) : sinf(ang);
  } else {
    zbase[(b-3840)*256 + tid] = 0.f;   // bytes 65536..393216 of ws
  }
}

// ---- fused layer prep: splitA(ow) | split3(vw) ----------------------------------------
__launch_bounds__(256)
__global__ void layerprep_k(const float* __restrict__ ow, unsigned short* __restrict__ Asp,
                            const float* __restrict__ vw, unsigned short* __restrict__ Bsp){
  __shared__ float t[64][65];
  int b = blockIdx.x, tid = threadIdx.x;
  if (b < 2048){
    splitA_body(ow, Asp, b, tid);
  } else {
    b -= 2048;   // 128 blocks: (16,8)
    permTsplit3_body<1>(vw, Bsp, 1024, 512, 1, 1, 0L, 0L, b&15, b>>4, 0, tid, t);
  }
}

// standalone wrapper (frame staging: must run after gp2_k; aliases part9)
template<int PAT>
__launch_bounds__(256)
__global__ void permTsplit3_k(const float* __restrict__ inp, unsigned short* __restrict__ outp,
                              int Cc, int R, int D, int G, long inS, long outS){
  __shared__ float t[64][65];
  permTsplit3_body<PAT>(inp, outp, Cc, R, D, G, inS, outS,
                        blockIdx.x, blockIdx.y, blockIdx.z, threadIdx.x, t);
}

// ================= unified MFMA GEMM: global_load_lds + N-buffer + counted vmcnt =========
// C[m][f] = sum_k A[m][k]*B[f][k], bf16. WM x WN waves, each owns (MTM*16) x (NTN*16).
// NBUF=3: 1-ahead staging, ONE barrier per K-step, no lgkm drain (round-10 race-freedom:
//   stage(t+1) writes buf last read at compute(t-2), finished before BAR(t-1)).
// NBUF=4: 2-ahead (kept for shapes with <2 waves/SIMD; round-11 A/B showed no gain for
//   conv -> conv reverted to 3-buf with a BIGGER GRID instead).
// ROUND-12 conv: latency-bound from grid-capped occupancy (468 blocks all-resident =
//   1.8 waves/SIMD; 2-ahead didn't help -> not load-latency). Fix: BN 128->64, grid
//   (13,8,9)=936 blocks, 36KB LDS -> 4 blocks/CU all-resident = 2x waves/SIMD.
// Residency rule (round-4): LDS blocks/CU >= grid demand.
// LDS image: linear dest slot (16B) = row*CPR + chunk'; swizzle chunk' = c ^ swz(row)
// on the GLOBAL source address (m104-safe); swz = (row>>1)&3 @BK32, row&7 @BK64.
// BN-FOLD: MODE 4 (weff): if gpf, scale cols by sc0 + atomicAdd sh0-dot into aux.
// MODE 0: bias+biasAdd, residual scaled by gpf, writes bf16 xcl + BN partials.
// MODE 1: conv3d im2col K-split z (XCD-bijective z-major swizzle -> B L2-resident),
// MODE 2: up1 (relu+bias, convT scatter, 3-block h/l/h), MODE 5: up2 + fused SG dot.
template<int WM, int WN, int MTM, int NTN, int MODE, int BK, int NBUF=3>
__launch_bounds__(256)
__global__ void mmL_k(const unsigned short* __restrict__ A,
                      const unsigned short* __restrict__ B,
                      const float* __restrict__ bias,
                      const unsigned short* __restrict__ res,
                      const float* __restrict__ gpf,
                      float* __restrict__ outf,
                      unsigned short* __restrict__ outs,
                      float* __restrict__ aux,
                      int K){
  constexpr int BM  = WM*MTM*16;
  constexpr int BN  = WN*NTN*16;
  constexpr int CPR = BK/8;            // 16B chunks per row
  constexpr int KS  = BK/32;           // k-subtiles per step
  constexpr int AIT = (BM*CPR)/256;    // A chunks per thread
  constexpr int NBC = (BN*CPR)/256;    // B chunks per thread
  constexpr int LPT = AIT + NBC;       // loads in flight per thread per stage
  __shared__ __align__(16) short As[NBUF*BM*BK];
  __shared__ __align__(16) short Bs[NBUF*BN*BK];
  const int tid = threadIdx.x;
  const int wv = tid>>6, lane = tid&63, l15 = lane&15, quad = lane>>4;
  const int wvm = wv / WN, wvf = wv % WN;
  const int wbase = wv<<6;             // wave-uniform LDS slot base (64 slots/wave)

  int bx = blockIdx.x, by = blockIdx.y, bz = blockIdx.z;
  if constexpr (MODE==1){
    const int gx = gridDim.x, gy = gridDim.y, gz = gridDim.z;
    const int n = gx*gy*gz;
    const int lin = bx + gx*(by + gy*bz);
    const int q = n >> 3, r = n & 7;
    const int xcd = lin & 7, j = lin >> 3;
    const int work = (xcd < r ? xcd*(q+1) : r*(q+1) + (xcd-r)*q) + j;
    by = work % gy;                 // y minor
    const int t = work / gy;
    bx = t % gx;                    // x middle
    bz = t / gx;                    // z major (chunk == one kt/kh slice)
  }
  const int m0 = bx*BM;
  const int fblk = by*BN;
  const int z = bz;

  auto swz = [](int row){ if constexpr (BK==32) return (row>>1)&3; else return row&7; };

  // ---- staging addresses (source-side swizzle; LDS dest linear: slot = it*256+tid) ----
  size_t aAddr[AIT];
  #pragma unroll
  for (int it=0; it<AIT; ++it){
    int s = tid + it*256;
    int arow = s/CPR;
    int ac = (s&(CPR-1)) ^ swz(arow);
    int m = m0 + arow;
    if constexpr (MODE==1){
      int mm = m < 1568 ? m : 1567;
      int b = mm/392, r = mm%392;
      int t = r/196, r2 = r%196;
      int hh = r2/14, ww = r2%14;
      int kt = z/3, kh = z%3;
      int sp = ((b*4 + t + kt)*16 + hh + kh)*16 + ww;
      aAddr[it] = (size_t)sp*1024 + ac*8;
    } else {
      aAddr[it] = (size_t)m*K + ac*8;
    }
  }
  size_t bAddr[NBC];
  #pragma unroll
  for (int it=0; it<NBC; ++it){
    int s = tid + it*256;
    int row = s/CPR;
    int c = (s&(CPR-1)) ^ swz(row);
    int f = fblk + row;
    if constexpr (MODE==0)      bAddr[it] = (size_t)f*1024 + c*8;
    else if constexpr (MODE==1) bAddr[it] = (size_t)f*27648 + (size_t)z*3072 + c*8;
    else                        bAddr[it] = ((size_t)z*512 + f)*(size_t)K + c*8;
  }
  // ---- fragment LDS slots (swizzled), per k-subtile ----
  int aslot[MTM][KS];
  #pragma unroll
  for (int mt=0;mt<MTM;++mt)
    #pragma unroll
    for (int ks=0;ks<KS;++ks){
      int row = wvm*MTM*16 + mt*16 + l15;
      aslot[mt][ks] = row*CPR + ((ks*4 + quad) ^ swz(row));
    }
  int bslot[NTN][KS];
  #pragma unroll
  for (int nt=0;nt<NTN;++nt)
    #pragma unroll
    for (int ks=0;ks<KS;++ks){
      int row = wvf*NTN*16 + nt*16 + l15;
      bslot[nt][ks] = row*CPR + ((ks*4 + quad) ^ swz(row));
    }

  float4v acc[MTM][NTN];
  #pragma unroll
  for (int i=0;i<MTM;i++)
    #pragma unroll
    for (int j=0;j<NTN;j++) acc[i][j]=(float4v){0,0,0,0};

  auto stage = [&](int buf, int k0){
    #pragma unroll
    for (int it=0; it<AIT; ++it)
      GLDS16(A + aAddr[it] + k0, As + buf*(BM*BK) + (it*256 + wbase)*8);
    #pragma unroll
    for (int it=0; it<NBC; ++it)
      GLDS16(B + bAddr[it] + k0, Bs + buf*(BN*BK) + (it*256 + wbase)*8);
  };
  auto computeTile = [&](int buf){
    const short* ap = As + buf*(BM*BK);
    const short* bp = Bs + buf*(BN*BK);
    #pragma unroll
    for (int ks=0; ks<KS; ++ks){
      short8 bf[NTN];
      #pragma unroll
      for (int nt=0;nt<NTN;++nt)
        bf[nt] = *reinterpret_cast<const short8*>(bp + bslot[nt][ks]*8);
      #pragma unroll
      for (int mt=0;mt<MTM;++mt){
        short8 af = *reinterpret_cast<const short8*>(ap + aslot[mt][ks]*8);
        #pragma unroll
        for (int nt=0;nt<NTN;++nt)
          acc[mt][nt] = __builtin_amdgcn_mfma_f32_16x16x32_bf16(af, bf[nt], acc[mt][nt],0,0,0);
      }
    }
  };

  const int nt = K/BK;
  if constexpr (NBUF==3){
    int b0=0, b1=1, b2=2;
    stage(b0, 0);
    for (int t=0; t<nt-1; ++t){
      stage(b1, (t+1)*BK);             // tile t+1 in flight across the barrier
      vwait<LPT>();
      __builtin_amdgcn_sched_barrier(0);
      __builtin_amdgcn_s_barrier();    // all waves' tile-t loads landed
      __builtin_amdgcn_sched_barrier(0);
      computeTile(b0);
      int tmp=b0; b0=b1; b1=b2; b2=tmp;
    }
    vwait<0>();
    __builtin_amdgcn_sched_barrier(0);
    __builtin_amdgcn_s_barrier();
    __builtin_amdgcn_sched_barrier(0);
    computeTile(b0);
  } else {
    // 4-buffer, 2-ahead
    stage(0, 0);
    stage(1, BK);
    for (int t=0; t<nt; ++t){
      if (t+2 < nt) stage((t+2)&3, (t+2)*BK);
      if (t+2 < nt)      vwait<2*LPT>();
      else if (t+1 < nt) vwait<LPT>();
      else               vwait<0>();
      __builtin_amdgcn_sched_barrier(0);
      __builtin_amdgcn_s_barrier();    // tile-t loads landed
      __builtin_amdgcn_sched_barrier(0);
      computeTile(t&3);
    }
  }

  if constexpr (MODE==0){
    // BN-folded nonlocal epilogue: v = relu(acc+bias+biasAdd) + res*sc + sh -> bf16 xcl,
    // plus per-block column stats (sum, sum^2) into aux.
    const float* badd = outf;          // bias-fold accumulator (l=1) or nullptr (l=0)
    float sacc[NTN] = {}, s2acc[NTN] = {};
    #pragma unroll
    for (int nt2=0;nt2<NTN;++nt2){
      int f = fblk + wvf*NTN*16 + nt2*16 + l15;
      float bi = bias[f] + (badd ? badd[f] : 0.f);
      float rsc = 1.f, rsh = 0.f;
      if (gpf){ rsc = gpf[f]; rsh = gpf[1024+f]; }
      #pragma unroll
      for (int mt=0;mt<MTM;++mt){
        #pragma unroll
        for (int r=0;r<4;++r){
          int m = m0 + wvm*MTM*16 + mt*16 + quad*4 + r;
          float v = fmaxf(acc[mt][nt2][r]+bi, 0.f) + b2f(res[(size_t)m*1024 + f])*rsc + rsh;
          outs[(size_t)m*1024 + f] = f2bu(v);
          sacc[nt2] += v; s2acc[nt2] += v*v;
        }
      }
    }
    #pragma unroll
    for (int nt2=0;nt2<NTN;++nt2){
      float s = sacc[nt2], s2 = s2acc[nt2];
      s  += __shfl_xor(s, 16);  s  += __shfl_xor(s, 32);
      s2 += __shfl_xor(s2, 16); s2 += __shfl_xor(s2, 32);
      if (quad==0){
        int f = fblk + wvf*NTN*16 + nt2*16 + l15;
        aux[(size_t)bx*2048 + f] = s;
        aux[(size_t)bx*2048 + 1024 + f] = s2;
      }
    }
  } else if constexpr (MODE==1){
    #pragma unroll
    for (int mt=0;mt<MTM;++mt)
      #pragma unroll
      for (int nt2=0;nt2<NTN;++nt2){
        int f = fblk + wvf*NTN*16 + nt2*16 + l15;
        #pragma unroll
        for (int r=0;r<4;++r){
          int m = m0 + wvm*MTM*16 + mt*16 + quad*4 + r;
          if (m < 1568) outf[((size_t)z*1568 + m)*512 + f] = acc[mt][nt2][r];
        }
      }
  } else if constexpr (MODE==2){
    int kk = z>>1, ll = z&1;
    #pragma unroll
    for (int mt=0;mt<MTM;++mt)
      #pragma unroll
      for (int nt2=0;nt2<NTN;++nt2){
        int f = fblk + wvf*NTN*16 + nt2*16 + l15;
        float bi = bias[f];
        #pragma unroll
        for (int r=0;r<4;++r){
          int m = m0 + wvm*MTM*16 + mt*16 + quad*4 + r;
          int bt = m>>6, p = m&63;
          long orow = (long)bt*256 + (2*(p>>3)+kk)*16 + 2*(p&7)+ll;
          float v = fmaxf(acc[mt][nt2][r]+bi, 0.f);
          unsigned short h = f2bu(v);
          unsigned short l = f2bu(v - b2f(h));
          unsigned short* rp = outs + (size_t)orow*1536 + f;
          rp[0] = h; rp[512] = l; rp[1024] = h;
        }
      }
  } else if constexpr (MODE==5){
    int kk = z>>1, ll = z&1;
    #pragma unroll
    for (int mt=0;mt<MTM;++mt){
      int mbase = m0 + wvm*MTM*16 + mt*16;
      int bt = mbase>>8, b6 = bt/6, p0 = mbase&255;
      float gv[NTN], bv[NTN];
      #pragma unroll
      for (int nt2=0;nt2<NTN;++nt2){
        int f = fblk + wvf*NTN*16 + nt2*16 + l15;
        gv[nt2] = gpf[b6*512 + f];
        bv[nt2] = bias[f];
      }
      #pragma unroll
      for (int r=0;r<4;++r){
        int p = p0 + quad*4 + r;
        long orow = (long)bt*1024 + (2*(p>>4)+kk)*32 + 2*(p&15)+ll;
        float sdot = 0.f;
        #pragma unroll
        for (int nt2=0;nt2<NTN;++nt2){
          int f = fblk + wvf*NTN*16 + nt2*16 + l15;
          float v = acc[mt][nt2][r] + bv[nt2];
          outf[(size_t)orow*512 + f] = v;
          sdot += v * gv[nt2];
        }
        sdot += __shfl_xor(sdot, 1); sdot += __shfl_xor(sdot, 2);
        sdot += __shfl_xor(sdot, 4); sdot += __shfl_xor(sdot, 8);
        if (l15==0) atomicAdd(aux + orow, sdot);
      }
    }
  } else {  // MODE 4: weff bf16 out; BN-fold: scale cols by sc0, bias partials via sh0
    if (gpf){
      float sc[NTN], sh[NTN];
      #pragma unroll
      for (int nt2=0;nt2<NTN;++nt2){
        int f = fblk + wvf*NTN*16 + nt2*16 + l15;
        sc[nt2] = gpf[f]; sh[nt2] = gpf[1024+f];
      }
      #pragma unroll
      for (int mt=0;mt<MTM;++mt){
        #pragma unroll
        for (int r=0;r<4;++r){
          int m = m0 + wvm*MTM*16 + mt*16 + quad*4 + r;
          float part = 0.f;
          #pragma unroll
          for (int nt2=0;nt2<NTN;++nt2){
            int f = fblk + wvf*NTN*16 + nt2*16 + l15;
            float a = acc[mt][nt2][r];
            part += a * sh[nt2];
            outs[(size_t)m*1024 + f] = f2bu(a * sc[nt2]);
          }
          part += __shfl_xor(part, 1); part += __shfl_xor(part, 2);
          part += __shfl_xor(part, 4); part += __shfl_xor(part, 8);
          if (l15==0) atomicAdd(aux + m, part);
        }
      }
    } else {
      #pragma unroll
      for (int mt=0;mt<MTM;++mt)
        #pragma unroll
        for (int nt2=0;nt2<NTN;++nt2){
          int f = fblk + wvf*NTN*16 + nt2*16 + l15;
          #pragma unroll
          for (int r=0;r<4;++r){
            int m = m0 + wvm*MTM*16 + mt*16 + quad*4 + r;
            outs[(size_t)m*1024 + f] = f2bu(acc[mt][nt2][r]);
          }
        }
    }
  }
}

// ---------------- BN stats combine: bnp[64][2][1024] -> scale/shift mv ------------------
__global__ void stats_comb(const float* __restrict__ bnp, const float* __restrict__ g,
                           const float* __restrict__ beta, float* __restrict__ mv){
  int c = blockIdx.x*256 + threadIdx.x;   // 1024
  float S=0.f, S2=0.f;
  #pragma unroll 8
  for (int s=0;s<64;s++){ S += bnp[(size_t)s*2048 + c]; S2 += bnp[(size_t)s*2048 + 1024 + c]; }
  float m = S * (1.f/4096.f);
  float var = S2 * (1.f/4096.f) - m*m;
  float inv = rsqrtf(var + 1e-5f);
  float sc = inv * g[c];
  mv[c] = sc;
  mv[1024 + c] = beta[c] - m*sc;
}

// ---- weight permute + BN fold, cc-parallel: one load->scatter phase per block ----------
__launch_bounds__(256)
__global__ void wperm_k(const float* __restrict__ w, const float* __restrict__ mv1,
                        unsigned short* __restrict__ wtt, float* __restrict__ tpb2){
  __shared__ float ls[3456];
  __shared__ float rs[256];
  int f = blockIdx.x, cc = blockIdx.y;
  const float* src = w + (size_t)f*27648 + cc*3456;
  unsigned short* dst = wtt + (size_t)f*27648;
  for (int i=threadIdx.x; i<3456; i+=256) ls[i] = src[i];
  __syncthreads();
  float part = 0.f;
  for (int u=threadIdx.x; u<3456; u+=256){
    int j = u >> 7, c = u & 127;
    int ch = cc*128 + c;
    float wv = ls[c*27 + j];
    dst[(size_t)j*1024 + ch] = f2bu(wv * mv1[ch]);
    part += wv * mv1[1024 + ch];
  }
  rs[threadIdx.x] = part; __syncthreads();
  for (int st=128; st>0; st>>=1){
    if (threadIdx.x < st) rs[threadIdx.x] += rs[threadIdx.x+st];
    __syncthreads();
  }
  if (threadIdx.x==0) atomicAdd(tpb2 + f, rs[0]);
}

// ---------------- goal_pre: z splits the 392 positions 8-ways; atomicAdd into gp --------
__launch_bounds__(256)
__global__ void gp2_k(const float* __restrict__ part9, const float* __restrict__ tpb,
                      const float* __restrict__ tpbA, float* __restrict__ gp){
  int b = blockIdx.x;
  int fc = blockIdx.y;
  int z = blockIdx.z;          // 8 p-chunks of 49
  int fi = threadIdx.x & 31, pi = threadIdx.x >> 5;
  int f = fc*32 + fi;
  float bias = tpb[f] + tpbA[f];
  float a = 0.f;
  for (int p = z*49 + pi; p < z*49 + 49; p += 8){
    size_t base = ((size_t)(b*392 + p))*512 + f;
    float v = bias;
    #pragma unroll
    for (int i=0;i<9;i++) v += part9[(size_t)i*802816 + base];
    a += fmaxf(v, 0.f);
  }
  __shared__ float red[256];
  red[threadIdx.x] = a; __syncthreads();
  for (int st=4; st>0; st>>=1){
    if (pi < st) red[pi*32+fi] += red[(pi+st)*32+fi];
    __syncthreads();
  }
  if (pi==0) atomicAdd(gp + b*512 + f, red[fi] * (1.f/392.f));
}

// ---- sga[bt][c] += sum_{n in slice} softmax(SG)[n]*(scl[n][c]+pe[n][c]) ----------------
// round 12: softmax fused in (each block recomputes row max/denominator from SG --
// 4KB L2-hot read, redundant across the 32 sl-blocks but removes softmax_k + attn buf).
__launch_bounds__(256)
__global__ void sga2_k(const float* __restrict__ scl, const float* __restrict__ peN,
                       const float* __restrict__ SG, float* __restrict__ sga){
  int bt = blockIdx.x, sl = blockIdx.y;   // 24 x 32
  int tid = threadIdx.x;
  __shared__ float red[256];
  __shared__ float at[32];
  float4 v = *reinterpret_cast<const float4*>(SG + bt*1024 + tid*4);
  float mx = fmaxf(fmaxf(v.x,v.y), fmaxf(v.z,v.w));
  red[tid] = mx; __syncthreads();
  for (int st=128; st>0; st>>=1){
    if (tid<st) red[tid] = fmaxf(red[tid], red[tid+st]);
    __syncthreads();
  }
  float m = red[0]; __syncthreads();
  red[tid] = expf(v.x-m)+expf(v.y-m)+expf(v.z-m)+expf(v.w-m); __syncthreads();
  for (int st=128; st>0; st>>=1){
    if (tid<st) red[tid] += red[tid+st];
    __syncthreads();
  }
  float inv = 1.0f/red[0];
  if (tid < 32) at[tid] = expf(SG[bt*1024 + sl*32 + tid] - m) * inv;
  __syncthreads();
  float acc0 = 0.f, acc1 = 0.f;
  for (int j=0;j<32;j++){
    int n = sl*32 + j;
    float a = at[j];
    const float* row = scl + ((size_t)bt*1024 + n)*512;
    const float* pe  = peN + (size_t)n*512;
    acc0 += a * (row[tid] + pe[tid]);
    acc1 += a * (row[tid+256] + pe[tid+256]);
  }
  atomicAdd(sga + (size_t)bt*512 + tid, acc0);
  atomicAdd(sga + (size_t)bt*512 + 256 + tid, acc1);
}

// ---------------- merged MLP heads: blocks 0-3 goal(gp), 4-27 state(sga) ----------------
__launch_bounds__(256)
__global__ void mlp2_k(const float* __restrict__ gp, const float* __restrict__ sga,
                       const float* __restrict__ og1w, const float* __restrict__ og1b,
                       const float* __restrict__ og2w, const float* __restrict__ og2b,
                       const float* __restrict__ os1w, const float* __restrict__ os1b,
                       const float* __restrict__ os2w, const float* __restrict__ os2b,
                       float* __restrict__ out){
  int b = blockIdx.x; int tid = threadIdx.x;
  const float *in, *w1, *b1, *w2, *b2; float* o;
  if (b < 4){ in = gp + (size_t)b*512;       w1=og1w; b1=og1b; w2=og2w; b2=og2b; o = out + (size_t)b*128; }
  else      { in = sga + (size_t)(b-4)*512;  w1=os1w; b1=os1b; w2=os2w; b2=os2b; o = out + 512 + (size_t)(b-4)*128; }
  __shared__ float xv[512]; __shared__ float h[512];
  xv[tid] = in[tid];
  xv[tid+256] = in[256 + tid];
  __syncthreads();
  #pragma unroll
  for (int oo=0;oo<2;oo++){
    int ox = tid + oo*256;
    const float* wr = w1 + (size_t)ox*512;
    float a=0.f;
    for (int c=0;c<512;c+=4){
      float4 q = *reinterpret_cast<const float4*>(wr+c);
      a += xv[c]*q.x + xv[c+1]*q.y + xv[c+2]*q.z + xv[c+3]*q.w;
    }
    h[ox] = fmaxf(a + b1[ox], 0.f);
  }
  __syncthreads();
  if (tid < 128){
    const float* wr = w2 + (size_t)tid*512;
    float a=0.f;
    for (int c=0;c<512;c+=4){
      float4 q = *reinterpret_cast<const float4*>(wr+c);
      a += h[c]*q.x + h[c+1]*q.y + h[c+2]*q.z + h[c+3]*q.w;
    }
    o[tid] = a + b2[tid];
  }
}

extern "C" void kernel_launch(void* const* d_in, const int* in_sizes, int n_in,
                              void* d_out, int out_size, void* d_ws, size_t ws_size,
                              hipStream_t stream){
  (void)in_sizes; (void)n_in; (void)out_size; (void)ws_size;
  const float* ctx   = (const float*)d_in[0];
  const float* frame = (const float*)d_in[1];
  const float* nl_vw[2] = {(const float*)d_in[4],  (const float*)d_in[11]};
  const float* nl_ow[2] = {(const float*)d_in[5],  (const float*)d_in[12]};
  const float* nl_ob[2] = {(const float*)d_in[6],  (const float*)d_in[13]};
  const float* nl_g[2]  = {(const float*)d_in[7],  (const float*)d_in[14]};
  const float* nl_be[2] = {(const float*)d_in[8],  (const float*)d_in[15]};
  const float* tp_w = (const float*)d_in[16]; const float* tp_b = (const float*)d_in[17];
  const float* up1w = (const float*)d_in[18]; const float* up1b = (const float*)d_in[19];
  const float* up2w = (const float*)d_in[20]; const float* up2b = (const float*)d_in[21];
  const float* og1w = (const float*)d_in[22]; const float* og1b = (const float*)d_in[23];
  const float* og2w = (const float*)d_in[24]; const float* og2b = (const float*)d_in[25];
  const float* os1w = (const float*)d_in[26]; const float* os1b = (const float*)d_in[27];
  const float* os2w = (const float*)d_in[28]; const float* os2b = (const float*)d_in[29];
  float* out = (float*)d_out;

  char* wsp = (char*)d_ws;
  // ---- persistent region ----
  float* bias2   = (float*)(wsp + 65536);         // 4KB  [1024] weff bias-fold acc
  float* tpb2    = (float*)(wsp + 69632);         // 2KB  [512] conv bias-fold (atomic)
  float* gp      = (float*)(wsp + 73728);         // 8KB  [4][512] (atomic-accumulated)
  float* mv0     = (float*)(wsp + 131072);        // 8KB  BN scale/shift layer 0
  float* mv1     = (float*)(wsp + 139264);        // 8KB  BN scale/shift layer 1
  float* SG      = (float*)(wsp + 147456);        // 98304 (atomic-accumulated)
  float* sga     = (float*)(wsp + 344064);        // 49152 (atomic-accumulated)
  float* peN     = (float*)(wsp + 786432);        // 2097152 [1024][512]
  bf16*  weff    = (bf16*) (wsp + 2883584);       // 2097152 [1024][1024] bf16
  unsigned short* w1sp = (unsigned short*)(wsp + 4980736);   // 12582912 [4][512][3072]
  unsigned short* w2sp = (unsigned short*)(wsp + 17563648);  // 6291456  [4][512][1536]
  char* ov = wsp + 23855104;
  // phase 1 (nonlocal, BN folded -> xcl ping-pong):
  bf16*  xclA = (bf16*) (ov);                     // 8 MB [4096][1024]
  bf16*  xclB = (bf16*) (ov + 8388608);           // 8 MB (dead after l=1 reads it)
  // phase 1 staging in the (dead until phase 2) part9 region:
  unsigned short* Asp = (unsigned short*)(ov + 36700160);            // 3 MB [1024][1536]
  unsigned short* Bsp = (unsigned short*)(ov + 36700160 + 3145728);  // 3 MB [1024][1536]
  float* bnp = (float*)(ov + 36700160 + 6291456); // 512 KB [64][2][1024] BN partials
  // phase 2 (conv): wtt aliases xclB region (written after l=1 MODE0 consumed xclB)
  unsigned short* wtt = (unsigned short*)(ov + 8388608);   // 28.3 MB [512][27648]
  float* part9 = (float*)(ov + 36700160);         // 28.9 MB [9][1568][512]
  // frame staging: aliases part9 (written after gp2_k reads part9)
  unsigned short* Fsp = (unsigned short*)(ov + 36700160);  // 9.4 MB [1536][3072]
  // phase 3 (after gp2_k; xclA/wtt dead):
  unsigned short* s1sp = (unsigned short*)(ov);   // 18.9 MB [6144][1536]
  float* scl  = (float*)(ov + 18874368);          // 50.3 MB [24576][512]

  // fused prep: permT(ctx) | split3(up1w) | split3(up2w) | PE | range-zero (1 launch)
  prep_k<<<4160,256,0,stream>>>(ctx, xclA, up1w, w1sp, up2w, w2sp, peN,
                                (float*)(wsp + 65536));

  // nonlocal layer 0: xclA -> xclB (BN deferred via fold into layer-1 consumers)
  layerprep_k<<<2176,256,0,stream>>>(nl_ow[0], Asp, nl_vw[0], Bsp);
  mmL_k<1,4,2,2,4,64><<<dim3(32,8,1),256,0,stream>>>(Asp, Bsp, nullptr, nullptr, nullptr,
      nullptr, (unsigned short*)weff, nullptr, 1536);
  mmL_k<1,4,4,2,0,64><<<dim3(64,8,1),256,0,stream>>>((const unsigned short*)xclA,
      (const unsigned short*)weff, nl_ob[0], (const unsigned short*)xclA, nullptr,
      nullptr, (unsigned short*)xclB, bnp, 1024);
  stats_comb<<<4,256,0,stream>>>(bnp, nl_g[0], nl_be[0], mv0);

  // nonlocal layer 1: xclB -> xclA; weff cols scaled by sc0, sh0 folded to bias2
  layerprep_k<<<2176,256,0,stream>>>(nl_ow[1], Asp, nl_vw[1], Bsp);
  mmL_k<1,4,2,2,4,64><<<dim3(32,8,1),256,0,stream>>>(Asp, Bsp, nullptr, nullptr, mv0,
      nullptr, (unsigned short*)weff, bias2, 1536);
  mmL_k<1,4,4,2,0,64><<<dim3(64,8,1),256,0,stream>>>((const unsigned short*)xclB,
      (const unsigned short*)weff, nl_ob[1], (const unsigned short*)xclB, mv0,
      bias2, (unsigned short*)xclA, bnp, 1024);
  stats_comb<<<4,256,0,stream>>>(bnp, nl_g[1], nl_be[1], mv1);

  // temporal-pool conv (im2col GEMM, K-split 9); BN-1 folded into wtt (sc1) + tpb2 (sh1)
  // round-12: BN=64, grid (13,8,9)=936 blocks, 3-buf 36KB -> 4 blocks/CU all-resident
  // (2x waves/SIMD vs 128-wide; conv was occupancy/latency-bound, not load-latency).
  wperm_k<<<dim3(512,8),256,0,stream>>>(tp_w, mv1, wtt, tpb2);
  mmL_k<2,2,4,2,1,32,3><<<dim3(13,8,9),256,0,stream>>>((const unsigned short*)xclA, wtt,
      nullptr, nullptr, nullptr, part9, nullptr, nullptr, 3072);
  gp2_k<<<dim3(4,16,8),256,0,stream>>>(part9, tp_b, tpb2, gp);

  // frame path (3-block split-bf16 == fp32-accurate); Fsp aliases part9 -> after gp2_k
  permTsplit3_k<0><<<dim3(1,16,24),256,0,stream>>>(frame, Fsp, 64, 1024, 1, 1, 65536L, 196608L);
  // up1: BM=64 (3-buf 72KB -> 2/CU; grid 384 = 1.5/CU demand)
  mmL_k<1,4,4,2,2,64><<<dim3(24,4,4),256,0,stream>>>(Fsp, w1sp, up1b, nullptr, nullptr,
      nullptr, s1sp, nullptr, 3072);
  // up2 + fused SG partial dot (3-buf BK=32: 48KB -> 3/CU = demand)
  mmL_k<2,2,4,4,5,32><<<dim3(48,4,4),256,0,stream>>>(s1sp, w2sp, up2b, nullptr, gp,
      scl, nullptr, SG, 1536);

  // attention tail (softmax fused into sga2)
  sga2_k<<<dim3(24,32),256,0,stream>>>(scl, peN, SG, sga);

  // heads (merged)
  mlp2_k<<<28,256,0,stream>>>(gp, sga, og1w, og1b, og2w, og2b,
                              os1w, os1b, os2w, os2b, out);
}

// Round 13
// 519.107 us; speedup vs baseline: 1.5696x; 1.0312x over previous
//
#include <hip/hip_runtime.h>
#include <hip/hip_bf16.h>

using bf16 = __hip_bfloat16;
typedef short short8 __attribute__((ext_vector_type(8)));
typedef float float4v __attribute__((ext_vector_type(4)));

__device__ __forceinline__ float b2f(unsigned short u){
  unsigned int x = ((unsigned int)u) << 16; float f;
  __builtin_memcpy(&f, &x, 4); return f;
}
__device__ __forceinline__ float b2f(bf16 v){ return __bfloat162float(v); }
__device__ __forceinline__ unsigned short f2bu(float x){
  bf16 h = __float2bfloat16(x); unsigned short u;
  __builtin_memcpy(&u, &h, 2); return u;
}

// async global->LDS, 16B per lane, dest = wave-uniform base + lane*16
#define GLDS16(g, l) __builtin_amdgcn_global_load_lds( \
    (const __attribute__((address_space(1))) void*)(g), \
    (__attribute__((address_space(3))) void*)(l), 16, 0, 0)

template<int N> __device__ __forceinline__ void vwait(){
  if constexpr (N==0)       asm volatile("s_waitcnt vmcnt(0)" ::: "memory");
  else if constexpr (N==3)  asm volatile("s_waitcnt vmcnt(3)" ::: "memory");
  else if constexpr (N==4)  asm volatile("s_waitcnt vmcnt(4)" ::: "memory");
  else if constexpr (N==5)  asm volatile("s_waitcnt vmcnt(5)" ::: "memory");
  else if constexpr (N==6)  asm volatile("s_waitcnt vmcnt(6)" ::: "memory");
  else if constexpr (N==8)  asm volatile("s_waitcnt vmcnt(8)" ::: "memory");
  else if constexpr (N==10) asm volatile("s_waitcnt vmcnt(10)" ::: "memory");
  else                      asm volatile("s_waitcnt vmcnt(12)" ::: "memory");
}

// ================= device bodies (shared by standalone kernels and prep_k) ==============
__device__ __forceinline__ void permT_body(const float* inp, bf16* outp,
    int Cc, int R, int D, int G, long inS, long outS,
    int bx, int by, int bz, int tid, float (*t)[65]){
  const float* in = inp + (size_t)bz*inS;
  bf16* out = outp + (size_t)bz*outS;
  int c0 = bx*64, r0 = by*64;
  int rr = tid>>2, c4 = (tid&3)*16;
  const float* p = in + (size_t)(r0+rr)*Cc + c0 + c4;
  #pragma unroll
  for (int j=0;j<16;j+=4){
    float4 q = *reinterpret_cast<const float4*>(p+j);
    t[rr][c4+j]=q.x; t[rr][c4+j+1]=q.y; t[rr][c4+j+2]=q.z; t[rr][c4+j+3]=q.w;
  }
  __syncthreads();
  int ql = tid>>2;
  int q = c0 + ql;
  int orow = (q % D)*G + q / D;
  bf16* op = out + (size_t)orow*R + r0 + c4;
  #pragma unroll
  for (int j=0;j<16;j++) op[j] = __float2bfloat16(t[c4+j][ql]);
}

// PAT=0 (A-side): blocks (hi, lo, hi). PAT=1 (B-side): blocks (hi, hi, lo).
// Paired dot over 3R gives ah*bh + al*bh + ah*bl == fp32-accurate product.
template<int PAT>
__device__ __forceinline__ void permTsplit3_body(const float* inp, unsigned short* outp,
    int Cc, int R, int D, int G, long inS, long outS,
    int bx, int by, int bz, int tid, float (*t)[65]){
  const float* in = inp + (size_t)bz*inS;
  unsigned short* out = outp + (size_t)bz*outS;
  int c0 = bx*64, r0 = by*64;
  int rr = tid>>2, c4 = (tid&3)*16;
  const float* p = in + (size_t)(r0+rr)*Cc + c0 + c4;
  #pragma unroll
  for (int j=0;j<16;j+=4){
    float4 q = *reinterpret_cast<const float4*>(p+j);
    t[rr][c4+j]=q.x; t[rr][c4+j+1]=q.y; t[rr][c4+j+2]=q.z; t[rr][c4+j+3]=q.w;
  }
  __syncthreads();
  int ql = tid>>2;
  int q = c0 + ql;
  int orow = (q % D)*G + q / D;
  unsigned short* op = out + (size_t)orow*(3*R);
  #pragma unroll
  for (int j=0;j<16;j++){
    float v = t[c4+j][ql];
    unsigned short h = f2bu(v);
    unsigned short l = f2bu(v - b2f(h));
    int idx = r0 + c4 + j;
    if constexpr (PAT==0){
      op[idx] = h; op[R+idx] = l; op[2*R+idx] = h;
    } else {
      op[idx] = h; op[R+idx] = h; op[2*R+idx] = l;
    }
  }
}

__device__ __forceinline__ void splitA_body(const float* in, unsigned short* out,
                                            int blk, int tid){
  int idx = blk*256 + tid;   // 1024*512
  int m = idx >> 9, j = idx & 511;
  float v = in[idx];
  unsigned short h = f2bu(v);
  unsigned short l = f2bu(v - b2f(h));
  unsigned short* op = out + (size_t)m*1536 + j;
  op[0] = h; op[512] = l; op[1024] = h;
}

// ---- fused prep: permT(ctx) | split3(up1w) | split3(up2w) | PE table | range-zero ------
__launch_bounds__(256)
__global__ void prep_k(const float* __restrict__ ctx, bf16* __restrict__ xclA,
                       const float* __restrict__ up1w, unsigned short* __restrict__ w1sp,
                       const float* __restrict__ up2w, unsigned short* __restrict__ w2sp,
                       float* __restrict__ peN, float* __restrict__ zbase){
  __shared__ float t[64][65];
  int b = blockIdx.x, tid = threadIdx.x;
  if (b < 1024){
    permT_body(ctx, xclA, 256, 1024, 1, 1, 262144L, 262144L,
               b&3, (b>>2)&15, b>>6, tid, t);
  } else if (b < 1536){
    b -= 1024;
    permTsplit3_body<1>(up1w, w1sp, 2048, 1024, 4, 512, 0L, 0L,
                        b&31, b>>5, 0, tid, t);
  } else if (b < 1792){
    b -= 1536;
    permTsplit3_body<1>(up2w, w2sp, 2048, 512, 4, 512, 0L, 0L,
                        b&31, b>>5, 0, tid, t);
  } else if (b < 3840){
    int idx = (b-1792)*256 + tid;   // 524288 PE entries
    int n = idx >> 9, c = idx & 511;
    float div = expf(-0.035977892f * (float)(c>>1));   // 2*ln(10000)/512
    float ang = (float)n * div;
    peN[idx] = (c & 1) ? cosf(ang) : sinf(ang);
  } else {
    zbase[(b-3840)*256 + tid] = 0.f;   // bytes 65536..393216 of ws
  }
}

// ---- fused layer prep: splitA(ow) | split3(vw) ----------------------------------------
__launch_bounds__(256)
__global__ void layerprep_k(const float* __restrict__ ow, unsigned short* __restrict__ Asp,
                            const float* __restrict__ vw, unsigned short* __restrict__ Bsp){
  __shared__ float t[64][65];
  int b = blockIdx.x, tid = threadIdx.x;
  if (b < 2048){
    splitA_body(ow, Asp, b, tid);
  } else {
    b -= 2048;   // 128 blocks: (16,8)
    permTsplit3_body<1>(vw, Bsp, 1024, 512, 1, 1, 0L, 0L, b&15, b>>4, 0, tid, t);
  }
}

// standalone wrapper (frame staging: must run after gp2_k; aliases part9)
template<int PAT>
__launch_bounds__(256)
__global__ void permTsplit3_k(const float* __restrict__ inp, unsigned short* __restrict__ outp,
                              int Cc, int R, int D, int G, long inS, long outS){
  __shared__ float t[64][65];
  permTsplit3_body<PAT>(inp, outp, Cc, R, D, G, inS, outS,
                        blockIdx.x, blockIdx.y, blockIdx.z, threadIdx.x, t);
}

// ================= unified MFMA GEMM: global_load_lds + N-buffer + counted vmcnt =========
// C[m][f] = sum_k A[m][k]*B[f][k], bf16. WM x WN waves, each owns (MTM*16) x (NTN*16).
// NBUF=3: 1-ahead staging, ONE barrier per K-step, no lgkm drain (round-10 race-freedom:
//   stage(t+1) writes buf last read at compute(t-2), finished before BAR(t-1)).
// NBUF=4: 2-ahead (round-11 A/B on conv: no change -> conv is not load-latency-bound).
// ROUND-13 conv: REVERTED to round-10 best (2,2,4,4,BK32,3buf)@(13,4,9) = 71us/638TF.
//   Exhaustive A/B history: 2-buf BK32 80us | BK64@48KB 85 | 128^2 BK32 2-buf 77 |
//   3-buf 71 | 2-ahead 71 | BN=64 2x-occupancy 90 (MfmaUtil DOWN, FETCH UP).
//   -> structure optimum for this shape; residual is the serial per-step chain (8-phase
//   rewrite territory), not occupancy/latency/traffic knobs.
// Residency rule (round-4): LDS blocks/CU >= grid demand.
// LDS image: linear dest slot (16B) = row*CPR + chunk'; swizzle chunk' = c ^ swz(row)
// on the GLOBAL source address (m104-safe); swz = (row>>1)&3 @BK32, row&7 @BK64.
// BN-FOLD: MODE 4 (weff): if gpf, scale cols by sc0 + atomicAdd sh0-dot into aux.
// MODE 0: bias+biasAdd, residual scaled by gpf, writes bf16 xcl + BN partials.
// MODE 1: conv3d im2col K-split z (XCD-bijective z-major swizzle -> B L2-resident),
// MODE 2: up1 (relu+bias, convT scatter, 3-block h/l/h), MODE 5: up2 + fused SG dot.
template<int WM, int WN, int MTM, int NTN, int MODE, int BK, int NBUF=3>
__launch_bounds__(256)
__global__ void mmL_k(const unsigned short* __restrict__ A,
                      const unsigned short* __restrict__ B,
                      const float* __restrict__ bias,
                      const unsigned short* __restrict__ res,
                      const float* __restrict__ gpf,
                      float* __restrict__ outf,
                      unsigned short* __restrict__ outs,
                      float* __restrict__ aux,
                      int K){
  constexpr int BM  = WM*MTM*16;
  constexpr int BN  = WN*NTN*16;
  constexpr int CPR = BK/8;            // 16B chunks per row
  constexpr int KS  = BK/32;           // k-subtiles per step
  constexpr int AIT = (BM*CPR)/256;    // A chunks per thread
  constexpr int NBC = (BN*CPR)/256;    // B chunks per thread
  constexpr int LPT = AIT + NBC;       // loads in flight per thread per stage
  __shared__ __align__(16) short As[NBUF*BM*BK];
  __shared__ __align__(16) short Bs[NBUF*BN*BK];
  const int tid = threadIdx.x;
  const int wv = tid>>6, lane = tid&63, l15 = lane&15, quad = lane>>4;
  const int wvm = wv / WN, wvf = wv % WN;
  const int wbase = wv<<6;             // wave-uniform LDS slot base (64 slots/wave)

  int bx = blockIdx.x, by = blockIdx.y, bz = blockIdx.z;
  if constexpr (MODE==1){
    const int gx = gridDim.x, gy = gridDim.y, gz = gridDim.z;
    const int n = gx*gy*gz;
    const int lin = bx + gx*(by + gy*bz);
    const int q = n >> 3, r = n & 7;
    const int xcd = lin & 7, j = lin >> 3;
    const int work = (xcd < r ? xcd*(q+1) : r*(q+1) + (xcd-r)*q) + j;
    by = work % gy;                 // y minor
    const int t = work / gy;
    bx = t % gx;                    // x middle
    bz = t / gx;                    // z major (chunk == one kt/kh slice)
  }
  const int m0 = bx*BM;
  const int fblk = by*BN;
  const int z = bz;

  auto swz = [](int row){ if constexpr (BK==32) return (row>>1)&3; else return row&7; };

  // ---- staging addresses (source-side swizzle; LDS dest linear: slot = it*256+tid) ----
  size_t aAddr[AIT];
  #pragma unroll
  for (int it=0; it<AIT; ++it){
    int s = tid + it*256;
    int arow = s/CPR;
    int ac = (s&(CPR-1)) ^ swz(arow);
    int m = m0 + arow;
    if constexpr (MODE==1){
      int mm = m < 1568 ? m : 1567;
      int b = mm/392, r = mm%392;
      int t = r/196, r2 = r%196;
      int hh = r2/14, ww = r2%14;
      int kt = z/3, kh = z%3;
      int sp = ((b*4 + t + kt)*16 + hh + kh)*16 + ww;
      aAddr[it] = (size_t)sp*1024 + ac*8;
    } else {
      aAddr[it] = (size_t)m*K + ac*8;
    }
  }
  size_t bAddr[NBC];
  #pragma unroll
  for (int it=0; it<NBC; ++it){
    int s = tid + it*256;
    int row = s/CPR;
    int c = (s&(CPR-1)) ^ swz(row);
    int f = fblk + row;
    if constexpr (MODE==0)      bAddr[it] = (size_t)f*1024 + c*8;
    else if constexpr (MODE==1) bAddr[it] = (size_t)f*27648 + (size_t)z*3072 + c*8;
    else                        bAddr[it] = ((size_t)z*512 + f)*(size_t)K + c*8;
  }
  // ---- fragment LDS slots (swizzled), per k-subtile ----
  int aslot[MTM][KS];
  #pragma unroll
  for (int mt=0;mt<MTM;++mt)
    #pragma unroll
    for (int ks=0;ks<KS;++ks){
      int row = wvm*MTM*16 + mt*16 + l15;
      aslot[mt][ks] = row*CPR + ((ks*4 + quad) ^ swz(row));
    }
  int bslot[NTN][KS];
  #pragma unroll
  for (int nt=0;nt<NTN;++nt)
    #pragma unroll
    for (int ks=0;ks<KS;++ks){
      int row = wvf*NTN*16 + nt*16 + l15;
      bslot[nt][ks] = row*CPR + ((ks*4 + quad) ^ swz(row));
    }

  float4v acc[MTM][NTN];
  #pragma unroll
  for (int i=0;i<MTM;i++)
    #pragma unroll
    for (int j=0;j<NTN;j++) acc[i][j]=(float4v){0,0,0,0};

  auto stage = [&](int buf, int k0){
    #pragma unroll
    for (int it=0; it<AIT; ++it)
      GLDS16(A + aAddr[it] + k0, As + buf*(BM*BK) + (it*256 + wbase)*8);
    #pragma unroll
    for (int it=0; it<NBC; ++it)
      GLDS16(B + bAddr[it] + k0, Bs + buf*(BN*BK) + (it*256 + wbase)*8);
  };
  auto computeTile = [&](int buf){
    const short* ap = As + buf*(BM*BK);
    const short* bp = Bs + buf*(BN*BK);
    #pragma unroll
    for (int ks=0; ks<KS; ++ks){
      short8 bf[NTN];
      #pragma unroll
      for (int nt=0;nt<NTN;++nt)
        bf[nt] = *reinterpret_cast<const short8*>(bp + bslot[nt][ks]*8);
      #pragma unroll
      for (int mt=0;mt<MTM;++mt){
        short8 af = *reinterpret_cast<const short8*>(ap + aslot[mt][ks]*8);
        #pragma unroll
        for (int nt=0;nt<NTN;++nt)
          acc[mt][nt] = __builtin_amdgcn_mfma_f32_16x16x32_bf16(af, bf[nt], acc[mt][nt],0,0,0);
      }
    }
  };

  const int nt = K/BK;
  if constexpr (NBUF==3){
    int b0=0, b1=1, b2=2;
    stage(b0, 0);
    for (int t=0; t<nt-1; ++t){
      stage(b1, (t+1)*BK);             // tile t+1 in flight across the barrier
      vwait<LPT>();
      __builtin_amdgcn_sched_barrier(0);
      __builtin_amdgcn_s_barrier();    // all waves' tile-t loads landed
      __builtin_amdgcn_sched_barrier(0);
      computeTile(b0);
      int tmp=b0; b0=b1; b1=b2; b2=tmp;
    }
    vwait<0>();
    __builtin_amdgcn_sched_barrier(0);
    __builtin_amdgcn_s_barrier();
    __builtin_amdgcn_sched_barrier(0);
    computeTile(b0);
  } else {
    // 4-buffer, 2-ahead
    stage(0, 0);
    stage(1, BK);
    for (int t=0; t<nt; ++t){
      if (t+2 < nt) stage((t+2)&3, (t+2)*BK);
      if (t+2 < nt)      vwait<2*LPT>();
      else if (t+1 < nt) vwait<LPT>();
      else               vwait<0>();
      __builtin_amdgcn_sched_barrier(0);
      __builtin_amdgcn_s_barrier();    // tile-t loads landed
      __builtin_amdgcn_sched_barrier(0);
      computeTile(t&3);
    }
  }

  if constexpr (MODE==0){
    // BN-folded nonlocal epilogue: v = relu(acc+bias+biasAdd) + res*sc + sh -> bf16 xcl,
    // plus per-block column stats (sum, sum^2) into aux.
    const float* badd = outf;          // bias-fold accumulator (l=1) or nullptr (l=0)
    float sacc[NTN] = {}, s2acc[NTN] = {};
    #pragma unroll
    for (int nt2=0;nt2<NTN;++nt2){
      int f = fblk + wvf*NTN*16 + nt2*16 + l15;
      float bi = bias[f] + (badd ? badd[f] : 0.f);
      float rsc = 1.f, rsh = 0.f;
      if (gpf){ rsc = gpf[f]; rsh = gpf[1024+f]; }
      #pragma unroll
      for (int mt=0;mt<MTM;++mt){
        #pragma unroll
        for (int r=0;r<4;++r){
          int m = m0 + wvm*MTM*16 + mt*16 + quad*4 + r;
          float v = fmaxf(acc[mt][nt2][r]+bi, 0.f) + b2f(res[(size_t)m*1024 + f])*rsc + rsh;
          outs[(size_t)m*1024 + f] = f2bu(v);
          sacc[nt2] += v; s2acc[nt2] += v*v;
        }
      }
    }
    #pragma unroll
    for (int nt2=0;nt2<NTN;++nt2){
      float s = sacc[nt2], s2 = s2acc[nt2];
      s  += __shfl_xor(s, 16);  s  += __shfl_xor(s, 32);
      s2 += __shfl_xor(s2, 16); s2 += __shfl_xor(s2, 32);
      if (quad==0){
        int f = fblk + wvf*NTN*16 + nt2*16 + l15;
        aux[(size_t)bx*2048 + f] = s;
        aux[(size_t)bx*2048 + 1024 + f] = s2;
      }
    }
  } else if constexpr (MODE==1){
    #pragma unroll
    for (int mt=0;mt<MTM;++mt)
      #pragma unroll
      for (int nt2=0;nt2<NTN;++nt2){
        int f = fblk + wvf*NTN*16 + nt2*16 + l15;
        #pragma unroll
        for (int r=0;r<4;++r){
          int m = m0 + wvm*MTM*16 + mt*16 + quad*4 + r;
          if (m < 1568) outf[((size_t)z*1568 + m)*512 + f] = acc[mt][nt2][r];
        }
      }
  } else if constexpr (MODE==2){
    int kk = z>>1, ll = z&1;
    #pragma unroll
    for (int mt=0;mt<MTM;++mt)
      #pragma unroll
      for (int nt2=0;nt2<NTN;++nt2){
        int f = fblk + wvf*NTN*16 + nt2*16 + l15;
        float bi = bias[f];
        #pragma unroll
        for (int r=0;r<4;++r){
          int m = m0 + wvm*MTM*16 + mt*16 + quad*4 + r;
          int bt = m>>6, p = m&63;
          long orow = (long)bt*256 + (2*(p>>3)+kk)*16 + 2*(p&7)+ll;
          float v = fmaxf(acc[mt][nt2][r]+bi, 0.f);
          unsigned short h = f2bu(v);
          unsigned short l = f2bu(v - b2f(h));
          unsigned short* rp = outs + (size_t)orow*1536 + f;
          rp[0] = h; rp[512] = l; rp[1024] = h;
        }
      }
  } else if constexpr (MODE==5){
    int kk = z>>1, ll = z&1;
    #pragma unroll
    for (int mt=0;mt<MTM;++mt){
      int mbase = m0 + wvm*MTM*16 + mt*16;
      int bt = mbase>>8, b6 = bt/6, p0 = mbase&255;
      float gv[NTN], bv[NTN];
      #pragma unroll
      for (int nt2=0;nt2<NTN;++nt2){
        int f = fblk + wvf*NTN*16 + nt2*16 + l15;
        gv[nt2] = gpf[b6*512 + f];
        bv[nt2] = bias[f];
      }
      #pragma unroll
      for (int r=0;r<4;++r){
        int p = p0 + quad*4 + r;
        long orow = (long)bt*1024 + (2*(p>>4)+kk)*32 + 2*(p&15)+ll;
        float sdot = 0.f;
        #pragma unroll
        for (int nt2=0;nt2<NTN;++nt2){
          int f = fblk + wvf*NTN*16 + nt2*16 + l15;
          float v = acc[mt][nt2][r] + bv[nt2];
          outf[(size_t)orow*512 + f] = v;
          sdot += v * gv[nt2];
        }
        sdot += __shfl_xor(sdot, 1); sdot += __shfl_xor(sdot, 2);
        sdot += __shfl_xor(sdot, 4); sdot += __shfl_xor(sdot, 8);
        if (l15==0) atomicAdd(aux + orow, sdot);
      }
    }
  } else {  // MODE 4: weff bf16 out; BN-fold: scale cols by sc0, bias partials via sh0
    if (gpf){
      float sc[NTN], sh[NTN];
      #pragma unroll
      for (int nt2=0;nt2<NTN;++nt2){
        int f = fblk + wvf*NTN*16 + nt2*16 + l15;
        sc[nt2] = gpf[f]; sh[nt2] = gpf[1024+f];
      }
      #pragma unroll
      for (int mt=0;mt<MTM;++mt){
        #pragma unroll
        for (int r=0;r<4;++r){
          int m = m0 + wvm*MTM*16 + mt*16 + quad*4 + r;
          float part = 0.f;
          #pragma unroll
          for (int nt2=0;nt2<NTN;++nt2){
            int f = fblk + wvf*NTN*16 + nt2*16 + l15;
            float a = acc[mt][nt2][r];
            part += a * sh[nt2];
            outs[(size_t)m*1024 + f] = f2bu(a * sc[nt2]);
          }
          part += __shfl_xor(part, 1); part += __shfl_xor(part, 2);
          part += __shfl_xor(part, 4); part += __shfl_xor(part, 8);
          if (l15==0) atomicAdd(aux + m, part);
        }
      }
    } else {
      #pragma unroll
      for (int mt=0;mt<MTM;++mt)
        #pragma unroll
        for (int nt2=0;nt2<NTN;++nt2){
          int f = fblk + wvf*NTN*16 + nt2*16 + l15;
          #pragma unroll
          for (int r=0;r<4;++r){
            int m = m0 + wvm*MTM*16 + mt*16 + quad*4 + r;
            outs[(size_t)m*1024 + f] = f2bu(acc[mt][nt2][r]);
          }
        }
    }
  }
}

// ---------------- BN stats combine: bnp[64][2][1024] -> scale/shift mv ------------------
__global__ void stats_comb(const float* __restrict__ bnp, const float* __restrict__ g,
                           const float* __restrict__ beta, float* __restrict__ mv){
  int c = blockIdx.x*256 + threadIdx.x;   // 1024
  float S=0.f, S2=0.f;
  #pragma unroll 8
  for (int s=0;s<64;s++){ S += bnp[(size_t)s*2048 + c]; S2 += bnp[(size_t)s*2048 + 1024 + c]; }
  float m = S * (1.f/4096.f);
  float var = S2 * (1.f/4096.f) - m*m;
  float inv = rsqrtf(var + 1e-5f);
  float sc = inv * g[c];
  mv[c] = sc;
  mv[1024 + c] = beta[c] - m*sc;
}

// ---- weight permute + BN fold, cc-parallel: one load->scatter phase per block ----------
__launch_bounds__(256)
__global__ void wperm_k(const float* __restrict__ w, const float* __restrict__ mv1,
                        unsigned short* __restrict__ wtt, float* __restrict__ tpb2){
  __shared__ float ls[3456];
  __shared__ float rs[256];
  int f = blockIdx.x, cc = blockIdx.y;
  const float* src = w + (size_t)f*27648 + cc*3456;
  unsigned short* dst = wtt + (size_t)f*27648;
  for (int i=threadIdx.x; i<3456; i+=256) ls[i] = src[i];
  __syncthreads();
  float part = 0.f;
  for (int u=threadIdx.x; u<3456; u+=256){
    int j = u >> 7, c = u & 127;
    int ch = cc*128 + c;
    float wv = ls[c*27 + j];
    dst[(size_t)j*1024 + ch] = f2bu(wv * mv1[ch]);
    part += wv * mv1[1024 + ch];
  }
  rs[threadIdx.x] = part; __syncthreads();
  for (int st=128; st>0; st>>=1){
    if (threadIdx.x < st) rs[threadIdx.x] += rs[threadIdx.x+st];
    __syncthreads();
  }
  if (threadIdx.x==0) atomicAdd(tpb2 + f, rs[0]);
}

// ---------------- goal_pre: z splits the 392 positions 8-ways; atomicAdd into gp --------
__launch_bounds__(256)
__global__ void gp2_k(const float* __restrict__ part9, const float* __restrict__ tpb,
                      const float* __restrict__ tpbA, float* __restrict__ gp){
  int b = blockIdx.x;
  int fc = blockIdx.y;
  int z = blockIdx.z;          // 8 p-chunks of 49
  int fi = threadIdx.x & 31, pi = threadIdx.x >> 5;
  int f = fc*32 + fi;
  float bias = tpb[f] + tpbA[f];
  float a = 0.f;
  for (int p = z*49 + pi; p < z*49 + 49; p += 8){
    size_t base = ((size_t)(b*392 + p))*512 + f;
    float v = bias;
    #pragma unroll
    for (int i=0;i<9;i++) v += part9[(size_t)i*802816 + base];
    a += fmaxf(v, 0.f);
  }
  __shared__ float red[256];
  red[threadIdx.x] = a; __syncthreads();
  for (int st=4; st>0; st>>=1){
    if (pi < st) red[pi*32+fi] += red[(pi+st)*32+fi];
    __syncthreads();
  }
  if (pi==0) atomicAdd(gp + b*512 + f, red[fi] * (1.f/392.f));
}

// ---- sga[bt][c] += sum_{n in slice} softmax(SG)[n]*(scl[n][c]+pe[n][c]) ----------------
// softmax fused: each block recomputes row max/denominator from SG (4KB L2-hot read).
__launch_bounds__(256)
__global__ void sga2_k(const float* __restrict__ scl, const float* __restrict__ peN,
                       const float* __restrict__ SG, float* __restrict__ sga){
  int bt = blockIdx.x, sl = blockIdx.y;   // 24 x 32
  int tid = threadIdx.x;
  __shared__ float red[256];
  __shared__ float at[32];
  float4 v = *reinterpret_cast<const float4*>(SG + bt*1024 + tid*4);
  float mx = fmaxf(fmaxf(v.x,v.y), fmaxf(v.z,v.w));
  red[tid] = mx; __syncthreads();
  for (int st=128; st>0; st>>=1){
    if (tid<st) red[tid] = fmaxf(red[tid], red[tid+st]);
    __syncthreads();
  }
  float m = red[0]; __syncthreads();
  red[tid] = expf(v.x-m)+expf(v.y-m)+expf(v.z-m)+expf(v.w-m); __syncthreads();
  for (int st=128; st>0; st>>=1){
    if (tid<st) red[tid] += red[tid+st];
    __syncthreads();
  }
  float inv = 1.0f/red[0];
  if (tid < 32) at[tid] = expf(SG[bt*1024 + sl*32 + tid] - m) * inv;
  __syncthreads();
  float acc0 = 0.f, acc1 = 0.f;
  for (int j=0;j<32;j++){
    int n = sl*32 + j;
    float a = at[j];
    const float* row = scl + ((size_t)bt*1024 + n)*512;
    const float* pe  = peN + (size_t)n*512;
    acc0 += a * (row[tid] + pe[tid]);
    acc1 += a * (row[tid+256] + pe[tid+256]);
  }
  atomicAdd(sga + (size_t)bt*512 + tid, acc0);
  atomicAdd(sga + (size_t)bt*512 + 256 + tid, acc1);
}

// ---------------- merged MLP heads: blocks 0-3 goal(gp), 4-27 state(sga) ----------------
__launch_bounds__(256)
__global__ void mlp2_k(const float* __restrict__ gp, const float* __restrict__ sga,
                       const float* __restrict__ og1w, const float* __restrict__ og1b,
                       const float* __restrict__ og2w, const float* __restrict__ og2b,
                       const float* __restrict__ os1w, const float* __restrict__ os1b,
                       const float* __restrict__ os2w, const float* __restrict__ os2b,
                       float* __restrict__ out){
  int b = blockIdx.x; int tid = threadIdx.x;
  const float *in, *w1, *b1, *w2, *b2; float* o;
  if (b < 4){ in = gp + (size_t)b*512;       w1=og1w; b1=og1b; w2=og2w; b2=og2b; o = out + (size_t)b*128; }
  else      { in = sga + (size_t)(b-4)*512;  w1=os1w; b1=os1b; w2=os2w; b2=os2b; o = out + 512 + (size_t)(b-4)*128; }
  __shared__ float xv[512]; __shared__ float h[512];
  xv[tid] = in[tid];
  xv[tid+256] = in[256 + tid];
  __syncthreads();
  #pragma unroll
  for (int oo=0;oo<2;oo++){
    int ox = tid + oo*256;
    const float* wr = w1 + (size_t)ox*512;
    float a=0.f;
    for (int c=0;c<512;c+=4){
      float4 q = *reinterpret_cast<const float4*>(wr+c);
      a += xv[c]*q.x + xv[c+1]*q.y + xv[c+2]*q.z + xv[c+3]*q.w;
    }
    h[ox] = fmaxf(a + b1[ox], 0.f);
  }
  __syncthreads();
  if (tid < 128){
    const float* wr = w2 + (size_t)tid*512;
    float a=0.f;
    for (int c=0;c<512;c+=4){
      float4 q = *reinterpret_cast<const float4*>(wr+c);
      a += h[c]*q.x + h[c+1]*q.y + h[c+2]*q.z + h[c+3]*q.w;
    }
    o[tid] = a + b2[tid];
  }
}

extern "C" void kernel_launch(void* const* d_in, const int* in_sizes, int n_in,
                              void* d_out, int out_size, void* d_ws, size_t ws_size,
                              hipStream_t stream){
  (void)in_sizes; (void)n_in; (void)out_size; (void)ws_size;
  const float* ctx   = (const float*)d_in[0];
  const float* frame = (const float*)d_in[1];
  const float* nl_vw[2] = {(const float*)d_in[4],  (const float*)d_in[11]};
  const float* nl_ow[2] = {(const float*)d_in[5],  (const float*)d_in[12]};
  const float* nl_ob[2] = {(const float*)d_in[6],  (const float*)d_in[13]};
  const float* nl_g[2]  = {(const float*)d_in[7],  (const float*)d_in[14]};
  const float* nl_be[2] = {(const float*)d_in[8],  (const float*)d_in[15]};
  const float* tp_w = (const float*)d_in[16]; const float* tp_b = (const float*)d_in[17];
  const float* up1w = (const float*)d_in[18]; const float* up1b = (const float*)d_in[19];
  const float* up2w = (const float*)d_in[20]; const float* up2b = (const float*)d_in[21];
  const float* og1w = (const float*)d_in[22]; const float* og1b = (const float*)d_in[23];
  const float* og2w = (const float*)d_in[24]; const float* og2b = (const float*)d_in[25];
  const float* os1w = (const float*)d_in[26]; const float* os1b = (const float*)d_in[27];
  const float* os2w = (const float*)d_in[28]; const float* os2b = (const float*)d_in[29];
  float* out = (float*)d_out;

  char* wsp = (char*)d_ws;
  // ---- persistent region ----
  float* bias2   = (float*)(wsp + 65536);         // 4KB  [1024] weff bias-fold acc
  float* tpb2    = (float*)(wsp + 69632);         // 2KB  [512] conv bias-fold (atomic)
  float* gp      = (float*)(wsp + 73728);         // 8KB  [4][512] (atomic-accumulated)
  float* mv0     = (float*)(wsp + 131072);        // 8KB  BN scale/shift layer 0
  float* mv1     = (float*)(wsp + 139264);        // 8KB  BN scale/shift layer 1
  float* SG      = (float*)(wsp + 147456);        // 98304 (atomic-accumulated)
  float* sga     = (float*)(wsp + 344064);        // 49152 (atomic-accumulated)
  float* peN     = (float*)(wsp + 786432);        // 2097152 [1024][512]
  bf16*  weff    = (bf16*) (wsp + 2883584);       // 2097152 [1024][1024] bf16
  unsigned short* w1sp = (unsigned short*)(wsp + 4980736);   // 12582912 [4][512][3072]
  unsigned short* w2sp = (unsigned short*)(wsp + 17563648);  // 6291456  [4][512][1536]
  char* ov = wsp + 23855104;
  // phase 1 (nonlocal, BN folded -> xcl ping-pong):
  bf16*  xclA = (bf16*) (ov);                     // 8 MB [4096][1024]
  bf16*  xclB = (bf16*) (ov + 8388608);           // 8 MB (dead after l=1 reads it)
  // phase 1 staging in the (dead until phase 2) part9 region:
  unsigned short* Asp = (unsigned short*)(ov + 36700160);            // 3 MB [1024][1536]
  unsigned short* Bsp = (unsigned short*)(ov + 36700160 + 3145728);  // 3 MB [1024][1536]
  float* bnp = (float*)(ov + 36700160 + 6291456); // 512 KB [64][2][1024] BN partials
  // phase 2 (conv): wtt aliases xclB region (written after l=1 MODE0 consumed xclB)
  unsigned short* wtt = (unsigned short*)(ov + 8388608);   // 28.3 MB [512][27648]
  float* part9 = (float*)(ov + 36700160);         // 28.9 MB [9][1568][512]
  // frame staging: aliases part9 (written after gp2_k reads part9)
  unsigned short* Fsp = (unsigned short*)(ov + 36700160);  // 9.4 MB [1536][3072]
  // phase 3 (after gp2_k; xclA/wtt dead):
  unsigned short* s1sp = (unsigned short*)(ov);   // 18.9 MB [6144][1536]
  float* scl  = (float*)(ov + 18874368);          // 50.3 MB [24576][512]

  // fused prep: permT(ctx) | split3(up1w) | split3(up2w) | PE | range-zero (1 launch)
  prep_k<<<4160,256,0,stream>>>(ctx, xclA, up1w, w1sp, up2w, w2sp, peN,
                                (float*)(wsp + 65536));

  // nonlocal layer 0: xclA -> xclB (BN deferred via fold into layer-1 consumers)
  layerprep_k<<<2176,256,0,stream>>>(nl_ow[0], Asp, nl_vw[0], Bsp);
  mmL_k<1,4,2,2,4,64><<<dim3(32,8,1),256,0,stream>>>(Asp, Bsp, nullptr, nullptr, nullptr,
      nullptr, (unsigned short*)weff, nullptr, 1536);
  mmL_k<1,4,4,2,0,64><<<dim3(64,8,1),256,0,stream>>>((const unsigned short*)xclA,
      (const unsigned short*)weff, nl_ob[0], (const unsigned short*)xclA, nullptr,
      nullptr, (unsigned short*)xclB, bnp, 1024);
  stats_comb<<<4,256,0,stream>>>(bnp, nl_g[0], nl_be[0], mv0);

  // nonlocal layer 1: xclB -> xclA; weff cols scaled by sc0, sh0 folded to bias2
  layerprep_k<<<2176,256,0,stream>>>(nl_ow[1], Asp, nl_vw[1], Bsp);
  mmL_k<1,4,2,2,4,64><<<dim3(32,8,1),256,0,stream>>>(Asp, Bsp, nullptr, nullptr, mv0,
      nullptr, (unsigned short*)weff, bias2, 1536);
  mmL_k<1,4,4,2,0,64><<<dim3(64,8,1),256,0,stream>>>((const unsigned short*)xclB,
      (const unsigned short*)weff, nl_ob[1], (const unsigned short*)xclB, mv0,
      bias2, (unsigned short*)xclA, bnp, 1024);
  stats_comb<<<4,256,0,stream>>>(bnp, nl_g[1], nl_be[1], mv1);

  // temporal-pool conv (im2col GEMM, K-split 9); BN-1 folded into wtt (sc1) + tpb2 (sh1)
  // round-13: conv REVERTED to verified-best round-10 config (128x128, BK32, 3-buf 48KB,
  // grid (13,4,9)) -- all other variants measured worse (see mmL_k header history).
  wperm_k<<<dim3(512,8),256,0,stream>>>(tp_w, mv1, wtt, tpb2);
  mmL_k<2,2,4,4,1,32,3><<<dim3(13,4,9),256,0,stream>>>((const unsigned short*)xclA, wtt,
      nullptr, nullptr, nullptr, part9, nullptr, nullptr, 3072);
  gp2_k<<<dim3(4,16,8),256,0,stream>>>(part9, tp_b, tpb2, gp);

  // frame path (3-block split-bf16 == fp32-accurate); Fsp aliases part9 -> after gp2_k
  permTsplit3_k<0><<<dim3(1,16,24),256,0,stream>>>(frame, Fsp, 64, 1024, 1, 1, 65536L, 196608L);
  // up1: BM=64 (3-buf 72KB -> 2/CU; grid 384 = 1.5/CU demand)
  mmL_k<1,4,4,2,2,64><<<dim3(24,4,4),256,0,stream>>>(Fsp, w1sp, up1b, nullptr, nullptr,
      nullptr, s1sp, nullptr, 3072);
  // up2 + fused SG partial dot (3-buf BK=32: 48KB -> 3/CU = demand)
  mmL_k<2,2,4,4,5,32><<<dim3(48,4,4),256,0,stream>>>(s1sp, w2sp, up2b, nullptr, gp,
      scl, nullptr, SG, 1536);

  // attention tail (softmax fused into sga2)
  sga2_k<<<dim3(24,32),256,0,stream>>>(scl, peN, SG, sga);

  // heads (merged)
  mlp2_k<<<28,256,0,stream>>>(gp, sga, og1w, og1b, og2w, og2b,
                              os1w, os1b, os2w, os2b, out);
}